// Round 1
// baseline (3762.532 us; speedup 1.0000x reference)
//
#include <hip/hip_runtime.h>
#include <math.h>

#define L_IN 65494
#define T_POOL 21490
#define KF 1025
#define KPAD 1032          // multiple of 12
#define X_TILE 1800        // 256*3 + KPAD
#define NSPLIT 16          // split-K for embed GEMM

__device__ inline float selu_f(float x) {
    float e = expf(fminf(x, 0.f));
    float neg = 1.6732632423543772f * (e - 1.f);
    return 1.0507009873554805f * (x > 0.f ? x : neg);
}

__device__ inline float gelu_f(float x) {
    return 0.5f * x * (1.f + erff(x * 0.7071067811865476f));
}

// ---------------- SincConv + |.| + maxpool3 ----------------
// grid (84, 32, 4), block 256. Each block: 8 filters x 256 pooled outputs.
// Thread: 2 filters x 12 rolling conv positions (4 pooled each filter).
__global__ __launch_bounds__(256)
void conv_kernel(const float* __restrict__ x, const float* __restrict__ filt,
                 float* __restrict__ h) {
    __shared__ float xs[X_TILE];
    __shared__ float fs[8][KPAD];
    const int tid = threadIdx.x;
    const int b = blockIdx.z;
    const int fbase = blockIdx.y * 8;
    const int t3base = blockIdx.x * 256;
    const int tbase = t3base * 3;

    for (int i = tid; i < 8 * KPAD; i += 256) {
        int fi = i / KPAD, kk = i - fi * KPAD;
        fs[fi][kk] = (kk < KF) ? filt[(fbase + fi) * KF + kk] : 0.f;
    }
    for (int i = tid; i < X_TILE; i += 256) {
        int gi = tbase + i;
        xs[i] = (gi < L_IN) ? x[b * L_IN + gi] : 0.f;
    }
    __syncthreads();

    const int fpair = tid >> 6;    // 0..3  (wave-uniform -> LDS broadcast)
    const int tg = tid & 63;       // lane
    const int lo = tg * 12;
    const float* f0 = fs[fpair * 2];
    const float* f1 = fs[fpair * 2 + 1];

    float acc0[12], acc1[12], w[12];
#pragma unroll
    for (int j = 0; j < 12; j++) { acc0[j] = 0.f; acc1[j] = 0.f; w[j] = xs[lo + j]; }

    for (int k = 0; k < KPAD; k += 12) {
#pragma unroll
        for (int s = 0; s < 12; s++) {
            float fv0 = f0[k + s];
            float fv1 = f1[k + s];
#pragma unroll
            for (int j = 0; j < 12; j++) {
                float xv = w[(s + j) % 12];
                acc0[j] = fmaf(fv0, xv, acc0[j]);
                acc1[j] = fmaf(fv1, xv, acc1[j]);
            }
            w[s] = xs[lo + k + s + 12];
        }
    }

    long base0 = ((long)(b * 256 + fbase + fpair * 2)) * T_POOL;
    long base1 = base0 + T_POOL;
#pragma unroll
    for (int p = 0; p < 4; p++) {
        int t3 = t3base + tg * 4 + p;
        if (t3 < T_POOL) {
            float v0 = fmaxf(fmaxf(fabsf(acc0[3 * p]), fabsf(acc0[3 * p + 1])), fabsf(acc0[3 * p + 2]));
            float v1 = fmaxf(fmaxf(fabsf(acc1[3 * p]), fabsf(acc1[3 * p + 1])), fabsf(acc1[3 * p + 2]));
            h[base0 + t3] = v0;
            h[base1 + t3] = v1;
        }
    }
}

// ---------------- BatchNorm stats (per-channel over (b, inner)) ----------------
// grid 256 (one per channel), block 256. Writes fused scale/shift.
__global__ __launch_bounds__(256)
void bn_stats_kernel(const float* __restrict__ xin, const float* __restrict__ g,
                     const float* __restrict__ bb, float* __restrict__ sc,
                     float* __restrict__ sh, int ilen, long bstride) {
    __shared__ float sm[8];
    int c = blockIdx.x, tid = threadIdx.x;
    float s1 = 0.f, s2 = 0.f;
    for (int b = 0; b < 4; b++) {
        const float* p = xin + b * bstride + (long)c * ilen;
        for (int t = tid; t < ilen; t += 256) {
            float v = p[t];
            s1 += v;
            s2 = fmaf(v, v, s2);
        }
    }
    for (int off = 32; off > 0; off >>= 1) { s1 += __shfl_down(s1, off); s2 += __shfl_down(s2, off); }
    int lane = tid & 63, wv = tid >> 6;
    if (lane == 0) { sm[wv] = s1; sm[4 + wv] = s2; }
    __syncthreads();
    if (tid == 0) {
        float S1 = sm[0] + sm[1] + sm[2] + sm[3];
        float S2 = sm[4] + sm[5] + sm[6] + sm[7];
        float n = 4.f * (float)ilen;
        float mean = S1 / n;
        float var = S2 / n - mean * mean;
        float rstd = rsqrtf(var + 1e-5f);
        float gc = g[c], bc = bb[c];
        sc[c] = rstd * gc;
        sh[c] = bc - mean * rstd * gc;
    }
}

// ---------------- Embedding GEMM, split-K, fused BN+SELU on A ----------------
// C[1024,256] partials: P[z][r][d]. A = selu(bn(h_raw)) [1024][21490], B = emb_w [256][21490]
__global__ __launch_bounds__(256)
void embed_gemm_kernel(const float* __restrict__ H, const float* __restrict__ W,
                       const float* __restrict__ sc, const float* __restrict__ sh,
                       float* __restrict__ P) {
    const int K = T_POOL;
    __shared__ float As[64][17], Bs[64][17];
    __shared__ float ssc[64], ssh[64];
    int tid = threadIdx.x;
    int rowBase = blockIdx.x * 64, colBase = blockIdx.y * 64, z = blockIdx.z;
    if (tid < 64) { int c = (rowBase + tid) & 255; ssc[tid] = sc[c]; ssh[tid] = sh[c]; }
    __syncthreads();
    int lrow = tid >> 2, kq = (tid & 3) * 4;
    const int kstart = z * 1344;   // 84 chunks of 16 per z; 16*1344 = 21504 >= K
    float acc[4][4] = {};
    const float* Arow = H + (long)(rowBase + lrow) * K;
    const float* Brow = W + (long)(colBase + lrow) * K;
    float asc = ssc[lrow], ash = ssh[lrow];
    int ty = tid >> 4, tx = tid & 15;
    for (int kc = 0; kc < 84; kc++) {
        int k0 = kstart + kc * 16 + kq;
#pragma unroll
        for (int c2 = 0; c2 < 4; c2++) {
            int k = k0 + c2;
            float av = 0.f, bv = 0.f;
            if (k < K) {
                av = selu_f(fmaf(Arow[k], asc, ash));
                bv = Brow[k];
            }
            As[lrow][kq + c2] = av;
            Bs[lrow][kq + c2] = bv;
        }
        __syncthreads();
#pragma unroll
        for (int kk = 0; kk < 16; kk++) {
            float a0 = As[ty * 4 + 0][kk], a1 = As[ty * 4 + 1][kk];
            float a2 = As[ty * 4 + 2][kk], a3 = As[ty * 4 + 3][kk];
            float b0 = Bs[tx * 4 + 0][kk], b1 = Bs[tx * 4 + 1][kk];
            float b2 = Bs[tx * 4 + 2][kk], b3 = Bs[tx * 4 + 3][kk];
            acc[0][0] = fmaf(a0, b0, acc[0][0]); acc[0][1] = fmaf(a0, b1, acc[0][1]);
            acc[0][2] = fmaf(a0, b2, acc[0][2]); acc[0][3] = fmaf(a0, b3, acc[0][3]);
            acc[1][0] = fmaf(a1, b0, acc[1][0]); acc[1][1] = fmaf(a1, b1, acc[1][1]);
            acc[1][2] = fmaf(a1, b2, acc[1][2]); acc[1][3] = fmaf(a1, b3, acc[1][3]);
            acc[2][0] = fmaf(a2, b0, acc[2][0]); acc[2][1] = fmaf(a2, b1, acc[2][1]);
            acc[2][2] = fmaf(a2, b2, acc[2][2]); acc[2][3] = fmaf(a2, b3, acc[2][3]);
            acc[3][0] = fmaf(a3, b0, acc[3][0]); acc[3][1] = fmaf(a3, b1, acc[3][1]);
            acc[3][2] = fmaf(a3, b2, acc[3][2]); acc[3][3] = fmaf(a3, b3, acc[3][3]);
        }
        __syncthreads();
    }
    float* Pz = P + (long)z * 1024 * 256;
#pragma unroll
    for (int i = 0; i < 4; i++)
#pragma unroll
        for (int j = 0; j < 4; j++)
            Pz[(long)(rowBase + ty * 4 + i) * 256 + colBase + tx * 4 + j] = acc[i][j];
}

__global__ __launch_bounds__(256)
void embed_combine_kernel(const float* __restrict__ P, const float* __restrict__ eb,
                          float* __restrict__ e) {
    int idx = blockIdx.x * 256 + threadIdx.x;
    float s = 0.f;
    for (int z = 0; z < NSPLIT; z++) s += P[(long)z * 262144 + idx];
    e[idx] = s + eb[idx & 255];
}

// ---------------- BN(e)+ReLU + positional ----------------
__global__ __launch_bounds__(256)
void zinit_kernel(const float* __restrict__ e, const float* __restrict__ sc,
                  const float* __restrict__ sh, float* __restrict__ z) {
    int idx = blockIdx.x * 256 + threadIdx.x;
    int d = idx & 255;
    int c = (idx >> 8) & 255;
    float v = fmaf(e[idx], sc[c], sh[c]);
    v = fmaxf(v, 0.f);
    int i2 = d >> 1;
    float ang = (float)c * expf(-0.03597789207803195f * (float)(2 * i2)); // ln(1e4)/256
    float pe = (d & 1) ? cosf(ang) : sinf(ang);
    z[idx] = v + pe;
}

// ---------------- generic tiled GEMM: C = A[M,K] * B[N,K]^T + epi ----------------
// EPI: 0 = +bias, 1 = +bias then gelu, 2 = +bias +residual
template <int EPI>
__global__ __launch_bounds__(256)
void gemm_kernel(const float* __restrict__ A, const float* __restrict__ Bm,
                 const float* __restrict__ bias, const float* __restrict__ res,
                 float* __restrict__ C, int M, int N, int K) {
    __shared__ float As[64][17], Bs[64][17];
    int tid = threadIdx.x;
    int rowBase = blockIdx.x * 64, colBase = blockIdx.y * 64;
    int lrow = tid >> 2, kq = (tid & 3) * 4;
    const float* Ap = A + (long)(rowBase + lrow) * K + kq;
    const float* Bp = Bm + (long)(colBase + lrow) * K + kq;
    float acc[4][4] = {};
    int ty = tid >> 4, tx = tid & 15;
    for (int k0 = 0; k0 < K; k0 += 16) {
        float4 av = *(const float4*)(Ap + k0);
        float4 bv = *(const float4*)(Bp + k0);
        As[lrow][kq] = av.x; As[lrow][kq + 1] = av.y; As[lrow][kq + 2] = av.z; As[lrow][kq + 3] = av.w;
        Bs[lrow][kq] = bv.x; Bs[lrow][kq + 1] = bv.y; Bs[lrow][kq + 2] = bv.z; Bs[lrow][kq + 3] = bv.w;
        __syncthreads();
#pragma unroll
        for (int kk = 0; kk < 16; kk++) {
            float a0 = As[ty * 4 + 0][kk], a1 = As[ty * 4 + 1][kk];
            float a2 = As[ty * 4 + 2][kk], a3 = As[ty * 4 + 3][kk];
            float b0 = Bs[tx * 4 + 0][kk], b1 = Bs[tx * 4 + 1][kk];
            float b2 = Bs[tx * 4 + 2][kk], b3 = Bs[tx * 4 + 3][kk];
            acc[0][0] = fmaf(a0, b0, acc[0][0]); acc[0][1] = fmaf(a0, b1, acc[0][1]);
            acc[0][2] = fmaf(a0, b2, acc[0][2]); acc[0][3] = fmaf(a0, b3, acc[0][3]);
            acc[1][0] = fmaf(a1, b0, acc[1][0]); acc[1][1] = fmaf(a1, b1, acc[1][1]);
            acc[1][2] = fmaf(a1, b2, acc[1][2]); acc[1][3] = fmaf(a1, b3, acc[1][3]);
            acc[2][0] = fmaf(a2, b0, acc[2][0]); acc[2][1] = fmaf(a2, b1, acc[2][1]);
            acc[2][2] = fmaf(a2, b2, acc[2][2]); acc[2][3] = fmaf(a2, b3, acc[2][3]);
            acc[3][0] = fmaf(a3, b0, acc[3][0]); acc[3][1] = fmaf(a3, b1, acc[3][1]);
            acc[3][2] = fmaf(a3, b2, acc[3][2]); acc[3][3] = fmaf(a3, b3, acc[3][3]);
        }
        __syncthreads();
    }
#pragma unroll
    for (int i = 0; i < 4; i++) {
        int r = rowBase + ty * 4 + i;
#pragma unroll
        for (int j = 0; j < 4; j++) {
            int cc = colBase + tx * 4 + j;
            float vv = acc[i][j] + bias[cc];
            if (EPI == 1) vv = gelu_f(vv);
            if (EPI == 2) vv += res[(long)r * N + cc];
            C[(long)r * N + cc] = vv;
        }
    }
}

// ---------------- attention: one block per (b, head), thread = query row ----------------
__global__ __launch_bounds__(256)
void attn_kernel(const float* __restrict__ q, const float* __restrict__ k,
                 const float* __restrict__ v, float* __restrict__ o) {
    int bh = blockIdx.x;
    int b = bh >> 3, hh = bh & 7;
    int l = threadIdx.x;
    const float scale = 0.17677669529663687f; // 1/sqrt(32)
    const float4* q4 = (const float4*)(q + ((long)(b * 256 + l) * 256 + hh * 32));
    float4 qv[8];
#pragma unroll
    for (int i = 0; i < 8; i++) qv[i] = q4[i];
    const float* kb = k + ((long)b * 256 * 256 + hh * 32);
    const float* vb = v + ((long)b * 256 * 256 + hh * 32);
    float m = -3.4e38f;
    for (int j = 0; j < 256; j++) {
        const float4* k4 = (const float4*)(kb + (long)j * 256);
        float s = 0.f;
#pragma unroll
        for (int i = 0; i < 8; i++) {
            float4 kv = k4[i];
            s = fmaf(qv[i].x, kv.x, s); s = fmaf(qv[i].y, kv.y, s);
            s = fmaf(qv[i].z, kv.z, s); s = fmaf(qv[i].w, kv.w, s);
        }
        m = fmaxf(m, s * scale);
    }
    float sum = 0.f;
    float4 acc[8];
#pragma unroll
    for (int i = 0; i < 8; i++) acc[i] = make_float4(0.f, 0.f, 0.f, 0.f);
    for (int j = 0; j < 256; j++) {
        const float4* k4 = (const float4*)(kb + (long)j * 256);
        float s = 0.f;
#pragma unroll
        for (int i = 0; i < 8; i++) {
            float4 kv = k4[i];
            s = fmaf(qv[i].x, kv.x, s); s = fmaf(qv[i].y, kv.y, s);
            s = fmaf(qv[i].z, kv.z, s); s = fmaf(qv[i].w, kv.w, s);
        }
        float p = expf(fmaf(s, scale, -m));
        sum += p;
        const float4* v4 = (const float4*)(vb + (long)j * 256);
#pragma unroll
        for (int i = 0; i < 8; i++) {
            float4 vv = v4[i];
            acc[i].x = fmaf(p, vv.x, acc[i].x); acc[i].y = fmaf(p, vv.y, acc[i].y);
            acc[i].z = fmaf(p, vv.z, acc[i].z); acc[i].w = fmaf(p, vv.w, acc[i].w);
        }
    }
    float inv = 1.f / sum;
    float4* o4 = (float4*)(o + ((long)(b * 256 + l) * 256 + hh * 32));
#pragma unroll
    for (int i = 0; i < 8; i++) {
        float4 a = acc[i];
        a.x *= inv; a.y *= inv; a.z *= inv; a.w *= inv;
        o4[i] = a;
    }
}

// ---------------- LayerNorm over last dim (256) ----------------
__global__ __launch_bounds__(256)
void ln_kernel(const float* __restrict__ xin, const float* __restrict__ g,
               const float* __restrict__ bb, float* __restrict__ out) {
    __shared__ float sm[8];
    int row = blockIdx.x, tid = threadIdx.x;
    float vv = xin[(long)row * 256 + tid];
    float s1 = vv, s2 = vv * vv;
    for (int off = 32; off > 0; off >>= 1) { s1 += __shfl_down(s1, off); s2 += __shfl_down(s2, off); }
    int lane = tid & 63, wv = tid >> 6;
    if (lane == 0) { sm[wv] = s1; sm[4 + wv] = s2; }
    __syncthreads();
    float S1 = sm[0] + sm[1] + sm[2] + sm[3];
    float S2 = sm[4] + sm[5] + sm[6] + sm[7];
    float mean = S1 * (1.f / 256.f);
    float var = S2 * (1.f / 256.f) - mean * mean;
    float rstd = rsqrtf(var + 1e-5f);
    out[(long)row * 256 + tid] = (vv - mean) * rstd * g[tid] + bb[tid];
}

// ---------------- final: LN'd z -> mean over seq -> proj ----------------
__global__ __launch_bounds__(256)
void final_kernel(const float* __restrict__ zf, const float* __restrict__ pw,
                  const float* __restrict__ pb, float* __restrict__ out) {
    __shared__ float sm[8];
    int b = blockIdx.x, d = threadIdx.x;
    float s = 0.f;
    for (int c = 0; c < 256; c++) s += zf[((long)(b * 256 + c)) * 256 + d];
    float pooled = s * (1.f / 256.f);
    float c0 = pooled * pw[d], c1 = pooled * pw[256 + d];
    for (int off = 32; off > 0; off >>= 1) { c0 += __shfl_down(c0, off); c1 += __shfl_down(c1, off); }
    int lane = d & 63, wv = d >> 6;
    if (lane == 0) { sm[wv] = c0; sm[4 + wv] = c1; }
    __syncthreads();
    if (d == 0) {
        out[b * 2 + 0] = sm[0] + sm[1] + sm[2] + sm[3] + pb[0];
        out[b * 2 + 1] = sm[4] + sm[5] + sm[6] + sm[7] + pb[1];
    }
}

extern "C" void kernel_launch(void* const* d_in, const int* in_sizes, int n_in,
                              void* d_out, int out_size, void* d_ws, size_t ws_size,
                              hipStream_t stream) {
    const float* x       = (const float*)d_in[0];
    const float* filters = (const float*)d_in[1];
    const float* bn1_g   = (const float*)d_in[2];
    const float* bn1_b   = (const float*)d_in[3];
    const float* emb_w   = (const float*)d_in[4];
    const float* emb_b   = (const float*)d_in[5];
    const float* embbn_g = (const float*)d_in[6];
    const float* embbn_b = (const float*)d_in[7];
    const float* wq      = (const float*)d_in[8];
    const float* bq      = (const float*)d_in[9];
    const float* wk      = (const float*)d_in[10];
    const float* bk      = (const float*)d_in[11];
    const float* wv      = (const float*)d_in[12];
    const float* bv      = (const float*)d_in[13];
    const float* wo      = (const float*)d_in[14];
    const float* bo      = (const float*)d_in[15];
    const float* c1w     = (const float*)d_in[16];
    const float* c1b     = (const float*)d_in[17];
    const float* c2w     = (const float*)d_in[18];
    const float* c2b     = (const float*)d_in[19];
    const float* ln1g    = (const float*)d_in[20];
    const float* ln1b    = (const float*)d_in[21];
    const float* ln2g    = (const float*)d_in[22];
    const float* ln2b    = (const float*)d_in[23];
    const float* lnfg    = (const float*)d_in[24];
    const float* lnfb    = (const float*)d_in[25];
    const float* projw   = (const float*)d_in[26];
    const float* projb   = (const float*)d_in[27];

    float* ws = (float*)d_ws;
    float* h_raw  = ws;                        // 4*256*21490 = 22,005,760
    float* bn1_sc = h_raw + 22005760;          // 256
    float* bn1_sh = bn1_sc + 256;              // 256
    float* part   = bn1_sh + 256;              // 16 * 262144 = 4,194,304
    float* e      = part + (long)NSPLIT * 262144;
    float* e_sc   = e + 262144;                // 256
    float* e_sh   = e_sc + 256;                // 256
    float* z      = e_sh + 256;                // 262144
    float* q      = z + 262144;
    float* k      = q + 262144;
    float* v      = k + 262144;
    float* o      = v + 262144;
    float* t1     = o + 262144;
    float* y      = t1 + 262144;               // 1,048,576

    conv_kernel<<<dim3(84, 32, 4), 256, 0, stream>>>(x, filters, h_raw);
    bn_stats_kernel<<<256, 256, 0, stream>>>(h_raw, bn1_g, bn1_b, bn1_sc, bn1_sh,
                                             T_POOL, 256L * T_POOL);
    embed_gemm_kernel<<<dim3(16, 4, NSPLIT), 256, 0, stream>>>(h_raw, emb_w, bn1_sc, bn1_sh, part);
    embed_combine_kernel<<<1024, 256, 0, stream>>>(part, emb_b, e);
    bn_stats_kernel<<<256, 256, 0, stream>>>(e, embbn_g, embbn_b, e_sc, e_sh,
                                             256, 256L * 256);
    zinit_kernel<<<1024, 256, 0, stream>>>(e, e_sc, e_sh, z);

    for (int l = 0; l < 4; l++) {
        const float* wq_l = wq + (long)l * 65536; const float* bq_l = bq + l * 256;
        const float* wk_l = wk + (long)l * 65536; const float* bk_l = bk + l * 256;
        const float* wv_l = wv + (long)l * 65536; const float* bv_l = bv + l * 256;
        const float* wo_l = wo + (long)l * 65536; const float* bo_l = bo + l * 256;
        const float* c1w_l = c1w + (long)l * 262144; const float* c1b_l = c1b + l * 1024;
        const float* c2w_l = c2w + (long)l * 262144; const float* c2b_l = c2b + l * 256;

        gemm_kernel<0><<<dim3(16, 4), 256, 0, stream>>>(z, wq_l, bq_l, nullptr, q, 1024, 256, 256);
        gemm_kernel<0><<<dim3(16, 4), 256, 0, stream>>>(z, wk_l, bk_l, nullptr, k, 1024, 256, 256);
        gemm_kernel<0><<<dim3(16, 4), 256, 0, stream>>>(z, wv_l, bv_l, nullptr, v, 1024, 256, 256);
        attn_kernel<<<32, 256, 0, stream>>>(q, k, v, o);
        gemm_kernel<2><<<dim3(16, 4), 256, 0, stream>>>(o, wo_l, bo_l, z, t1, 1024, 256, 256);
        ln_kernel<<<1024, 256, 0, stream>>>(t1, ln1g + l * 256, ln1b + l * 256, z);
        gemm_kernel<1><<<dim3(16, 16), 256, 0, stream>>>(z, c1w_l, c1b_l, nullptr, y, 1024, 1024, 256);
        gemm_kernel<2><<<dim3(16, 4), 256, 0, stream>>>(y, c2w_l, c2b_l, z, t1, 1024, 256, 1024);
        ln_kernel<<<1024, 256, 0, stream>>>(t1, ln2g + l * 256, ln2b + l * 256, z);
    }

    ln_kernel<<<1024, 256, 0, stream>>>(z, lnfg, lnfb, t1);
    final_kernel<<<4, 256, 0, stream>>>(t1, projw, projb, (float*)d_out);
}

// Round 2
// 2612.946 us; speedup vs baseline: 1.4400x; 1.4400x over previous
//
#include <hip/hip_runtime.h>
#include <math.h>

#define L_IN 65494
#define T_POOL 21490
#define KF 1025
#define NSPLIT 16          // split-K for embed GEMM
#define FKPAD 1040         // filter taps padded to 65*16
#define RS 1144            // replica row stride (elements); RS*2/16=143 odd -> bank spread
#define CWIN 1136          // x window per block: 96 + 1040

typedef short s16x8 __attribute__((ext_vector_type(8)));
typedef float f32x16 __attribute__((ext_vector_type(16)));

__device__ inline float selu_f(float x) {
    float e = expf(fminf(x, 0.f));
    float neg = 1.6732632423543772f * (e - 1.f);
    return 1.0507009873554805f * (x > 0.f ? x : neg);
}

__device__ inline float gelu_f(float x) {
    return 0.5f * x * (1.f + erff(x * 0.7071067811865476f));
}

__device__ inline void bf16split(float v, short& hs, short& ls) {
    unsigned u = __float_as_uint(v);
    unsigned rh = (u + 0x7fffu + ((u >> 16) & 1u)) & 0xffff0000u;
    float hf = __uint_as_float(rh);
    float lo = v - hf;
    unsigned ul = __float_as_uint(lo);
    unsigned rl = (ul + 0x7fffu + ((ul >> 16) & 1u)) >> 16;
    hs = (short)(rh >> 16);
    ls = (short)rl;
}

// ---------------- filter prep: fp32 -> bf16 hi/lo, padded [256][1040] ----------------
__global__ __launch_bounds__(256)
void filt_prep_kernel(const float* __restrict__ filt, short* __restrict__ fh,
                      short* __restrict__ fl) {
    int f = blockIdx.x;
    for (int k = threadIdx.x; k < FKPAD; k += 256) {
        float v = (k < KF) ? filt[f * KF + k] : 0.f;
        short hs, ls;
        bf16split(v, hs, ls);
        fh[f * FKPAD + k] = hs;
        fl[f * FKPAD + k] = ls;
    }
}

// ---------------- SincConv via MFMA (3-pass bf16 hi/lo) + |.| + maxpool3 ----------------
// grid (672, 4), block 256 (4 waves). Block: 96 conv positions x 256 filters -> 32 pooled.
// A = x (M=positions) from 8-way shifted LDS replicas; B = filters (N) from global bf16.
union ConvLDS {
    struct { short xh[8][RS]; short xl[8][RS]; } st;
    float ebuf[96][129];
};

#define MFMA3(ACC, AH, AL, BH, BL) \
    ACC = __builtin_amdgcn_mfma_f32_32x32x16_bf16(AL, BH, ACC, 0, 0, 0); \
    ACC = __builtin_amdgcn_mfma_f32_32x32x16_bf16(AH, BL, ACC, 0, 0, 0); \
    ACC = __builtin_amdgcn_mfma_f32_32x32x16_bf16(AH, BH, ACC, 0, 0, 0);

__global__ __launch_bounds__(256, 2)
void conv_mfma_kernel(const float* __restrict__ x, const short* __restrict__ fh,
                      const short* __restrict__ fl, float* __restrict__ h) {
    __shared__ ConvLDS u;
    const int tid = threadIdx.x;
    const int pb = blockIdx.x;
    const int b = blockIdx.y;
    const int t0 = pb * 96;

    // stage x window as bf16 hi/lo into 8 shifted replicas
    for (int i = tid; i < CWIN; i += 256) {
        int gi = t0 + i;
        float v = (gi < L_IN) ? x[b * L_IN + gi] : 0.f;
        short hs, ls;
        bf16split(v, hs, ls);
#pragma unroll
        for (int s = 0; s < 8; s++) {
            int e = i - s;
            if (e >= 0) { u.st.xh[s][e] = hs; u.st.xl[s][e] = ls; }
        }
    }
    __syncthreads();

    const int lane = tid & 63;
    const int wid = tid >> 6;
    const int l31 = lane & 31;
    const int hi = lane >> 5;
    const int f0w = wid * 64;

    const short* aH = &u.st.xh[l31 & 7][8 * (l31 >> 3) + 8 * hi];
    const short* aL = &u.st.xl[l31 & 7][8 * (l31 >> 3) + 8 * hi];
    const short* bH0 = fh + (f0w + l31) * FKPAD + hi * 8;
    const short* bH1 = bH0 + 32 * FKPAD;
    const short* bL0 = fl + (f0w + l31) * FKPAD + hi * 8;
    const short* bL1 = bL0 + 32 * FKPAD;

    f32x16 a00 = {0}, a01 = {0}, a10 = {0}, a11 = {0}, a20 = {0}, a21 = {0};

#pragma unroll 1
    for (int kc = 0; kc < 65; kc++) {
        const int ko = kc * 16;
        s16x8 ah0 = *(const s16x8*)(aH + ko);
        s16x8 ah1 = *(const s16x8*)(aH + ko + 32);
        s16x8 ah2 = *(const s16x8*)(aH + ko + 64);
        s16x8 al0 = *(const s16x8*)(aL + ko);
        s16x8 al1 = *(const s16x8*)(aL + ko + 32);
        s16x8 al2 = *(const s16x8*)(aL + ko + 64);
        s16x8 bh0 = *(const s16x8*)(bH0 + ko);
        s16x8 bh1 = *(const s16x8*)(bH1 + ko);
        s16x8 bl0 = *(const s16x8*)(bL0 + ko);
        s16x8 bl1 = *(const s16x8*)(bL1 + ko);
        MFMA3(a00, ah0, al0, bh0, bl0)
        MFMA3(a01, ah0, al0, bh1, bl1)
        MFMA3(a10, ah1, al1, bh0, bl0)
        MFMA3(a11, ah1, al1, bh1, bl1)
        MFMA3(a20, ah2, al2, bh0, bl0)
        MFMA3(a21, ah2, al2, bh1, bl1)
    }

    __syncthreads();
    const int t3l = tid & 31;
    const int t3 = pb * 32 + t3l;

#pragma unroll
    for (int half = 0; half < 2; half++) {
        if ((wid >> 1) == half) {
            int fcb = f0w - half * 128;
#define WRF(ACC, MT, NT)                                                   \
            {                                                              \
                int fc = fcb + NT * 32 + l31;                              \
                _Pragma("unroll")                                          \
                for (int r = 0; r < 16; r++) {                             \
                    int pos = MT * 32 + (r & 3) + 8 * (r >> 2) + 4 * hi;   \
                    u.ebuf[pos][fc] = fabsf(ACC[r]);                       \
                }                                                          \
            }
            WRF(a00, 0, 0) WRF(a01, 0, 1)
            WRF(a10, 1, 0) WRF(a11, 1, 1)
            WRF(a20, 2, 0) WRF(a21, 2, 1)
#undef WRF
        }
        __syncthreads();
        if (t3 < T_POOL) {
            for (int ff = tid >> 5; ff < 128; ff += 8) {
                float v = fmaxf(fmaxf(u.ebuf[3 * t3l][ff], u.ebuf[3 * t3l + 1][ff]),
                                u.ebuf[3 * t3l + 2][ff]);
                h[((long)(b * 256 + half * 128 + ff)) * T_POOL + t3] = v;
            }
        }
        __syncthreads();
    }
}

// ---------------- BatchNorm stats (per-channel over (b, inner)) ----------------
__global__ __launch_bounds__(256)
void bn_stats_kernel(const float* __restrict__ xin, const float* __restrict__ g,
                     const float* __restrict__ bb, float* __restrict__ sc,
                     float* __restrict__ sh, int ilen, long bstride) {
    __shared__ float sm[8];
    int c = blockIdx.x, tid = threadIdx.x;
    float s1 = 0.f, s2 = 0.f;
    for (int b = 0; b < 4; b++) {
        const float* p = xin + b * bstride + (long)c * ilen;
        for (int t = tid; t < ilen; t += 256) {
            float v = p[t];
            s1 += v;
            s2 = fmaf(v, v, s2);
        }
    }
    for (int off = 32; off > 0; off >>= 1) { s1 += __shfl_down(s1, off); s2 += __shfl_down(s2, off); }
    int lane = tid & 63, wv = tid >> 6;
    if (lane == 0) { sm[wv] = s1; sm[4 + wv] = s2; }
    __syncthreads();
    if (tid == 0) {
        float S1 = sm[0] + sm[1] + sm[2] + sm[3];
        float S2 = sm[4] + sm[5] + sm[6] + sm[7];
        float n = 4.f * (float)ilen;
        float mean = S1 / n;
        float var = S2 / n - mean * mean;
        float rstd = rsqrtf(var + 1e-5f);
        float gc = g[c], bc = bb[c];
        sc[c] = rstd * gc;
        sh[c] = bc - mean * rstd * gc;
    }
}

// ---------------- Embedding GEMM, split-K, fused BN+SELU on A ----------------
__global__ __launch_bounds__(256)
void embed_gemm_kernel(const float* __restrict__ H, const float* __restrict__ W,
                       const float* __restrict__ sc, const float* __restrict__ sh,
                       float* __restrict__ P) {
    const int K = T_POOL;
    __shared__ float As[64][17], Bs[64][17];
    __shared__ float ssc[64], ssh[64];
    int tid = threadIdx.x;
    int rowBase = blockIdx.x * 64, colBase = blockIdx.y * 64, z = blockIdx.z;
    if (tid < 64) { int c = (rowBase + tid) & 255; ssc[tid] = sc[c]; ssh[tid] = sh[c]; }
    __syncthreads();
    int lrow = tid >> 2, kq = (tid & 3) * 4;
    const int kstart = z * 1344;
    float acc[4][4] = {};
    const float* Arow = H + (long)(rowBase + lrow) * K;
    const float* Brow = W + (long)(colBase + lrow) * K;
    float asc = ssc[lrow], ash = ssh[lrow];
    int ty = tid >> 4, tx = tid & 15;
    for (int kc = 0; kc < 84; kc++) {
        int k0 = kstart + kc * 16 + kq;
#pragma unroll
        for (int c2 = 0; c2 < 4; c2++) {
            int k = k0 + c2;
            float av = 0.f, bv = 0.f;
            if (k < K) {
                av = selu_f(fmaf(Arow[k], asc, ash));
                bv = Brow[k];
            }
            As[lrow][kq + c2] = av;
            Bs[lrow][kq + c2] = bv;
        }
        __syncthreads();
#pragma unroll
        for (int kk = 0; kk < 16; kk++) {
            float a0 = As[ty * 4 + 0][kk], a1 = As[ty * 4 + 1][kk];
            float a2 = As[ty * 4 + 2][kk], a3 = As[ty * 4 + 3][kk];
            float b0 = Bs[tx * 4 + 0][kk], b1 = Bs[tx * 4 + 1][kk];
            float b2 = Bs[tx * 4 + 2][kk], b3 = Bs[tx * 4 + 3][kk];
            acc[0][0] = fmaf(a0, b0, acc[0][0]); acc[0][1] = fmaf(a0, b1, acc[0][1]);
            acc[0][2] = fmaf(a0, b2, acc[0][2]); acc[0][3] = fmaf(a0, b3, acc[0][3]);
            acc[1][0] = fmaf(a1, b0, acc[1][0]); acc[1][1] = fmaf(a1, b1, acc[1][1]);
            acc[1][2] = fmaf(a1, b2, acc[1][2]); acc[1][3] = fmaf(a1, b3, acc[1][3]);
            acc[2][0] = fmaf(a2, b0, acc[2][0]); acc[2][1] = fmaf(a2, b1, acc[2][1]);
            acc[2][2] = fmaf(a2, b2, acc[2][2]); acc[2][3] = fmaf(a2, b3, acc[2][3]);
            acc[3][0] = fmaf(a3, b0, acc[3][0]); acc[3][1] = fmaf(a3, b1, acc[3][1]);
            acc[3][2] = fmaf(a3, b2, acc[3][2]); acc[3][3] = fmaf(a3, b3, acc[3][3]);
        }
        __syncthreads();
    }
    float* Pz = P + (long)z * 1024 * 256;
#pragma unroll
    for (int i = 0; i < 4; i++)
#pragma unroll
        for (int j = 0; j < 4; j++)
            Pz[(long)(rowBase + ty * 4 + i) * 256 + colBase + tx * 4 + j] = acc[i][j];
}

__global__ __launch_bounds__(256)
void embed_combine_kernel(const float* __restrict__ P, const float* __restrict__ eb,
                          float* __restrict__ e) {
    int idx = blockIdx.x * 256 + threadIdx.x;
    float s = 0.f;
    for (int z = 0; z < NSPLIT; z++) s += P[(long)z * 262144 + idx];
    e[idx] = s + eb[idx & 255];
}

// ---------------- BN(e)+ReLU + positional ----------------
__global__ __launch_bounds__(256)
void zinit_kernel(const float* __restrict__ e, const float* __restrict__ sc,
                  const float* __restrict__ sh, float* __restrict__ z) {
    int idx = blockIdx.x * 256 + threadIdx.x;
    int d = idx & 255;
    int c = (idx >> 8) & 255;
    float v = fmaf(e[idx], sc[c], sh[c]);
    v = fmaxf(v, 0.f);
    int i2 = d >> 1;
    float ang = (float)c * expf(-0.03597789207803195f * (float)(2 * i2));
    float pe = (d & 1) ? cosf(ang) : sinf(ang);
    z[idx] = v + pe;
}

// ---------------- generic tiled GEMM: C = A[M,K] * B[N,K]^T + epi ----------------
template <int EPI>
__global__ __launch_bounds__(256)
void gemm_kernel(const float* __restrict__ A, const float* __restrict__ Bm,
                 const float* __restrict__ bias, const float* __restrict__ res,
                 float* __restrict__ C, int M, int N, int K) {
    __shared__ float As[64][17], Bs[64][17];
    int tid = threadIdx.x;
    int rowBase = blockIdx.x * 64, colBase = blockIdx.y * 64;
    int lrow = tid >> 2, kq = (tid & 3) * 4;
    const float* Ap = A + (long)(rowBase + lrow) * K + kq;
    const float* Bp = Bm + (long)(colBase + lrow) * K + kq;
    float acc[4][4] = {};
    int ty = tid >> 4, tx = tid & 15;
    for (int k0 = 0; k0 < K; k0 += 16) {
        float4 av = *(const float4*)(Ap + k0);
        float4 bv = *(const float4*)(Bp + k0);
        As[lrow][kq] = av.x; As[lrow][kq + 1] = av.y; As[lrow][kq + 2] = av.z; As[lrow][kq + 3] = av.w;
        Bs[lrow][kq] = bv.x; Bs[lrow][kq + 1] = bv.y; Bs[lrow][kq + 2] = bv.z; Bs[lrow][kq + 3] = bv.w;
        __syncthreads();
#pragma unroll
        for (int kk = 0; kk < 16; kk++) {
            float a0 = As[ty * 4 + 0][kk], a1 = As[ty * 4 + 1][kk];
            float a2 = As[ty * 4 + 2][kk], a3 = As[ty * 4 + 3][kk];
            float b0 = Bs[tx * 4 + 0][kk], b1 = Bs[tx * 4 + 1][kk];
            float b2 = Bs[tx * 4 + 2][kk], b3 = Bs[tx * 4 + 3][kk];
            acc[0][0] = fmaf(a0, b0, acc[0][0]); acc[0][1] = fmaf(a0, b1, acc[0][1]);
            acc[0][2] = fmaf(a0, b2, acc[0][2]); acc[0][3] = fmaf(a0, b3, acc[0][3]);
            acc[1][0] = fmaf(a1, b0, acc[1][0]); acc[1][1] = fmaf(a1, b1, acc[1][1]);
            acc[1][2] = fmaf(a1, b2, acc[1][2]); acc[1][3] = fmaf(a1, b3, acc[1][3]);
            acc[2][0] = fmaf(a2, b0, acc[2][0]); acc[2][1] = fmaf(a2, b1, acc[2][1]);
            acc[2][2] = fmaf(a2, b2, acc[2][2]); acc[2][3] = fmaf(a2, b3, acc[2][3]);
            acc[3][0] = fmaf(a3, b0, acc[3][0]); acc[3][1] = fmaf(a3, b1, acc[3][1]);
            acc[3][2] = fmaf(a3, b2, acc[3][2]); acc[3][3] = fmaf(a3, b3, acc[3][3]);
        }
        __syncthreads();
    }
#pragma unroll
    for (int i = 0; i < 4; i++) {
        int r = rowBase + ty * 4 + i;
#pragma unroll
        for (int j = 0; j < 4; j++) {
            int cc = colBase + tx * 4 + j;
            float vv = acc[i][j] + bias[cc];
            if (EPI == 1) vv = gelu_f(vv);
            if (EPI == 2) vv += res[(long)r * N + cc];
            C[(long)r * N + cc] = vv;
        }
    }
}

// ---------------- attention ----------------
__global__ __launch_bounds__(256)
void attn_kernel(const float* __restrict__ q, const float* __restrict__ k,
                 const float* __restrict__ v, float* __restrict__ o) {
    int bh = blockIdx.x;
    int b = bh >> 3, hh = bh & 7;
    int l = threadIdx.x;
    const float scale = 0.17677669529663687f;
    const float4* q4 = (const float4*)(q + ((long)(b * 256 + l) * 256 + hh * 32));
    float4 qv[8];
#pragma unroll
    for (int i = 0; i < 8; i++) qv[i] = q4[i];
    const float* kb = k + ((long)b * 256 * 256 + hh * 32);
    const float* vb = v + ((long)b * 256 * 256 + hh * 32);
    float m = -3.4e38f;
    for (int j = 0; j < 256; j++) {
        const float4* k4 = (const float4*)(kb + (long)j * 256);
        float s = 0.f;
#pragma unroll
        for (int i = 0; i < 8; i++) {
            float4 kv = k4[i];
            s = fmaf(qv[i].x, kv.x, s); s = fmaf(qv[i].y, kv.y, s);
            s = fmaf(qv[i].z, kv.z, s); s = fmaf(qv[i].w, kv.w, s);
        }
        m = fmaxf(m, s * scale);
    }
    float sum = 0.f;
    float4 acc[8];
#pragma unroll
    for (int i = 0; i < 8; i++) acc[i] = make_float4(0.f, 0.f, 0.f, 0.f);
    for (int j = 0; j < 256; j++) {
        const float4* k4 = (const float4*)(kb + (long)j * 256);
        float s = 0.f;
#pragma unroll
        for (int i = 0; i < 8; i++) {
            float4 kv = k4[i];
            s = fmaf(qv[i].x, kv.x, s); s = fmaf(qv[i].y, kv.y, s);
            s = fmaf(qv[i].z, kv.z, s); s = fmaf(qv[i].w, kv.w, s);
        }
        float p = expf(fmaf(s, scale, -m));
        sum += p;
        const float4* v4 = (const float4*)(vb + (long)j * 256);
#pragma unroll
        for (int i = 0; i < 8; i++) {
            float4 vv = v4[i];
            acc[i].x = fmaf(p, vv.x, acc[i].x); acc[i].y = fmaf(p, vv.y, acc[i].y);
            acc[i].z = fmaf(p, vv.z, acc[i].z); acc[i].w = fmaf(p, vv.w, acc[i].w);
        }
    }
    float inv = 1.f / sum;
    float4* o4 = (float4*)(o + ((long)(b * 256 + l) * 256 + hh * 32));
#pragma unroll
    for (int i = 0; i < 8; i++) {
        float4 a = acc[i];
        a.x *= inv; a.y *= inv; a.z *= inv; a.w *= inv;
        o4[i] = a;
    }
}

// ---------------- LayerNorm over last dim (256) ----------------
__global__ __launch_bounds__(256)
void ln_kernel(const float* __restrict__ xin, const float* __restrict__ g,
               const float* __restrict__ bb, float* __restrict__ out) {
    __shared__ float sm[8];
    int row = blockIdx.x, tid = threadIdx.x;
    float vv = xin[(long)row * 256 + tid];
    float s1 = vv, s2 = vv * vv;
    for (int off = 32; off > 0; off >>= 1) { s1 += __shfl_down(s1, off); s2 += __shfl_down(s2, off); }
    int lane = tid & 63, wv = tid >> 6;
    if (lane == 0) { sm[wv] = s1; sm[4 + wv] = s2; }
    __syncthreads();
    float S1 = sm[0] + sm[1] + sm[2] + sm[3];
    float S2 = sm[4] + sm[5] + sm[6] + sm[7];
    float mean = S1 * (1.f / 256.f);
    float var = S2 * (1.f / 256.f) - mean * mean;
    float rstd = rsqrtf(var + 1e-5f);
    out[(long)row * 256 + tid] = (vv - mean) * rstd * g[tid] + bb[tid];
}

// ---------------- final ----------------
__global__ __launch_bounds__(256)
void final_kernel(const float* __restrict__ zf, const float* __restrict__ pw,
                  const float* __restrict__ pb, float* __restrict__ out) {
    __shared__ float sm[8];
    int b = blockIdx.x, d = threadIdx.x;
    float s = 0.f;
    for (int c = 0; c < 256; c++) s += zf[((long)(b * 256 + c)) * 256 + d];
    float pooled = s * (1.f / 256.f);
    float c0 = pooled * pw[d], c1 = pooled * pw[256 + d];
    for (int off = 32; off > 0; off >>= 1) { c0 += __shfl_down(c0, off); c1 += __shfl_down(c1, off); }
    int lane = d & 63, wv = d >> 6;
    if (lane == 0) { sm[wv] = c0; sm[4 + wv] = c1; }
    __syncthreads();
    if (d == 0) {
        out[b * 2 + 0] = sm[0] + sm[1] + sm[2] + sm[3] + pb[0];
        out[b * 2 + 1] = sm[4] + sm[5] + sm[6] + sm[7] + pb[1];
    }
}

extern "C" void kernel_launch(void* const* d_in, const int* in_sizes, int n_in,
                              void* d_out, int out_size, void* d_ws, size_t ws_size,
                              hipStream_t stream) {
    const float* x       = (const float*)d_in[0];
    const float* filters = (const float*)d_in[1];
    const float* bn1_g   = (const float*)d_in[2];
    const float* bn1_b   = (const float*)d_in[3];
    const float* emb_w   = (const float*)d_in[4];
    const float* emb_b   = (const float*)d_in[5];
    const float* embbn_g = (const float*)d_in[6];
    const float* embbn_b = (const float*)d_in[7];
    const float* wq      = (const float*)d_in[8];
    const float* bq      = (const float*)d_in[9];
    const float* wk      = (const float*)d_in[10];
    const float* bk      = (const float*)d_in[11];
    const float* wv      = (const float*)d_in[12];
    const float* bv      = (const float*)d_in[13];
    const float* wo      = (const float*)d_in[14];
    const float* bo      = (const float*)d_in[15];
    const float* c1w     = (const float*)d_in[16];
    const float* c1b     = (const float*)d_in[17];
    const float* c2w     = (const float*)d_in[18];
    const float* c2b     = (const float*)d_in[19];
    const float* ln1g    = (const float*)d_in[20];
    const float* ln1b    = (const float*)d_in[21];
    const float* ln2g    = (const float*)d_in[22];
    const float* ln2b    = (const float*)d_in[23];
    const float* lnfg    = (const float*)d_in[24];
    const float* lnfb    = (const float*)d_in[25];
    const float* projw   = (const float*)d_in[26];
    const float* projb   = (const float*)d_in[27];

    float* ws = (float*)d_ws;
    float* h_raw  = ws;                        // 22,005,760 floats
    float* bn1_sc = h_raw + 22005760;
    float* bn1_sh = bn1_sc + 256;
    float* part   = bn1_sh + 256;              // NSPLIT * 262144
    float* e      = part + (long)NSPLIT * 262144;
    float* e_sc   = e + 262144;
    float* e_sh   = e_sc + 256;
    float* z      = e_sh + 256;
    float* q      = z + 262144;
    float* k      = q + 262144;
    float* v      = k + 262144;
    float* o      = v + 262144;
    float* t1     = o + 262144;
    float* y      = t1 + 262144;               // 1,048,576

    // filter bf16 hi/lo arrays aliased onto `part` (part only written after conv)
    short* filt_h = (short*)part;              // 256*1040 shorts
    short* filt_l = filt_h + 256 * FKPAD;

    filt_prep_kernel<<<256, 256, 0, stream>>>(filters, filt_h, filt_l);
    conv_mfma_kernel<<<dim3(672, 4), 256, 0, stream>>>(x, filt_h, filt_l, h_raw);
    bn_stats_kernel<<<256, 256, 0, stream>>>(h_raw, bn1_g, bn1_b, bn1_sc, bn1_sh,
                                             T_POOL, 256L * T_POOL);
    embed_gemm_kernel<<<dim3(16, 4, NSPLIT), 256, 0, stream>>>(h_raw, emb_w, bn1_sc, bn1_sh, part);
    embed_combine_kernel<<<1024, 256, 0, stream>>>(part, emb_b, e);
    bn_stats_kernel<<<256, 256, 0, stream>>>(e, embbn_g, embbn_b, e_sc, e_sh,
                                             256, 256L * 256);
    zinit_kernel<<<1024, 256, 0, stream>>>(e, e_sc, e_sh, z);

    for (int l = 0; l < 4; l++) {
        const float* wq_l = wq + (long)l * 65536; const float* bq_l = bq + l * 256;
        const float* wk_l = wk + (long)l * 65536; const float* bk_l = bk + l * 256;
        const float* wv_l = wv + (long)l * 65536; const float* bv_l = bv + l * 256;
        const float* wo_l = wo + (long)l * 65536; const float* bo_l = bo + l * 256;
        const float* c1w_l = c1w + (long)l * 262144; const float* c1b_l = c1b + l * 1024;
        const float* c2w_l = c2w + (long)l * 262144; const float* c2b_l = c2b + l * 256;

        gemm_kernel<0><<<dim3(16, 4), 256, 0, stream>>>(z, wq_l, bq_l, nullptr, q, 1024, 256, 256);
        gemm_kernel<0><<<dim3(16, 4), 256, 0, stream>>>(z, wk_l, bk_l, nullptr, k, 1024, 256, 256);
        gemm_kernel<0><<<dim3(16, 4), 256, 0, stream>>>(z, wv_l, bv_l, nullptr, v, 1024, 256, 256);
        attn_kernel<<<32, 256, 0, stream>>>(q, k, v, o);
        gemm_kernel<2><<<dim3(16, 4), 256, 0, stream>>>(o, wo_l, bo_l, z, t1, 1024, 256, 256);
        ln_kernel<<<1024, 256, 0, stream>>>(t1, ln1g + l * 256, ln1b + l * 256, z);
        gemm_kernel<1><<<dim3(16, 16), 256, 0, stream>>>(z, c1w_l, c1b_l, nullptr, y, 1024, 1024, 256);
        gemm_kernel<2><<<dim3(16, 4), 256, 0, stream>>>(y, c2w_l, c2b_l, z, t1, 1024, 256, 1024);
        ln_kernel<<<1024, 256, 0, stream>>>(t1, ln2g + l * 256, ln2b + l * 256, z);
    }

    ln_kernel<<<1024, 256, 0, stream>>>(z, lnfg, lnfb, t1);
    final_kernel<<<4, 256, 0, stream>>>(t1, projw, projb, (float*)d_out);
}

// Round 3
// 1838.647 us; speedup vs baseline: 2.0464x; 1.4211x over previous
//
#include <hip/hip_runtime.h>
#include <math.h>

#define L_IN 65494
#define T_POOL 21490
#define KF 1025
#define FKPAD 1040         // filter taps padded to 65*16
#define RS 1144            // conv replica row stride (elements)
#define CWIN 1136          // conv x window per block: 96 + 1040
#define KEMB 21490
#define KEMBP 21504        // padded to 32 | KEMBP

typedef short s16x4 __attribute__((ext_vector_type(4)));
typedef short s16x8 __attribute__((ext_vector_type(8)));
typedef float f32x16 __attribute__((ext_vector_type(16)));

__device__ inline float selu_f(float x) {
    float e = expf(fminf(x, 0.f));
    float neg = 1.6732632423543772f * (e - 1.f);
    return 1.0507009873554805f * (x > 0.f ? x : neg);
}

__device__ inline float gelu_f(float x) {
    return 0.5f * x * (1.f + erff(x * 0.7071067811865476f));
}

__device__ inline void bf16split(float v, short& hs, short& ls) {
    unsigned u = __float_as_uint(v);
    unsigned rh = (u + 0x7fffu + ((u >> 16) & 1u)) & 0xffff0000u;
    float hf = __uint_as_float(rh);
    float lo = v - hf;
    unsigned ul = __float_as_uint(lo);
    unsigned rl = (ul + 0x7fffu + ((ul >> 16) & 1u)) >> 16;
    hs = (short)(rh >> 16);
    ls = (short)rl;
}

__device__ inline s16x8 ld8lds(const short* p) {
    union { s16x8 v; unsigned long long q[2]; } u;
    u.q[0] = *(const unsigned long long*)(p);
    u.q[1] = *(const unsigned long long*)(p + 4);
    return u.v;
}

// ---------------- filter prep ----------------
__global__ __launch_bounds__(256)
void filt_prep_kernel(const float* __restrict__ filt, short* __restrict__ fh,
                      short* __restrict__ fl) {
    int f = blockIdx.x;
    for (int k = threadIdx.x; k < FKPAD; k += 256) {
        float v = (k < KF) ? filt[f * KF + k] : 0.f;
        short hs, ls;
        bf16split(v, hs, ls);
        fh[f * FKPAD + k] = hs;
        fl[f * FKPAD + k] = ls;
    }
}

// ---------------- SincConv via MFMA (3-pass bf16 hi/lo) + |.| + maxpool3 ----------------
union ConvLDS {
    struct { short xh[8][RS]; short xl[8][RS]; } st;
    float ebuf[96][129];
};

#define MFMA3(ACC, AH, AL, BH, BL) \
    ACC = __builtin_amdgcn_mfma_f32_32x32x16_bf16(AL, BH, ACC, 0, 0, 0); \
    ACC = __builtin_amdgcn_mfma_f32_32x32x16_bf16(AH, BL, ACC, 0, 0, 0); \
    ACC = __builtin_amdgcn_mfma_f32_32x32x16_bf16(AH, BH, ACC, 0, 0, 0);

__global__ __launch_bounds__(256, 2)
void conv_mfma_kernel(const float* __restrict__ x, const short* __restrict__ fh,
                      const short* __restrict__ fl, float* __restrict__ h) {
    __shared__ ConvLDS u;
    const int tid = threadIdx.x;
    const int pb = blockIdx.x;
    const int b = blockIdx.y;
    const int t0 = pb * 96;

    for (int i = tid; i < CWIN; i += 256) {
        int gi = t0 + i;
        float v = (gi < L_IN) ? x[b * L_IN + gi] : 0.f;
        short hs, ls;
        bf16split(v, hs, ls);
#pragma unroll
        for (int s = 0; s < 8; s++) {
            int e = i - s;
            if (e >= 0) { u.st.xh[s][e] = hs; u.st.xl[s][e] = ls; }
        }
    }
    __syncthreads();

    const int lane = tid & 63;
    const int wid = tid >> 6;
    const int l31 = lane & 31;
    const int hi = lane >> 5;
    const int f0w = wid * 64;

    const short* aH = &u.st.xh[l31 & 7][8 * (l31 >> 3) + 8 * hi];
    const short* aL = &u.st.xl[l31 & 7][8 * (l31 >> 3) + 8 * hi];
    const short* bH0 = fh + (f0w + l31) * FKPAD + hi * 8;
    const short* bH1 = bH0 + 32 * FKPAD;
    const short* bL0 = fl + (f0w + l31) * FKPAD + hi * 8;
    const short* bL1 = bL0 + 32 * FKPAD;

    f32x16 a00 = {0}, a01 = {0}, a10 = {0}, a11 = {0}, a20 = {0}, a21 = {0};

#pragma unroll 1
    for (int kc = 0; kc < 65; kc++) {
        const int ko = kc * 16;
        s16x8 ah0 = *(const s16x8*)(aH + ko);
        s16x8 ah1 = *(const s16x8*)(aH + ko + 32);
        s16x8 ah2 = *(const s16x8*)(aH + ko + 64);
        s16x8 al0 = *(const s16x8*)(aL + ko);
        s16x8 al1 = *(const s16x8*)(aL + ko + 32);
        s16x8 al2 = *(const s16x8*)(aL + ko + 64);
        s16x8 bh0 = *(const s16x8*)(bH0 + ko);
        s16x8 bh1 = *(const s16x8*)(bH1 + ko);
        s16x8 bl0 = *(const s16x8*)(bL0 + ko);
        s16x8 bl1 = *(const s16x8*)(bL1 + ko);
        MFMA3(a00, ah0, al0, bh0, bl0)
        MFMA3(a01, ah0, al0, bh1, bl1)
        MFMA3(a10, ah1, al1, bh0, bl0)
        MFMA3(a11, ah1, al1, bh1, bl1)
        MFMA3(a20, ah2, al2, bh0, bl0)
        MFMA3(a21, ah2, al2, bh1, bl1)
    }

    __syncthreads();
    const int t3l = tid & 31;
    const int t3 = pb * 32 + t3l;

#pragma unroll
    for (int half = 0; half < 2; half++) {
        if ((wid >> 1) == half) {
            int fcb = f0w - half * 128;
#define WRF(ACC, MT, NT)                                                   \
            {                                                              \
                int fc = fcb + NT * 32 + l31;                              \
                _Pragma("unroll")                                          \
                for (int r = 0; r < 16; r++) {                             \
                    int pos = MT * 32 + (r & 3) + 8 * (r >> 2) + 4 * hi;   \
                    u.ebuf[pos][fc] = fabsf(ACC[r]);                       \
                }                                                          \
            }
            WRF(a00, 0, 0) WRF(a01, 0, 1)
            WRF(a10, 1, 0) WRF(a11, 1, 1)
            WRF(a20, 2, 0) WRF(a21, 2, 1)
#undef WRF
        }
        __syncthreads();
        if (t3 < T_POOL) {
            for (int ff = tid >> 5; ff < 128; ff += 8) {
                float v = fmaxf(fmaxf(u.ebuf[3 * t3l][ff], u.ebuf[3 * t3l + 1][ff]),
                                u.ebuf[3 * t3l + 2][ff]);
                h[((long)(b * 256 + half * 128 + ff)) * T_POOL + t3] = v;
            }
        }
        __syncthreads();
    }
}

// ---------------- BatchNorm stats ----------------
__global__ __launch_bounds__(256)
void bn_stats_kernel(const float* __restrict__ xin, const float* __restrict__ g,
                     const float* __restrict__ bb, float* __restrict__ sc,
                     float* __restrict__ sh, int ilen, long bstride) {
    __shared__ float sm[8];
    int c = blockIdx.x, tid = threadIdx.x;
    float s1 = 0.f, s2 = 0.f;
    for (int b = 0; b < 4; b++) {
        const float* p = xin + b * bstride + (long)c * ilen;
        for (int t = tid; t < ilen; t += 256) {
            float v = p[t];
            s1 += v;
            s2 = fmaf(v, v, s2);
        }
    }
    for (int off = 32; off > 0; off >>= 1) { s1 += __shfl_down(s1, off); s2 += __shfl_down(s2, off); }
    int lane = tid & 63, wv = tid >> 6;
    if (lane == 0) { sm[wv] = s1; sm[4 + wv] = s2; }
    __syncthreads();
    if (tid == 0) {
        float S1 = sm[0] + sm[1] + sm[2] + sm[3];
        float S2 = sm[4] + sm[5] + sm[6] + sm[7];
        float n = 4.f * (float)ilen;
        float mean = S1 / n;
        float var = S2 / n - mean * mean;
        float rstd = rsqrtf(var + 1e-5f);
        float gc = g[c], bc = bb[c];
        sc[c] = rstd * gc;
        sh[c] = bc - mean * rstd * gc;
    }
}

// ---------------- emb_w prep: fp32 -> padded bf16 hi/lo [256][KEMBP] ----------------
__global__ __launch_bounds__(256)
void wprep_kernel(const float* __restrict__ w, short* __restrict__ wh,
                  short* __restrict__ wl) {
    int d = blockIdx.x;
    for (int k = threadIdx.x; k < KEMBP; k += 256) {
        float v = (k < KEMB) ? w[(long)d * KEMB + k] : 0.f;
        short hs, ls;
        bf16split(v, hs, ls);
        wh[(long)d * KEMBP + k] = hs;
        wl[(long)d * KEMBP + k] = ls;
    }
}

// ---------------- Embedding GEMM via MFMA (3-pass), split-K ----------------
// A = selu(bn(h)) [1024][KEMB] staged in LDS; B = emb_w bf16 hi/lo from global.
__global__ __launch_bounds__(256, 2)
void embed_mfma_kernel(const float* __restrict__ H, const short* __restrict__ Wh,
                       const short* __restrict__ Wl, const float* __restrict__ sc,
                       const float* __restrict__ sh, float* __restrict__ P,
                       int kPerZ) {
    __shared__ short Ah[128][36];
    __shared__ short Al[128][36];
    const int tid = threadIdx.x;
    const int rowBase = blockIdx.x * 128;   // grid.x = 8
    const int colBase = blockIdx.y * 128;   // grid.y = 2
    const int z = blockIdx.z;
    const int kz = z * kPerZ;
    const int iters = kPerZ >> 5;

    const int trow = tid >> 1, th = (tid & 1) * 16;
    const int arow = rowBase + trow;
    const float asc = sc[arow & 255], ash = sh[arow & 255];
    const float* Ap = H + (long)arow * KEMB;

    const int lane = tid & 63, wid = tid >> 6;
    const int l31 = lane & 31, hi = lane >> 5;
    const int wm = wid >> 1, wn = wid & 1;

    const short* bhp[2]; const short* blp[2];
#pragma unroll
    for (int nt = 0; nt < 2; nt++) {
        int brow = colBase + wn * 64 + nt * 32 + l31;
        bhp[nt] = Wh + (long)brow * KEMBP + hi * 8;
        blp[nt] = Wl + (long)brow * KEMBP + hi * 8;
    }

    f32x16 acc[2][2] = {{{0}, {0}}, {{0}, {0}}};

    for (int it = 0; it < iters; it++) {
        const int k0 = kz + it * 32;
        __syncthreads();
        // stage A tile [128][32] with bn+selu, split to bf16 hi/lo
        float av[16];
        if (k0 + 32 <= KEMB) {
            const float4* p4 = (const float4*)(Ap + k0 + th);
#pragma unroll
            for (int q = 0; q < 4; q++) {
                float4 f = p4[q];
                av[q * 4 + 0] = f.x; av[q * 4 + 1] = f.y;
                av[q * 4 + 2] = f.z; av[q * 4 + 3] = f.w;
            }
        } else {
#pragma unroll
            for (int e = 0; e < 16; e++) {
                int k = k0 + th + e;
                av[e] = (k < KEMB) ? Ap[k] : 0.f;
            }
        }
#pragma unroll
        for (int q = 0; q < 4; q++) {
            s16x4 h4, l4;
#pragma unroll
            for (int e = 0; e < 4; e++) {
                float v = selu_f(fmaf(av[q * 4 + e], asc, ash));
                short hs, ls;
                bf16split(v, hs, ls);
                h4[e] = hs; l4[e] = ls;
            }
            *(s16x4*)&Ah[trow][th + q * 4] = h4;
            *(s16x4*)&Al[trow][th + q * 4] = l4;
        }
        __syncthreads();

#pragma unroll
        for (int ks = 0; ks < 2; ks++) {
            const int kloc = ks * 16 + hi * 8;
            s16x8 ah[2], al[2], bh[2], bl[2];
#pragma unroll
            for (int mt = 0; mt < 2; mt++) {
                const int r = wm * 64 + mt * 32 + l31;
                ah[mt] = ld8lds(&Ah[r][kloc]);
                al[mt] = ld8lds(&Al[r][kloc]);
            }
#pragma unroll
            for (int nt = 0; nt < 2; nt++) {
                bh[nt] = *(const s16x8*)(bhp[nt] + k0 + ks * 16);
                bl[nt] = *(const s16x8*)(blp[nt] + k0 + ks * 16);
            }
#pragma unroll
            for (int mt = 0; mt < 2; mt++)
#pragma unroll
                for (int nt = 0; nt < 2; nt++) {
                    MFMA3(acc[mt][nt], ah[mt], al[mt], bh[nt], bl[nt])
                }
        }
    }

    float* Pz = P + (long)z * 262144;
#pragma unroll
    for (int mt = 0; mt < 2; mt++)
#pragma unroll
        for (int nt = 0; nt < 2; nt++) {
            int col = colBase + wn * 64 + nt * 32 + l31;
#pragma unroll
            for (int r = 0; r < 16; r++) {
                int row = rowBase + wm * 64 + mt * 32 + (r & 3) + 8 * (r >> 2) + 4 * hi;
                Pz[(long)row * 256 + col] = acc[mt][nt][r];
            }
        }
}

__global__ __launch_bounds__(256)
void embed_combine_kernel(const float* __restrict__ P, const float* __restrict__ eb,
                          float* __restrict__ e, int nsplit) {
    int idx = blockIdx.x * 256 + threadIdx.x;
    float s = 0.f;
    for (int z = 0; z < nsplit; z++) s += P[(long)z * 262144 + idx];
    e[idx] = s + eb[idx & 255];
}

// ---------------- BN(e)+ReLU + positional ----------------
__global__ __launch_bounds__(256)
void zinit_kernel(const float* __restrict__ e, const float* __restrict__ sc,
                  const float* __restrict__ sh, float* __restrict__ z) {
    int idx = blockIdx.x * 256 + threadIdx.x;
    int d = idx & 255;
    int c = (idx >> 8) & 255;
    float v = fmaf(e[idx], sc[c], sh[c]);
    v = fmaxf(v, 0.f);
    int i2 = d >> 1;
    float ang = (float)c * expf(-0.03597789207803195f * (float)(2 * i2));
    float pe = (d & 1) ? cosf(ang) : sinf(ang);
    z[idx] = v + pe;
}

// ---------------- tiled GEMM (fp32): C = A[M,K] * B[N,K]^T + bias ----------------
__global__ __launch_bounds__(256)
void gemm_kernel(const float* __restrict__ A, const float* __restrict__ Bm,
                 const float* __restrict__ bias, float* __restrict__ C,
                 int M, int N, int K) {
    __shared__ float As[64][17], Bs[64][17];
    int tid = threadIdx.x;
    int rowBase = blockIdx.x * 64, colBase = blockIdx.y * 64;
    int lrow = tid >> 2, kq = (tid & 3) * 4;
    const float* Ap = A + (long)(rowBase + lrow) * K + kq;
    const float* Bp = Bm + (long)(colBase + lrow) * K + kq;
    float acc[4][4] = {};
    int ty = tid >> 4, tx = tid & 15;
    for (int k0 = 0; k0 < K; k0 += 16) {
        float4 av = *(const float4*)(Ap + k0);
        float4 bv = *(const float4*)(Bp + k0);
        As[lrow][kq] = av.x; As[lrow][kq + 1] = av.y; As[lrow][kq + 2] = av.z; As[lrow][kq + 3] = av.w;
        Bs[lrow][kq] = bv.x; Bs[lrow][kq + 1] = bv.y; Bs[lrow][kq + 2] = bv.z; Bs[lrow][kq + 3] = bv.w;
        __syncthreads();
#pragma unroll
        for (int kk = 0; kk < 16; kk++) {
            float a0 = As[ty * 4 + 0][kk], a1 = As[ty * 4 + 1][kk];
            float a2 = As[ty * 4 + 2][kk], a3 = As[ty * 4 + 3][kk];
            float b0 = Bs[tx * 4 + 0][kk], b1 = Bs[tx * 4 + 1][kk];
            float b2 = Bs[tx * 4 + 2][kk], b3 = Bs[tx * 4 + 3][kk];
            acc[0][0] = fmaf(a0, b0, acc[0][0]); acc[0][1] = fmaf(a0, b1, acc[0][1]);
            acc[0][2] = fmaf(a0, b2, acc[0][2]); acc[0][3] = fmaf(a0, b3, acc[0][3]);
            acc[1][0] = fmaf(a1, b0, acc[1][0]); acc[1][1] = fmaf(a1, b1, acc[1][1]);
            acc[1][2] = fmaf(a1, b2, acc[1][2]); acc[1][3] = fmaf(a1, b3, acc[1][3]);
            acc[2][0] = fmaf(a2, b0, acc[2][0]); acc[2][1] = fmaf(a2, b1, acc[2][1]);
            acc[2][2] = fmaf(a2, b2, acc[2][2]); acc[2][3] = fmaf(a2, b3, acc[2][3]);
            acc[3][0] = fmaf(a3, b0, acc[3][0]); acc[3][1] = fmaf(a3, b1, acc[3][1]);
            acc[3][2] = fmaf(a3, b2, acc[3][2]); acc[3][3] = fmaf(a3, b3, acc[3][3]);
        }
        __syncthreads();
    }
#pragma unroll
    for (int i = 0; i < 4; i++) {
        int r = rowBase + ty * 4 + i;
#pragma unroll
        for (int j = 0; j < 4; j++) {
            int cc = colBase + tx * 4 + j;
            C[(long)r * N + cc] = acc[i][j] + bias[cc];
        }
    }
}

// ---------------- fused transformer layer ----------------
// grid 256 blocks x 512 threads; block handles 4 consecutive rows of one batch.
__device__ inline void ln_reduce4(const float (*buf)[256], float (*mr)[2], int t) {
    int wid = t >> 6, lane = t & 63;
    if (wid < 4) {
        float4 v = *(const float4*)&buf[wid][lane * 4];
        float s = v.x + v.y + v.z + v.w;
        float q = v.x * v.x + v.y * v.y + v.z * v.z + v.w * v.w;
#pragma unroll
        for (int off = 32; off > 0; off >>= 1) {
            s += __shfl_xor(s, off);
            q += __shfl_xor(q, off);
        }
        if (lane == 0) {
            float mean = s * (1.f / 256.f);
            float var = q * (1.f / 256.f) - mean * mean;
            mr[wid][0] = mean;
            mr[wid][1] = rsqrtf(var + 1e-5f);
        }
    }
}

template <int LAST>
__global__ __launch_bounds__(512)
void layer_kernel(const float* __restrict__ zin, const float* __restrict__ qin,
                  const float* __restrict__ kin, const float* __restrict__ vin,
                  const float* __restrict__ wo_l, const float* __restrict__ bo_l,
                  const float* __restrict__ c1w_l, const float* __restrict__ c1b_l,
                  const float* __restrict__ c2w_l, const float* __restrict__ c2b_l,
                  const float* __restrict__ ln1g_l, const float* __restrict__ ln1b_l,
                  const float* __restrict__ ln2g_l, const float* __restrict__ ln2b_l,
                  const float* __restrict__ wq_n, const float* __restrict__ bq_n,
                  const float* __restrict__ wk_n, const float* __restrict__ bk_n,
                  const float* __restrict__ wv_n, const float* __restrict__ bv_n,
                  const float* __restrict__ lnfg, const float* __restrict__ lnfb,
                  float* __restrict__ zout, float* __restrict__ qo,
                  float* __restrict__ ko, float* __restrict__ vo,
                  float* __restrict__ lnf_out) {
    __shared__ float zr[4][256];
    __shared__ float qb[4][256];
    __shared__ float ao[4][256];
    __shared__ union { float s[4][8][256]; float y[4][1024]; } sy;
    __shared__ float mr[4][2];

    const int t = threadIdx.x;
    const int g = blockIdx.x;
    const int b = g >> 6;
    const int lr0 = (g & 63) * 4;
    const long rowg0 = (long)(b * 256 + lr0);

    // P1: stage z and q rows
    for (int i = t; i < 1024; i += 512) {
        int r = i >> 8, d = i & 255;
        zr[r][d] = zin[(rowg0 + r) * 256 + d];
        qb[r][d] = qin[(rowg0 + r) * 256 + d];
    }
    __syncthreads();

    // P2: scores
    {
        const int j = t & 255;
        const int half = t >> 8;
        const float scale = 0.17677669529663687f;
        const float* krow = kin + ((long)(b * 256 + j)) * 256;
        for (int h = 0; h < 8; h++) {
            float4 kv[8];
            const float4* k4 = (const float4*)(krow + h * 32);
#pragma unroll
            for (int u = 0; u < 8; u++) kv[u] = k4[u];
#pragma unroll
            for (int i2 = 0; i2 < 2; i2++) {
                int i = half * 2 + i2;
                const float* qp = &qb[i][h * 32];
                float s = 0.f;
#pragma unroll
                for (int u = 0; u < 8; u++) {
                    s = fmaf(kv[u].x, qp[u * 4 + 0], s);
                    s = fmaf(kv[u].y, qp[u * 4 + 1], s);
                    s = fmaf(kv[u].z, qp[u * 4 + 2], s);
                    s = fmaf(kv[u].w, qp[u * 4 + 3], s);
                }
                sy.s[i][h][j] = s * scale;
            }
        }
    }
    __syncthreads();

    // P3: softmax over keys, per (row, head)
    {
        int wid = t >> 6, lane = t & 63;
#pragma unroll
        for (int p = 0; p < 4; p++) {
            int pair = wid * 4 + p;
            int i = pair >> 3, h = pair & 7;
            float* row = sy.s[i][h];
            float v0 = row[lane], v1 = row[lane + 64];
            float v2 = row[lane + 128], v3 = row[lane + 192];
            float m = fmaxf(fmaxf(v0, v1), fmaxf(v2, v3));
#pragma unroll
            for (int off = 32; off > 0; off >>= 1) m = fmaxf(m, __shfl_xor(m, off));
            float e0 = expf(v0 - m), e1 = expf(v1 - m);
            float e2 = expf(v2 - m), e3 = expf(v3 - m);
            float su = e0 + e1 + e2 + e3;
#pragma unroll
            for (int off = 32; off > 0; off >>= 1) su += __shfl_xor(su, off);
            float inv = 1.f / su;
            row[lane] = e0 * inv; row[lane + 64] = e1 * inv;
            row[lane + 128] = e2 * inv; row[lane + 192] = e3 * inv;
        }
    }
    __syncthreads();

    float t1v[2];
    const int d = t & 255, half = t >> 8;

    // P4: PV
    {
        int h = d >> 5;
        const float* vcol = vin + (long)b * 65536 + d;
        float a0 = 0.f, a1 = 0.f;
        const float* p0 = sy.s[half * 2 + 0][h];
        const float* p1 = sy.s[half * 2 + 1][h];
#pragma unroll 4
        for (int j = 0; j < 256; j++) {
            float vv = vcol[(long)j * 256];
            a0 = fmaf(p0[j], vv, a0);
            a1 = fmaf(p1[j], vv, a1);
        }
        ao[half * 2 + 0][d] = a0;
        ao[half * 2 + 1][d] = a1;
    }
    __syncthreads();

    // P5: O-proj + residual -> t1 (stored in qb)
    {
        const float4* wrow = (const float4*)(wo_l + (long)d * 256);
        float av0 = bo_l[d], av1 = av0;
#pragma unroll 4
        for (int k4 = 0; k4 < 64; k4++) {
            float4 w = wrow[k4];
            const float* a0p = &ao[half * 2 + 0][k4 * 4];
            const float* a1p = &ao[half * 2 + 1][k4 * 4];
            av0 = fmaf(w.x, a0p[0], av0); av0 = fmaf(w.y, a0p[1], av0);
            av0 = fmaf(w.z, a0p[2], av0); av0 = fmaf(w.w, a0p[3], av0);
            av1 = fmaf(w.x, a1p[0], av1); av1 = fmaf(w.y, a1p[1], av1);
            av1 = fmaf(w.z, a1p[2], av1); av1 = fmaf(w.w, a1p[3], av1);
        }
        t1v[0] = av0 + zr[half * 2 + 0][d];
        t1v[1] = av1 + zr[half * 2 + 1][d];
        qb[half * 2 + 0][d] = t1v[0];
        qb[half * 2 + 1][d] = t1v[1];
    }
    __syncthreads();
    ln_reduce4(qb, mr, t);
    __syncthreads();
    {
        float g1 = ln1g_l[d], b1 = ln1b_l[d];
#pragma unroll
        for (int i2 = 0; i2 < 2; i2++) {
            int i = half * 2 + i2;
            zr[i][d] = (t1v[i2] - mr[i][0]) * mr[i][1] * g1 + b1;
        }
    }
    __syncthreads();

    // P7: FFN1 (gelu)
    {
        int i = t >> 7, fb = t & 127;
#pragma unroll
        for (int c = 0; c < 8; c++) {
            int f = fb + 128 * c;
            const float4* wrow = (const float4*)(c1w_l + (long)f * 256);
            float acc = c1b_l[f];
#pragma unroll 4
            for (int k4 = 0; k4 < 64; k4++) {
                float4 w = wrow[k4];
                const float* zp = &zr[i][k4 * 4];
                acc = fmaf(w.x, zp[0], acc); acc = fmaf(w.y, zp[1], acc);
                acc = fmaf(w.z, zp[2], acc); acc = fmaf(w.w, zp[3], acc);
            }
            sy.y[i][f] = gelu_f(acc);
        }
    }
    __syncthreads();

    // P8: FFN2 + residual -> t1 (qb)
    {
        const float4* wrow = (const float4*)(c2w_l + (long)d * 1024);
        float av0 = c2b_l[d], av1 = av0;
#pragma unroll 4
        for (int f4 = 0; f4 < 256; f4++) {
            float4 w = wrow[f4];
            const float* y0 = &sy.y[half * 2 + 0][f4 * 4];
            const float* y1 = &sy.y[half * 2 + 1][f4 * 4];
            av0 = fmaf(w.x, y0[0], av0); av0 = fmaf(w.y, y0[1], av0);
            av0 = fmaf(w.z, y0[2], av0); av0 = fmaf(w.w, y0[3], av0);
            av1 = fmaf(w.x, y1[0], av1); av1 = fmaf(w.y, y1[1], av1);
            av1 = fmaf(w.z, y1[2], av1); av1 = fmaf(w.w, y1[3], av1);
        }
        t1v[0] = av0 + zr[half * 2 + 0][d];
        t1v[1] = av1 + zr[half * 2 + 1][d];
        qb[half * 2 + 0][d] = t1v[0];
        qb[half * 2 + 1][d] = t1v[1];
    }
    __syncthreads();
    ln_reduce4(qb, mr, t);
    __syncthreads();
    {
        float g2 = ln2g_l[d], b2 = ln2b_l[d];
#pragma unroll
        for (int i2 = 0; i2 < 2; i2++) {
            int i = half * 2 + i2;
            float z2 = (t1v[i2] - mr[i][0]) * mr[i][1] * g2 + b2;
            zr[i][d] = z2;
            zout[(rowg0 + i) * 256 + d] = z2;
        }
    }
    __syncthreads();

    if (!LAST) {
        // P9: QKV projections for next layer
#pragma unroll
        for (int c = 0; c < 6; c++) {
            int o = t + 512 * c;
            int mat = o >> 10, rem = o & 1023, i = rem >> 8, dd = rem & 255;
            const float* W = (mat == 0 ? wq_n : (mat == 1 ? wk_n : wv_n)) + (long)dd * 256;
            float acc = (mat == 0 ? bq_n : (mat == 1 ? bk_n : bv_n))[dd];
            const float4* w4 = (const float4*)W;
#pragma unroll 4
            for (int k4 = 0; k4 < 64; k4++) {
                float4 w = w4[k4];
                const float* zp = &zr[i][k4 * 4];
                acc = fmaf(w.x, zp[0], acc); acc = fmaf(w.y, zp[1], acc);
                acc = fmaf(w.z, zp[2], acc); acc = fmaf(w.w, zp[3], acc);
            }
            float* outp = (mat == 0 ? qo : (mat == 1 ? ko : vo));
            outp[(rowg0 + i) * 256 + dd] = acc;
        }
    } else {
        ln_reduce4(zr, mr, t);
        __syncthreads();
        float gf = lnfg[d], bf = lnfb[d];
#pragma unroll
        for (int i2 = 0; i2 < 2; i2++) {
            int i = half * 2 + i2;
            lnf_out[(rowg0 + i) * 256 + d] = (zr[i][d] - mr[i][0]) * mr[i][1] * gf + bf;
        }
    }
}

// ---------------- final: pooled mean over seq -> proj ----------------
__global__ __launch_bounds__(256)
void final_kernel(const float* __restrict__ zf, const float* __restrict__ pw,
                  const float* __restrict__ pb, float* __restrict__ out) {
    __shared__ float sm[8];
    int b = blockIdx.x, d = threadIdx.x;
    float s = 0.f;
    for (int c = 0; c < 256; c++) s += zf[((long)(b * 256 + c)) * 256 + d];
    float pooled = s * (1.f / 256.f);
    float c0 = pooled * pw[d], c1 = pooled * pw[256 + d];
    for (int off = 32; off > 0; off >>= 1) { c0 += __shfl_down(c0, off); c1 += __shfl_down(c1, off); }
    int lane = d & 63, wv = d >> 6;
    if (lane == 0) { sm[wv] = c0; sm[4 + wv] = c1; }
    __syncthreads();
    if (d == 0) {
        out[b * 2 + 0] = sm[0] + sm[1] + sm[2] + sm[3] + pb[0];
        out[b * 2 + 1] = sm[4] + sm[5] + sm[6] + sm[7] + pb[1];
    }
}

extern "C" void kernel_launch(void* const* d_in, const int* in_sizes, int n_in,
                              void* d_out, int out_size, void* d_ws, size_t ws_size,
                              hipStream_t stream) {
    const float* x       = (const float*)d_in[0];
    const float* filters = (const float*)d_in[1];
    const float* bn1_g   = (const float*)d_in[2];
    const float* bn1_b   = (const float*)d_in[3];
    const float* emb_w   = (const float*)d_in[4];
    const float* emb_b   = (const float*)d_in[5];
    const float* embbn_g = (const float*)d_in[6];
    const float* embbn_b = (const float*)d_in[7];
    const float* wq      = (const float*)d_in[8];
    const float* bq      = (const float*)d_in[9];
    const float* wk      = (const float*)d_in[10];
    const float* bk      = (const float*)d_in[11];
    const float* wv      = (const float*)d_in[12];
    const float* bv      = (const float*)d_in[13];
    const float* wo      = (const float*)d_in[14];
    const float* bo      = (const float*)d_in[15];
    const float* c1w     = (const float*)d_in[16];
    const float* c1b     = (const float*)d_in[17];
    const float* c2w     = (const float*)d_in[18];
    const float* c2b     = (const float*)d_in[19];
    const float* ln1g    = (const float*)d_in[20];
    const float* ln1b    = (const float*)d_in[21];
    const float* ln2g    = (const float*)d_in[22];
    const float* ln2b    = (const float*)d_in[23];
    const float* lnfg    = (const float*)d_in[24];
    const float* lnfb    = (const float*)d_in[25];
    const float* projw   = (const float*)d_in[26];
    const float* projb   = (const float*)d_in[27];

    // pick split-K factor that fits ws
    const long smallBufs = 10L * 262144;           // e,z,qA..vB,t1
    const long wBufs = 2L * 256 * KEMBP / 2;       // Wh+Wl as float-equivalents
    long Z = 32;
    {
        long wsFloats = (long)(ws_size / 4);
        while (Z > 8 && 22005760L + 1024 + Z * 262144L + wBufs + smallBufs > wsFloats)
            Z >>= 1;
    }
    const int kPerZ = KEMBP / (int)Z;

    float* ws = (float*)d_ws;
    float* h_raw  = ws;                            // 22,005,760
    float* bn1_sc = h_raw + 22005760;
    float* bn1_sh = bn1_sc + 256;
    float* e_sc   = bn1_sh + 256;
    float* e_sh   = e_sc + 256;
    float* part   = e_sh + 256;                    // Z * 262144
    float* wsp    = part + Z * 262144L;
    short* w_h    = (short*)wsp;                   // 256*KEMBP shorts
    short* w_l    = w_h + 256L * KEMBP;
    float* e      = wsp + wBufs;
    float* z      = e + 262144;
    float* qA     = z + 262144;
    float* kA     = qA + 262144;
    float* vA     = kA + 262144;
    float* qB     = vA + 262144;
    float* kB     = qB + 262144;
    float* vB     = kB + 262144;
    float* t1     = vB + 262144;

    // conv filter bf16 arrays alias onto `part` (only used after conv)
    short* filt_h = (short*)part;
    short* filt_l = filt_h + 256 * FKPAD;

    filt_prep_kernel<<<256, 256, 0, stream>>>(filters, filt_h, filt_l);
    conv_mfma_kernel<<<dim3(672, 4), 256, 0, stream>>>(x, filt_h, filt_l, h_raw);
    bn_stats_kernel<<<256, 256, 0, stream>>>(h_raw, bn1_g, bn1_b, bn1_sc, bn1_sh,
                                             T_POOL, 256L * T_POOL);
    wprep_kernel<<<256, 256, 0, stream>>>(emb_w, w_h, w_l);
    embed_mfma_kernel<<<dim3(8, 2, (int)Z), 256, 0, stream>>>(h_raw, w_h, w_l,
                                                              bn1_sc, bn1_sh, part, kPerZ);
    embed_combine_kernel<<<1024, 256, 0, stream>>>(part, emb_b, e, (int)Z);
    bn_stats_kernel<<<256, 256, 0, stream>>>(e, embbn_g, embbn_b, e_sc, e_sh,
                                             256, 256L * 256);
    zinit_kernel<<<1024, 256, 0, stream>>>(e, e_sc, e_sh, z);

    // layer-0 QKV
    gemm_kernel<<<dim3(16, 4), 256, 0, stream>>>(z, wq, bq, qA, 1024, 256, 256);
    gemm_kernel<<<dim3(16, 4), 256, 0, stream>>>(z, wk, bk, kA, 1024, 256, 256);
    gemm_kernel<<<dim3(16, 4), 256, 0, stream>>>(z, wv, bv, vA, 1024, 256, 256);

    float* qs[2][3] = {{qA, kA, vA}, {qB, kB, vB}};
    for (int l = 0; l < 4; l++) {
        float** in = qs[l & 1];
        float** ou = qs[(l + 1) & 1];
        const float* wo_l = wo + (long)l * 65536;  const float* bo_l = bo + l * 256;
        const float* c1w_l = c1w + (long)l * 262144; const float* c1b_l = c1b + l * 1024;
        const float* c2w_l = c2w + (long)l * 262144; const float* c2b_l = c2b + l * 256;
        const float* l1g = ln1g + l * 256, *l1b = ln1b + l * 256;
        const float* l2g = ln2g + l * 256, *l2b = ln2b + l * 256;
        if (l < 3) {
            const float* wq_n = wq + (long)(l + 1) * 65536; const float* bq_n = bq + (l + 1) * 256;
            const float* wk_n = wk + (long)(l + 1) * 65536; const float* bk_n = bk + (l + 1) * 256;
            const float* wv_n = wv + (long)(l + 1) * 65536; const float* bv_n = bv + (l + 1) * 256;
            layer_kernel<0><<<256, 512, 0, stream>>>(z, in[0], in[1], in[2],
                wo_l, bo_l, c1w_l, c1b_l, c2w_l, c2b_l, l1g, l1b, l2g, l2b,
                wq_n, bq_n, wk_n, bk_n, wv_n, bv_n, lnfg, lnfb,
                z, ou[0], ou[1], ou[2], t1);
        } else {
            layer_kernel<1><<<256, 512, 0, stream>>>(z, in[0], in[1], in[2],
                wo_l, bo_l, c1w_l, c1b_l, c2w_l, c2b_l, l1g, l1b, l2g, l2b,
                wq, bq, wk, bk, wv, bv, lnfg, lnfb,
                z, ou[0], ou[1], ou[2], t1);
        }
    }

    final_kernel<<<4, 256, 0, stream>>>(t1, projw, projb, (float*)d_out);
}

// Round 4
// 1454.093 us; speedup vs baseline: 2.5875x; 1.2645x over previous
//
#include <hip/hip_runtime.h>
#include <math.h>

#define L_IN 65494
#define T_POOL 21490
#define KF 1025
#define RS 1144            // conv replica row stride (elements)
#define CWIN 1136          // conv x window per block: 96 + 1040
#define KEMB 21490
#define KEMBP 21504        // padded
#define NKC 1344           // KEMBP/16

typedef short s16x4 __attribute__((ext_vector_type(4)));
typedef short s16x8 __attribute__((ext_vector_type(8)));
typedef float f32x16 __attribute__((ext_vector_type(16)));

__device__ inline float selu_f(float x) {
    float e = expf(fminf(x, 0.f));
    float neg = 1.6732632423543772f * (e - 1.f);
    return 1.0507009873554805f * (x > 0.f ? x : neg);
}

__device__ inline float gelu_f(float x) {
    return 0.5f * x * (1.f + erff(x * 0.7071067811865476f));
}

__device__ inline float dot4(float4 a, float4 b) {
    return fmaf(a.x, b.x, fmaf(a.y, b.y, fmaf(a.z, b.z, a.w * b.w)));
}

__device__ inline float sel4(float a0, float a1, float a2, float a3, int i) {
    float r = a0;
    r = (i == 1) ? a1 : r;
    r = (i == 2) ? a2 : r;
    r = (i == 3) ? a3 : r;
    return r;
}

#define WREDUCE4(A0, A1, A2, A3)                         \
    _Pragma("unroll")                                    \
    for (int off_ = 1; off_ < 64; off_ <<= 1) {          \
        A0 += __shfl_xor(A0, off_);                      \
        A1 += __shfl_xor(A1, off_);                      \
        A2 += __shfl_xor(A2, off_);                      \
        A3 += __shfl_xor(A3, off_);                      \
    }

__device__ inline void bf16split(float v, short& hs, short& ls) {
    unsigned u = __float_as_uint(v);
    unsigned rh = (u + 0x7fffu + ((u >> 16) & 1u)) & 0xffff0000u;
    float hf = __uint_as_float(rh);
    float lo = v - hf;
    unsigned ul = __float_as_uint(lo);
    unsigned rl = (ul + 0x7fffu + ((ul >> 16) & 1u)) >> 16;
    hs = (short)(rh >> 16);
    ls = (short)rl;
}

// ---------------- filter pack: fragment-major [ft][kc][lane][8], hi/lo ----------------
__global__ __launch_bounds__(512)
void filt_pack_kernel(const float* __restrict__ filt, short* __restrict__ fpH,
                      short* __restrict__ fpL) {
    int blk = blockIdx.x;            // ft*65 + kc  (grid 520)
    int ft = blk / 65, kc = blk % 65;
    int t = threadIdx.x, lane = t >> 3, e = t & 7;
    int f = ft * 32 + (lane & 31);
    int tap = kc * 16 + (lane >> 5) * 8 + e;
    float v = (tap < KF) ? filt[f * KF + tap] : 0.f;
    short hs, ls;
    bf16split(v, hs, ls);
    fpH[blk * 512 + t] = hs;
    fpL[blk * 512 + t] = ls;
}

// ---------------- emb_w pack: fragment-major [ft][kc][lane][8], hi/lo ----------------
__global__ __launch_bounds__(512)
void wpack_kernel(const float* __restrict__ wsrc, short* __restrict__ wpH,
                  short* __restrict__ wpL) {
    int blk = blockIdx.x;            // ft*NKC + kc  (grid 8*NKC)
    int ft = blk / NKC, kc = blk % NKC;
    int t = threadIdx.x, lane = t >> 3, e = t & 7;
    int row = ft * 32 + (lane & 31);
    int tap = kc * 16 + (lane >> 5) * 8 + e;
    float v = (tap < KEMB) ? wsrc[(long)row * KEMB + tap] : 0.f;
    short hs, ls;
    bf16split(v, hs, ls);
    wpH[(long)blk * 512 + t] = hs;
    wpL[(long)blk * 512 + t] = ls;
}

// ---------------- SincConv via MFMA (3-pass bf16 hi/lo) + |.| + maxpool3 ----------------
union ConvLDS {
    struct { short xh[8][RS]; short xl[8][RS]; } st;
    float ebuf[96][129];
};

#define MFMA3(ACC, AH, AL, BH, BL) \
    ACC = __builtin_amdgcn_mfma_f32_32x32x16_bf16(AL, BH, ACC, 0, 0, 0); \
    ACC = __builtin_amdgcn_mfma_f32_32x32x16_bf16(AH, BL, ACC, 0, 0, 0); \
    ACC = __builtin_amdgcn_mfma_f32_32x32x16_bf16(AH, BH, ACC, 0, 0, 0);

__global__ __launch_bounds__(256, 2)
void conv_mfma_kernel(const float* __restrict__ x, const short* __restrict__ fpH,
                      const short* __restrict__ fpL, float* __restrict__ h) {
    __shared__ ConvLDS u;
    const int tid = threadIdx.x;
    const int pb = blockIdx.x;
    const int b = blockIdx.y;
    const int t0 = pb * 96;

    for (int i = tid; i < CWIN; i += 256) {
        int gi = t0 + i;
        float v = (gi < L_IN) ? x[b * L_IN + gi] : 0.f;
        short hs, ls;
        bf16split(v, hs, ls);
#pragma unroll
        for (int s = 0; s < 8; s++) {
            int e = i - s;
            if (e >= 0) { u.st.xh[s][e] = hs; u.st.xl[s][e] = ls; }
        }
    }
    __syncthreads();

    const int lane = tid & 63;
    const int wid = tid >> 6;
    const int l31 = lane & 31;
    const int hi = lane >> 5;
    const int f0w = wid * 64;

    const short* aH = &u.st.xh[l31 & 7][8 * (l31 >> 3) + 8 * hi];
    const short* aL = &u.st.xl[l31 & 7][8 * (l31 >> 3) + 8 * hi];
    // packed filters: tile ft = wid*2 + nt; per kc offset = kc*512
    const short* bp0h = fpH + (long)(wid * 2) * 33280 + lane * 8;   // 65*512
    const short* bp1h = bp0h + 33280;
    const short* bp0l = fpL + (long)(wid * 2) * 33280 + lane * 8;
    const short* bp1l = bp0l + 33280;

    f32x16 a00 = {0}, a01 = {0}, a10 = {0}, a11 = {0}, a20 = {0}, a21 = {0};

#pragma unroll 1
    for (int kc = 0; kc < 65; kc++) {
        const int ko = kc * 16;
        const int kf = kc * 512;
        s16x8 ah0 = *(const s16x8*)(aH + ko);
        s16x8 ah1 = *(const s16x8*)(aH + ko + 32);
        s16x8 ah2 = *(const s16x8*)(aH + ko + 64);
        s16x8 al0 = *(const s16x8*)(aL + ko);
        s16x8 al1 = *(const s16x8*)(aL + ko + 32);
        s16x8 al2 = *(const s16x8*)(aL + ko + 64);
        s16x8 bh0 = *(const s16x8*)(bp0h + kf);
        s16x8 bh1 = *(const s16x8*)(bp1h + kf);
        s16x8 bl0 = *(const s16x8*)(bp0l + kf);
        s16x8 bl1 = *(const s16x8*)(bp1l + kf);
        MFMA3(a00, ah0, al0, bh0, bl0)
        MFMA3(a01, ah0, al0, bh1, bl1)
        MFMA3(a10, ah1, al1, bh0, bl0)
        MFMA3(a11, ah1, al1, bh1, bl1)
        MFMA3(a20, ah2, al2, bh0, bl0)
        MFMA3(a21, ah2, al2, bh1, bl1)
    }

    __syncthreads();
    const int t3l = tid & 31;
    const int t3 = pb * 32 + t3l;

#pragma unroll
    for (int half = 0; half < 2; half++) {
        if ((wid >> 1) == half) {
            int fcb = f0w - half * 128;
#define WRF(ACC, MT, NT)                                                   \
            {                                                              \
                int fc = fcb + NT * 32 + l31;                              \
                _Pragma("unroll")                                          \
                for (int r = 0; r < 16; r++) {                             \
                    int pos = MT * 32 + (r & 3) + 8 * (r >> 2) + 4 * hi;   \
                    u.ebuf[pos][fc] = fabsf(ACC[r]);                       \
                }                                                          \
            }
            WRF(a00, 0, 0) WRF(a01, 0, 1)
            WRF(a10, 1, 0) WRF(a11, 1, 1)
            WRF(a20, 2, 0) WRF(a21, 2, 1)
#undef WRF
        }
        __syncthreads();
        if (t3 < T_POOL) {
            for (int ff = tid >> 5; ff < 128; ff += 8) {
                float v = fmaxf(fmaxf(u.ebuf[3 * t3l][ff], u.ebuf[3 * t3l + 1][ff]),
                                u.ebuf[3 * t3l + 2][ff]);
                h[((long)(b * 256 + half * 128 + ff)) * T_POOL + t3] = v;
            }
        }
        __syncthreads();
    }
}

// ---------------- BatchNorm stats for h_raw: two-stage ----------------
__global__ __launch_bounds__(256)
void bn_part_kernel(const float* __restrict__ xin, float* __restrict__ p1,
                    float* __restrict__ p2) {
    __shared__ float sm[8];
    int c = blockIdx.x, s = blockIdx.y, tid = threadIdx.x;
    int t0 = s * 2687, t1 = min(T_POOL, t0 + 2687);
    float s1 = 0.f, s2 = 0.f;
    for (int b = 0; b < 4; b++) {
        const float* p = xin + (long)b * 256 * T_POOL + (long)c * T_POOL;
        for (int t = t0 + tid; t < t1; t += 256) {
            float v = p[t];
            s1 += v;
            s2 = fmaf(v, v, s2);
        }
    }
    for (int off = 32; off > 0; off >>= 1) { s1 += __shfl_down(s1, off); s2 += __shfl_down(s2, off); }
    int lane = tid & 63, wv = tid >> 6;
    if (lane == 0) { sm[wv] = s1; sm[4 + wv] = s2; }
    __syncthreads();
    if (tid == 0) {
        p1[c * 8 + s] = sm[0] + sm[1] + sm[2] + sm[3];
        p2[c * 8 + s] = sm[4] + sm[5] + sm[6] + sm[7];
    }
}

__global__ __launch_bounds__(256)
void bn_fin_kernel(const float* __restrict__ p1, const float* __restrict__ p2,
                   const float* __restrict__ g, const float* __restrict__ bb,
                   float* __restrict__ sc, float* __restrict__ sh) {
    int c = threadIdx.x;
    float S1 = 0.f, S2 = 0.f;
#pragma unroll
    for (int s = 0; s < 8; s++) { S1 += p1[c * 8 + s]; S2 += p2[c * 8 + s]; }
    float n = 4.f * (float)T_POOL;
    float mean = S1 / n;
    float var = S2 / n - mean * mean;
    float rstd = rsqrtf(var + 1e-5f);
    float gc = g[c], bc = bb[c];
    sc[c] = rstd * gc;
    sh[c] = bc - mean * rstd * gc;
}

// ---------------- BatchNorm stats (small, for e) ----------------
__global__ __launch_bounds__(256)
void bn_stats_kernel(const float* __restrict__ xin, const float* __restrict__ g,
                     const float* __restrict__ bb, float* __restrict__ sc,
                     float* __restrict__ sh, int ilen, long bstride) {
    __shared__ float sm[8];
    int c = blockIdx.x, tid = threadIdx.x;
    float s1 = 0.f, s2 = 0.f;
    for (int b = 0; b < 4; b++) {
        const float* p = xin + b * bstride + (long)c * ilen;
        for (int t = tid; t < ilen; t += 256) {
            float v = p[t];
            s1 += v;
            s2 = fmaf(v, v, s2);
        }
    }
    for (int off = 32; off > 0; off >>= 1) { s1 += __shfl_down(s1, off); s2 += __shfl_down(s2, off); }
    int lane = tid & 63, wv = tid >> 6;
    if (lane == 0) { sm[wv] = s1; sm[4 + wv] = s2; }
    __syncthreads();
    if (tid == 0) {
        float S1 = sm[0] + sm[1] + sm[2] + sm[3];
        float S2 = sm[4] + sm[5] + sm[6] + sm[7];
        float n = 4.f * (float)ilen;
        float mean = S1 / n;
        float var = S2 / n - mean * mean;
        float rstd = rsqrtf(var + 1e-5f);
        float gc = g[c], bc = bb[c];
        sc[c] = rstd * gc;
        sh[c] = bc - mean * rstd * gc;
    }
}

// ---------------- Embedding GEMM via MFMA (3-pass), split-K, packed B ----------------
__global__ __launch_bounds__(256, 2)
void embed_mfma_kernel(const float* __restrict__ H, const short* __restrict__ Wh,
                       const short* __restrict__ Wl, const float* __restrict__ sc,
                       const float* __restrict__ sh, float* __restrict__ P,
                       int kPerZ) {
    __shared__ short Ah[128][36];
    __shared__ short Al[128][36];
    const int tid = threadIdx.x;
    const int rowBase = blockIdx.x * 128;   // grid.x = 8
    const int colBase = blockIdx.y * 128;   // grid.y = 2
    const int z = blockIdx.z;
    const int kz = z * kPerZ;
    const int iters = kPerZ >> 5;

    const int trow = tid >> 1, th = (tid & 1) * 16;
    const int arow = rowBase + trow;
    const float asc = sc[arow & 255], ash = sh[arow & 255];
    const float* Ap = H + (long)arow * KEMB;

    const int lane = tid & 63, wid = tid >> 6;
    const int l31 = lane & 31, hi = lane >> 5;
    const int wm = wid >> 1, wn = wid & 1;

    const short* bhp[2]; const short* blp[2];
#pragma unroll
    for (int nt = 0; nt < 2; nt++) {
        int ft = (colBase >> 5) + wn * 2 + nt;
        bhp[nt] = Wh + (long)ft * NKC * 512 + lane * 8;
        blp[nt] = Wl + (long)ft * NKC * 512 + lane * 8;
    }

    f32x16 acc[2][2] = {{{0}, {0}}, {{0}, {0}}};

    for (int it = 0; it < iters; it++) {
        const int k0 = kz + it * 32;
        __syncthreads();
        float av[16];
        if (k0 + 32 <= KEMB) {
            const float4* p4 = (const float4*)(Ap + k0 + th);
#pragma unroll
            for (int q = 0; q < 4; q++) {
                float4 f = p4[q];
                av[q * 4 + 0] = f.x; av[q * 4 + 1] = f.y;
                av[q * 4 + 2] = f.z; av[q * 4 + 3] = f.w;
            }
        } else {
#pragma unroll
            for (int e = 0; e < 16; e++) {
                int k = k0 + th + e;
                av[e] = (k < KEMB) ? Ap[k] : 0.f;
            }
        }
#pragma unroll
        for (int q = 0; q < 4; q++) {
            s16x4 h4, l4;
#pragma unroll
            for (int e = 0; e < 4; e++) {
                float v = selu_f(fmaf(av[q * 4 + e], asc, ash));
                short hs, ls;
                bf16split(v, hs, ls);
                h4[e] = hs; l4[e] = ls;
            }
            *(s16x4*)&Ah[trow][th + q * 4] = h4;
            *(s16x4*)&Al[trow][th + q * 4] = l4;
        }
        __syncthreads();

#pragma unroll
        for (int ks = 0; ks < 2; ks++) {
            const int kloc = ks * 16 + hi * 8;
            const long kcg = (long)((k0 >> 4) + ks) * 512;
            s16x8 ah[2], al[2], bh[2], bl[2];
#pragma unroll
            for (int mt = 0; mt < 2; mt++) {
                const int r = wm * 64 + mt * 32 + l31;
                const short* ph = &Ah[r][kloc];
                const short* pl = &Al[r][kloc];
                union { s16x8 v; unsigned long long q[2]; } uh, ul;
                uh.q[0] = *(const unsigned long long*)(ph);
                uh.q[1] = *(const unsigned long long*)(ph + 4);
                ul.q[0] = *(const unsigned long long*)(pl);
                ul.q[1] = *(const unsigned long long*)(pl + 4);
                ah[mt] = uh.v; al[mt] = ul.v;
            }
#pragma unroll
            for (int nt = 0; nt < 2; nt++) {
                bh[nt] = *(const s16x8*)(bhp[nt] + kcg);
                bl[nt] = *(const s16x8*)(blp[nt] + kcg);
            }
#pragma unroll
            for (int mt = 0; mt < 2; mt++)
#pragma unroll
                for (int nt = 0; nt < 2; nt++) {
                    MFMA3(acc[mt][nt], ah[mt], al[mt], bh[nt], bl[nt])
                }
        }
    }

    float* Pz = P + (long)z * 262144;
#pragma unroll
    for (int mt = 0; mt < 2; mt++)
#pragma unroll
        for (int nt = 0; nt < 2; nt++) {
            int col = colBase + wn * 64 + nt * 32 + l31;
#pragma unroll
            for (int r = 0; r < 16; r++) {
                int row = rowBase + wm * 64 + mt * 32 + (r & 3) + 8 * (r >> 2) + 4 * hi;
                Pz[(long)row * 256 + col] = acc[mt][nt][r];
            }
        }
}

__global__ __launch_bounds__(256)
void embed_combine_kernel(const float* __restrict__ P, const float* __restrict__ eb,
                          float* __restrict__ e, int nsplit) {
    int idx = blockIdx.x * 256 + threadIdx.x;
    float s = 0.f;
    for (int z = 0; z < nsplit; z++) s += P[(long)z * 262144 + idx];
    e[idx] = s + eb[idx & 255];
}

// ---------------- fused zinit + layer-0 QKV ----------------
__global__ __launch_bounds__(512)
void qkv_init_kernel(const float* __restrict__ e, const float* __restrict__ sc,
                     const float* __restrict__ sh,
                     const float* __restrict__ wq0, const float* __restrict__ bq0,
                     const float* __restrict__ wk0, const float* __restrict__ bk0,
                     const float* __restrict__ wv0, const float* __restrict__ bv0,
                     float* __restrict__ z, float* __restrict__ qo,
                     float* __restrict__ ko, float* __restrict__ vo) {
    __shared__ float zs[4][256];
    const int t = threadIdx.x, w = t >> 6, lane = t & 63;
    const long rowg0 = (long)blockIdx.x * 4;

    for (int idx = t; idx < 1024; idx += 512) {
        int i = idx >> 8, dd = idx & 255;
        int c = (int)((rowg0 + i) & 255);
        float v = fmaf(e[(rowg0 + i) * 256 + dd], sc[c], sh[c]);
        v = fmaxf(v, 0.f);
        int i2 = dd >> 1;
        float ang = (float)c * expf(-0.03597789207803195f * (float)(2 * i2));
        float pe = (dd & 1) ? cosf(ang) : sinf(ang);
        float zz = v + pe;
        zs[i][dd] = zz;
        z[(rowg0 + i) * 256 + dd] = zz;
    }
    __syncthreads();

    float4 x0 = *(const float4*)&zs[0][lane * 4];
    float4 x1 = *(const float4*)&zs[1][lane * 4];
    float4 x2 = *(const float4*)&zs[2][lane * 4];
    float4 x3 = *(const float4*)&zs[3][lane * 4];
    for (int f = w; f < 256; f += 8) {
        float4 wv;
        float a0, a1, a2, a3;
        wv = *(const float4*)(wq0 + f * 256 + lane * 4);
        a0 = dot4(wv, x0); a1 = dot4(wv, x1); a2 = dot4(wv, x2); a3 = dot4(wv, x3);
        WREDUCE4(a0, a1, a2, a3)
        if (lane < 4) qo[(rowg0 + lane) * 256 + f] = sel4(a0, a1, a2, a3, lane) + bq0[f];
        wv = *(const float4*)(wk0 + f * 256 + lane * 4);
        a0 = dot4(wv, x0); a1 = dot4(wv, x1); a2 = dot4(wv, x2); a3 = dot4(wv, x3);
        WREDUCE4(a0, a1, a2, a3)
        if (lane < 4) ko[(rowg0 + lane) * 256 + f] = sel4(a0, a1, a2, a3, lane) + bk0[f];
        wv = *(const float4*)(wv0 + f * 256 + lane * 4);
        a0 = dot4(wv, x0); a1 = dot4(wv, x1); a2 = dot4(wv, x2); a3 = dot4(wv, x3);
        WREDUCE4(a0, a1, a2, a3)
        if (lane < 4) vo[(rowg0 + lane) * 256 + f] = sel4(a0, a1, a2, a3, lane) + bv0[f];
    }
}

// ---------------- fused transformer layer (coalesced wave-GEMV) ----------------
__device__ inline void ln_reduce4(const float (*buf)[256], float (*mr)[2], int t) {
    int wid = t >> 6, lane = t & 63;
    if (wid < 4) {
        float4 v = *(const float4*)&buf[wid][lane * 4];
        float s = v.x + v.y + v.z + v.w;
        float q = v.x * v.x + v.y * v.y + v.z * v.z + v.w * v.w;
#pragma unroll
        for (int off = 32; off > 0; off >>= 1) {
            s += __shfl_xor(s, off);
            q += __shfl_xor(q, off);
        }
        if (lane == 0) {
            float mean = s * (1.f / 256.f);
            float var = q * (1.f / 256.f) - mean * mean;
            mr[wid][0] = mean;
            mr[wid][1] = rsqrtf(var + 1e-5f);
        }
    }
}

template <int LAST>
__global__ __launch_bounds__(512)
void layer_kernel(const float* __restrict__ zin, const float* __restrict__ qin,
                  const float* __restrict__ kin, const float* __restrict__ vin,
                  const float* __restrict__ wo_l, const float* __restrict__ bo_l,
                  const float* __restrict__ c1w_l, const float* __restrict__ c1b_l,
                  const float* __restrict__ c2w_l, const float* __restrict__ c2b_l,
                  const float* __restrict__ ln1g_l, const float* __restrict__ ln1b_l,
                  const float* __restrict__ ln2g_l, const float* __restrict__ ln2b_l,
                  const float* __restrict__ wq_n, const float* __restrict__ bq_n,
                  const float* __restrict__ wk_n, const float* __restrict__ bk_n,
                  const float* __restrict__ wv_n, const float* __restrict__ bv_n,
                  const float* __restrict__ lnfg, const float* __restrict__ lnfb,
                  float* __restrict__ zout, float* __restrict__ qo,
                  float* __restrict__ ko, float* __restrict__ vo,
                  float* __restrict__ lnf_out) {
    __shared__ float zs[4][256];
    __shared__ float qb[4][256];
    __shared__ float ao[4][256];
    __shared__ union { float s[4][8][256]; float y[4][1024]; } sy;
    __shared__ float mr[4][2];

    const int t = threadIdx.x;
    const int w = t >> 6, lane = t & 63;
    const long rowg0 = (long)blockIdx.x * 4;
    const int b = blockIdx.x >> 6;

    // P1: stage z (residual) and q rows
    for (int i = t; i < 1024; i += 512) {
        int r = i >> 8, dd = i & 255;
        zs[r][dd] = zin[(rowg0 + r) * 256 + dd];
        qb[r][dd] = qin[(rowg0 + r) * 256 + dd];
    }
    __syncthreads();

    // P2: scores — wave w owns head w; 8-lane groups per key row (coalesced)
    {
        const float scale = 0.17677669529663687f;
        const int jq = lane >> 3, li = lane & 7, d4 = li * 4;
        const float* kb = kin + (long)b * 65536 + w * 32 + d4;
        float4 q0 = *(const float4*)&qb[0][w * 32 + d4];
        float4 q1 = *(const float4*)&qb[1][w * 32 + d4];
        float4 q2 = *(const float4*)&qb[2][w * 32 + d4];
        float4 q3 = *(const float4*)&qb[3][w * 32 + d4];
        for (int jb = 0; jb < 32; jb++) {
            int j = jb * 8 + jq;
            float4 kv = *(const float4*)(kb + (long)j * 256);
            float a0 = dot4(kv, q0), a1 = dot4(kv, q1);
            float a2 = dot4(kv, q2), a3 = dot4(kv, q3);
#pragma unroll
            for (int off = 1; off < 8; off <<= 1) {
                a0 += __shfl_xor(a0, off); a1 += __shfl_xor(a1, off);
                a2 += __shfl_xor(a2, off); a3 += __shfl_xor(a3, off);
            }
            if (li < 4) sy.s[li][w][j] = sel4(a0, a1, a2, a3, li) * scale;
        }
    }
    __syncthreads();

    // P3: softmax over keys per (row, head)
    {
#pragma unroll
        for (int p = 0; p < 4; p++) {
            int pair = w * 4 + p;
            int i = pair >> 3, hh = pair & 7;
            float* row = sy.s[i][hh];
            float v0 = row[lane], v1 = row[lane + 64];
            float v2 = row[lane + 128], v3 = row[lane + 192];
            float m = fmaxf(fmaxf(v0, v1), fmaxf(v2, v3));
#pragma unroll
            for (int off = 32; off > 0; off >>= 1) m = fmaxf(m, __shfl_xor(m, off));
            float e0 = expf(v0 - m), e1 = expf(v1 - m);
            float e2 = expf(v2 - m), e3 = expf(v3 - m);
            float su = e0 + e1 + e2 + e3;
#pragma unroll
            for (int off = 32; off > 0; off >>= 1) su += __shfl_xor(su, off);
            float inv = 1.f / su;
            row[lane] = e0 * inv; row[lane + 64] = e1 * inv;
            row[lane + 128] = e2 * inv; row[lane + 192] = e3 * inv;
        }
    }
    __syncthreads();

    const int d = t & 255, half = t >> 8;

    // P4: PV (coalesced v columns, broadcast P via float4)
    {
        int hh = d >> 5;
        const float* vcol = vin + (long)b * 65536 + d;
        const float* p0 = sy.s[half * 2 + 0][hh];
        const float* p1 = sy.s[half * 2 + 1][hh];
        float a0 = 0.f, a1 = 0.f;
#pragma unroll 4
        for (int j4 = 0; j4 < 64; j4++) {
            float4 pv0 = *(const float4*)(p0 + j4 * 4);
            float4 pv1 = *(const float4*)(p1 + j4 * 4);
            float v0 = vcol[(long)(j4 * 4 + 0) * 256];
            float v1 = vcol[(long)(j4 * 4 + 1) * 256];
            float v2 = vcol[(long)(j4 * 4 + 2) * 256];
            float v3 = vcol[(long)(j4 * 4 + 3) * 256];
            a0 = fmaf(pv0.x, v0, a0); a0 = fmaf(pv0.y, v1, a0);
            a0 = fmaf(pv0.z, v2, a0); a0 = fmaf(pv0.w, v3, a0);
            a1 = fmaf(pv1.x, v0, a1); a1 = fmaf(pv1.y, v1, a1);
            a1 = fmaf(pv1.z, v2, a1); a1 = fmaf(pv1.w, v3, a1);
        }
        ao[half * 2 + 0][d] = a0;
        ao[half * 2 + 1][d] = a1;
    }
    __syncthreads();

    // P5: O-proj + residual -> qb
    {
        float4 x0 = *(const float4*)&ao[0][lane * 4];
        float4 x1 = *(const float4*)&ao[1][lane * 4];
        float4 x2 = *(const float4*)&ao[2][lane * 4];
        float4 x3 = *(const float4*)&ao[3][lane * 4];
        for (int f = w; f < 256; f += 8) {
            float4 wv = *(const float4*)(wo_l + f * 256 + lane * 4);
            float a0 = dot4(wv, x0), a1 = dot4(wv, x1);
            float a2 = dot4(wv, x2), a3 = dot4(wv, x3);
            WREDUCE4(a0, a1, a2, a3)
            if (lane < 4)
                qb[lane][f] = sel4(a0, a1, a2, a3, lane) + bo_l[f] + zs[lane][f];
        }
    }
    __syncthreads();
    ln_reduce4(qb, mr, t);
    __syncthreads();
#pragma unroll
    for (int i2 = 0; i2 < 2; i2++) {
        int i = half * 2 + i2;
        zs[i][d] = (qb[i][d] - mr[i][0]) * mr[i][1] * ln1g_l[d] + ln1b_l[d];
    }
    __syncthreads();

    // P7: FFN1 + gelu -> sy.y
    {
        float4 x0 = *(const float4*)&zs[0][lane * 4];
        float4 x1 = *(const float4*)&zs[1][lane * 4];
        float4 x2 = *(const float4*)&zs[2][lane * 4];
        float4 x3 = *(const float4*)&zs[3][lane * 4];
        for (int f = w; f < 1024; f += 8) {
            float4 wv = *(const float4*)(c1w_l + (long)f * 256 + lane * 4);
            float a0 = dot4(wv, x0), a1 = dot4(wv, x1);
            float a2 = dot4(wv, x2), a3 = dot4(wv, x3);
            WREDUCE4(a0, a1, a2, a3)
            if (lane < 4)
                sy.y[lane][f] = gelu_f(sel4(a0, a1, a2, a3, lane) + c1b_l[f]);
        }
    }
    __syncthreads();

    // P8: FFN2 + residual -> qb
    {
        float4 y0[4], y1[4], y2[4], y3[4];
#pragma unroll
        for (int seg = 0; seg < 4; seg++) {
            y0[seg] = *(const float4*)&sy.y[0][seg * 256 + lane * 4];
            y1[seg] = *(const float4*)&sy.y[1][seg * 256 + lane * 4];
            y2[seg] = *(const float4*)&sy.y[2][seg * 256 + lane * 4];
            y3[seg] = *(const float4*)&sy.y[3][seg * 256 + lane * 4];
        }
        for (int f = w; f < 256; f += 8) {
            float a0 = 0.f, a1 = 0.f, a2 = 0.f, a3 = 0.f;
#pragma unroll
            for (int seg = 0; seg < 4; seg++) {
                float4 wv = *(const float4*)(c2w_l + (long)f * 1024 + seg * 256 + lane * 4);
                a0 += dot4(wv, y0[seg]); a1 += dot4(wv, y1[seg]);
                a2 += dot4(wv, y2[seg]); a3 += dot4(wv, y3[seg]);
            }
            WREDUCE4(a0, a1, a2, a3)
            if (lane < 4)
                qb[lane][f] = sel4(a0, a1, a2, a3, lane) + c2b_l[f] + zs[lane][f];
        }
    }
    __syncthreads();
    ln_reduce4(qb, mr, t);
    __syncthreads();
#pragma unroll
    for (int i2 = 0; i2 < 2; i2++) {
        int i = half * 2 + i2;
        float z2 = (qb[i][d] - mr[i][0]) * mr[i][1] * ln2g_l[d] + ln2b_l[d];
        zs[i][d] = z2;
        zout[(rowg0 + i) * 256 + d] = z2;
    }
    __syncthreads();

    if (!LAST) {
        // P9: QKV projections for next layer
        float4 x0 = *(const float4*)&zs[0][lane * 4];
        float4 x1 = *(const float4*)&zs[1][lane * 4];
        float4 x2 = *(const float4*)&zs[2][lane * 4];
        float4 x3 = *(const float4*)&zs[3][lane * 4];
        for (int f = w; f < 256; f += 8) {
            float4 wv;
            float a0, a1, a2, a3;
            wv = *(const float4*)(wq_n + f * 256 + lane * 4);
            a0 = dot4(wv, x0); a1 = dot4(wv, x1); a2 = dot4(wv, x2); a3 = dot4(wv, x3);
            WREDUCE4(a0, a1, a2, a3)
            if (lane < 4) qo[(rowg0 + lane) * 256 + f] = sel4(a0, a1, a2, a3, lane) + bq_n[f];
            wv = *(const float4*)(wk_n + f * 256 + lane * 4);
            a0 = dot4(wv, x0); a1 = dot4(wv, x1); a2 = dot4(wv, x2); a3 = dot4(wv, x3);
            WREDUCE4(a0, a1, a2, a3)
            if (lane < 4) ko[(rowg0 + lane) * 256 + f] = sel4(a0, a1, a2, a3, lane) + bk_n[f];
            wv = *(const float4*)(wv_n + f * 256 + lane * 4);
            a0 = dot4(wv, x0); a1 = dot4(wv, x1); a2 = dot4(wv, x2); a3 = dot4(wv, x3);
            WREDUCE4(a0, a1, a2, a3)
            if (lane < 4) vo[(rowg0 + lane) * 256 + f] = sel4(a0, a1, a2, a3, lane) + bv_n[f];
        }
    } else {
        ln_reduce4(zs, mr, t);
        __syncthreads();
#pragma unroll
        for (int i2 = 0; i2 < 2; i2++) {
            int i = half * 2 + i2;
            lnf_out[(rowg0 + i) * 256 + d] =
                (zs[i][d] - mr[i][0]) * mr[i][1] * lnfg[d] + lnfb[d];
        }
    }
}

// ---------------- final: pooled mean over seq -> proj ----------------
__global__ __launch_bounds__(256)
void final_kernel(const float* __restrict__ zf, const float* __restrict__ pw,
                  const float* __restrict__ pb, float* __restrict__ out) {
    __shared__ float sm[8];
    int b = blockIdx.x, d = threadIdx.x;
    float s = 0.f;
    for (int c = 0; c < 256; c++) s += zf[((long)(b * 256 + c)) * 256 + d];
    float pooled = s * (1.f / 256.f);
    float c0 = pooled * pw[d], c1 = pooled * pw[256 + d];
    for (int off = 32; off > 0; off >>= 1) { c0 += __shfl_down(c0, off); c1 += __shfl_down(c1, off); }
    int lane = d & 63, wv = d >> 6;
    if (lane == 0) { sm[wv] = c0; sm[4 + wv] = c1; }
    __syncthreads();
    if (d == 0) {
        out[b * 2 + 0] = sm[0] + sm[1] + sm[2] + sm[3] + pb[0];
        out[b * 2 + 1] = sm[4] + sm[5] + sm[6] + sm[7] + pb[1];
    }
}

extern "C" void kernel_launch(void* const* d_in, const int* in_sizes, int n_in,
                              void* d_out, int out_size, void* d_ws, size_t ws_size,
                              hipStream_t stream) {
    const float* x       = (const float*)d_in[0];
    const float* filters = (const float*)d_in[1];
    const float* bn1_g   = (const float*)d_in[2];
    const float* bn1_b   = (const float*)d_in[3];
    const float* emb_w   = (const float*)d_in[4];
    const float* emb_b   = (const float*)d_in[5];
    const float* embbn_g = (const float*)d_in[6];
    const float* embbn_b = (const float*)d_in[7];
    const float* wq      = (const float*)d_in[8];
    const float* bq      = (const float*)d_in[9];
    const float* wk      = (const float*)d_in[10];
    const float* bk      = (const float*)d_in[11];
    const float* wv      = (const float*)d_in[12];
    const float* bv      = (const float*)d_in[13];
    const float* wo      = (const float*)d_in[14];
    const float* bo      = (const float*)d_in[15];
    const float* c1w     = (const float*)d_in[16];
    const float* c1b     = (const float*)d_in[17];
    const float* c2w     = (const float*)d_in[18];
    const float* c2b     = (const float*)d_in[19];
    const float* ln1g    = (const float*)d_in[20];
    const float* ln1b    = (const float*)d_in[21];
    const float* ln2g    = (const float*)d_in[22];
    const float* ln2b    = (const float*)d_in[23];
    const float* lnfg    = (const float*)d_in[24];
    const float* lnfb    = (const float*)d_in[25];
    const float* projw   = (const float*)d_in[26];
    const float* projb   = (const float*)d_in[27];

    const long wpackF = 5505024L;                   // 2 * 8*NKC*512 shorts, in floats
    const long fixedF = 22005760L + 5120 + wpackF + 9L * 262144;
    long wsFloats = (long)(ws_size / 4);
    long Z = 32;
    while (Z > 8 && fixedF + Z * 262144L > wsFloats) Z >>= 1;
    const int kPerZ = KEMBP / (int)Z;

    float* ws = (float*)d_ws;
    float* h_raw  = ws;                             // 22,005,760
    float* bn1_sc = h_raw + 22005760;
    float* bn1_sh = bn1_sc + 256;
    float* e_sc   = bn1_sh + 256;
    float* e_sh   = e_sc + 256;
    float* bnp1   = e_sh + 256;                     // 2048
    float* bnp2   = bnp1 + 2048;                    // 2048
    float* part   = bnp2 + 2048;                    // Z * 262144
    float* wsp    = part + Z * 262144L;
    short* wpH    = (short*)wsp;                    // 8*NKC*512 shorts
    short* wpL    = wpH + 8L * NKC * 512;
    float* e      = wsp + wpackF;
    float* z      = e + 262144;
    float* qA     = z + 262144;
    float* kA     = qA + 262144;
    float* vA     = kA + 262144;
    float* qB     = vA + 262144;
    float* kB     = qB + 262144;
    float* vB     = kB + 262144;
    float* t1     = vB + 262144;

    // conv packed filters alias onto `part` (only used before embed writes part)
    short* fpH = (short*)part;                      // 520*512 shorts
    short* fpL = fpH + 266240;

    filt_pack_kernel<<<520, 512, 0, stream>>>(filters, fpH, fpL);
    wpack_kernel<<<8 * NKC, 512, 0, stream>>>(emb_w, wpH, wpL);
    conv_mfma_kernel<<<dim3(672, 4), 256, 0, stream>>>(x, fpH, fpL, h_raw);
    bn_part_kernel<<<dim3(256, 8), 256, 0, stream>>>(h_raw, bnp1, bnp2);
    bn_fin_kernel<<<1, 256, 0, stream>>>(bnp1, bnp2, bn1_g, bn1_b, bn1_sc, bn1_sh);
    embed_mfma_kernel<<<dim3(8, 2, (int)Z), 256, 0, stream>>>(h_raw, wpH, wpL,
                                                              bn1_sc, bn1_sh, part, kPerZ);
    embed_combine_kernel<<<1024, 256, 0, stream>>>(part, emb_b, e, (int)Z);
    bn_stats_kernel<<<256, 256, 0, stream>>>(e, embbn_g, embbn_b, e_sc, e_sh,
                                             256, 256L * 256);
    qkv_init_kernel<<<256, 512, 0, stream>>>(e, e_sc, e_sh, wq, bq, wk, bk, wv, bv,
                                             z, qA, kA, vA);

    float* qs[2][3] = {{qA, kA, vA}, {qB, kB, vB}};
    for (int l = 0; l < 4; l++) {
        float** in = qs[l & 1];
        float** ou = qs[(l + 1) & 1];
        const float* wo_l = wo + (long)l * 65536;  const float* bo_l = bo + l * 256;
        const float* c1w_l = c1w + (long)l * 262144; const float* c1b_l = c1b + l * 1024;
        const float* c2w_l = c2w + (long)l * 262144; const float* c2b_l = c2b + l * 256;
        const float* l1g = ln1g + l * 256; const float* l1b = ln1b + l * 256;
        const float* l2g = ln2g + l * 256; const float* l2b = ln2b + l * 256;
        if (l < 3) {
            const float* wq_n = wq + (long)(l + 1) * 65536; const float* bq_n = bq + (l + 1) * 256;
            const float* wk_n = wk + (long)(l + 1) * 65536; const float* bk_n = bk + (l + 1) * 256;
            const float* wv_n = wv + (long)(l + 1) * 65536; const float* bv_n = bv + (l + 1) * 256;
            layer_kernel<0><<<256, 512, 0, stream>>>(z, in[0], in[1], in[2],
                wo_l, bo_l, c1w_l, c1b_l, c2w_l, c2b_l, l1g, l1b, l2g, l2b,
                wq_n, bq_n, wk_n, bk_n, wv_n, bv_n, lnfg, lnfb,
                z, ou[0], ou[1], ou[2], t1);
        } else {
            layer_kernel<1><<<256, 512, 0, stream>>>(z, in[0], in[1], in[2],
                wo_l, bo_l, c1w_l, c1b_l, c2w_l, c2b_l, l1g, l1b, l2g, l2b,
                wq, bq, wk, bk, wv, bv, lnfg, lnfb,
                z, ou[0], ou[1], ou[2], t1);
        }
    }

    final_kernel<<<4, 256, 0, stream>>>(t1, projw, projb, (float*)d_out);
}

// Round 5
// 1011.648 us; speedup vs baseline: 3.7192x; 1.4373x over previous
//
#include <hip/hip_runtime.h>
#include <math.h>

#define L_IN 65494
#define T_POOL 21490
#define KF 1025
#define RS 1144            // conv replica row stride (elements)
#define CWIN 1136          // conv x window per block: 96 + 1040
#define KEMB 21490
#define KEMBP 21504        // padded
#define NKC 1344           // KEMBP/16

typedef short s16x4 __attribute__((ext_vector_type(4)));
typedef short s16x8 __attribute__((ext_vector_type(8)));
typedef float f32x16 __attribute__((ext_vector_type(16)));

__device__ inline float selu_f(float x) {
    float e = expf(fminf(x, 0.f));
    float neg = 1.6732632423543772f * (e - 1.f);
    return 1.0507009873554805f * (x > 0.f ? x : neg);
}

__device__ inline float gelu_f(float x) {
    return 0.5f * x * (1.f + erff(x * 0.7071067811865476f));
}

__device__ inline void bf16split(float v, short& hs, short& ls) {
    unsigned u = __float_as_uint(v);
    unsigned rh = (u + 0x7fffu + ((u >> 16) & 1u)) & 0xffff0000u;
    float hf = __uint_as_float(rh);
    float lo = v - hf;
    unsigned ul = __float_as_uint(lo);
    unsigned rl = (ul + 0x7fffu + ((ul >> 16) & 1u)) >> 16;
    hs = (short)(rh >> 16);
    ls = (short)rl;
}

// ---------------- filter pack: fragment-major [ft][kc][lane][8], hi/lo ----------------
__global__ __launch_bounds__(512)
void filt_pack_kernel(const float* __restrict__ filt, short* __restrict__ fpH,
                      short* __restrict__ fpL) {
    int blk = blockIdx.x;            // ft*65 + kc  (grid 520)
    int ft = blk / 65, kc = blk % 65;
    int t = threadIdx.x, lane = t >> 3, e = t & 7;
    int f = ft * 32 + (lane & 31);
    int tap = kc * 16 + (lane >> 5) * 8 + e;
    float v = (tap < KF) ? filt[f * KF + tap] : 0.f;
    short hs, ls;
    bf16split(v, hs, ls);
    fpH[blk * 512 + t] = hs;
    fpL[blk * 512 + t] = ls;
}

// ---------------- emb_w pack: fragment-major [ft][kc][lane][8], hi/lo ----------------
__global__ __launch_bounds__(512)
void wpack_kernel(const float* __restrict__ wsrc, short* __restrict__ wpH,
                  short* __restrict__ wpL) {
    int blk = blockIdx.x;            // ft*NKC + kc  (grid 8*NKC)
    int ft = blk / NKC, kc = blk % NKC;
    int t = threadIdx.x, lane = t >> 3, e = t & 7;
    int row = ft * 32 + (lane & 31);
    int tap = kc * 16 + (lane >> 5) * 8 + e;
    float v = (tap < KEMB) ? wsrc[(long)row * KEMB + tap] : 0.f;
    short hs, ls;
    bf16split(v, hs, ls);
    wpH[(long)blk * 512 + t] = hs;
    wpL[(long)blk * 512 + t] = ls;
}

// ---------------- weight transpose pack: Wt[k][f] = W[f][k] ----------------
__device__ inline void transpose_tile(const float* __restrict__ src, float* __restrict__ dst,
                                      int F, int K, int tf, int tk) {
    __shared__ float tile[32][33];
    int tx = threadIdx.x, ty = threadIdx.y;  // 32 x 8
#pragma unroll
    for (int r = 0; r < 4; r++) {
        int fi = tf * 32 + ty * 4 + r;
        tile[ty * 4 + r][tx] = src[(long)fi * K + tk * 32 + tx];
    }
    __syncthreads();
#pragma unroll
    for (int r = 0; r < 4; r++) {
        int ki = tk * 32 + ty * 4 + r;
        dst[(long)ki * F + tf * 32 + tx] = tile[tx][ty * 4 + r];
    }
}

__global__ __launch_bounds__(256)
void wtrans_kernel(const float* __restrict__ wq, const float* __restrict__ wk,
                   const float* __restrict__ wv, const float* __restrict__ wo,
                   const float* __restrict__ c1w, const float* __restrict__ c2w,
                   float* __restrict__ wqT, float* __restrict__ wkT,
                   float* __restrict__ wvT, float* __restrict__ woT,
                   float* __restrict__ c1T, float* __restrict__ c2T) {
    int bx = blockIdx.x;
    if (bx < 1024) {
        int m = bx >> 6, tile = bx & 63;
        int which = m >> 2, l = m & 3;
        int tk = tile >> 3, tf = tile & 7;
        const float* s; float* dd;
        if (which == 0) { s = wq; dd = wqT; }
        else if (which == 1) { s = wk; dd = wkT; }
        else if (which == 2) { s = wv; dd = wvT; }
        else { s = wo; dd = woT; }
        transpose_tile(s + l * 65536, dd + l * 65536, 256, 256, tf, tk);
    } else if (bx < 2048) {
        int b2 = bx - 1024, l = b2 >> 8, tile = b2 & 255;
        int tf = tile & 31, tk = tile >> 5;
        transpose_tile(c1w + (long)l * 262144, c1T + (long)l * 262144, 1024, 256, tf, tk);
    } else {
        int b2 = bx - 2048, l = b2 >> 8, tile = b2 & 255;
        int tf = tile & 7, tk = tile >> 3;
        transpose_tile(c2w + (long)l * 262144, c2T + (long)l * 262144, 256, 1024, tf, tk);
    }
}

// ---------------- SincConv via MFMA (3-pass bf16 hi/lo) + |.| + maxpool3 ----------------
union ConvLDS {
    struct { short xh[8][RS]; short xl[8][RS]; } st;
    float ebuf[96][129];
};

#define MFMA3(ACC, AH, AL, BH, BL) \
    ACC = __builtin_amdgcn_mfma_f32_32x32x16_bf16(AL, BH, ACC, 0, 0, 0); \
    ACC = __builtin_amdgcn_mfma_f32_32x32x16_bf16(AH, BL, ACC, 0, 0, 0); \
    ACC = __builtin_amdgcn_mfma_f32_32x32x16_bf16(AH, BH, ACC, 0, 0, 0);

__global__ __launch_bounds__(256, 2)
void conv_mfma_kernel(const float* __restrict__ x, const short* __restrict__ fpH,
                      const short* __restrict__ fpL, float* __restrict__ h) {
    __shared__ ConvLDS u;
    const int tid = threadIdx.x;
    const int pb = blockIdx.x;
    const int b = blockIdx.y;
    const int t0 = pb * 96;

    for (int i = tid; i < CWIN; i += 256) {
        int gi = t0 + i;
        float v = (gi < L_IN) ? x[b * L_IN + gi] : 0.f;
        short hs, ls;
        bf16split(v, hs, ls);
#pragma unroll
        for (int s = 0; s < 8; s++) {
            int e = i - s;
            if (e >= 0) { u.st.xh[s][e] = hs; u.st.xl[s][e] = ls; }
        }
    }
    __syncthreads();

    const int lane = tid & 63;
    const int wid = tid >> 6;
    const int l31 = lane & 31;
    const int hi = lane >> 5;
    const int f0w = wid * 64;

    const short* aH = &u.st.xh[l31 & 7][8 * (l31 >> 3) + 8 * hi];
    const short* aL = &u.st.xl[l31 & 7][8 * (l31 >> 3) + 8 * hi];
    const short* bp0h = fpH + (long)(wid * 2) * 33280 + lane * 8;
    const short* bp1h = bp0h + 33280;
    const short* bp0l = fpL + (long)(wid * 2) * 33280 + lane * 8;
    const short* bp1l = bp0l + 33280;

    f32x16 a00 = {0}, a01 = {0}, a10 = {0}, a11 = {0}, a20 = {0}, a21 = {0};

#pragma unroll 1
    for (int kc = 0; kc < 65; kc++) {
        const int ko = kc * 16;
        const int kf = kc * 512;
        s16x8 ah0 = *(const s16x8*)(aH + ko);
        s16x8 ah1 = *(const s16x8*)(aH + ko + 32);
        s16x8 ah2 = *(const s16x8*)(aH + ko + 64);
        s16x8 al0 = *(const s16x8*)(aL + ko);
        s16x8 al1 = *(const s16x8*)(aL + ko + 32);
        s16x8 al2 = *(const s16x8*)(aL + ko + 64);
        s16x8 bh0 = *(const s16x8*)(bp0h + kf);
        s16x8 bh1 = *(const s16x8*)(bp1h + kf);
        s16x8 bl0 = *(const s16x8*)(bp0l + kf);
        s16x8 bl1 = *(const s16x8*)(bp1l + kf);
        MFMA3(a00, ah0, al0, bh0, bl0)
        MFMA3(a01, ah0, al0, bh1, bl1)
        MFMA3(a10, ah1, al1, bh0, bl0)
        MFMA3(a11, ah1, al1, bh1, bl1)
        MFMA3(a20, ah2, al2, bh0, bl0)
        MFMA3(a21, ah2, al2, bh1, bl1)
    }

    __syncthreads();
    const int t3l = tid & 31;
    const int t3 = pb * 32 + t3l;

#pragma unroll
    for (int half = 0; half < 2; half++) {
        if ((wid >> 1) == half) {
            int fcb = f0w - half * 128;
#define WRF(ACC, MT, NT)                                                   \
            {                                                              \
                int fc = fcb + NT * 32 + l31;                              \
                _Pragma("unroll")                                          \
                for (int r = 0; r < 16; r++) {                             \
                    int pos = MT * 32 + (r & 3) + 8 * (r >> 2) + 4 * hi;   \
                    u.ebuf[pos][fc] = fabsf(ACC[r]);                       \
                }                                                          \
            }
            WRF(a00, 0, 0) WRF(a01, 0, 1)
            WRF(a10, 1, 0) WRF(a11, 1, 1)
            WRF(a20, 2, 0) WRF(a21, 2, 1)
#undef WRF
        }
        __syncthreads();
        if (t3 < T_POOL) {
            for (int ff = tid >> 5; ff < 128; ff += 8) {
                float v = fmaxf(fmaxf(u.ebuf[3 * t3l][ff], u.ebuf[3 * t3l + 1][ff]),
                                u.ebuf[3 * t3l + 2][ff]);
                h[((long)(b * 256 + half * 128 + ff)) * T_POOL + t3] = v;
            }
        }
        __syncthreads();
    }
}

// ---------------- BatchNorm stats for h_raw: two-stage ----------------
__global__ __launch_bounds__(256)
void bn_part_kernel(const float* __restrict__ xin, float* __restrict__ p1,
                    float* __restrict__ p2) {
    __shared__ float sm[8];
    int c = blockIdx.x, s = blockIdx.y, tid = threadIdx.x;
    int t0 = s * 2687, t1 = min(T_POOL, t0 + 2687);
    float s1 = 0.f, s2 = 0.f;
    for (int b = 0; b < 4; b++) {
        const float* p = xin + (long)b * 256 * T_POOL + (long)c * T_POOL;
        for (int t = t0 + tid; t < t1; t += 256) {
            float v = p[t];
            s1 += v;
            s2 = fmaf(v, v, s2);
        }
    }
    for (int off = 32; off > 0; off >>= 1) { s1 += __shfl_down(s1, off); s2 += __shfl_down(s2, off); }
    int lane = tid & 63, wv = tid >> 6;
    if (lane == 0) { sm[wv] = s1; sm[4 + wv] = s2; }
    __syncthreads();
    if (tid == 0) {
        p1[c * 8 + s] = sm[0] + sm[1] + sm[2] + sm[3];
        p2[c * 8 + s] = sm[4] + sm[5] + sm[6] + sm[7];
    }
}

__global__ __launch_bounds__(256)
void bn_fin_kernel(const float* __restrict__ p1, const float* __restrict__ p2,
                   const float* __restrict__ g, const float* __restrict__ bb,
                   float* __restrict__ sc, float* __restrict__ sh) {
    int c = threadIdx.x;
    float S1 = 0.f, S2 = 0.f;
#pragma unroll
    for (int s = 0; s < 8; s++) { S1 += p1[c * 8 + s]; S2 += p2[c * 8 + s]; }
    float n = 4.f * (float)T_POOL;
    float mean = S1 / n;
    float var = S2 / n - mean * mean;
    float rstd = rsqrtf(var + 1e-5f);
    float gc = g[c], bc = bb[c];
    sc[c] = rstd * gc;
    sh[c] = bc - mean * rstd * gc;
}

// ---------------- BatchNorm stats (small, for e) ----------------
__global__ __launch_bounds__(256)
void bn_stats_kernel(const float* __restrict__ xin, const float* __restrict__ g,
                     const float* __restrict__ bb, float* __restrict__ sc,
                     float* __restrict__ sh, int ilen, long bstride) {
    __shared__ float sm[8];
    int c = blockIdx.x, tid = threadIdx.x;
    float s1 = 0.f, s2 = 0.f;
    for (int b = 0; b < 4; b++) {
        const float* p = xin + b * bstride + (long)c * ilen;
        for (int t = tid; t < ilen; t += 256) {
            float v = p[t];
            s1 += v;
            s2 = fmaf(v, v, s2);
        }
    }
    for (int off = 32; off > 0; off >>= 1) { s1 += __shfl_down(s1, off); s2 += __shfl_down(s2, off); }
    int lane = tid & 63, wv = tid >> 6;
    if (lane == 0) { sm[wv] = s1; sm[4 + wv] = s2; }
    __syncthreads();
    if (tid == 0) {
        float S1 = sm[0] + sm[1] + sm[2] + sm[3];
        float S2 = sm[4] + sm[5] + sm[6] + sm[7];
        float n = 4.f * (float)ilen;
        float mean = S1 / n;
        float var = S2 / n - mean * mean;
        float rstd = rsqrtf(var + 1e-5f);
        float gc = g[c], bc = bb[c];
        sc[c] = rstd * gc;
        sh[c] = bc - mean * rstd * gc;
    }
}

// ---------------- Embedding GEMM via MFMA (3-pass), split-K, packed B ----------------
__global__ __launch_bounds__(256, 2)
void embed_mfma_kernel(const float* __restrict__ H, const short* __restrict__ Wh,
                       const short* __restrict__ Wl, const float* __restrict__ sc,
                       const float* __restrict__ sh, float* __restrict__ P,
                       int kPerZ) {
    __shared__ short Ah[128][36];
    __shared__ short Al[128][36];
    const int tid = threadIdx.x;
    const int rowBase = blockIdx.x * 128;
    const int colBase = blockIdx.y * 128;
    const int z = blockIdx.z;
    const int kz = z * kPerZ;
    const int iters = kPerZ >> 5;

    const int trow = tid >> 1, th = (tid & 1) * 16;
    const int arow = rowBase + trow;
    const float asc = sc[arow & 255], ash = sh[arow & 255];
    const float* Ap = H + (long)arow * KEMB;

    const int lane = tid & 63, wid = tid >> 6;
    const int l31 = lane & 31, hi = lane >> 5;
    const int wm = wid >> 1, wn = wid & 1;

    const short* bhp[2]; const short* blp[2];
#pragma unroll
    for (int nt = 0; nt < 2; nt++) {
        int ft = (colBase >> 5) + wn * 2 + nt;
        bhp[nt] = Wh + (long)ft * NKC * 512 + lane * 8;
        blp[nt] = Wl + (long)ft * NKC * 512 + lane * 8;
    }

    f32x16 acc[2][2] = {{{0}, {0}}, {{0}, {0}}};

    for (int it = 0; it < iters; it++) {
        const int k0 = kz + it * 32;
        __syncthreads();
        float av[16];
        if (k0 + 32 <= KEMB) {
            const float4* p4 = (const float4*)(Ap + k0 + th);
#pragma unroll
            for (int q = 0; q < 4; q++) {
                float4 f = p4[q];
                av[q * 4 + 0] = f.x; av[q * 4 + 1] = f.y;
                av[q * 4 + 2] = f.z; av[q * 4 + 3] = f.w;
            }
        } else {
#pragma unroll
            for (int e = 0; e < 16; e++) {
                int k = k0 + th + e;
                av[e] = (k < KEMB) ? Ap[k] : 0.f;
            }
        }
#pragma unroll
        for (int q = 0; q < 4; q++) {
            s16x4 h4, l4;
#pragma unroll
            for (int e = 0; e < 4; e++) {
                float v = selu_f(fmaf(av[q * 4 + e], asc, ash));
                short hs, ls;
                bf16split(v, hs, ls);
                h4[e] = hs; l4[e] = ls;
            }
            *(s16x4*)&Ah[trow][th + q * 4] = h4;
            *(s16x4*)&Al[trow][th + q * 4] = l4;
        }
        __syncthreads();

#pragma unroll
        for (int ks = 0; ks < 2; ks++) {
            const int kloc = ks * 16 + hi * 8;
            const long kcg = (long)((k0 >> 4) + ks) * 512;
            s16x8 ah[2], al[2], bh[2], bl[2];
#pragma unroll
            for (int mt = 0; mt < 2; mt++) {
                const int r = wm * 64 + mt * 32 + l31;
                const short* ph = &Ah[r][kloc];
                const short* pl = &Al[r][kloc];
                union { s16x8 v; unsigned long long q[2]; } uh, ul;
                uh.q[0] = *(const unsigned long long*)(ph);
                uh.q[1] = *(const unsigned long long*)(ph + 4);
                ul.q[0] = *(const unsigned long long*)(pl);
                ul.q[1] = *(const unsigned long long*)(pl + 4);
                ah[mt] = uh.v; al[mt] = ul.v;
            }
#pragma unroll
            for (int nt = 0; nt < 2; nt++) {
                bh[nt] = *(const s16x8*)(bhp[nt] + kcg);
                bl[nt] = *(const s16x8*)(blp[nt] + kcg);
            }
#pragma unroll
            for (int mt = 0; mt < 2; mt++)
#pragma unroll
                for (int nt = 0; nt < 2; nt++) {
                    MFMA3(acc[mt][nt], ah[mt], al[mt], bh[nt], bl[nt])
                }
        }
    }

    float* Pz = P + (long)z * 262144;
#pragma unroll
    for (int mt = 0; mt < 2; mt++)
#pragma unroll
        for (int nt = 0; nt < 2; nt++) {
            int col = colBase + wn * 64 + nt * 32 + l31;
#pragma unroll
            for (int r = 0; r < 16; r++) {
                int row = rowBase + wm * 64 + mt * 32 + (r & 3) + 8 * (r >> 2) + 4 * hi;
                Pz[(long)row * 256 + col] = acc[mt][nt][r];
            }
        }
}

__global__ __launch_bounds__(256)
void embed_combine_kernel(const float* __restrict__ P, const float* __restrict__ eb,
                          float* __restrict__ e, int nsplit) {
    int idx = blockIdx.x * 256 + threadIdx.x;
    float s = 0.f;
    for (int z = 0; z < nsplit; z++) s += P[(long)z * 262144 + idx];
    e[idx] = s + eb[idx & 255];
}

// ---------------- GEMV helper macro: 2 rows, scalar Wt column reads ----------------
#define GEMV2(WT, F, X0, X1, A0, A1)                                  \
    for (int k4_ = 0; k4_ < 64; k4_++) {                              \
        float4 x0_ = *(const float4*)&X0[k4_ * 4];                    \
        float4 x1_ = *(const float4*)&X1[k4_ * 4];                    \
        float w0_ = WT[(k4_ * 4 + 0) * F];                            \
        float w1_ = WT[(k4_ * 4 + 1) * F];                            \
        float w2_ = WT[(k4_ * 4 + 2) * F];                            \
        float w3_ = WT[(k4_ * 4 + 3) * F];                            \
        A0 = fmaf(w0_, x0_.x, A0); A0 = fmaf(w1_, x0_.y, A0);         \
        A0 = fmaf(w2_, x0_.z, A0); A0 = fmaf(w3_, x0_.w, A0);         \
        A1 = fmaf(w0_, x1_.x, A1); A1 = fmaf(w1_, x1_.y, A1);         \
        A1 = fmaf(w2_, x1_.z, A1); A1 = fmaf(w3_, x1_.w, A1);         \
    }

// ---------------- fused zinit + layer-0 QKV (transposed weights) ----------------
__global__ __launch_bounds__(512)
void qkv_init_kernel(const float* __restrict__ e, const float* __restrict__ sc,
                     const float* __restrict__ sh,
                     const float* __restrict__ wqT0, const float* __restrict__ bq0,
                     const float* __restrict__ wkT0, const float* __restrict__ bk0,
                     const float* __restrict__ wvT0, const float* __restrict__ bv0,
                     float* __restrict__ z, float* __restrict__ qo,
                     float* __restrict__ ko, float* __restrict__ vo) {
    __shared__ float zs[4][256];
    const int t = threadIdx.x;
    const long rowg0 = (long)blockIdx.x * 4;

    for (int idx = t; idx < 1024; idx += 512) {
        int i = idx >> 8, dd = idx & 255;
        int c = (int)((rowg0 + i) & 255);
        float v = fmaf(e[(rowg0 + i) * 256 + dd], sc[c], sh[c]);
        v = fmaxf(v, 0.f);
        int i2 = dd >> 1;
        float ang = (float)c * expf(-0.03597789207803195f * (float)(2 * i2));
        float pe = (dd & 1) ? cosf(ang) : sinf(ang);
        float zz = v + pe;
        zs[i][dd] = zz;
        z[(rowg0 + i) * 256 + dd] = zz;
    }
    __syncthreads();

    const int f = t & 255;
    const int r0 = (t >> 8) * 2;
#pragma unroll
    for (int mat = 0; mat < 3; mat++) {
        const float* wt = (mat == 0 ? wqT0 : mat == 1 ? wkT0 : wvT0) + f;
        float a0 = 0.f, a1 = 0.f;
        GEMV2(wt, 256, zs[r0], zs[r0 + 1], a0, a1)
        float bv = (mat == 0 ? bq0 : mat == 1 ? bk0 : bv0)[f];
        float* op = (mat == 0 ? qo : mat == 1 ? ko : vo);
        op[(rowg0 + r0) * 256 + f] = a0 + bv;
        op[(rowg0 + r0 + 1) * 256 + f] = a1 + bv;
    }
}

// ---------------- fused transformer layer (shuffle-free GEMV, W^T) ----------------
__device__ inline void ln_reduce4(const float (*buf)[256], float (*mr)[2], int t) {
    int wid = t >> 6, lane = t & 63;
    if (wid < 4) {
        float4 v = *(const float4*)&buf[wid][lane * 4];
        float s = v.x + v.y + v.z + v.w;
        float q = v.x * v.x + v.y * v.y + v.z * v.z + v.w * v.w;
#pragma unroll
        for (int off = 32; off > 0; off >>= 1) {
            s += __shfl_xor(s, off);
            q += __shfl_xor(q, off);
        }
        if (lane == 0) {
            float mean = s * (1.f / 256.f);
            float var = q * (1.f / 256.f) - mean * mean;
            mr[wid][0] = mean;
            mr[wid][1] = rsqrtf(var + 1e-5f);
        }
    }
}

__device__ inline float dot4(float4 a, float4 b) {
    return fmaf(a.x, b.x, fmaf(a.y, b.y, fmaf(a.z, b.z, a.w * b.w)));
}

__device__ inline float sel4(float a0, float a1, float a2, float a3, int i) {
    float r = a0;
    r = (i == 1) ? a1 : r;
    r = (i == 2) ? a2 : r;
    r = (i == 3) ? a3 : r;
    return r;
}

template <int LAST>
__global__ __launch_bounds__(512)
void layer_kernel(const float* __restrict__ zin, const float* __restrict__ qin,
                  const float* __restrict__ kin, const float* __restrict__ vin,
                  const float* __restrict__ woT_l, const float* __restrict__ bo_l,
                  const float* __restrict__ c1T_l, const float* __restrict__ c1b_l,
                  const float* __restrict__ c2T_l, const float* __restrict__ c2b_l,
                  const float* __restrict__ ln1g_l, const float* __restrict__ ln1b_l,
                  const float* __restrict__ ln2g_l, const float* __restrict__ ln2b_l,
                  const float* __restrict__ wqT_n, const float* __restrict__ bq_n,
                  const float* __restrict__ wkT_n, const float* __restrict__ bk_n,
                  const float* __restrict__ wvT_n, const float* __restrict__ bv_n,
                  const float* __restrict__ lnfg, const float* __restrict__ lnfb,
                  float* __restrict__ zout, float* __restrict__ qo,
                  float* __restrict__ ko, float* __restrict__ vo,
                  float* __restrict__ lnf_out) {
    __shared__ float zs[4][256];
    __shared__ float qb[4][256];
    __shared__ float ao[4][256];
    __shared__ union { float s[4][8][256]; float y[4][1024]; } sy;
    __shared__ float mr[4][2];

    const int t = threadIdx.x;
    const int w = t >> 6, lane = t & 63;
    const long rowg0 = (long)blockIdx.x * 4;
    const int b = blockIdx.x >> 6;

    // P1: stage z (residual) and q rows
    for (int i = t; i < 1024; i += 512) {
        int r = i >> 8, dd = i & 255;
        zs[r][dd] = zin[(rowg0 + r) * 256 + dd];
        qb[r][dd] = qin[(rowg0 + r) * 256 + dd];
    }
    __syncthreads();

    // P2: scores — wave w owns head w; 8-lane groups per key row (coalesced)
    {
        const float scale = 0.17677669529663687f;
        const int jq = lane >> 3, li = lane & 7, d4 = li * 4;
        const float* kb = kin + (long)b * 65536 + w * 32 + d4;
        float4 q0 = *(const float4*)&qb[0][w * 32 + d4];
        float4 q1 = *(const float4*)&qb[1][w * 32 + d4];
        float4 q2 = *(const float4*)&qb[2][w * 32 + d4];
        float4 q3 = *(const float4*)&qb[3][w * 32 + d4];
        for (int jb = 0; jb < 32; jb++) {
            int j = jb * 8 + jq;
            float4 kv = *(const float4*)(kb + (long)j * 256);
            float a0 = dot4(kv, q0), a1 = dot4(kv, q1);
            float a2 = dot4(kv, q2), a3 = dot4(kv, q3);
#pragma unroll
            for (int off = 1; off < 8; off <<= 1) {
                a0 += __shfl_xor(a0, off); a1 += __shfl_xor(a1, off);
                a2 += __shfl_xor(a2, off); a3 += __shfl_xor(a3, off);
            }
            if (li < 4) sy.s[li][w][j] = sel4(a0, a1, a2, a3, li) * scale;
        }
    }
    __syncthreads();

    // P3: softmax over keys per (row, head)
    {
#pragma unroll
        for (int p = 0; p < 4; p++) {
            int pair = w * 4 + p;
            int i = pair >> 3, hh = pair & 7;
            float* row = sy.s[i][hh];
            float v0 = row[lane], v1 = row[lane + 64];
            float v2 = row[lane + 128], v3 = row[lane + 192];
            float m = fmaxf(fmaxf(v0, v1), fmaxf(v2, v3));
#pragma unroll
            for (int off = 32; off > 0; off >>= 1) m = fmaxf(m, __shfl_xor(m, off));
            float e0 = expf(v0 - m), e1 = expf(v1 - m);
            float e2 = expf(v2 - m), e3 = expf(v3 - m);
            float su = e0 + e1 + e2 + e3;
#pragma unroll
            for (int off = 32; off > 0; off >>= 1) su += __shfl_xor(su, off);
            float inv = 1.f / su;
            row[lane] = e0 * inv; row[lane + 64] = e1 * inv;
            row[lane + 128] = e2 * inv; row[lane + 192] = e3 * inv;
        }
    }
    __syncthreads();

    const int d = t & 255, half = t >> 8;

    // P4: PV (coalesced v columns, broadcast P via float4)
    {
        int hh = d >> 5;
        const float* vcol = vin + (long)b * 65536 + d;
        const float* p0 = sy.s[half * 2 + 0][hh];
        const float* p1 = sy.s[half * 2 + 1][hh];
        float a0 = 0.f, a1 = 0.f;
#pragma unroll 4
        for (int j4 = 0; j4 < 64; j4++) {
            float4 pv0 = *(const float4*)(p0 + j4 * 4);
            float4 pv1 = *(const float4*)(p1 + j4 * 4);
            float v0 = vcol[(long)(j4 * 4 + 0) * 256];
            float v1 = vcol[(long)(j4 * 4 + 1) * 256];
            float v2 = vcol[(long)(j4 * 4 + 2) * 256];
            float v3 = vcol[(long)(j4 * 4 + 3) * 256];
            a0 = fmaf(pv0.x, v0, a0); a0 = fmaf(pv0.y, v1, a0);
            a0 = fmaf(pv0.z, v2, a0); a0 = fmaf(pv0.w, v3, a0);
            a1 = fmaf(pv1.x, v0, a1); a1 = fmaf(pv1.y, v1, a1);
            a1 = fmaf(pv1.z, v2, a1); a1 = fmaf(pv1.w, v3, a1);
        }
        ao[half * 2 + 0][d] = a0;
        ao[half * 2 + 1][d] = a1;
    }
    __syncthreads();

    // P5: O-proj + residual -> qb  (lane-owns-f, W^T scalar column reads)
    {
        const int f = t & 255;
        const int r0 = (t >> 8) * 2;
        const float* wt = woT_l + f;
        float a0 = 0.f, a1 = 0.f;
        GEMV2(wt, 256, ao[r0], ao[r0 + 1], a0, a1)
        float bv = bo_l[f];
        qb[r0][f] = a0 + bv + zs[r0][f];
        qb[r0 + 1][f] = a1 + bv + zs[r0 + 1][f];
    }
    __syncthreads();
    ln_reduce4(qb, mr, t);
    __syncthreads();
#pragma unroll
    for (int i2 = 0; i2 < 2; i2++) {
        int i = half * 2 + i2;
        zs[i][d] = (qb[i][d] - mr[i][0]) * mr[i][1] * ln1g_l[d] + ln1b_l[d];
    }
    __syncthreads();

    // P7: FFN1 + gelu -> sy.y  (thread owns f-pair, all 4 rows)
    {
        const int f2 = t << 1;
        const float* wt = c1T_l + f2;
        float a0 = 0.f, a1 = 0.f, a2 = 0.f, a3 = 0.f;
        float b0 = 0.f, b1 = 0.f, b2 = 0.f, b3 = 0.f;
        for (int k4 = 0; k4 < 64; k4++) {
            float4 x0 = *(const float4*)&zs[0][k4 * 4];
            float4 x1 = *(const float4*)&zs[1][k4 * 4];
            float4 x2 = *(const float4*)&zs[2][k4 * 4];
            float4 x3 = *(const float4*)&zs[3][k4 * 4];
#pragma unroll
            for (int e = 0; e < 4; e++) {
                float2 wv = *(const float2*)(wt + ((k4 * 4 + e) << 10));
                float xe0 = (e == 0) ? x0.x : (e == 1) ? x0.y : (e == 2) ? x0.z : x0.w;
                float xe1 = (e == 0) ? x1.x : (e == 1) ? x1.y : (e == 2) ? x1.z : x1.w;
                float xe2 = (e == 0) ? x2.x : (e == 1) ? x2.y : (e == 2) ? x2.z : x2.w;
                float xe3 = (e == 0) ? x3.x : (e == 1) ? x3.y : (e == 2) ? x3.z : x3.w;
                a0 = fmaf(wv.x, xe0, a0); b0 = fmaf(wv.y, xe0, b0);
                a1 = fmaf(wv.x, xe1, a1); b1 = fmaf(wv.y, xe1, b1);
                a2 = fmaf(wv.x, xe2, a2); b2 = fmaf(wv.y, xe2, b2);
                a3 = fmaf(wv.x, xe3, a3); b3 = fmaf(wv.y, xe3, b3);
            }
        }
        float c0 = c1b_l[f2], c1 = c1b_l[f2 + 1];
        sy.y[0][f2] = gelu_f(a0 + c0); sy.y[0][f2 + 1] = gelu_f(b0 + c1);
        sy.y[1][f2] = gelu_f(a1 + c0); sy.y[1][f2 + 1] = gelu_f(b1 + c1);
        sy.y[2][f2] = gelu_f(a2 + c0); sy.y[2][f2 + 1] = gelu_f(b2 + c1);
        sy.y[3][f2] = gelu_f(a3 + c0); sy.y[3][f2 + 1] = gelu_f(b3 + c1);
    }
    __syncthreads();

    // P8: FFN2 + residual -> qb  (thread owns f-pair for one row, K=1024)
    {
        const int fp = (t & 127) << 1;
        const int row = t >> 7;
        const float* wt = c2T_l + fp;
        const float* yr = sy.y[row];
        float a0 = 0.f, a1 = 0.f;
        for (int k4 = 0; k4 < 256; k4++) {
            float4 x = *(const float4*)&yr[k4 * 4];
#pragma unroll
            for (int e = 0; e < 4; e++) {
                float2 wv = *(const float2*)(wt + ((k4 * 4 + e) << 8));
                float xe = (e == 0) ? x.x : (e == 1) ? x.y : (e == 2) ? x.z : x.w;
                a0 = fmaf(wv.x, xe, a0);
                a1 = fmaf(wv.y, xe, a1);
            }
        }
        qb[row][fp] = a0 + c2b_l[fp] + zs[row][fp];
        qb[row][fp + 1] = a1 + c2b_l[fp + 1] + zs[row][fp + 1];
    }
    __syncthreads();
    ln_reduce4(qb, mr, t);
    __syncthreads();
#pragma unroll
    for (int i2 = 0; i2 < 2; i2++) {
        int i = half * 2 + i2;
        float z2 = (qb[i][d] - mr[i][0]) * mr[i][1] * ln2g_l[d] + ln2b_l[d];
        zs[i][d] = z2;
        zout[(rowg0 + i) * 256 + d] = z2;
    }
    __syncthreads();

    if (!LAST) {
        // P9: QKV projections for next layer
        const int f = t & 255;
        const int r0 = (t >> 8) * 2;
#pragma unroll
        for (int mat = 0; mat < 3; mat++) {
            const float* wt = (mat == 0 ? wqT_n : mat == 1 ? wkT_n : wvT_n) + f;
            float a0 = 0.f, a1 = 0.f;
            GEMV2(wt, 256, zs[r0], zs[r0 + 1], a0, a1)
            float bv = (mat == 0 ? bq_n : mat == 1 ? bk_n : bv_n)[f];
            float* op = (mat == 0 ? qo : mat == 1 ? ko : vo);
            op[(rowg0 + r0) * 256 + f] = a0 + bv;
            op[(rowg0 + r0 + 1) * 256 + f] = a1 + bv;
        }
    } else {
        ln_reduce4(zs, mr, t);
        __syncthreads();
#pragma unroll
        for (int i2 = 0; i2 < 2; i2++) {
            int i = half * 2 + i2;
            lnf_out[(rowg0 + i) * 256 + d] =
                (zs[i][d] - mr[i][0]) * mr[i][1] * lnfg[d] + lnfb[d];
        }
    }
}

// ---------------- final: pooled mean over seq -> proj ----------------
__global__ __launch_bounds__(256)
void final_kernel(const float* __restrict__ zf, const float* __restrict__ pw,
                  const float* __restrict__ pb, float* __restrict__ out) {
    __shared__ float sm[8];
    int b = blockIdx.x, d = threadIdx.x;
    float s = 0.f;
    for (int c = 0; c < 256; c++) s += zf[((long)(b * 256 + c)) * 256 + d];
    float pooled = s * (1.f / 256.f);
    float c0 = pooled * pw[d], c1 = pooled * pw[256 + d];
    for (int off = 32; off > 0; off >>= 1) { c0 += __shfl_down(c0, off); c1 += __shfl_down(c1, off); }
    int lane = d & 63, wv = d >> 6;
    if (lane == 0) { sm[wv] = c0; sm[4 + wv] = c1; }
    __syncthreads();
    if (d == 0) {
        out[b * 2 + 0] = sm[0] + sm[1] + sm[2] + sm[3] + pb[0];
        out[b * 2 + 1] = sm[4] + sm[5] + sm[6] + sm[7] + pb[1];
    }
}

extern "C" void kernel_launch(void* const* d_in, const int* in_sizes, int n_in,
                              void* d_out, int out_size, void* d_ws, size_t ws_size,
                              hipStream_t stream) {
    const float* x       = (const float*)d_in[0];
    const float* filters = (const float*)d_in[1];
    const float* bn1_g   = (const float*)d_in[2];
    const float* bn1_b   = (const float*)d_in[3];
    const float* emb_w   = (const float*)d_in[4];
    const float* emb_b   = (const float*)d_in[5];
    const float* embbn_g = (const float*)d_in[6];
    const float* embbn_b = (const float*)d_in[7];
    const float* wq      = (const float*)d_in[8];
    const float* bq      = (const float*)d_in[9];
    const float* wk      = (const float*)d_in[10];
    const float* bk      = (const float*)d_in[11];
    const float* wv      = (const float*)d_in[12];
    const float* bv      = (const float*)d_in[13];
    const float* wo      = (const float*)d_in[14];
    const float* bo      = (const float*)d_in[15];
    const float* c1w     = (const float*)d_in[16];
    const float* c1b     = (const float*)d_in[17];
    const float* c2w     = (const float*)d_in[18];
    const float* c2b     = (const float*)d_in[19];
    const float* ln1g    = (const float*)d_in[20];
    const float* ln1b    = (const float*)d_in[21];
    const float* ln2g    = (const float*)d_in[22];
    const float* ln2b    = (const float*)d_in[23];
    const float* lnfg    = (const float*)d_in[24];
    const float* lnfb    = (const float*)d_in[25];
    const float* projw   = (const float*)d_in[26];
    const float* projb   = (const float*)d_in[27];

    const long wpackF = 5505024L;                   // 2 * 8*NKC*512 shorts, in floats
    const long wTF = 3145728L;                      // transposed layer weights
    const long fixedF = 22005760L + 5120 + wpackF + 9L * 262144 + wTF;
    long wsFloats = (long)(ws_size / 4);
    long Z = 32;
    while (Z > 8 && fixedF + Z * 262144L > wsFloats) Z >>= 1;
    const int kPerZ = KEMBP / (int)Z;

    float* ws = (float*)d_ws;
    float* h_raw  = ws;                             // 22,005,760
    float* bn1_sc = h_raw + 22005760;
    float* bn1_sh = bn1_sc + 256;
    float* e_sc   = bn1_sh + 256;
    float* e_sh   = e_sc + 256;
    float* bnp1   = e_sh + 256;                     // 2048
    float* bnp2   = bnp1 + 2048;                    // 2048
    float* part   = bnp2 + 2048;                    // Z * 262144
    float* wsp    = part + Z * 262144L;
    short* wpH    = (short*)wsp;                    // 8*NKC*512 shorts
    short* wpL    = wpH + 8L * NKC * 512;
    float* e      = wsp + wpackF;
    float* z      = e + 262144;
    float* qA     = z + 262144;
    float* kA     = qA + 262144;
    float* vA     = kA + 262144;
    float* qB     = vA + 262144;
    float* kB     = qB + 262144;
    float* vB     = kB + 262144;
    float* t1     = vB + 262144;
    float* wqT    = t1 + 262144;                    // 4*65536
    float* wkT    = wqT + 262144;
    float* wvT    = wkT + 262144;
    float* woT    = wvT + 262144;
    float* c1T    = woT + 262144;                   // 4*262144
    float* c2T    = c1T + 1048576;

    // conv packed filters alias onto `part` (only used before embed writes part)
    short* fpH = (short*)part;                      // 520*512 shorts
    short* fpL = fpH + 266240;

    filt_pack_kernel<<<520, 512, 0, stream>>>(filters, fpH, fpL);
    wpack_kernel<<<8 * NKC, 512, 0, stream>>>(emb_w, wpH, wpL);
    wtrans_kernel<<<3072, dim3(32, 8), 0, stream>>>(wq, wk, wv, wo, c1w, c2w,
                                                    wqT, wkT, wvT, woT, c1T, c2T);
    conv_mfma_kernel<<<dim3(672, 4), 256, 0, stream>>>(x, fpH, fpL, h_raw);
    bn_part_kernel<<<dim3(256, 8), 256, 0, stream>>>(h_raw, bnp1, bnp2);
    bn_fin_kernel<<<1, 256, 0, stream>>>(bnp1, bnp2, bn1_g, bn1_b, bn1_sc, bn1_sh);
    embed_mfma_kernel<<<dim3(8, 2, (int)Z), 256, 0, stream>>>(h_raw, wpH, wpL,
                                                              bn1_sc, bn1_sh, part, kPerZ);
    embed_combine_kernel<<<1024, 256, 0, stream>>>(part, emb_b, e, (int)Z);
    bn_stats_kernel<<<256, 256, 0, stream>>>(e, embbn_g, embbn_b, e_sc, e_sh,
                                             256, 256L * 256);
    qkv_init_kernel<<<256, 512, 0, stream>>>(e, e_sc, e_sh, wqT, bq, wkT, bk, wvT, bv,
                                             z, qA, kA, vA);

    float* qs[2][3] = {{qA, kA, vA}, {qB, kB, vB}};
    for (int l = 0; l < 4; l++) {
        float** in = qs[l & 1];
        float** ou = qs[(l + 1) & 1];
        const float* woT_l = woT + (long)l * 65536; const float* bo_l = bo + l * 256;
        const float* c1T_l = c1T + (long)l * 262144; const float* c1b_l = c1b + l * 1024;
        const float* c2T_l = c2T + (long)l * 262144; const float* c2b_l = c2b + l * 256;
        const float* l1g = ln1g + l * 256; const float* l1b = ln1b + l * 256;
        const float* l2g = ln2g + l * 256; const float* l2b = ln2b + l * 256;
        if (l < 3) {
            const float* wqT_n = wqT + (long)(l + 1) * 65536; const float* bq_n = bq + (l + 1) * 256;
            const float* wkT_n = wkT + (long)(l + 1) * 65536; const float* bk_n = bk + (l + 1) * 256;
            const float* wvT_n = wvT + (long)(l + 1) * 65536; const float* bv_n = bv + (l + 1) * 256;
            layer_kernel<0><<<256, 512, 0, stream>>>(z, in[0], in[1], in[2],
                woT_l, bo_l, c1T_l, c1b_l, c2T_l, c2b_l, l1g, l1b, l2g, l2b,
                wqT_n, bq_n, wkT_n, bk_n, wvT_n, bv_n, lnfg, lnfb,
                z, ou[0], ou[1], ou[2], t1);
        } else {
            layer_kernel<1><<<256, 512, 0, stream>>>(z, in[0], in[1], in[2],
                woT_l, bo_l, c1T_l, c1b_l, c2T_l, c2b_l, l1g, l1b, l2g, l2b,
                wqT, bq, wkT, bk, wvT, bv, lnfg, lnfb,
                z, ou[0], ou[1], ou[2], t1);
        }
    }

    final_kernel<<<4, 256, 0, stream>>>(t1, projw, projb, (float*)d_out);
}

// Round 6
// 964.782 us; speedup vs baseline: 3.8999x; 1.0486x over previous
//
#include <hip/hip_runtime.h>
#include <math.h>

#define L_IN 65494
#define T_POOL 21490
#define KF 1025
#define KEMB 21490
#define KEMBP 21504        // padded
#define NKC 1344           // KEMBP/16
#define NKCF 33            // folded conv K chunks (528/16)
#define CWIN2 1120         // conv x window: 96 + 1024
#define FTILE 16896        // 33*512 shorts per filter tile

typedef short s16x4 __attribute__((ext_vector_type(4)));
typedef short s16x8 __attribute__((ext_vector_type(8)));
typedef float f32x16 __attribute__((ext_vector_type(16)));

__device__ inline float selu_f(float x) {
    float e = expf(fminf(x, 0.f));
    float neg = 1.6732632423543772f * (e - 1.f);
    return 1.0507009873554805f * (x > 0.f ? x : neg);
}

__device__ inline float gelu_f(float x) {
    return 0.5f * x * (1.f + erff(x * 0.7071067811865476f));
}

__device__ inline float dot4(float4 a, float4 b) {
    return fmaf(a.x, b.x, fmaf(a.y, b.y, fmaf(a.z, b.z, a.w * b.w)));
}

__device__ inline float sel4(float a0, float a1, float a2, float a3, int i) {
    float r = a0;
    r = (i == 1) ? a1 : r;
    r = (i == 2) ? a2 : r;
    r = (i == 3) ? a3 : r;
    return r;
}

__device__ inline void bf16split(float v, short& hs, short& ls) {
    unsigned u = __float_as_uint(v);
    unsigned rh = (u + 0x7fffu + ((u >> 16) & 1u)) & 0xffff0000u;
    float hf = __uint_as_float(rh);
    float lo = v - hf;
    unsigned ul = __float_as_uint(lo);
    unsigned rl = (ul + 0x7fffu + ((ul >> 16) & 1u)) >> 16;
    hs = (short)(rh >> 16);
    ls = (short)rl;
}

// ---------------- filter pack: symmetrized fold, fragment-major [ft][kc][lane][8] ----------------
__global__ __launch_bounds__(512)
void filt_pack_kernel(const float* __restrict__ filt, short* __restrict__ fpH,
                      short* __restrict__ fpL) {
    int blk = blockIdx.x;            // ft*33 + kc  (grid 264)
    int ft = blk / NKCF, kc = blk % NKCF;
    int t = threadIdx.x, lane = t >> 3, e = t & 7;
    int f = ft * 32 + (lane & 31);
    int tap = kc * 16 + (lane >> 5) * 8 + e;      // 0..527
    float v;
    if (tap < 512) v = 0.5f * (filt[f * KF + tap] + filt[f * KF + 1024 - tap]);
    else if (tap == 512) v = filt[f * KF + 512];
    else v = 0.f;
    short hs, ls;
    bf16split(v, hs, ls);
    fpH[blk * 512 + t] = hs;
    fpL[blk * 512 + t] = ls;
}

// ---------------- emb_w pack: fragment-major [ft][kc][lane][8], hi/lo ----------------
__global__ __launch_bounds__(512)
void wpack_kernel(const float* __restrict__ wsrc, short* __restrict__ wpH,
                  short* __restrict__ wpL) {
    int blk = blockIdx.x;            // ft*NKC + kc  (grid 8*NKC)
    int ft = blk / NKC, kc = blk % NKC;
    int t = threadIdx.x, lane = t >> 3, e = t & 7;
    int row = ft * 32 + (lane & 31);
    int tap = kc * 16 + (lane >> 5) * 8 + e;
    float v = (tap < KEMB) ? wsrc[(long)row * KEMB + tap] : 0.f;
    short hs, ls;
    bf16split(v, hs, ls);
    wpH[(long)blk * 512 + t] = hs;
    wpL[(long)blk * 512 + t] = ls;
}

// ---------------- weight transpose pack: Wt[k][f] = W[f][k] ----------------
__device__ inline void transpose_tile(const float* __restrict__ src, float* __restrict__ dst,
                                      int F, int K, int tf, int tk) {
    __shared__ float tile[32][33];
    int tx = threadIdx.x, ty = threadIdx.y;  // 32 x 8
#pragma unroll
    for (int r = 0; r < 4; r++) {
        int fi = tf * 32 + ty * 4 + r;
        tile[ty * 4 + r][tx] = src[(long)fi * K + tk * 32 + tx];
    }
    __syncthreads();
#pragma unroll
    for (int r = 0; r < 4; r++) {
        int ki = tk * 32 + ty * 4 + r;
        dst[(long)ki * F + tf * 32 + tx] = tile[tx][ty * 4 + r];
    }
}

__global__ __launch_bounds__(256)
void wtrans_kernel(const float* __restrict__ wq, const float* __restrict__ wk,
                   const float* __restrict__ wv, const float* __restrict__ wo,
                   const float* __restrict__ c1w, const float* __restrict__ c2w,
                   float* __restrict__ wqT, float* __restrict__ wkT,
                   float* __restrict__ wvT, float* __restrict__ woT,
                   float* __restrict__ c1T, float* __restrict__ c2T) {
    int bx = blockIdx.x;
    if (bx < 1024) {
        int m = bx >> 6, tile = bx & 63;
        int which = m >> 2, l = m & 3;
        int tk = tile >> 3, tf = tile & 7;
        const float* s; float* dd;
        if (which == 0) { s = wq; dd = wqT; }
        else if (which == 1) { s = wk; dd = wkT; }
        else if (which == 2) { s = wv; dd = wvT; }
        else { s = wo; dd = woT; }
        transpose_tile(s + l * 65536, dd + l * 65536, 256, 256, tf, tk);
    } else if (bx < 2048) {
        int b2 = bx - 1024, l = b2 >> 8, tile = b2 & 255;
        int tf = tile & 31, tk = tile >> 5;
        transpose_tile(c1w + (long)l * 262144, c1T + (long)l * 262144, 1024, 256, tf, tk);
    } else {
        int b2 = bx - 2048, l = b2 >> 8, tile = b2 & 255;
        int tf = tile & 7, tk = tile >> 3;
        transpose_tile(c2w + (long)l * 262144, c2T + (long)l * 262144, 256, 1024, tf, tk);
    }
}

// ---------------- SincConv via MFMA, symmetric fold (K=528), 3-pass bf16 ----------------
union ConvLDS {
    struct { float xs[CWIN2]; short uh[96][152]; short ul[96][152]; } st;
    float ebuf[96][129];
};

#define MFMA3(ACC, AH, AL, BH, BL) \
    ACC = __builtin_amdgcn_mfma_f32_32x32x16_bf16(AL, BH, ACC, 0, 0, 0); \
    ACC = __builtin_amdgcn_mfma_f32_32x32x16_bf16(AH, BL, ACC, 0, 0, 0); \
    ACC = __builtin_amdgcn_mfma_f32_32x32x16_bf16(AH, BH, ACC, 0, 0, 0);

__global__ __launch_bounds__(256, 2)
void conv_mfma_kernel(const float* __restrict__ x, const short* __restrict__ fpH,
                      const short* __restrict__ fpL, float* __restrict__ h) {
    __shared__ ConvLDS u;
    const int tid = threadIdx.x;
    const int pb = blockIdx.x;
    const int b = blockIdx.y;
    const int t0 = pb * 96;

    for (int i = tid; i < CWIN2; i += 256) {
        int gi = t0 + i;
        u.st.xs[i] = (gi < L_IN) ? x[b * L_IN + gi] : 0.f;
    }
    __syncthreads();

    const int lane = tid & 63;
    const int wid = tid >> 6;
    const int l31 = lane & 31;
    const int hi = lane >> 5;
    const int f0w = wid * 64;

    const short* bp0h = fpH + (long)(wid * 2) * FTILE + lane * 8;
    const short* bp1h = bp0h + FTILE;
    const short* bp0l = fpL + (long)(wid * 2) * FTILE + lane * 8;
    const short* bp1l = bp0l + FTILE;

    f32x16 a00 = {0}, a01 = {0}, a10 = {0}, a11 = {0}, a20 = {0}, a21 = {0};

#pragma unroll 1
    for (int ph = 0; ph < 4; ph++) {
        const int kcStart = (ph == 0) ? 0 : 8 * ph + 1;   // 0,9,17,25
        const int nkc = (ph == 0) ? 9 : 8;
        const int c0 = kcStart * 16;
        const int total = 96 * nkc * 16;

        // stage folded A-tile u[t][k] = x[t+k] + x[t+1024-k]
        int tt = tid % 96;
        int kk = tid / 96;
        for (int idx = tid; idx < total; idx += 256) {
            int kg = c0 + kk;
            float v;
            if (kg < 512) v = u.st.xs[tt + kg] + u.st.xs[tt + 1024 - kg];
            else if (kg == 512) v = u.st.xs[tt + 512];
            else v = 0.f;
            short hs, ls;
            bf16split(v, hs, ls);
            u.st.uh[tt][kk] = hs;
            u.st.ul[tt][kk] = ls;
            tt += 64; kk += 2;
            if (tt >= 96) { tt -= 96; kk += 1; }
        }
        __syncthreads();

        for (int kcl = 0; kcl < nkc; kcl++) {
            const int kloc = kcl * 16 + hi * 8;
            const int kf = (kcStart + kcl) * 512;
            s16x8 ah0 = *(const s16x8*)&u.st.uh[l31][kloc];
            s16x8 ah1 = *(const s16x8*)&u.st.uh[32 + l31][kloc];
            s16x8 ah2 = *(const s16x8*)&u.st.uh[64 + l31][kloc];
            s16x8 al0 = *(const s16x8*)&u.st.ul[l31][kloc];
            s16x8 al1 = *(const s16x8*)&u.st.ul[32 + l31][kloc];
            s16x8 al2 = *(const s16x8*)&u.st.ul[64 + l31][kloc];
            s16x8 bh0 = *(const s16x8*)(bp0h + kf);
            s16x8 bh1 = *(const s16x8*)(bp1h + kf);
            s16x8 bl0 = *(const s16x8*)(bp0l + kf);
            s16x8 bl1 = *(const s16x8*)(bp1l + kf);
            MFMA3(a00, ah0, al0, bh0, bl0)
            MFMA3(a01, ah0, al0, bh1, bl1)
            MFMA3(a10, ah1, al1, bh0, bl0)
            MFMA3(a11, ah1, al1, bh1, bl1)
            MFMA3(a20, ah2, al2, bh0, bl0)
            MFMA3(a21, ah2, al2, bh1, bl1)
        }
        __syncthreads();
    }

    const int t3l = tid & 31;
    const int t3 = pb * 32 + t3l;

#pragma unroll
    for (int half = 0; half < 2; half++) {
        if ((wid >> 1) == half) {
            int fcb = f0w - half * 128;
#define WRF(ACC, MT, NT)                                                   \
            {                                                              \
                int fc = fcb + NT * 32 + l31;                              \
                _Pragma("unroll")                                          \
                for (int r = 0; r < 16; r++) {                             \
                    int pos = MT * 32 + (r & 3) + 8 * (r >> 2) + 4 * hi;   \
                    u.ebuf[pos][fc] = fabsf(ACC[r]);                       \
                }                                                          \
            }
            WRF(a00, 0, 0) WRF(a01, 0, 1)
            WRF(a10, 1, 0) WRF(a11, 1, 1)
            WRF(a20, 2, 0) WRF(a21, 2, 1)
#undef WRF
        }
        __syncthreads();
        if (t3 < T_POOL) {
            for (int ff = tid >> 5; ff < 128; ff += 8) {
                float v = fmaxf(fmaxf(u.ebuf[3 * t3l][ff], u.ebuf[3 * t3l + 1][ff]),
                                u.ebuf[3 * t3l + 2][ff]);
                h[((long)(b * 256 + half * 128 + ff)) * T_POOL + t3] = v;
            }
        }
        __syncthreads();
    }
}

// ---------------- BatchNorm stats for h_raw: two-stage ----------------
__global__ __launch_bounds__(256)
void bn_part_kernel(const float* __restrict__ xin, float* __restrict__ p1,
                    float* __restrict__ p2) {
    __shared__ float sm[8];
    int c = blockIdx.x, s = blockIdx.y, tid = threadIdx.x;
    int t0 = s * 2687, t1 = min(T_POOL, t0 + 2687);
    float s1 = 0.f, s2 = 0.f;
    for (int b = 0; b < 4; b++) {
        const float* p = xin + (long)b * 256 * T_POOL + (long)c * T_POOL;
        for (int t = t0 + tid; t < t1; t += 256) {
            float v = p[t];
            s1 += v;
            s2 = fmaf(v, v, s2);
        }
    }
    for (int off = 32; off > 0; off >>= 1) { s1 += __shfl_down(s1, off); s2 += __shfl_down(s2, off); }
    int lane = tid & 63, wv = tid >> 6;
    if (lane == 0) { sm[wv] = s1; sm[4 + wv] = s2; }
    __syncthreads();
    if (tid == 0) {
        p1[c * 8 + s] = sm[0] + sm[1] + sm[2] + sm[3];
        p2[c * 8 + s] = sm[4] + sm[5] + sm[6] + sm[7];
    }
}

__global__ __launch_bounds__(256)
void bn_fin_kernel(const float* __restrict__ p1, const float* __restrict__ p2,
                   const float* __restrict__ g, const float* __restrict__ bb,
                   float* __restrict__ sc, float* __restrict__ sh) {
    int c = threadIdx.x;
    float S1 = 0.f, S2 = 0.f;
#pragma unroll
    for (int s = 0; s < 8; s++) { S1 += p1[c * 8 + s]; S2 += p2[c * 8 + s]; }
    float n = 4.f * (float)T_POOL;
    float mean = S1 / n;
    float var = S2 / n - mean * mean;
    float rstd = rsqrtf(var + 1e-5f);
    float gc = g[c], bc = bb[c];
    sc[c] = rstd * gc;
    sh[c] = bc - mean * rstd * gc;
}

// ---------------- BatchNorm stats (small, for e) ----------------
__global__ __launch_bounds__(256)
void bn_stats_kernel(const float* __restrict__ xin, const float* __restrict__ g,
                     const float* __restrict__ bb, float* __restrict__ sc,
                     float* __restrict__ sh, int ilen, long bstride) {
    __shared__ float sm[8];
    int c = blockIdx.x, tid = threadIdx.x;
    float s1 = 0.f, s2 = 0.f;
    for (int b = 0; b < 4; b++) {
        const float* p = xin + b * bstride + (long)c * ilen;
        for (int t = tid; t < ilen; t += 256) {
            float v = p[t];
            s1 += v;
            s2 = fmaf(v, v, s2);
        }
    }
    for (int off = 32; off > 0; off >>= 1) { s1 += __shfl_down(s1, off); s2 += __shfl_down(s2, off); }
    int lane = tid & 63, wv = tid >> 6;
    if (lane == 0) { sm[wv] = s1; sm[4 + wv] = s2; }
    __syncthreads();
    if (tid == 0) {
        float S1 = sm[0] + sm[1] + sm[2] + sm[3];
        float S2 = sm[4] + sm[5] + sm[6] + sm[7];
        float n = 4.f * (float)ilen;
        float mean = S1 / n;
        float var = S2 / n - mean * mean;
        float rstd = rsqrtf(var + 1e-5f);
        float gc = g[c], bc = bb[c];
        sc[c] = rstd * gc;
        sh[c] = bc - mean * rstd * gc;
    }
}

// ---------------- Embedding GEMM via MFMA (3-pass), split-K, packed B ----------------
__global__ __launch_bounds__(256, 2)
void embed_mfma_kernel(const float* __restrict__ H, const short* __restrict__ Wh,
                       const short* __restrict__ Wl, const float* __restrict__ sc,
                       const float* __restrict__ sh, float* __restrict__ P,
                       int kPerZ) {
    __shared__ short Ah[128][36];
    __shared__ short Al[128][36];
    const int tid = threadIdx.x;
    const int rowBase = blockIdx.x * 128;
    const int colBase = blockIdx.y * 128;
    const int z = blockIdx.z;
    const int kz = z * kPerZ;
    const int iters = kPerZ >> 5;

    const int trow = tid >> 1, th = (tid & 1) * 16;
    const int arow = rowBase + trow;
    const float asc = sc[arow & 255], ash = sh[arow & 255];
    const float* Ap = H + (long)arow * KEMB;

    const int lane = tid & 63, wid = tid >> 6;
    const int l31 = lane & 31, hi = lane >> 5;
    const int wm = wid >> 1, wn = wid & 1;

    const short* bhp[2]; const short* blp[2];
#pragma unroll
    for (int nt = 0; nt < 2; nt++) {
        int ft = (colBase >> 5) + wn * 2 + nt;
        bhp[nt] = Wh + (long)ft * NKC * 512 + lane * 8;
        blp[nt] = Wl + (long)ft * NKC * 512 + lane * 8;
    }

    f32x16 acc[2][2] = {{{0}, {0}}, {{0}, {0}}};

    for (int it = 0; it < iters; it++) {
        const int k0 = kz + it * 32;
        __syncthreads();
        float av[16];
        if (k0 + 32 <= KEMB) {
            const float4* p4 = (const float4*)(Ap + k0 + th);
#pragma unroll
            for (int q = 0; q < 4; q++) {
                float4 f = p4[q];
                av[q * 4 + 0] = f.x; av[q * 4 + 1] = f.y;
                av[q * 4 + 2] = f.z; av[q * 4 + 3] = f.w;
            }
        } else {
#pragma unroll
            for (int e = 0; e < 16; e++) {
                int k = k0 + th + e;
                av[e] = (k < KEMB) ? Ap[k] : 0.f;
            }
        }
#pragma unroll
        for (int q = 0; q < 4; q++) {
            s16x4 h4, l4;
#pragma unroll
            for (int e = 0; e < 4; e++) {
                float v = selu_f(fmaf(av[q * 4 + e], asc, ash));
                short hs, ls;
                bf16split(v, hs, ls);
                h4[e] = hs; l4[e] = ls;
            }
            *(s16x4*)&Ah[trow][th + q * 4] = h4;
            *(s16x4*)&Al[trow][th + q * 4] = l4;
        }
        __syncthreads();

#pragma unroll
        for (int ks = 0; ks < 2; ks++) {
            const int kloc = ks * 16 + hi * 8;
            const long kcg = (long)((k0 >> 4) + ks) * 512;
            s16x8 ah[2], al[2], bh[2], bl[2];
#pragma unroll
            for (int mt = 0; mt < 2; mt++) {
                const int r = wm * 64 + mt * 32 + l31;
                const short* ph = &Ah[r][kloc];
                const short* pl = &Al[r][kloc];
                union { s16x8 v; unsigned long long q[2]; } uh, ul;
                uh.q[0] = *(const unsigned long long*)(ph);
                uh.q[1] = *(const unsigned long long*)(ph + 4);
                ul.q[0] = *(const unsigned long long*)(pl);
                ul.q[1] = *(const unsigned long long*)(pl + 4);
                ah[mt] = uh.v; al[mt] = ul.v;
            }
#pragma unroll
            for (int nt = 0; nt < 2; nt++) {
                bh[nt] = *(const s16x8*)(bhp[nt] + kcg);
                bl[nt] = *(const s16x8*)(blp[nt] + kcg);
            }
#pragma unroll
            for (int mt = 0; mt < 2; mt++)
#pragma unroll
                for (int nt = 0; nt < 2; nt++) {
                    MFMA3(acc[mt][nt], ah[mt], al[mt], bh[nt], bl[nt])
                }
        }
    }

    float* Pz = P + (long)z * 262144;
#pragma unroll
    for (int mt = 0; mt < 2; mt++)
#pragma unroll
        for (int nt = 0; nt < 2; nt++) {
            int col = colBase + wn * 64 + nt * 32 + l31;
#pragma unroll
            for (int r = 0; r < 16; r++) {
                int row = rowBase + wm * 64 + mt * 32 + (r & 3) + 8 * (r >> 2) + 4 * hi;
                Pz[(long)row * 256 + col] = acc[mt][nt][r];
            }
        }
}

__global__ __launch_bounds__(256)
void embed_combine_kernel(const float* __restrict__ P, const float* __restrict__ eb,
                          float* __restrict__ e, int nsplit) {
    int idx = blockIdx.x * 256 + threadIdx.x;
    float s = 0.f;
    for (int z = 0; z < nsplit; z++) s += P[(long)z * 262144 + idx];
    e[idx] = s + eb[idx & 255];
}

// ---------------- fused zinit + layer-0 QKV (k-split, W read once/block) ----------------
__global__ __launch_bounds__(512)
void qkv_init_kernel(const float* __restrict__ e, const float* __restrict__ sc,
                     const float* __restrict__ sh,
                     const float* __restrict__ wqT0, const float* __restrict__ bq0,
                     const float* __restrict__ wkT0, const float* __restrict__ bk0,
                     const float* __restrict__ wvT0, const float* __restrict__ bv0,
                     float* __restrict__ z, float* __restrict__ qo,
                     float* __restrict__ ko, float* __restrict__ vo) {
    __shared__ float zs[4][256];
    __shared__ float pp[2][4][256];
    const int t = threadIdx.x;
    const long rowg0 = (long)blockIdx.x * 4;

    for (int idx = t; idx < 1024; idx += 512) {
        int i = idx >> 8, dd = idx & 255;
        int c = (int)((rowg0 + i) & 255);
        float v = fmaf(e[(rowg0 + i) * 256 + dd], sc[c], sh[c]);
        v = fmaxf(v, 0.f);
        int i2 = dd >> 1;
        float ang = (float)c * expf(-0.03597789207803195f * (float)(2 * i2));
        float pe = (dd & 1) ? cosf(ang) : sinf(ang);
        float zz = v + pe;
        zs[i][dd] = zz;
        z[(rowg0 + i) * 256 + dd] = zz;
    }
    __syncthreads();

    const int f = t & 255, kh = t >> 8, kb = kh * 128;
    for (int mat = 0; mat < 3; mat++) {
        const float* wt = (mat == 0 ? wqT0 : mat == 1 ? wkT0 : wvT0) + f;
        float a0 = 0.f, a1 = 0.f, a2 = 0.f, a3 = 0.f;
        for (int k4 = 0; k4 < 32; k4++) {
            int kk = kb + k4 * 4;
            float w0 = wt[(kk + 0) << 8], w1 = wt[(kk + 1) << 8];
            float w2 = wt[(kk + 2) << 8], w3 = wt[(kk + 3) << 8];
            float4 x0 = *(const float4*)&zs[0][kk];
            float4 x1 = *(const float4*)&zs[1][kk];
            float4 x2 = *(const float4*)&zs[2][kk];
            float4 x3 = *(const float4*)&zs[3][kk];
            a0 = fmaf(w0, x0.x, a0); a0 = fmaf(w1, x0.y, a0);
            a0 = fmaf(w2, x0.z, a0); a0 = fmaf(w3, x0.w, a0);
            a1 = fmaf(w0, x1.x, a1); a1 = fmaf(w1, x1.y, a1);
            a1 = fmaf(w2, x1.z, a1); a1 = fmaf(w3, x1.w, a1);
            a2 = fmaf(w0, x2.x, a2); a2 = fmaf(w1, x2.y, a2);
            a2 = fmaf(w2, x2.z, a2); a2 = fmaf(w3, x2.w, a2);
            a3 = fmaf(w0, x3.x, a3); a3 = fmaf(w1, x3.y, a3);
            a3 = fmaf(w2, x3.z, a3); a3 = fmaf(w3, x3.w, a3);
        }
        pp[kh][0][f] = a0; pp[kh][1][f] = a1; pp[kh][2][f] = a2; pp[kh][3][f] = a3;
        __syncthreads();
        {
            float bvv = (mat == 0 ? bq0 : mat == 1 ? bk0 : bv0)[f];
            float* op = (mat == 0 ? qo : mat == 1 ? ko : vo);
            int r0 = (t >> 8) * 2;
            op[(rowg0 + r0) * 256 + f] = pp[0][r0][f] + pp[1][r0][f] + bvv;
            op[(rowg0 + r0 + 1) * 256 + f] = pp[0][r0 + 1][f] + pp[1][r0 + 1][f] + bvv;
        }
        __syncthreads();
    }
}

// ---------------- fused transformer layer (k-split GEMV, W once per block) ----------------
__device__ inline void ln_reduce4(const float (*buf)[256], float (*mr)[2], int t) {
    int wid = t >> 6, lane = t & 63;
    if (wid < 4) {
        float4 v = *(const float4*)&buf[wid][lane * 4];
        float s = v.x + v.y + v.z + v.w;
        float q = v.x * v.x + v.y * v.y + v.z * v.z + v.w * v.w;
#pragma unroll
        for (int off = 32; off > 0; off >>= 1) {
            s += __shfl_xor(s, off);
            q += __shfl_xor(q, off);
        }
        if (lane == 0) {
            float mean = s * (1.f / 256.f);
            float var = q * (1.f / 256.f) - mean * mean;
            mr[wid][0] = mean;
            mr[wid][1] = rsqrtf(var + 1e-5f);
        }
    }
}

template <int LAST>
__global__ __launch_bounds__(512)
void layer_kernel(const float* __restrict__ zin, const float* __restrict__ qin,
                  const float* __restrict__ kin, const float* __restrict__ vin,
                  const float* __restrict__ woT_l, const float* __restrict__ bo_l,
                  const float* __restrict__ c1T_l, const float* __restrict__ c1b_l,
                  const float* __restrict__ c2T_l, const float* __restrict__ c2b_l,
                  const float* __restrict__ ln1g_l, const float* __restrict__ ln1b_l,
                  const float* __restrict__ ln2g_l, const float* __restrict__ ln2b_l,
                  const float* __restrict__ wqT_n, const float* __restrict__ bq_n,
                  const float* __restrict__ wkT_n, const float* __restrict__ bk_n,
                  const float* __restrict__ wvT_n, const float* __restrict__ bv_n,
                  const float* __restrict__ lnfg, const float* __restrict__ lnfb,
                  float* __restrict__ zout, float* __restrict__ qo,
                  float* __restrict__ ko, float* __restrict__ vo,
                  float* __restrict__ lnf_out) {
    __shared__ float zs[4][256];
    __shared__ float qb[4][256];
    __shared__ float ao[4][256];
    __shared__ float pp[2][4][256];
    __shared__ union { float s[4][8][256]; float y[4][1024]; } sy;
    __shared__ float mr[4][2];

    const int t = threadIdx.x;
    const int w = t >> 6, lane = t & 63;
    const long rowg0 = (long)blockIdx.x * 4;
    const int b = blockIdx.x >> 6;

    // P1: stage z (residual) and q rows
    for (int i = t; i < 1024; i += 512) {
        int r = i >> 8, dd = i & 255;
        zs[r][dd] = zin[(rowg0 + r) * 256 + dd];
        qb[r][dd] = qin[(rowg0 + r) * 256 + dd];
    }
    __syncthreads();

    // P2: scores — wave w owns head w; 8-lane groups per key row
    {
        const float scale = 0.17677669529663687f;
        const int jq = lane >> 3, li = lane & 7, d4 = li * 4;
        const float* kb = kin + (long)b * 65536 + w * 32 + d4;
        float4 q0 = *(const float4*)&qb[0][w * 32 + d4];
        float4 q1 = *(const float4*)&qb[1][w * 32 + d4];
        float4 q2 = *(const float4*)&qb[2][w * 32 + d4];
        float4 q3 = *(const float4*)&qb[3][w * 32 + d4];
        for (int jb = 0; jb < 32; jb++) {
            int j = jb * 8 + jq;
            float4 kv = *(const float4*)(kb + (long)j * 256);
            float a0 = dot4(kv, q0), a1 = dot4(kv, q1);
            float a2 = dot4(kv, q2), a3 = dot4(kv, q3);
#pragma unroll
            for (int off = 1; off < 8; off <<= 1) {
                a0 += __shfl_xor(a0, off); a1 += __shfl_xor(a1, off);
                a2 += __shfl_xor(a2, off); a3 += __shfl_xor(a3, off);
            }
            if (li < 4) sy.s[li][w][j] = sel4(a0, a1, a2, a3, li) * scale;
        }
    }
    __syncthreads();

    // P3: softmax over keys per (row, head)
    {
#pragma unroll
        for (int p = 0; p < 4; p++) {
            int pair = w * 4 + p;
            int i = pair >> 3, hh = pair & 7;
            float* row = sy.s[i][hh];
            float v0 = row[lane], v1 = row[lane + 64];
            float v2 = row[lane + 128], v3 = row[lane + 192];
            float m = fmaxf(fmaxf(v0, v1), fmaxf(v2, v3));
#pragma unroll
            for (int off = 32; off > 0; off >>= 1) m = fmaxf(m, __shfl_xor(m, off));
            float e0 = expf(v0 - m), e1 = expf(v1 - m);
            float e2 = expf(v2 - m), e3 = expf(v3 - m);
            float su = e0 + e1 + e2 + e3;
#pragma unroll
            for (int off = 32; off > 0; off >>= 1) su += __shfl_xor(su, off);
            float inv = 1.f / su;
            row[lane] = e0 * inv; row[lane + 64] = e1 * inv;
            row[lane + 128] = e2 * inv; row[lane + 192] = e3 * inv;
        }
    }
    __syncthreads();

    const int d = t & 255, half = t >> 8;
    const int f = t & 255, kh = t >> 8;

    // P4: PV (coalesced v columns, broadcast P via float4)
    {
        int hh = d >> 5;
        const float* vcol = vin + (long)b * 65536 + d;
        const float* p0 = sy.s[half * 2 + 0][hh];
        const float* p1 = sy.s[half * 2 + 1][hh];
        float a0 = 0.f, a1 = 0.f;
#pragma unroll 4
        for (int j4 = 0; j4 < 64; j4++) {
            float4 pv0 = *(const float4*)(p0 + j4 * 4);
            float4 pv1 = *(const float4*)(p1 + j4 * 4);
            float v0 = vcol[(long)(j4 * 4 + 0) * 256];
            float v1 = vcol[(long)(j4 * 4 + 1) * 256];
            float v2 = vcol[(long)(j4 * 4 + 2) * 256];
            float v3 = vcol[(long)(j4 * 4 + 3) * 256];
            a0 = fmaf(pv0.x, v0, a0); a0 = fmaf(pv0.y, v1, a0);
            a0 = fmaf(pv0.z, v2, a0); a0 = fmaf(pv0.w, v3, a0);
            a1 = fmaf(pv1.x, v0, a1); a1 = fmaf(pv1.y, v1, a1);
            a1 = fmaf(pv1.z, v2, a1); a1 = fmaf(pv1.w, v3, a1);
        }
        ao[half * 2 + 0][d] = a0;
        ao[half * 2 + 1][d] = a1;
    }
    __syncthreads();

    // P5: O-proj (k-split) + residual -> qb
    {
        const float* wt = woT_l + f;
        const int kb = kh * 128;
        float a0 = 0.f, a1 = 0.f, a2 = 0.f, a3 = 0.f;
        for (int k4 = 0; k4 < 32; k4++) {
            int kk = kb + k4 * 4;
            float w0 = wt[(kk + 0) << 8], w1 = wt[(kk + 1) << 8];
            float w2 = wt[(kk + 2) << 8], w3 = wt[(kk + 3) << 8];
            float4 x0 = *(const float4*)&ao[0][kk];
            float4 x1 = *(const float4*)&ao[1][kk];
            float4 x2 = *(const float4*)&ao[2][kk];
            float4 x3 = *(const float4*)&ao[3][kk];
            a0 = fmaf(w0, x0.x, a0); a0 = fmaf(w1, x0.y, a0);
            a0 = fmaf(w2, x0.z, a0); a0 = fmaf(w3, x0.w, a0);
            a1 = fmaf(w0, x1.x, a1); a1 = fmaf(w1, x1.y, a1);
            a1 = fmaf(w2, x1.z, a1); a1 = fmaf(w3, x1.w, a1);
            a2 = fmaf(w0, x2.x, a2); a2 = fmaf(w1, x2.y, a2);
            a2 = fmaf(w2, x2.z, a2); a2 = fmaf(w3, x2.w, a2);
            a3 = fmaf(w0, x3.x, a3); a3 = fmaf(w1, x3.y, a3);
            a3 = fmaf(w2, x3.z, a3); a3 = fmaf(w3, x3.w, a3);
        }
        pp[kh][0][f] = a0; pp[kh][1][f] = a1; pp[kh][2][f] = a2; pp[kh][3][f] = a3;
    }
    __syncthreads();
    {
        int r0 = (t >> 8) * 2;
        float bvv = bo_l[f];
        qb[r0][f] = pp[0][r0][f] + pp[1][r0][f] + bvv + zs[r0][f];
        qb[r0 + 1][f] = pp[0][r0 + 1][f] + pp[1][r0 + 1][f] + bvv + zs[r0 + 1][f];
    }
    __syncthreads();
    ln_reduce4(qb, mr, t);
    __syncthreads();
#pragma unroll
    for (int i2 = 0; i2 < 2; i2++) {
        int i = half * 2 + i2;
        zs[i][d] = (qb[i][d] - mr[i][0]) * mr[i][1] * ln1g_l[d] + ln1b_l[d];
    }
    __syncthreads();

    // P7: FFN1 + gelu -> sy.y  (thread owns f-pair, all 4 rows; c1T read once)
    {
        const int f2 = t << 1;
        const float* wt = c1T_l + f2;
        float a0 = 0.f, a1 = 0.f, a2 = 0.f, a3 = 0.f;
        float b0 = 0.f, b1 = 0.f, b2 = 0.f, b3 = 0.f;
        for (int k4 = 0; k4 < 64; k4++) {
            float4 x0 = *(const float4*)&zs[0][k4 * 4];
            float4 x1 = *(const float4*)&zs[1][k4 * 4];
            float4 x2 = *(const float4*)&zs[2][k4 * 4];
            float4 x3 = *(const float4*)&zs[3][k4 * 4];
#pragma unroll
            for (int e = 0; e < 4; e++) {
                float2 wv = *(const float2*)(wt + ((k4 * 4 + e) << 10));
                float xe0 = (e == 0) ? x0.x : (e == 1) ? x0.y : (e == 2) ? x0.z : x0.w;
                float xe1 = (e == 0) ? x1.x : (e == 1) ? x1.y : (e == 2) ? x1.z : x1.w;
                float xe2 = (e == 0) ? x2.x : (e == 1) ? x2.y : (e == 2) ? x2.z : x2.w;
                float xe3 = (e == 0) ? x3.x : (e == 1) ? x3.y : (e == 2) ? x3.z : x3.w;
                a0 = fmaf(wv.x, xe0, a0); b0 = fmaf(wv.y, xe0, b0);
                a1 = fmaf(wv.x, xe1, a1); b1 = fmaf(wv.y, xe1, b1);
                a2 = fmaf(wv.x, xe2, a2); b2 = fmaf(wv.y, xe2, b2);
                a3 = fmaf(wv.x, xe3, a3); b3 = fmaf(wv.y, xe3, b3);
            }
        }
        float c0 = c1b_l[f2], c1 = c1b_l[f2 + 1];
        sy.y[0][f2] = gelu_f(a0 + c0); sy.y[0][f2 + 1] = gelu_f(b0 + c1);
        sy.y[1][f2] = gelu_f(a1 + c0); sy.y[1][f2 + 1] = gelu_f(b1 + c1);
        sy.y[2][f2] = gelu_f(a2 + c0); sy.y[2][f2 + 1] = gelu_f(b2 + c1);
        sy.y[3][f2] = gelu_f(a3 + c0); sy.y[3][f2 + 1] = gelu_f(b3 + c1);
    }
    __syncthreads();

    // P8: FFN2 (k-split, c2T read once) + residual -> qb
    {
        const float* wt = c2T_l + f;
        const int kb = kh * 512;
        float a0 = 0.f, a1 = 0.f, a2 = 0.f, a3 = 0.f;
        for (int k4 = 0; k4 < 128; k4++) {
            int kk = kb + k4 * 4;
            float w0 = wt[(kk + 0) << 8], w1 = wt[(kk + 1) << 8];
            float w2 = wt[(kk + 2) << 8], w3 = wt[(kk + 3) << 8];
            float4 y0 = *(const float4*)&sy.y[0][kk];
            float4 y1 = *(const float4*)&sy.y[1][kk];
            float4 y2 = *(const float4*)&sy.y[2][kk];
            float4 y3 = *(const float4*)&sy.y[3][kk];
            a0 = fmaf(w0, y0.x, a0); a0 = fmaf(w1, y0.y, a0);
            a0 = fmaf(w2, y0.z, a0); a0 = fmaf(w3, y0.w, a0);
            a1 = fmaf(w0, y1.x, a1); a1 = fmaf(w1, y1.y, a1);
            a1 = fmaf(w2, y1.z, a1); a1 = fmaf(w3, y1.w, a1);
            a2 = fmaf(w0, y2.x, a2); a2 = fmaf(w1, y2.y, a2);
            a2 = fmaf(w2, y2.z, a2); a2 = fmaf(w3, y2.w, a2);
            a3 = fmaf(w0, y3.x, a3); a3 = fmaf(w1, y3.y, a3);
            a3 = fmaf(w2, y3.z, a3); a3 = fmaf(w3, y3.w, a3);
        }
        pp[kh][0][f] = a0; pp[kh][1][f] = a1; pp[kh][2][f] = a2; pp[kh][3][f] = a3;
    }
    __syncthreads();
    {
        int r0 = (t >> 8) * 2;
        float bvv = c2b_l[f];
        qb[r0][f] = pp[0][r0][f] + pp[1][r0][f] + bvv + zs[r0][f];
        qb[r0 + 1][f] = pp[0][r0 + 1][f] + pp[1][r0 + 1][f] + bvv + zs[r0 + 1][f];
    }
    __syncthreads();
    ln_reduce4(qb, mr, t);
    __syncthreads();
#pragma unroll
    for (int i2 = 0; i2 < 2; i2++) {
        int i = half * 2 + i2;
        float z2 = (qb[i][d] - mr[i][0]) * mr[i][1] * ln2g_l[d] + ln2b_l[d];
        zs[i][d] = z2;
        zout[(rowg0 + i) * 256 + d] = z2;
    }
    __syncthreads();

    if (!LAST) {
        // P9: QKV projections for next layer (k-split, each W read once)
        const int kb = kh * 128;
        for (int mat = 0; mat < 3; mat++) {
            const float* wt = (mat == 0 ? wqT_n : mat == 1 ? wkT_n : wvT_n) + f;
            float a0 = 0.f, a1 = 0.f, a2 = 0.f, a3 = 0.f;
            for (int k4 = 0; k4 < 32; k4++) {
                int kk = kb + k4 * 4;
                float w0 = wt[(kk + 0) << 8], w1 = wt[(kk + 1) << 8];
                float w2 = wt[(kk + 2) << 8], w3 = wt[(kk + 3) << 8];
                float4 x0 = *(const float4*)&zs[0][kk];
                float4 x1 = *(const float4*)&zs[1][kk];
                float4 x2 = *(const float4*)&zs[2][kk];
                float4 x3 = *(const float4*)&zs[3][kk];
                a0 = fmaf(w0, x0.x, a0); a0 = fmaf(w1, x0.y, a0);
                a0 = fmaf(w2, x0.z, a0); a0 = fmaf(w3, x0.w, a0);
                a1 = fmaf(w0, x1.x, a1); a1 = fmaf(w1, x1.y, a1);
                a1 = fmaf(w2, x1.z, a1); a1 = fmaf(w3, x1.w, a1);
                a2 = fmaf(w0, x2.x, a2); a2 = fmaf(w1, x2.y, a2);
                a2 = fmaf(w2, x2.z, a2); a2 = fmaf(w3, x2.w, a2);
                a3 = fmaf(w0, x3.x, a3); a3 = fmaf(w1, x3.y, a3);
                a3 = fmaf(w2, x3.z, a3); a3 = fmaf(w3, x3.w, a3);
            }
            pp[kh][0][f] = a0; pp[kh][1][f] = a1; pp[kh][2][f] = a2; pp[kh][3][f] = a3;
            __syncthreads();
            {
                float bvv = (mat == 0 ? bq_n : mat == 1 ? bk_n : bv_n)[f];
                float* op = (mat == 0 ? qo : mat == 1 ? ko : vo);
                int r0 = (t >> 8) * 2;
                op[(rowg0 + r0) * 256 + f] = pp[0][r0][f] + pp[1][r0][f] + bvv;
                op[(rowg0 + r0 + 1) * 256 + f] = pp[0][r0 + 1][f] + pp[1][r0 + 1][f] + bvv;
            }
            __syncthreads();
        }
    } else {
        ln_reduce4(zs, mr, t);
        __syncthreads();
#pragma unroll
        for (int i2 = 0; i2 < 2; i2++) {
            int i = half * 2 + i2;
            lnf_out[(rowg0 + i) * 256 + d] =
                (zs[i][d] - mr[i][0]) * mr[i][1] * lnfg[d] + lnfb[d];
        }
    }
}

// ---------------- final: pooled mean over seq -> proj ----------------
__global__ __launch_bounds__(256)
void final_kernel(const float* __restrict__ zf, const float* __restrict__ pw,
                  const float* __restrict__ pb, float* __restrict__ out) {
    __shared__ float sm[8];
    int b = blockIdx.x, d = threadIdx.x;
    float s = 0.f;
    for (int c = 0; c < 256; c++) s += zf[((long)(b * 256 + c)) * 256 + d];
    float pooled = s * (1.f / 256.f);
    float c0 = pooled * pw[d], c1 = pooled * pw[256 + d];
    for (int off = 32; off > 0; off >>= 1) { c0 += __shfl_down(c0, off); c1 += __shfl_down(c1, off); }
    int lane = d & 63, wv = d >> 6;
    if (lane == 0) { sm[wv] = c0; sm[4 + wv] = c1; }
    __syncthreads();
    if (d == 0) {
        out[b * 2 + 0] = sm[0] + sm[1] + sm[2] + sm[3] + pb[0];
        out[b * 2 + 1] = sm[4] + sm[5] + sm[6] + sm[7] + pb[1];
    }
}

extern "C" void kernel_launch(void* const* d_in, const int* in_sizes, int n_in,
                              void* d_out, int out_size, void* d_ws, size_t ws_size,
                              hipStream_t stream) {
    const float* x       = (const float*)d_in[0];
    const float* filters = (const float*)d_in[1];
    const float* bn1_g   = (const float*)d_in[2];
    const float* bn1_b   = (const float*)d_in[3];
    const float* emb_w   = (const float*)d_in[4];
    const float* emb_b   = (const float*)d_in[5];
    const float* embbn_g = (const float*)d_in[6];
    const float* embbn_b = (const float*)d_in[7];
    const float* wq      = (const float*)d_in[8];
    const float* bq      = (const float*)d_in[9];
    const float* wk      = (const float*)d_in[10];
    const float* bk      = (const float*)d_in[11];
    const float* wv      = (const float*)d_in[12];
    const float* bv      = (const float*)d_in[13];
    const float* wo      = (const float*)d_in[14];
    const float* bo      = (const float*)d_in[15];
    const float* c1w     = (const float*)d_in[16];
    const float* c1b     = (const float*)d_in[17];
    const float* c2w     = (const float*)d_in[18];
    const float* c2b     = (const float*)d_in[19];
    const float* ln1g    = (const float*)d_in[20];
    const float* ln1b    = (const float*)d_in[21];
    const float* ln2g    = (const float*)d_in[22];
    const float* ln2b    = (const float*)d_in[23];
    const float* lnfg    = (const float*)d_in[24];
    const float* lnfb    = (const float*)d_in[25];
    const float* projw   = (const float*)d_in[26];
    const float* projb   = (const float*)d_in[27];

    const long wpackF = 5505024L;                   // 2 * 8*NKC*512 shorts, in floats
    const long wTF = 3145728L;                      // transposed layer weights
    const long fixedF = 22005760L + 5120 + wpackF + 9L * 262144 + wTF;
    long wsFloats = (long)(ws_size / 4);
    long Z = 32;
    while (Z > 8 && fixedF + Z * 262144L > wsFloats) Z >>= 1;
    const int kPerZ = KEMBP / (int)Z;

    float* ws = (float*)d_ws;
    float* h_raw  = ws;                             // 22,005,760
    float* bn1_sc = h_raw + 22005760;
    float* bn1_sh = bn1_sc + 256;
    float* e_sc   = bn1_sh + 256;
    float* e_sh   = e_sc + 256;
    float* bnp1   = e_sh + 256;                     // 2048
    float* bnp2   = bnp1 + 2048;                    // 2048
    float* part   = bnp2 + 2048;                    // Z * 262144
    float* wsp    = part + Z * 262144L;
    short* wpH    = (short*)wsp;                    // 8*NKC*512 shorts
    short* wpL    = wpH + 8L * NKC * 512;
    float* e      = wsp + wpackF;
    float* z      = e + 262144;
    float* qA     = z + 262144;
    float* kA     = qA + 262144;
    float* vA     = kA + 262144;
    float* qB     = vA + 262144;
    float* kB     = qB + 262144;
    float* vB     = kB + 262144;
    float* t1     = vB + 262144;
    float* wqT    = t1 + 262144;                    // 4*65536
    float* wkT    = wqT + 262144;
    float* wvT    = wkT + 262144;
    float* woT    = wvT + 262144;
    float* c1T    = woT + 262144;                   // 4*262144
    float* c2T    = c1T + 1048576;

    // conv packed filters alias onto `part` (only used before embed writes part)
    short* fpH = (short*)part;                      // 264*512 shorts
    short* fpL = fpH + 264 * 512;

    filt_pack_kernel<<<8 * NKCF, 512, 0, stream>>>(filters, fpH, fpL);
    wpack_kernel<<<8 * NKC, 512, 0, stream>>>(emb_w, wpH, wpL);
    wtrans_kernel<<<3072, dim3(32, 8), 0, stream>>>(wq, wk, wv, wo, c1w, c2w,
                                                    wqT, wkT, wvT, woT, c1T, c2T);
    conv_mfma_kernel<<<dim3(672, 4), 256, 0, stream>>>(x, fpH, fpL, h_raw);
    bn_part_kernel<<<dim3(256, 8), 256, 0, stream>>>(h_raw, bnp1, bnp2);
    bn_fin_kernel<<<1, 256, 0, stream>>>(bnp1, bnp2, bn1_g, bn1_b, bn1_sc, bn1_sh);
    embed_mfma_kernel<<<dim3(8, 2, (int)Z), 256, 0, stream>>>(h_raw, wpH, wpL,
                                                              bn1_sc, bn1_sh, part, kPerZ);
    embed_combine_kernel<<<1024, 256, 0, stream>>>(part, emb_b, e, (int)Z);
    bn_stats_kernel<<<256, 256, 0, stream>>>(e, embbn_g, embbn_b, e_sc, e_sh,
                                             256, 256L * 256);
    qkv_init_kernel<<<256, 512, 0, stream>>>(e, e_sc, e_sh, wqT, bq, wkT, bk, wvT, bv,
                                             z, qA, kA, vA);

    float* qs[2][3] = {{qA, kA, vA}, {qB, kB, vB}};
    for (int l = 0; l < 4; l++) {
        float** in = qs[l & 1];
        float** ou = qs[(l + 1) & 1];
        const float* woT_l = woT + (long)l * 65536; const float* bo_l = bo + l * 256;
        const float* c1T_l = c1T + (long)l * 262144; const float* c1b_l = c1b + l * 1024;
        const float* c2T_l = c2T + (long)l * 262144; const float* c2b_l = c2b + l * 256;
        const float* l1g = ln1g + l * 256; const float* l1b = ln1b + l * 256;
        const float* l2g = ln2g + l * 256; const float* l2b = ln2b + l * 256;
        if (l < 3) {
            const float* wqT_n = wqT + (long)(l + 1) * 65536; const float* bq_n = bq + (l + 1) * 256;
            const float* wkT_n = wkT + (long)(l + 1) * 65536; const float* bk_n = bk + (l + 1) * 256;
            const float* wvT_n = wvT + (long)(l + 1) * 65536; const float* bv_n = bv + (l + 1) * 256;
            layer_kernel<0><<<256, 512, 0, stream>>>(z, in[0], in[1], in[2],
                woT_l, bo_l, c1T_l, c1b_l, c2T_l, c2b_l, l1g, l1b, l2g, l2b,
                wqT_n, bq_n, wkT_n, bk_n, wvT_n, bv_n, lnfg, lnfb,
                z, ou[0], ou[1], ou[2], t1);
        } else {
            layer_kernel<1><<<256, 512, 0, stream>>>(z, in[0], in[1], in[2],
                woT_l, bo_l, c1T_l, c1b_l, c2T_l, c2b_l, l1g, l1b, l2g, l2b,
                wqT, bq, wkT, bk, wvT, bv, lnfg, lnfb,
                z, ou[0], ou[1], ou[2], t1);
        }
    }

    final_kernel<<<4, 256, 0, stream>>>(t1, projw, projb, (float*)d_out);
}

// Round 7
// 827.056 us; speedup vs baseline: 4.5493x; 1.1665x over previous
//
#include <hip/hip_runtime.h>
#include <math.h>

#define L_IN 65494
#define T_POOL 21490
#define KF 1025
#define RS 1144            // conv replica row stride (elements)
#define CWIN 1136          // conv x window per block: 96 + 1040
#define KEMB 21490
#define KEMBP 21504        // padded
#define NKC 1344           // KEMBP/16
#define FTILE 33280        // 65*512 shorts per conv filter tile

typedef short s16x4 __attribute__((ext_vector_type(4)));
typedef short s16x8 __attribute__((ext_vector_type(8)));
typedef float f32x16 __attribute__((ext_vector_type(16)));

__device__ inline float selu_f(float x) {
    float e = expf(fminf(x, 0.f));
    float neg = 1.6732632423543772f * (e - 1.f);
    return 1.0507009873554805f * (x > 0.f ? x : neg);
}

__device__ inline float gelu_f(float x) {
    return 0.5f * x * (1.f + erff(x * 0.7071067811865476f));
}

__device__ inline float dot4(float4 a, float4 b) {
    return fmaf(a.x, b.x, fmaf(a.y, b.y, fmaf(a.z, b.z, a.w * b.w)));
}

__device__ inline float sel4(float a0, float a1, float a2, float a3, int i) {
    float r = a0;
    r = (i == 1) ? a1 : r;
    r = (i == 2) ? a2 : r;
    r = (i == 3) ? a3 : r;
    return r;
}

__device__ inline void bf16split(float v, short& hs, short& ls) {
    unsigned u = __float_as_uint(v);
    unsigned rh = (u + 0x7fffu + ((u >> 16) & 1u)) & 0xffff0000u;
    float hf = __uint_as_float(rh);
    float lo = v - hf;
    unsigned ul = __float_as_uint(lo);
    unsigned rl = (ul + 0x7fffu + ((ul >> 16) & 1u)) >> 16;
    hs = (short)(rh >> 16);
    ls = (short)rl;
}

// ---------------- filter pack: fragment-major [ft][kc][lane][8], hi/lo (K=1040) ----------------
__global__ __launch_bounds__(512)
void filt_pack_kernel(const float* __restrict__ filt, short* __restrict__ fpH,
                      short* __restrict__ fpL) {
    int blk = blockIdx.x;            // ft*65 + kc  (grid 520)
    int ft = blk / 65, kc = blk % 65;
    int t = threadIdx.x, lane = t >> 3, e = t & 7;
    int f = ft * 32 + (lane & 31);
    int tap = kc * 16 + (lane >> 5) * 8 + e;
    float v = (tap < KF) ? filt[f * KF + tap] : 0.f;
    short hs, ls;
    bf16split(v, hs, ls);
    fpH[blk * 512 + t] = hs;
    fpL[blk * 512 + t] = ls;
}

// ---------------- emb_w pack: fragment-major [ft][kc][lane][8], hi/lo ----------------
__global__ __launch_bounds__(512)
void wpack_kernel(const float* __restrict__ wsrc, short* __restrict__ wpH,
                  short* __restrict__ wpL) {
    int blk = blockIdx.x;            // ft*NKC + kc  (grid 8*NKC)
    int ft = blk / NKC, kc = blk % NKC;
    int t = threadIdx.x, lane = t >> 3, e = t & 7;
    int row = ft * 32 + (lane & 31);
    int tap = kc * 16 + (lane >> 5) * 8 + e;
    float v = (tap < KEMB) ? wsrc[(long)row * KEMB + tap] : 0.f;
    short hs, ls;
    bf16split(v, hs, ls);
    wpH[(long)blk * 512 + t] = hs;
    wpL[(long)blk * 512 + t] = ls;
}

// ---------------- weight transpose pack: Wt[k][f] = W[f][k] ----------------
__device__ inline void transpose_tile(const float* __restrict__ src, float* __restrict__ dst,
                                      int F, int K, int tf, int tk) {
    __shared__ float tile[32][33];
    int tx = threadIdx.x, ty = threadIdx.y;  // 32 x 8
#pragma unroll
    for (int r = 0; r < 4; r++) {
        int fi = tf * 32 + ty * 4 + r;
        tile[ty * 4 + r][tx] = src[(long)fi * K + tk * 32 + tx];
    }
    __syncthreads();
#pragma unroll
    for (int r = 0; r < 4; r++) {
        int ki = tk * 32 + ty * 4 + r;
        dst[(long)ki * F + tf * 32 + tx] = tile[tx][ty * 4 + r];
    }
}

__global__ __launch_bounds__(256)
void wtrans_kernel(const float* __restrict__ wq, const float* __restrict__ wk,
                   const float* __restrict__ wv, const float* __restrict__ wo,
                   const float* __restrict__ c1w, const float* __restrict__ c2w,
                   float* __restrict__ wqT, float* __restrict__ wkT,
                   float* __restrict__ wvT, float* __restrict__ woT,
                   float* __restrict__ c1T, float* __restrict__ c2T) {
    int bx = blockIdx.x;
    if (bx < 1024) {
        int m = bx >> 6, tile = bx & 63;
        int which = m >> 2, l = m & 3;
        int tk = tile >> 3, tf = tile & 7;
        const float* s; float* dd;
        if (which == 0) { s = wq; dd = wqT; }
        else if (which == 1) { s = wk; dd = wkT; }
        else if (which == 2) { s = wv; dd = wvT; }
        else { s = wo; dd = woT; }
        transpose_tile(s + l * 65536, dd + l * 65536, 256, 256, tf, tk);
    } else if (bx < 2048) {
        int b2 = bx - 1024, l = b2 >> 8, tile = b2 & 255;
        int tf = tile & 31, tk = tile >> 5;
        transpose_tile(c1w + (long)l * 262144, c1T + (long)l * 262144, 1024, 256, tf, tk);
    } else {
        int b2 = bx - 2048, l = b2 >> 8, tile = b2 & 255;
        int tf = tile & 7, tk = tile >> 3;
        transpose_tile(c2w + (long)l * 262144, c2T + (long)l * 262144, 256, 1024, tf, tk);
    }
}

// ---------------- SincConv via MFMA (3-pass bf16 hi/lo) + |.| + maxpool3 ----------------
// round-4 structure: 8-way shifted replicas, packed filter fragments.
union ConvLDS {
    struct { short xh[8][RS]; short xl[8][RS]; } st;
    float ebuf[96][129];
};

#define MFMA3(ACC, AH, AL, BH, BL) \
    ACC = __builtin_amdgcn_mfma_f32_32x32x16_bf16(AL, BH, ACC, 0, 0, 0); \
    ACC = __builtin_amdgcn_mfma_f32_32x32x16_bf16(AH, BL, ACC, 0, 0, 0); \
    ACC = __builtin_amdgcn_mfma_f32_32x32x16_bf16(AH, BH, ACC, 0, 0, 0);

__global__ __launch_bounds__(256, 2)
void conv_mfma_kernel(const float* __restrict__ x, const short* __restrict__ fpH,
                      const short* __restrict__ fpL, float* __restrict__ h) {
    __shared__ ConvLDS u;
    const int tid = threadIdx.x;
    const int pb = blockIdx.x;
    const int b = blockIdx.y;
    const int t0 = pb * 96;

    for (int i = tid; i < CWIN; i += 256) {
        int gi = t0 + i;
        float v = (gi < L_IN) ? x[b * L_IN + gi] : 0.f;
        short hs, ls;
        bf16split(v, hs, ls);
#pragma unroll
        for (int s = 0; s < 8; s++) {
            int e = i - s;
            if (e >= 0) { u.st.xh[s][e] = hs; u.st.xl[s][e] = ls; }
        }
    }
    __syncthreads();

    const int lane = tid & 63;
    const int wid = tid >> 6;
    const int l31 = lane & 31;
    const int hi = lane >> 5;
    const int f0w = wid * 64;

    const short* aH = &u.st.xh[l31 & 7][8 * (l31 >> 3) + 8 * hi];
    const short* aL = &u.st.xl[l31 & 7][8 * (l31 >> 3) + 8 * hi];
    const short* bp0h = fpH + (long)(wid * 2) * FTILE + lane * 8;
    const short* bp1h = bp0h + FTILE;
    const short* bp0l = fpL + (long)(wid * 2) * FTILE + lane * 8;
    const short* bp1l = bp0l + FTILE;

    f32x16 a00 = {0}, a01 = {0}, a10 = {0}, a11 = {0}, a20 = {0}, a21 = {0};

#pragma unroll 1
    for (int kc = 0; kc < 65; kc++) {
        const int ko = kc * 16;
        const int kf = kc * 512;
        s16x8 ah0 = *(const s16x8*)(aH + ko);
        s16x8 ah1 = *(const s16x8*)(aH + ko + 32);
        s16x8 ah2 = *(const s16x8*)(aH + ko + 64);
        s16x8 al0 = *(const s16x8*)(aL + ko);
        s16x8 al1 = *(const s16x8*)(aL + ko + 32);
        s16x8 al2 = *(const s16x8*)(aL + ko + 64);
        s16x8 bh0 = *(const s16x8*)(bp0h + kf);
        s16x8 bh1 = *(const s16x8*)(bp1h + kf);
        s16x8 bl0 = *(const s16x8*)(bp0l + kf);
        s16x8 bl1 = *(const s16x8*)(bp1l + kf);
        MFMA3(a00, ah0, al0, bh0, bl0)
        MFMA3(a01, ah0, al0, bh1, bl1)
        MFMA3(a10, ah1, al1, bh0, bl0)
        MFMA3(a11, ah1, al1, bh1, bl1)
        MFMA3(a20, ah2, al2, bh0, bl0)
        MFMA3(a21, ah2, al2, bh1, bl1)
    }

    __syncthreads();
    const int t3l = tid & 31;
    const int t3 = pb * 32 + t3l;

#pragma unroll
    for (int half = 0; half < 2; half++) {
        if ((wid >> 1) == half) {
            int fcb = f0w - half * 128;
#define WRF(ACC, MT, NT)                                                   \
            {                                                              \
                int fc = fcb + NT * 32 + l31;                              \
                _Pragma("unroll")                                          \
                for (int r = 0; r < 16; r++) {                             \
                    int pos = MT * 32 + (r & 3) + 8 * (r >> 2) + 4 * hi;   \
                    u.ebuf[pos][fc] = fabsf(ACC[r]);                       \
                }                                                          \
            }
            WRF(a00, 0, 0) WRF(a01, 0, 1)
            WRF(a10, 1, 0) WRF(a11, 1, 1)
            WRF(a20, 2, 0) WRF(a21, 2, 1)
#undef WRF
        }
        __syncthreads();
        if (t3 < T_POOL) {
            for (int ff = tid >> 5; ff < 128; ff += 8) {
                float v = fmaxf(fmaxf(u.ebuf[3 * t3l][ff], u.ebuf[3 * t3l + 1][ff]),
                                u.ebuf[3 * t3l + 2][ff]);
                h[((long)(b * 256 + half * 128 + ff)) * T_POOL + t3] = v;
            }
        }
        __syncthreads();
    }
}

// ---------------- BatchNorm stats for h_raw: two-stage ----------------
__global__ __launch_bounds__(256)
void bn_part_kernel(const float* __restrict__ xin, float* __restrict__ p1,
                    float* __restrict__ p2) {
    __shared__ float sm[8];
    int c = blockIdx.x, s = blockIdx.y, tid = threadIdx.x;
    int t0 = s * 2687, t1 = min(T_POOL, t0 + 2687);
    float s1 = 0.f, s2 = 0.f;
    for (int b = 0; b < 4; b++) {
        const float* p = xin + (long)b * 256 * T_POOL + (long)c * T_POOL;
        for (int t = t0 + tid; t < t1; t += 256) {
            float v = p[t];
            s1 += v;
            s2 = fmaf(v, v, s2);
        }
    }
    for (int off = 32; off > 0; off >>= 1) { s1 += __shfl_down(s1, off); s2 += __shfl_down(s2, off); }
    int lane = tid & 63, wv = tid >> 6;
    if (lane == 0) { sm[wv] = s1; sm[4 + wv] = s2; }
    __syncthreads();
    if (tid == 0) {
        p1[c * 8 + s] = sm[0] + sm[1] + sm[2] + sm[3];
        p2[c * 8 + s] = sm[4] + sm[5] + sm[6] + sm[7];
    }
}

__global__ __launch_bounds__(256)
void bn_fin_kernel(const float* __restrict__ p1, const float* __restrict__ p2,
                   const float* __restrict__ g, const float* __restrict__ bb,
                   float* __restrict__ sc, float* __restrict__ sh) {
    int c = threadIdx.x;
    float S1 = 0.f, S2 = 0.f;
#pragma unroll
    for (int s = 0; s < 8; s++) { S1 += p1[c * 8 + s]; S2 += p2[c * 8 + s]; }
    float n = 4.f * (float)T_POOL;
    float mean = S1 / n;
    float var = S2 / n - mean * mean;
    float rstd = rsqrtf(var + 1e-5f);
    float gc = g[c], bc = bb[c];
    sc[c] = rstd * gc;
    sh[c] = bc - mean * rstd * gc;
}

// ---------------- BatchNorm stats (small, for e) ----------------
__global__ __launch_bounds__(256)
void bn_stats_kernel(const float* __restrict__ xin, const float* __restrict__ g,
                     const float* __restrict__ bb, float* __restrict__ sc,
                     float* __restrict__ sh, int ilen, long bstride) {
    __shared__ float sm[8];
    int c = blockIdx.x, tid = threadIdx.x;
    float s1 = 0.f, s2 = 0.f;
    for (int b = 0; b < 4; b++) {
        const float* p = xin + b * bstride + (long)c * ilen;
        for (int t = tid; t < ilen; t += 256) {
            float v = p[t];
            s1 += v;
            s2 = fmaf(v, v, s2);
        }
    }
    for (int off = 32; off > 0; off >>= 1) { s1 += __shfl_down(s1, off); s2 += __shfl_down(s2, off); }
    int lane = tid & 63, wv = tid >> 6;
    if (lane == 0) { sm[wv] = s1; sm[4 + wv] = s2; }
    __syncthreads();
    if (tid == 0) {
        float S1 = sm[0] + sm[1] + sm[2] + sm[3];
        float S2 = sm[4] + sm[5] + sm[6] + sm[7];
        float n = 4.f * (float)ilen;
        float mean = S1 / n;
        float var = S2 / n - mean * mean;
        float rstd = rsqrtf(var + 1e-5f);
        float gc = g[c], bc = bb[c];
        sc[c] = rstd * gc;
        sh[c] = bc - mean * rstd * gc;
    }
}

// ---------------- Embedding GEMM via MFMA (3-pass), split-K, packed B ----------------
__global__ __launch_bounds__(256, 2)
void embed_mfma_kernel(const float* __restrict__ H, const short* __restrict__ Wh,
                       const short* __restrict__ Wl, const float* __restrict__ sc,
                       const float* __restrict__ sh, float* __restrict__ P,
                       int kPerZ) {
    __shared__ short Ah[128][36];
    __shared__ short Al[128][36];
    const int tid = threadIdx.x;
    const int rowBase = blockIdx.x * 128;
    const int colBase = blockIdx.y * 128;
    const int z = blockIdx.z;
    const int kz = z * kPerZ;
    const int iters = kPerZ >> 5;

    const int trow = tid >> 1, th = (tid & 1) * 16;
    const int arow = rowBase + trow;
    const float asc = sc[arow & 255], ash = sh[arow & 255];
    const float* Ap = H + (long)arow * KEMB;

    const int lane = tid & 63, wid = tid >> 6;
    const int l31 = lane & 31, hi = lane >> 5;
    const int wm = wid >> 1, wn = wid & 1;

    const short* bhp[2]; const short* blp[2];
#pragma unroll
    for (int nt = 0; nt < 2; nt++) {
        int ft = (colBase >> 5) + wn * 2 + nt;
        bhp[nt] = Wh + (long)ft * NKC * 512 + lane * 8;
        blp[nt] = Wl + (long)ft * NKC * 512 + lane * 8;
    }

    f32x16 acc[2][2] = {{{0}, {0}}, {{0}, {0}}};

    for (int it = 0; it < iters; it++) {
        const int k0 = kz + it * 32;
        __syncthreads();
        float av[16];
        if (k0 + 32 <= KEMB) {
            const float4* p4 = (const float4*)(Ap + k0 + th);
#pragma unroll
            for (int q = 0; q < 4; q++) {
                float4 f = p4[q];
                av[q * 4 + 0] = f.x; av[q * 4 + 1] = f.y;
                av[q * 4 + 2] = f.z; av[q * 4 + 3] = f.w;
            }
        } else {
#pragma unroll
            for (int e = 0; e < 16; e++) {
                int k = k0 + th + e;
                av[e] = (k < KEMB) ? Ap[k] : 0.f;
            }
        }
#pragma unroll
        for (int q = 0; q < 4; q++) {
            s16x4 h4, l4;
#pragma unroll
            for (int e = 0; e < 4; e++) {
                float v = selu_f(fmaf(av[q * 4 + e], asc, ash));
                short hs, ls;
                bf16split(v, hs, ls);
                h4[e] = hs; l4[e] = ls;
            }
            *(s16x4*)&Ah[trow][th + q * 4] = h4;
            *(s16x4*)&Al[trow][th + q * 4] = l4;
        }
        __syncthreads();

#pragma unroll
        for (int ks = 0; ks < 2; ks++) {
            const int kloc = ks * 16 + hi * 8;
            const long kcg = (long)((k0 >> 4) + ks) * 512;
            s16x8 ah[2], al[2], bh[2], bl[2];
#pragma unroll
            for (int mt = 0; mt < 2; mt++) {
                const int r = wm * 64 + mt * 32 + l31;
                const short* ph = &Ah[r][kloc];
                const short* pl = &Al[r][kloc];
                union { s16x8 v; unsigned long long q[2]; } uh, ul;
                uh.q[0] = *(const unsigned long long*)(ph);
                uh.q[1] = *(const unsigned long long*)(ph + 4);
                ul.q[0] = *(const unsigned long long*)(pl);
                ul.q[1] = *(const unsigned long long*)(pl + 4);
                ah[mt] = uh.v; al[mt] = ul.v;
            }
#pragma unroll
            for (int nt = 0; nt < 2; nt++) {
                bh[nt] = *(const s16x8*)(bhp[nt] + kcg);
                bl[nt] = *(const s16x8*)(blp[nt] + kcg);
            }
#pragma unroll
            for (int mt = 0; mt < 2; mt++)
#pragma unroll
                for (int nt = 0; nt < 2; nt++) {
                    MFMA3(acc[mt][nt], ah[mt], al[mt], bh[nt], bl[nt])
                }
        }
    }

    float* Pz = P + (long)z * 262144;
#pragma unroll
    for (int mt = 0; mt < 2; mt++)
#pragma unroll
        for (int nt = 0; nt < 2; nt++) {
            int col = colBase + wn * 64 + nt * 32 + l31;
#pragma unroll
            for (int r = 0; r < 16; r++) {
                int row = rowBase + wm * 64 + mt * 32 + (r & 3) + 8 * (r >> 2) + 4 * hi;
                Pz[(long)row * 256 + col] = acc[mt][nt][r];
            }
        }
}

__global__ __launch_bounds__(256)
void embed_combine_kernel(const float* __restrict__ P, const float* __restrict__ eb,
                          float* __restrict__ e, int nsplit) {
    int idx = blockIdx.x * 256 + threadIdx.x;
    float s = 0.f;
    for (int z = 0; z < nsplit; z++) s += P[(long)z * 262144 + idx];
    e[idx] = s + eb[idx & 255];
}

// ---------------- fused zinit + layer-0 QKV (k-split, W read once/block) ----------------
__global__ __launch_bounds__(512)
void qkv_init_kernel(const float* __restrict__ e, const float* __restrict__ sc,
                     const float* __restrict__ sh,
                     const float* __restrict__ wqT0, const float* __restrict__ bq0,
                     const float* __restrict__ wkT0, const float* __restrict__ bk0,
                     const float* __restrict__ wvT0, const float* __restrict__ bv0,
                     float* __restrict__ z, float* __restrict__ qo,
                     float* __restrict__ ko, float* __restrict__ vo) {
    __shared__ float zs[4][256];
    __shared__ float pp[2][4][256];
    const int t = threadIdx.x;
    const long rowg0 = (long)blockIdx.x * 4;

    for (int idx = t; idx < 1024; idx += 512) {
        int i = idx >> 8, dd = idx & 255;
        int c = (int)((rowg0 + i) & 255);
        float v = fmaf(e[(rowg0 + i) * 256 + dd], sc[c], sh[c]);
        v = fmaxf(v, 0.f);
        int i2 = dd >> 1;
        float ang = (float)c * expf(-0.03597789207803195f * (float)(2 * i2));
        float pe = (dd & 1) ? cosf(ang) : sinf(ang);
        float zz = v + pe;
        zs[i][dd] = zz;
        z[(rowg0 + i) * 256 + dd] = zz;
    }
    __syncthreads();

    const int f = t & 255, kh = t >> 8, kb = kh * 128;
    for (int mat = 0; mat < 3; mat++) {
        const float* wt = (mat == 0 ? wqT0 : mat == 1 ? wkT0 : wvT0) + f;
        float a0 = 0.f, a1 = 0.f, a2 = 0.f, a3 = 0.f;
        for (int k4 = 0; k4 < 32; k4++) {
            int kk = kb + k4 * 4;
            float w0 = wt[(kk + 0) << 8], w1 = wt[(kk + 1) << 8];
            float w2 = wt[(kk + 2) << 8], w3 = wt[(kk + 3) << 8];
            float4 x0 = *(const float4*)&zs[0][kk];
            float4 x1 = *(const float4*)&zs[1][kk];
            float4 x2 = *(const float4*)&zs[2][kk];
            float4 x3 = *(const float4*)&zs[3][kk];
            a0 = fmaf(w0, x0.x, a0); a0 = fmaf(w1, x0.y, a0);
            a0 = fmaf(w2, x0.z, a0); a0 = fmaf(w3, x0.w, a0);
            a1 = fmaf(w0, x1.x, a1); a1 = fmaf(w1, x1.y, a1);
            a1 = fmaf(w2, x1.z, a1); a1 = fmaf(w3, x1.w, a1);
            a2 = fmaf(w0, x2.x, a2); a2 = fmaf(w1, x2.y, a2);
            a2 = fmaf(w2, x2.z, a2); a2 = fmaf(w3, x2.w, a2);
            a3 = fmaf(w0, x3.x, a3); a3 = fmaf(w1, x3.y, a3);
            a3 = fmaf(w2, x3.z, a3); a3 = fmaf(w3, x3.w, a3);
        }
        pp[kh][0][f] = a0; pp[kh][1][f] = a1; pp[kh][2][f] = a2; pp[kh][3][f] = a3;
        __syncthreads();
        {
            float bvv = (mat == 0 ? bq0 : mat == 1 ? bk0 : bv0)[f];
            float* op = (mat == 0 ? qo : mat == 1 ? ko : vo);
            int r0 = (t >> 8) * 2;
            op[(rowg0 + r0) * 256 + f] = pp[0][r0][f] + pp[1][r0][f] + bvv;
            op[(rowg0 + r0 + 1) * 256 + f] = pp[0][r0 + 1][f] + pp[1][r0 + 1][f] + bvv;
        }
        __syncthreads();
    }
}

// ---------------- fused transformer layer: 1024 threads, 4-way k-split ----------------
__device__ inline void ln_reduce4(const float (*buf)[256], float (*mr)[2], int t) {
    int wid = t >> 6, lane = t & 63;
    if (wid < 4) {
        float4 v = *(const float4*)&buf[wid][lane * 4];
        float s = v.x + v.y + v.z + v.w;
        float q = v.x * v.x + v.y * v.y + v.z * v.z + v.w * v.w;
#pragma unroll
        for (int off = 32; off > 0; off >>= 1) {
            s += __shfl_xor(s, off);
            q += __shfl_xor(q, off);
        }
        if (lane == 0) {
            float mean = s * (1.f / 256.f);
            float var = q * (1.f / 256.f) - mean * mean;
            mr[wid][0] = mean;
            mr[wid][1] = rsqrtf(var + 1e-5f);
        }
    }
}

template <int LAST>
__global__ __launch_bounds__(1024)
void layer_kernel(const float* __restrict__ zin, const float* __restrict__ qin,
                  const float* __restrict__ kin, const float* __restrict__ vin,
                  const float* __restrict__ woT_l, const float* __restrict__ bo_l,
                  const float* __restrict__ c1T_l, const float* __restrict__ c1b_l,
                  const float* __restrict__ c2T_l, const float* __restrict__ c2b_l,
                  const float* __restrict__ ln1g_l, const float* __restrict__ ln1b_l,
                  const float* __restrict__ ln2g_l, const float* __restrict__ ln2b_l,
                  const float* __restrict__ wqT_n, const float* __restrict__ bq_n,
                  const float* __restrict__ wkT_n, const float* __restrict__ bk_n,
                  const float* __restrict__ wvT_n, const float* __restrict__ bv_n,
                  const float* __restrict__ lnfg, const float* __restrict__ lnfb,
                  float* __restrict__ zout, float* __restrict__ qo,
                  float* __restrict__ ko, float* __restrict__ vo,
                  float* __restrict__ lnf_out) {
    __shared__ float zs[4][256];
    __shared__ float qb[4][256];
    __shared__ float ao[4][256];
    __shared__ float pp[4][4][256];
    __shared__ union { float s[4][8][256]; float y[4][1024]; } sy;
    __shared__ float mr[4][2];

    const int t = threadIdx.x;
    const int w = t >> 6, lane = t & 63;
    const long rowg0 = (long)blockIdx.x * 4;
    const int b = blockIdx.x >> 6;

    const int f = t & 255;       // output dim for 256-wide phases
    const int kq = t >> 8;       // k-quarter 0..3

    // P1: stage z (residual) and q rows — one element per thread
    {
        int r = t >> 8, dd = t & 255;
        zs[r][dd] = zin[(rowg0 + r) * 256 + dd];
        qb[r][dd] = qin[(rowg0 + r) * 256 + dd];
    }
    __syncthreads();

    // P2: scores — wave pair per head: head = w>>1, j-half = w&1
    {
        const float scale = 0.17677669529663687f;
        const int jq = lane >> 3, li = lane & 7, d4 = li * 4;
        const int hh = w >> 1, jh = w & 1;
        const float* kb = kin + (long)b * 65536 + hh * 32 + d4;
        float4 q0 = *(const float4*)&qb[0][hh * 32 + d4];
        float4 q1 = *(const float4*)&qb[1][hh * 32 + d4];
        float4 q2 = *(const float4*)&qb[2][hh * 32 + d4];
        float4 q3 = *(const float4*)&qb[3][hh * 32 + d4];
        for (int jb = 0; jb < 16; jb++) {
            int j = jh * 128 + jb * 8 + jq;
            float4 kv = *(const float4*)(kb + (long)j * 256);
            float a0 = dot4(kv, q0), a1 = dot4(kv, q1);
            float a2 = dot4(kv, q2), a3 = dot4(kv, q3);
#pragma unroll
            for (int off = 1; off < 8; off <<= 1) {
                a0 += __shfl_xor(a0, off); a1 += __shfl_xor(a1, off);
                a2 += __shfl_xor(a2, off); a3 += __shfl_xor(a3, off);
            }
            if (li < 4) sy.s[li][hh][j] = sel4(a0, a1, a2, a3, li) * scale;
        }
    }
    __syncthreads();

    // P3: softmax — 32 (row,head) pairs over 16 waves
    {
#pragma unroll
        for (int p = 0; p < 2; p++) {
            int pair = w * 2 + p;
            int i = pair >> 3, hh = pair & 7;
            float* row = sy.s[i][hh];
            float v0 = row[lane], v1 = row[lane + 64];
            float v2 = row[lane + 128], v3 = row[lane + 192];
            float m = fmaxf(fmaxf(v0, v1), fmaxf(v2, v3));
#pragma unroll
            for (int off = 32; off > 0; off >>= 1) m = fmaxf(m, __shfl_xor(m, off));
            float e0 = expf(v0 - m), e1 = expf(v1 - m);
            float e2 = expf(v2 - m), e3 = expf(v3 - m);
            float su = e0 + e1 + e2 + e3;
#pragma unroll
            for (int off = 32; off > 0; off >>= 1) su += __shfl_xor(su, off);
            float inv = 1.f / su;
            row[lane] = e0 * inv; row[lane + 64] = e1 * inv;
            row[lane + 128] = e2 * inv; row[lane + 192] = e3 * inv;
        }
    }
    __syncthreads();

    // P4: PV — thread owns (d, row)
    {
        int row = kq;
        int hh = f >> 5;
        const float* vcol = vin + (long)b * 65536 + f;
        const float* p0 = sy.s[row][hh];
        float a0 = 0.f;
#pragma unroll 4
        for (int j4 = 0; j4 < 64; j4++) {
            float4 pv0 = *(const float4*)(p0 + j4 * 4);
            float v0 = vcol[(long)(j4 * 4 + 0) * 256];
            float v1 = vcol[(long)(j4 * 4 + 1) * 256];
            float v2 = vcol[(long)(j4 * 4 + 2) * 256];
            float v3 = vcol[(long)(j4 * 4 + 3) * 256];
            a0 = fmaf(pv0.x, v0, a0); a0 = fmaf(pv0.y, v1, a0);
            a0 = fmaf(pv0.z, v2, a0); a0 = fmaf(pv0.w, v3, a0);
        }
        ao[row][f] = a0;
    }
    __syncthreads();

    // P5: O-proj (4-way k-split) + residual -> qb
    {
        const float* wt = woT_l + f;
        const int kb2 = kq * 64;
        float a0 = 0.f, a1 = 0.f, a2 = 0.f, a3 = 0.f;
        for (int k4 = 0; k4 < 16; k4++) {
            int kk = kb2 + k4 * 4;
            float w0 = wt[(kk + 0) << 8], w1 = wt[(kk + 1) << 8];
            float w2 = wt[(kk + 2) << 8], w3 = wt[(kk + 3) << 8];
            float4 x0 = *(const float4*)&ao[0][kk];
            float4 x1 = *(const float4*)&ao[1][kk];
            float4 x2 = *(const float4*)&ao[2][kk];
            float4 x3 = *(const float4*)&ao[3][kk];
            a0 = fmaf(w0, x0.x, a0); a0 = fmaf(w1, x0.y, a0);
            a0 = fmaf(w2, x0.z, a0); a0 = fmaf(w3, x0.w, a0);
            a1 = fmaf(w0, x1.x, a1); a1 = fmaf(w1, x1.y, a1);
            a1 = fmaf(w2, x1.z, a1); a1 = fmaf(w3, x1.w, a1);
            a2 = fmaf(w0, x2.x, a2); a2 = fmaf(w1, x2.y, a2);
            a2 = fmaf(w2, x2.z, a2); a2 = fmaf(w3, x2.w, a2);
            a3 = fmaf(w0, x3.x, a3); a3 = fmaf(w1, x3.y, a3);
            a3 = fmaf(w2, x3.z, a3); a3 = fmaf(w3, x3.w, a3);
        }
        pp[kq][0][f] = a0; pp[kq][1][f] = a1; pp[kq][2][f] = a2; pp[kq][3][f] = a3;
    }
    __syncthreads();
    {
        int r = kq;
        qb[r][f] = pp[0][r][f] + pp[1][r][f] + pp[2][r][f] + pp[3][r][f]
                 + bo_l[f] + zs[r][f];
    }
    __syncthreads();
    ln_reduce4(qb, mr, t);
    __syncthreads();
    {
        int r = kq;
        zs[r][f] = (qb[r][f] - mr[r][0]) * mr[r][1] * ln1g_l[f] + ln1b_l[f];
    }
    __syncthreads();

    // P7: FFN1 + gelu — thread owns one FFN dim (t), all 4 rows
    {
        const float* wt = c1T_l + t;
        float a0 = 0.f, a1 = 0.f, a2 = 0.f, a3 = 0.f;
        for (int k4 = 0; k4 < 64; k4++) {
            float w0 = wt[(k4 * 4 + 0) << 10], w1 = wt[(k4 * 4 + 1) << 10];
            float w2 = wt[(k4 * 4 + 2) << 10], w3 = wt[(k4 * 4 + 3) << 10];
            float4 x0 = *(const float4*)&zs[0][k4 * 4];
            float4 x1 = *(const float4*)&zs[1][k4 * 4];
            float4 x2 = *(const float4*)&zs[2][k4 * 4];
            float4 x3 = *(const float4*)&zs[3][k4 * 4];
            a0 = fmaf(w0, x0.x, a0); a0 = fmaf(w1, x0.y, a0);
            a0 = fmaf(w2, x0.z, a0); a0 = fmaf(w3, x0.w, a0);
            a1 = fmaf(w0, x1.x, a1); a1 = fmaf(w1, x1.y, a1);
            a1 = fmaf(w2, x1.z, a1); a1 = fmaf(w3, x1.w, a1);
            a2 = fmaf(w0, x2.x, a2); a2 = fmaf(w1, x2.y, a2);
            a2 = fmaf(w2, x2.z, a2); a2 = fmaf(w3, x2.w, a2);
            a3 = fmaf(w0, x3.x, a3); a3 = fmaf(w1, x3.y, a3);
            a3 = fmaf(w2, x3.z, a3); a3 = fmaf(w3, x3.w, a3);
        }
        float cb = c1b_l[t];
        sy.y[0][t] = gelu_f(a0 + cb);
        sy.y[1][t] = gelu_f(a1 + cb);
        sy.y[2][t] = gelu_f(a2 + cb);
        sy.y[3][t] = gelu_f(a3 + cb);
    }
    __syncthreads();

    // P8: FFN2 (4-way k-split over K=1024) + residual -> qb
    {
        const float* wt = c2T_l + f;
        const int kb2 = kq * 256;
        float a0 = 0.f, a1 = 0.f, a2 = 0.f, a3 = 0.f;
        for (int k4 = 0; k4 < 64; k4++) {
            int kk = kb2 + k4 * 4;
            float w0 = wt[(kk + 0) << 8], w1 = wt[(kk + 1) << 8];
            float w2 = wt[(kk + 2) << 8], w3 = wt[(kk + 3) << 8];
            float4 y0 = *(const float4*)&sy.y[0][kk];
            float4 y1 = *(const float4*)&sy.y[1][kk];
            float4 y2 = *(const float4*)&sy.y[2][kk];
            float4 y3 = *(const float4*)&sy.y[3][kk];
            a0 = fmaf(w0, y0.x, a0); a0 = fmaf(w1, y0.y, a0);
            a0 = fmaf(w2, y0.z, a0); a0 = fmaf(w3, y0.w, a0);
            a1 = fmaf(w0, y1.x, a1); a1 = fmaf(w1, y1.y, a1);
            a1 = fmaf(w2, y1.z, a1); a1 = fmaf(w3, y1.w, a1);
            a2 = fmaf(w0, y2.x, a2); a2 = fmaf(w1, y2.y, a2);
            a2 = fmaf(w2, y2.z, a2); a2 = fmaf(w3, y2.w, a2);
            a3 = fmaf(w0, y3.x, a3); a3 = fmaf(w1, y3.y, a3);
            a3 = fmaf(w2, y3.z, a3); a3 = fmaf(w3, y3.w, a3);
        }
        pp[kq][0][f] = a0; pp[kq][1][f] = a1; pp[kq][2][f] = a2; pp[kq][3][f] = a3;
    }
    __syncthreads();
    {
        int r = kq;
        qb[r][f] = pp[0][r][f] + pp[1][r][f] + pp[2][r][f] + pp[3][r][f]
                 + c2b_l[f] + zs[r][f];
    }
    __syncthreads();
    ln_reduce4(qb, mr, t);
    __syncthreads();
    {
        int r = kq;
        float z2 = (qb[r][f] - mr[r][0]) * mr[r][1] * ln2g_l[f] + ln2b_l[f];
        zs[r][f] = z2;
        zout[(rowg0 + r) * 256 + f] = z2;
    }
    __syncthreads();

    if (!LAST) {
        // P9: QKV projections for next layer (4-way k-split, each W read once)
        const int kb2 = kq * 64;
        for (int mat = 0; mat < 3; mat++) {
            const float* wt = (mat == 0 ? wqT_n : mat == 1 ? wkT_n : wvT_n) + f;
            float a0 = 0.f, a1 = 0.f, a2 = 0.f, a3 = 0.f;
            for (int k4 = 0; k4 < 16; k4++) {
                int kk = kb2 + k4 * 4;
                float w0 = wt[(kk + 0) << 8], w1 = wt[(kk + 1) << 8];
                float w2 = wt[(kk + 2) << 8], w3 = wt[(kk + 3) << 8];
                float4 x0 = *(const float4*)&zs[0][kk];
                float4 x1 = *(const float4*)&zs[1][kk];
                float4 x2 = *(const float4*)&zs[2][kk];
                float4 x3 = *(const float4*)&zs[3][kk];
                a0 = fmaf(w0, x0.x, a0); a0 = fmaf(w1, x0.y, a0);
                a0 = fmaf(w2, x0.z, a0); a0 = fmaf(w3, x0.w, a0);
                a1 = fmaf(w0, x1.x, a1); a1 = fmaf(w1, x1.y, a1);
                a1 = fmaf(w2, x1.z, a1); a1 = fmaf(w3, x1.w, a1);
                a2 = fmaf(w0, x2.x, a2); a2 = fmaf(w1, x2.y, a2);
                a2 = fmaf(w2, x2.z, a2); a2 = fmaf(w3, x2.w, a2);
                a3 = fmaf(w0, x3.x, a3); a3 = fmaf(w1, x3.y, a3);
                a3 = fmaf(w2, x3.z, a3); a3 = fmaf(w3, x3.w, a3);
            }
            pp[kq][0][f] = a0; pp[kq][1][f] = a1; pp[kq][2][f] = a2; pp[kq][3][f] = a3;
            __syncthreads();
            {
                float bvv = (mat == 0 ? bq_n : mat == 1 ? bk_n : bv_n)[f];
                float* op = (mat == 0 ? qo : mat == 1 ? ko : vo);
                int r = kq;
                op[(rowg0 + r) * 256 + f] = pp[0][r][f] + pp[1][r][f] + pp[2][r][f] + pp[3][r][f] + bvv;
            }
            __syncthreads();
        }
    } else {
        ln_reduce4(zs, mr, t);
        __syncthreads();
        {
            int r = kq;
            lnf_out[(rowg0 + r) * 256 + f] =
                (zs[r][f] - mr[r][0]) * mr[r][1] * lnfg[f] + lnfb[f];
        }
    }
}

// ---------------- final: pooled mean over seq -> proj ----------------
__global__ __launch_bounds__(256)
void final_kernel(const float* __restrict__ zf, const float* __restrict__ pw,
                  const float* __restrict__ pb, float* __restrict__ out) {
    __shared__ float sm[8];
    int b = blockIdx.x, d = threadIdx.x;
    float s = 0.f;
    for (int c = 0; c < 256; c++) s += zf[((long)(b * 256 + c)) * 256 + d];
    float pooled = s * (1.f / 256.f);
    float c0 = pooled * pw[d], c1 = pooled * pw[256 + d];
    for (int off = 32; off > 0; off >>= 1) { c0 += __shfl_down(c0, off); c1 += __shfl_down(c1, off); }
    int lane = d & 63, wv = d >> 6;
    if (lane == 0) { sm[wv] = c0; sm[4 + wv] = c1; }
    __syncthreads();
    if (d == 0) {
        out[b * 2 + 0] = sm[0] + sm[1] + sm[2] + sm[3] + pb[0];
        out[b * 2 + 1] = sm[4] + sm[5] + sm[6] + sm[7] + pb[1];
    }
}

extern "C" void kernel_launch(void* const* d_in, const int* in_sizes, int n_in,
                              void* d_out, int out_size, void* d_ws, size_t ws_size,
                              hipStream_t stream) {
    const float* x       = (const float*)d_in[0];
    const float* filters = (const float*)d_in[1];
    const float* bn1_g   = (const float*)d_in[2];
    const float* bn1_b   = (const float*)d_in[3];
    const float* emb_w   = (const float*)d_in[4];
    const float* emb_b   = (const float*)d_in[5];
    const float* embbn_g = (const float*)d_in[6];
    const float* embbn_b = (const float*)d_in[7];
    const float* wq      = (const float*)d_in[8];
    const float* bq      = (const float*)d_in[9];
    const float* wk      = (const float*)d_in[10];
    const float* bk      = (const float*)d_in[11];
    const float* wv      = (const float*)d_in[12];
    const float* bv      = (const float*)d_in[13];
    const float* wo      = (const float*)d_in[14];
    const float* bo      = (const float*)d_in[15];
    const float* c1w     = (const float*)d_in[16];
    const float* c1b     = (const float*)d_in[17];
    const float* c2w     = (const float*)d_in[18];
    const float* c2b     = (const float*)d_in[19];
    const float* ln1g    = (const float*)d_in[20];
    const float* ln1b    = (const float*)d_in[21];
    const float* ln2g    = (const float*)d_in[22];
    const float* ln2b    = (const float*)d_in[23];
    const float* lnfg    = (const float*)d_in[24];
    const float* lnfb    = (const float*)d_in[25];
    const float* projw   = (const float*)d_in[26];
    const float* projb   = (const float*)d_in[27];

    const long wpackF = 5505024L;                   // 2 * 8*NKC*512 shorts, in floats
    const long wTF = 3145728L;                      // transposed layer weights
    const long fixedF = 22005760L + 5120 + wpackF + 9L * 262144 + wTF;
    long wsFloats = (long)(ws_size / 4);
    long Z = 32;
    while (Z > 8 && fixedF + Z * 262144L > wsFloats) Z >>= 1;
    const int kPerZ = KEMBP / (int)Z;

    float* ws = (float*)d_ws;
    float* h_raw  = ws;                             // 22,005,760
    float* bn1_sc = h_raw + 22005760;
    float* bn1_sh = bn1_sc + 256;
    float* e_sc   = bn1_sh + 256;
    float* e_sh   = e_sc + 256;
    float* bnp1   = e_sh + 256;                     // 2048
    float* bnp2   = bnp1 + 2048;                    // 2048
    float* part   = bnp2 + 2048;                    // Z * 262144
    float* wsp    = part + Z * 262144L;
    short* wpH    = (short*)wsp;                    // 8*NKC*512 shorts
    short* wpL    = wpH + 8L * NKC * 512;
    float* e      = wsp + wpackF;
    float* z      = e + 262144;
    float* qA     = z + 262144;
    float* kA     = qA + 262144;
    float* vA     = kA + 262144;
    float* qB     = vA + 262144;
    float* kB     = qB + 262144;
    float* vB     = kB + 262144;
    float* t1     = vB + 262144;
    float* wqT    = t1 + 262144;                    // 4*65536
    float* wkT    = wqT + 262144;
    float* wvT    = wkT + 262144;
    float* woT    = wvT + 262144;
    float* c1T    = woT + 262144;                   // 4*262144
    float* c2T    = c1T + 1048576;

    // conv packed filters alias onto `part` (only used before embed writes part)
    short* fpH = (short*)part;                      // 520*512 shorts
    short* fpL = fpH + 266240;

    filt_pack_kernel<<<520, 512, 0, stream>>>(filters, fpH, fpL);
    wpack_kernel<<<8 * NKC, 512, 0, stream>>>(emb_w, wpH, wpL);
    wtrans_kernel<<<3072, dim3(32, 8), 0, stream>>>(wq, wk, wv, wo, c1w, c2w,
                                                    wqT, wkT, wvT, woT, c1T, c2T);
    conv_mfma_kernel<<<dim3(672, 4), 256, 0, stream>>>(x, fpH, fpL, h_raw);
    bn_part_kernel<<<dim3(256, 8), 256, 0, stream>>>(h_raw, bnp1, bnp2);
    bn_fin_kernel<<<1, 256, 0, stream>>>(bnp1, bnp2, bn1_g, bn1_b, bn1_sc, bn1_sh);
    embed_mfma_kernel<<<dim3(8, 2, (int)Z), 256, 0, stream>>>(h_raw, wpH, wpL,
                                                              bn1_sc, bn1_sh, part, kPerZ);
    embed_combine_kernel<<<1024, 256, 0, stream>>>(part, emb_b, e, (int)Z);
    bn_stats_kernel<<<256, 256, 0, stream>>>(e, embbn_g, embbn_b, e_sc, e_sh,
                                             256, 256L * 256);
    qkv_init_kernel<<<256, 512, 0, stream>>>(e, e_sc, e_sh, wqT, bq, wkT, bk, wvT, bv,
                                             z, qA, kA, vA);

    float* qs[2][3] = {{qA, kA, vA}, {qB, kB, vB}};
    for (int l = 0; l < 4; l++) {
        float** in = qs[l & 1];
        float** ou = qs[(l + 1) & 1];
        const float* woT_l = woT + (long)l * 65536; const float* bo_l = bo + l * 256;
        const float* c1T_l = c1T + (long)l * 262144; const float* c1b_l = c1b + l * 1024;
        const float* c2T_l = c2T + (long)l * 262144; const float* c2b_l = c2b + l * 256;
        const float* l1g = ln1g + l * 256; const float* l1b = ln1b + l * 256;
        const float* l2g = ln2g + l * 256; const float* l2b = ln2b + l * 256;
        if (l < 3) {
            const float* wqT_n = wqT + (long)(l + 1) * 65536; const float* bq_n = bq + (l + 1) * 256;
            const float* wkT_n = wkT + (long)(l + 1) * 65536; const float* bk_n = bk + (l + 1) * 256;
            const float* wvT_n = wvT + (long)(l + 1) * 65536; const float* bv_n = bv + (l + 1) * 256;
            layer_kernel<0><<<256, 1024, 0, stream>>>(z, in[0], in[1], in[2],
                woT_l, bo_l, c1T_l, c1b_l, c2T_l, c2b_l, l1g, l1b, l2g, l2b,
                wqT_n, bq_n, wkT_n, bk_n, wvT_n, bv_n, lnfg, lnfb,
                z, ou[0], ou[1], ou[2], t1);
        } else {
            layer_kernel<1><<<256, 1024, 0, stream>>>(z, in[0], in[1], in[2],
                woT_l, bo_l, c1T_l, c1b_l, c2T_l, c2b_l, l1g, l1b, l2g, l2b,
                wqT, bq, wkT, bk, wvT, bv, lnfg, lnfb,
                z, ou[0], ou[1], ou[2], t1);
        }
    }

    final_kernel<<<4, 256, 0, stream>>>(t1, projw, projb, (float*)d_out);
}

// Round 8
// 718.680 us; speedup vs baseline: 5.2353x; 1.1508x over previous
//
#include <hip/hip_runtime.h>
#include <math.h>

#define L_IN 65494
#define T_POOL 21490
#define KF 1025
#define RS 1144            // conv replica row stride (elements)
#define CWIN 1136          // conv x window per block: 96 + 1040
#define KEMB 21490
#define KEMBP 21504        // padded
#define NKC 1344           // KEMBP/16
#define FTILE 33280        // 65*512 shorts per conv filter tile

typedef short s16x4 __attribute__((ext_vector_type(4)));
typedef _Float16 f16x8 __attribute__((ext_vector_type(8)));
typedef float f32x16 __attribute__((ext_vector_type(16)));

__device__ inline float selu_f(float x) {
    float e = expf(fminf(x, 0.f));
    float neg = 1.6732632423543772f * (e - 1.f);
    return 1.0507009873554805f * (x > 0.f ? x : neg);
}

__device__ inline float gelu_f(float x) {
    return 0.5f * x * (1.f + erff(x * 0.7071067811865476f));
}

__device__ inline float dot4(float4 a, float4 b) {
    return fmaf(a.x, b.x, fmaf(a.y, b.y, fmaf(a.z, b.z, a.w * b.w)));
}

__device__ inline float sel4(float a0, float a1, float a2, float a3, int i) {
    float r = a0;
    r = (i == 1) ? a1 : r;
    r = (i == 2) ? a2 : r;
    r = (i == 3) ? a3 : r;
    return r;
}

__device__ inline short f2h_bits(float v) {
    _Float16 h = (_Float16)v;
    return *(short*)&h;
}

// x = hi + lo in fp16 (hi RTNE, lo = residual): exact to ~2^-22
__device__ inline void f16split(float v, short& hs, short& ls) {
    _Float16 h = (_Float16)v;
    float hf = (float)h;
    _Float16 l = (_Float16)(v - hf);
    hs = *(short*)&h;
    ls = *(short*)&l;
}

// ---------------- filter pack: fp16 single, fragment-major [ft][kc][lane][8] ----------------
__global__ __launch_bounds__(512)
void filt_pack_kernel(const float* __restrict__ filt, short* __restrict__ fpH) {
    int blk = blockIdx.x;            // ft*65 + kc  (grid 520)
    int ft = blk / 65, kc = blk % 65;
    int t = threadIdx.x, lane = t >> 3, e = t & 7;
    int f = ft * 32 + (lane & 31);
    int tap = kc * 16 + (lane >> 5) * 8 + e;
    float v = (tap < KF) ? filt[f * KF + tap] : 0.f;
    fpH[blk * 512 + t] = f2h_bits(v);
}

// ---------------- emb_w pack: fp16 single, fragment-major [ft][kc][lane][8] ----------------
__global__ __launch_bounds__(512)
void wpack_kernel(const float* __restrict__ wsrc, short* __restrict__ wpH) {
    int blk = blockIdx.x;            // ft*NKC + kc  (grid 8*NKC)
    int ft = blk / NKC, kc = blk % NKC;
    int t = threadIdx.x, lane = t >> 3, e = t & 7;
    int row = ft * 32 + (lane & 31);
    int tap = kc * 16 + (lane >> 5) * 8 + e;
    float v = (tap < KEMB) ? wsrc[(long)row * KEMB + tap] : 0.f;
    wpH[(long)blk * 512 + t] = f2h_bits(v);
}

// ---------------- weight transpose pack: Wt[k][f] = W[f][k] ----------------
__device__ inline void transpose_tile(const float* __restrict__ src, float* __restrict__ dst,
                                      int F, int K, int tf, int tk) {
    __shared__ float tile[32][33];
    int tx = threadIdx.x, ty = threadIdx.y;  // 32 x 8
#pragma unroll
    for (int r = 0; r < 4; r++) {
        int fi = tf * 32 + ty * 4 + r;
        tile[ty * 4 + r][tx] = src[(long)fi * K + tk * 32 + tx];
    }
    __syncthreads();
#pragma unroll
    for (int r = 0; r < 4; r++) {
        int ki = tk * 32 + ty * 4 + r;
        dst[(long)ki * F + tf * 32 + tx] = tile[tx][ty * 4 + r];
    }
}

__global__ __launch_bounds__(256)
void wtrans_kernel(const float* __restrict__ wq, const float* __restrict__ wk,
                   const float* __restrict__ wv, const float* __restrict__ wo,
                   const float* __restrict__ c1w, const float* __restrict__ c2w,
                   float* __restrict__ wqT, float* __restrict__ wkT,
                   float* __restrict__ wvT, float* __restrict__ woT,
                   float* __restrict__ c1T, float* __restrict__ c2T) {
    int bx = blockIdx.x;
    if (bx < 1024) {
        int m = bx >> 6, tile = bx & 63;
        int which = m >> 2, l = m & 3;
        int tk = tile >> 3, tf = tile & 7;
        const float* s; float* dd;
        if (which == 0) { s = wq; dd = wqT; }
        else if (which == 1) { s = wk; dd = wkT; }
        else if (which == 2) { s = wv; dd = wvT; }
        else { s = wo; dd = woT; }
        transpose_tile(s + l * 65536, dd + l * 65536, 256, 256, tf, tk);
    } else if (bx < 2048) {
        int b2 = bx - 1024, l = b2 >> 8, tile = b2 & 255;
        int tf = tile & 31, tk = tile >> 5;
        transpose_tile(c1w + (long)l * 262144, c1T + (long)l * 262144, 1024, 256, tf, tk);
    } else {
        int b2 = bx - 2048, l = b2 >> 8, tile = b2 & 255;
        int tf = tile & 7, tk = tile >> 3;
        transpose_tile(c2w + (long)l * 262144, c2T + (long)l * 262144, 256, 1024, tf, tk);
    }
}

// ---------------- SincConv via MFMA (fp16 2-pass) + |.| + maxpool3 ----------------
// 512 threads = 8 waves; wave owns 32 filters. 8-way shifted x replicas in LDS.
union ConvLDS {
    struct { short xh[8][RS]; short xl[8][RS]; } st;
    float ebuf[96][129];
};

#define MFMA2(ACC, AH, AL, BH) \
    ACC = __builtin_amdgcn_mfma_f32_32x32x16_f16(AL, BH, ACC, 0, 0, 0); \
    ACC = __builtin_amdgcn_mfma_f32_32x32x16_f16(AH, BH, ACC, 0, 0, 0);

__global__ __launch_bounds__(512)
void conv_mfma_kernel(const float* __restrict__ x, const short* __restrict__ fpH,
                      float* __restrict__ h) {
    __shared__ ConvLDS u;
    const int tid = threadIdx.x;
    const int pb = blockIdx.x;
    const int b = blockIdx.y;
    const int t0 = pb * 96;

    for (int i = tid; i < CWIN; i += 512) {
        int gi = t0 + i;
        float v = (gi < L_IN) ? x[b * L_IN + gi] : 0.f;
        short hs, ls;
        f16split(v, hs, ls);
#pragma unroll
        for (int s = 0; s < 8; s++) {
            int e = i - s;
            if (e >= 0) { u.st.xh[s][e] = hs; u.st.xl[s][e] = ls; }
        }
    }
    __syncthreads();

    const int lane = tid & 63;
    const int wid = tid >> 6;      // 0..7, wave owns filters [wid*32, wid*32+32)
    const int l31 = lane & 31;
    const int hi = lane >> 5;

    const short* aH = &u.st.xh[l31 & 7][8 * (l31 >> 3) + 8 * hi];
    const short* aL = &u.st.xl[l31 & 7][8 * (l31 >> 3) + 8 * hi];
    const short* bp = fpH + (long)wid * FTILE + lane * 8;

    f32x16 a0 = {0}, a1 = {0}, a2 = {0};

#pragma unroll 1
    for (int kc = 0; kc < 65; kc++) {
        const int ko = kc * 16;
        const int kf = kc * 512;
        f16x8 ah0 = *(const f16x8*)(aH + ko);
        f16x8 ah1 = *(const f16x8*)(aH + ko + 32);
        f16x8 ah2 = *(const f16x8*)(aH + ko + 64);
        f16x8 al0 = *(const f16x8*)(aL + ko);
        f16x8 al1 = *(const f16x8*)(aL + ko + 32);
        f16x8 al2 = *(const f16x8*)(aL + ko + 64);
        f16x8 bh = *(const f16x8*)(bp + kf);
        MFMA2(a0, ah0, al0, bh)
        MFMA2(a1, ah1, al1, bh)
        MFMA2(a2, ah2, al2, bh)
    }

    __syncthreads();
    const int t3l = tid & 31;
    const int t3 = pb * 32 + t3l;

#pragma unroll
    for (int half = 0; half < 2; half++) {
        if ((wid >> 2) == half) {
            int fc = (wid & 3) * 32 + l31;
#define WRF(ACC, MT)                                                       \
            {                                                              \
                _Pragma("unroll")                                          \
                for (int r = 0; r < 16; r++) {                             \
                    int pos = MT * 32 + (r & 3) + 8 * (r >> 2) + 4 * hi;   \
                    u.ebuf[pos][fc] = fabsf(ACC[r]);                       \
                }                                                          \
            }
            WRF(a0, 0) WRF(a1, 1) WRF(a2, 2)
#undef WRF
        }
        __syncthreads();
        if (t3 < T_POOL) {
            for (int ff = tid >> 5; ff < 128; ff += 16) {
                float v = fmaxf(fmaxf(u.ebuf[3 * t3l][ff], u.ebuf[3 * t3l + 1][ff]),
                                u.ebuf[3 * t3l + 2][ff]);
                h[((long)(b * 256 + half * 128 + ff)) * T_POOL + t3] = v;
            }
        }
        __syncthreads();
    }
}

// ---------------- BatchNorm stats for h_raw: two-stage ----------------
__global__ __launch_bounds__(256)
void bn_part_kernel(const float* __restrict__ xin, float* __restrict__ p1,
                    float* __restrict__ p2) {
    __shared__ float sm[8];
    int c = blockIdx.x, s = blockIdx.y, tid = threadIdx.x;
    int t0 = s * 2687, t1 = min(T_POOL, t0 + 2687);
    float s1 = 0.f, s2 = 0.f;
    for (int b = 0; b < 4; b++) {
        const float* p = xin + (long)b * 256 * T_POOL + (long)c * T_POOL;
        for (int t = t0 + tid; t < t1; t += 256) {
            float v = p[t];
            s1 += v;
            s2 = fmaf(v, v, s2);
        }
    }
    for (int off = 32; off > 0; off >>= 1) { s1 += __shfl_down(s1, off); s2 += __shfl_down(s2, off); }
    int lane = tid & 63, wv = tid >> 6;
    if (lane == 0) { sm[wv] = s1; sm[4 + wv] = s2; }
    __syncthreads();
    if (tid == 0) {
        p1[c * 8 + s] = sm[0] + sm[1] + sm[2] + sm[3];
        p2[c * 8 + s] = sm[4] + sm[5] + sm[6] + sm[7];
    }
}

__global__ __launch_bounds__(256)
void bn_fin_kernel(const float* __restrict__ p1, const float* __restrict__ p2,
                   const float* __restrict__ g, const float* __restrict__ bb,
                   float* __restrict__ sc, float* __restrict__ sh) {
    int c = threadIdx.x;
    float S1 = 0.f, S2 = 0.f;
#pragma unroll
    for (int s = 0; s < 8; s++) { S1 += p1[c * 8 + s]; S2 += p2[c * 8 + s]; }
    float n = 4.f * (float)T_POOL;
    float mean = S1 / n;
    float var = S2 / n - mean * mean;
    float rstd = rsqrtf(var + 1e-5f);
    float gc = g[c], bc = bb[c];
    sc[c] = rstd * gc;
    sh[c] = bc - mean * rstd * gc;
}

// ---------------- BatchNorm stats (small, for e) ----------------
__global__ __launch_bounds__(256)
void bn_stats_kernel(const float* __restrict__ xin, const float* __restrict__ g,
                     const float* __restrict__ bb, float* __restrict__ sc,
                     float* __restrict__ sh, int ilen, long bstride) {
    __shared__ float sm[8];
    int c = blockIdx.x, tid = threadIdx.x;
    float s1 = 0.f, s2 = 0.f;
    for (int b = 0; b < 4; b++) {
        const float* p = xin + b * bstride + (long)c * ilen;
        for (int t = tid; t < ilen; t += 256) {
            float v = p[t];
            s1 += v;
            s2 = fmaf(v, v, s2);
        }
    }
    for (int off = 32; off > 0; off >>= 1) { s1 += __shfl_down(s1, off); s2 += __shfl_down(s2, off); }
    int lane = tid & 63, wv = tid >> 6;
    if (lane == 0) { sm[wv] = s1; sm[4 + wv] = s2; }
    __syncthreads();
    if (tid == 0) {
        float S1 = sm[0] + sm[1] + sm[2] + sm[3];
        float S2 = sm[4] + sm[5] + sm[6] + sm[7];
        float n = 4.f * (float)ilen;
        float mean = S1 / n;
        float var = S2 / n - mean * mean;
        float rstd = rsqrtf(var + 1e-5f);
        float gc = g[c], bc = bb[c];
        sc[c] = rstd * gc;
        sh[c] = bc - mean * rstd * gc;
    }
}

// ---------------- Embedding GEMM via MFMA (fp16 2-pass), split-K, packed B ----------------
__global__ __launch_bounds__(256, 2)
void embed_mfma_kernel(const float* __restrict__ H, const short* __restrict__ Wh,
                       const float* __restrict__ sc, const float* __restrict__ sh,
                       float* __restrict__ P, int kPerZ) {
    __shared__ short Ah[128][36];
    __shared__ short Al[128][36];
    const int tid = threadIdx.x;
    const int rowBase = blockIdx.x * 128;
    const int colBase = blockIdx.y * 128;
    const int z = blockIdx.z;
    const int kz = z * kPerZ;
    const int iters = kPerZ >> 5;

    const int trow = tid >> 1, th = (tid & 1) * 16;
    const int arow = rowBase + trow;
    const float asc = sc[arow & 255], ash = sh[arow & 255];
    const float* Ap = H + (long)arow * KEMB;

    const int lane = tid & 63, wid = tid >> 6;
    const int l31 = lane & 31, hi = lane >> 5;
    const int wm = wid >> 1, wn = wid & 1;

    const short* bhp[2];
#pragma unroll
    for (int nt = 0; nt < 2; nt++) {
        int ft = (colBase >> 5) + wn * 2 + nt;
        bhp[nt] = Wh + (long)ft * NKC * 512 + lane * 8;
    }

    f32x16 acc[2][2] = {{{0}, {0}}, {{0}, {0}}};

    for (int it = 0; it < iters; it++) {
        const int k0 = kz + it * 32;
        __syncthreads();
        float av[16];
        if (k0 + 32 <= KEMB) {
            const float4* p4 = (const float4*)(Ap + k0 + th);
#pragma unroll
            for (int q = 0; q < 4; q++) {
                float4 f = p4[q];
                av[q * 4 + 0] = f.x; av[q * 4 + 1] = f.y;
                av[q * 4 + 2] = f.z; av[q * 4 + 3] = f.w;
            }
        } else {
#pragma unroll
            for (int e = 0; e < 16; e++) {
                int k = k0 + th + e;
                av[e] = (k < KEMB) ? Ap[k] : 0.f;
            }
        }
#pragma unroll
        for (int q = 0; q < 4; q++) {
            s16x4 h4, l4;
#pragma unroll
            for (int e = 0; e < 4; e++) {
                float v = selu_f(fmaf(av[q * 4 + e], asc, ash));
                short hs, ls;
                f16split(v, hs, ls);
                h4[e] = hs; l4[e] = ls;
            }
            *(s16x4*)&Ah[trow][th + q * 4] = h4;
            *(s16x4*)&Al[trow][th + q * 4] = l4;
        }
        __syncthreads();

#pragma unroll
        for (int ks = 0; ks < 2; ks++) {
            const int kloc = ks * 16 + hi * 8;
            const long kcg = (long)((k0 >> 4) + ks) * 512;
            f16x8 ah[2], al[2], bh[2];
#pragma unroll
            for (int mt = 0; mt < 2; mt++) {
                const int r = wm * 64 + mt * 32 + l31;
                const short* ph = &Ah[r][kloc];
                const short* pl = &Al[r][kloc];
                union { f16x8 v; unsigned long long q[2]; } uh, ul;
                uh.q[0] = *(const unsigned long long*)(ph);
                uh.q[1] = *(const unsigned long long*)(ph + 4);
                ul.q[0] = *(const unsigned long long*)(pl);
                ul.q[1] = *(const unsigned long long*)(pl + 4);
                ah[mt] = uh.v; al[mt] = ul.v;
            }
#pragma unroll
            for (int nt = 0; nt < 2; nt++)
                bh[nt] = *(const f16x8*)(bhp[nt] + kcg);
#pragma unroll
            for (int mt = 0; mt < 2; mt++)
#pragma unroll
                for (int nt = 0; nt < 2; nt++) {
                    MFMA2(acc[mt][nt], ah[mt], al[mt], bh[nt])
                }
        }
    }

    float* Pz = P + (long)z * 262144;
#pragma unroll
    for (int mt = 0; mt < 2; mt++)
#pragma unroll
        for (int nt = 0; nt < 2; nt++) {
            int col = colBase + wn * 64 + nt * 32 + l31;
#pragma unroll
            for (int r = 0; r < 16; r++) {
                int row = rowBase + wm * 64 + mt * 32 + (r & 3) + 8 * (r >> 2) + 4 * hi;
                Pz[(long)row * 256 + col] = acc[mt][nt][r];
            }
        }
}

__global__ __launch_bounds__(256)
void embed_combine_kernel(const float* __restrict__ P, const float* __restrict__ eb,
                          float* __restrict__ e, int nsplit) {
    int idx = blockIdx.x * 256 + threadIdx.x;
    float s = 0.f;
    for (int z = 0; z < nsplit; z++) s += P[(long)z * 262144 + idx];
    e[idx] = s + eb[idx & 255];
}

// ---------------- fused zinit + layer-0 QKV (k-split, W read once/block) ----------------
__global__ __launch_bounds__(512)
void qkv_init_kernel(const float* __restrict__ e, const float* __restrict__ sc,
                     const float* __restrict__ sh,
                     const float* __restrict__ wqT0, const float* __restrict__ bq0,
                     const float* __restrict__ wkT0, const float* __restrict__ bk0,
                     const float* __restrict__ wvT0, const float* __restrict__ bv0,
                     float* __restrict__ z, float* __restrict__ qo,
                     float* __restrict__ ko, float* __restrict__ vo) {
    __shared__ float zs[4][256];
    __shared__ float pp[2][4][256];
    const int t = threadIdx.x;
    const long rowg0 = (long)blockIdx.x * 4;

    for (int idx = t; idx < 1024; idx += 512) {
        int i = idx >> 8, dd = idx & 255;
        int c = (int)((rowg0 + i) & 255);
        float v = fmaf(e[(rowg0 + i) * 256 + dd], sc[c], sh[c]);
        v = fmaxf(v, 0.f);
        int i2 = dd >> 1;
        float ang = (float)c * expf(-0.03597789207803195f * (float)(2 * i2));
        float pe = (dd & 1) ? cosf(ang) : sinf(ang);
        float zz = v + pe;
        zs[i][dd] = zz;
        z[(rowg0 + i) * 256 + dd] = zz;
    }
    __syncthreads();

    const int f = t & 255, kh = t >> 8, kb = kh * 128;
    for (int mat = 0; mat < 3; mat++) {
        const float* wt = (mat == 0 ? wqT0 : mat == 1 ? wkT0 : wvT0) + f;
        float a0 = 0.f, a1 = 0.f, a2 = 0.f, a3 = 0.f;
        for (int k4 = 0; k4 < 32; k4++) {
            int kk = kb + k4 * 4;
            float w0 = wt[(kk + 0) << 8], w1 = wt[(kk + 1) << 8];
            float w2 = wt[(kk + 2) << 8], w3 = wt[(kk + 3) << 8];
            float4 x0 = *(const float4*)&zs[0][kk];
            float4 x1 = *(const float4*)&zs[1][kk];
            float4 x2 = *(const float4*)&zs[2][kk];
            float4 x3 = *(const float4*)&zs[3][kk];
            a0 = fmaf(w0, x0.x, a0); a0 = fmaf(w1, x0.y, a0);
            a0 = fmaf(w2, x0.z, a0); a0 = fmaf(w3, x0.w, a0);
            a1 = fmaf(w0, x1.x, a1); a1 = fmaf(w1, x1.y, a1);
            a1 = fmaf(w2, x1.z, a1); a1 = fmaf(w3, x1.w, a1);
            a2 = fmaf(w0, x2.x, a2); a2 = fmaf(w1, x2.y, a2);
            a2 = fmaf(w2, x2.z, a2); a2 = fmaf(w3, x2.w, a2);
            a3 = fmaf(w0, x3.x, a3); a3 = fmaf(w1, x3.y, a3);
            a3 = fmaf(w2, x3.z, a3); a3 = fmaf(w3, x3.w, a3);
        }
        pp[kh][0][f] = a0; pp[kh][1][f] = a1; pp[kh][2][f] = a2; pp[kh][3][f] = a3;
        __syncthreads();
        {
            float bvv = (mat == 0 ? bq0 : mat == 1 ? bk0 : bv0)[f];
            float* op = (mat == 0 ? qo : mat == 1 ? ko : vo);
            int r0 = (t >> 8) * 2;
            op[(rowg0 + r0) * 256 + f] = pp[0][r0][f] + pp[1][r0][f] + bvv;
            op[(rowg0 + r0 + 1) * 256 + f] = pp[0][r0 + 1][f] + pp[1][r0 + 1][f] + bvv;
        }
        __syncthreads();
    }
}

// ---------------- fused transformer layer: 1024 threads, 4-way k-split ----------------
__device__ inline void ln_reduce4(const float (*buf)[256], float (*mr)[2], int t) {
    int wid = t >> 6, lane = t & 63;
    if (wid < 4) {
        float4 v = *(const float4*)&buf[wid][lane * 4];
        float s = v.x + v.y + v.z + v.w;
        float q = v.x * v.x + v.y * v.y + v.z * v.z + v.w * v.w;
#pragma unroll
        for (int off = 32; off > 0; off >>= 1) {
            s += __shfl_xor(s, off);
            q += __shfl_xor(q, off);
        }
        if (lane == 0) {
            float mean = s * (1.f / 256.f);
            float var = q * (1.f / 256.f) - mean * mean;
            mr[wid][0] = mean;
            mr[wid][1] = rsqrtf(var + 1e-5f);
        }
    }
}

template <int LAST>
__global__ __launch_bounds__(1024)
void layer_kernel(const float* __restrict__ zin, const float* __restrict__ qin,
                  const float* __restrict__ kin, const float* __restrict__ vin,
                  const float* __restrict__ woT_l, const float* __restrict__ bo_l,
                  const float* __restrict__ c1T_l, const float* __restrict__ c1b_l,
                  const float* __restrict__ c2T_l, const float* __restrict__ c2b_l,
                  const float* __restrict__ ln1g_l, const float* __restrict__ ln1b_l,
                  const float* __restrict__ ln2g_l, const float* __restrict__ ln2b_l,
                  const float* __restrict__ wqT_n, const float* __restrict__ bq_n,
                  const float* __restrict__ wkT_n, const float* __restrict__ bk_n,
                  const float* __restrict__ wvT_n, const float* __restrict__ bv_n,
                  const float* __restrict__ lnfg, const float* __restrict__ lnfb,
                  float* __restrict__ zout, float* __restrict__ qo,
                  float* __restrict__ ko, float* __restrict__ vo,
                  float* __restrict__ lnf_out) {
    __shared__ float zs[4][256];
    __shared__ float qb[4][256];
    __shared__ float ao[4][256];
    __shared__ float pp[4][4][256];
    __shared__ union { float s[4][8][256]; float y[4][1024]; } sy;
    __shared__ float mr[4][2];

    const int t = threadIdx.x;
    const int w = t >> 6, lane = t & 63;
    const long rowg0 = (long)blockIdx.x * 4;
    const int b = blockIdx.x >> 6;

    const int f = t & 255;       // output dim for 256-wide phases
    const int kq = t >> 8;       // k-quarter 0..3

    // P1: stage z (residual) and q rows — one element per thread
    {
        int r = t >> 8, dd = t & 255;
        zs[r][dd] = zin[(rowg0 + r) * 256 + dd];
        qb[r][dd] = qin[(rowg0 + r) * 256 + dd];
    }
    __syncthreads();

    // P2: scores — wave pair per head: head = w>>1, j-half = w&1
    {
        const float scale = 0.17677669529663687f;
        const int jq = lane >> 3, li = lane & 7, d4 = li * 4;
        const int hh = w >> 1, jh = w & 1;
        const float* kb = kin + (long)b * 65536 + hh * 32 + d4;
        float4 q0 = *(const float4*)&qb[0][hh * 32 + d4];
        float4 q1 = *(const float4*)&qb[1][hh * 32 + d4];
        float4 q2 = *(const float4*)&qb[2][hh * 32 + d4];
        float4 q3 = *(const float4*)&qb[3][hh * 32 + d4];
        for (int jb = 0; jb < 16; jb++) {
            int j = jh * 128 + jb * 8 + jq;
            float4 kv = *(const float4*)(kb + (long)j * 256);
            float a0 = dot4(kv, q0), a1 = dot4(kv, q1);
            float a2 = dot4(kv, q2), a3 = dot4(kv, q3);
#pragma unroll
            for (int off = 1; off < 8; off <<= 1) {
                a0 += __shfl_xor(a0, off); a1 += __shfl_xor(a1, off);
                a2 += __shfl_xor(a2, off); a3 += __shfl_xor(a3, off);
            }
            if (li < 4) sy.s[li][hh][j] = sel4(a0, a1, a2, a3, li) * scale;
        }
    }
    __syncthreads();

    // P3: softmax — 32 (row,head) pairs over 16 waves
    {
#pragma unroll
        for (int p = 0; p < 2; p++) {
            int pair = w * 2 + p;
            int i = pair >> 3, hh = pair & 7;
            float* row = sy.s[i][hh];
            float v0 = row[lane], v1 = row[lane + 64];
            float v2 = row[lane + 128], v3 = row[lane + 192];
            float m = fmaxf(fmaxf(v0, v1), fmaxf(v2, v3));
#pragma unroll
            for (int off = 32; off > 0; off >>= 1) m = fmaxf(m, __shfl_xor(m, off));
            float e0 = expf(v0 - m), e1 = expf(v1 - m);
            float e2 = expf(v2 - m), e3 = expf(v3 - m);
            float su = e0 + e1 + e2 + e3;
#pragma unroll
            for (int off = 32; off > 0; off >>= 1) su += __shfl_xor(su, off);
            float inv = 1.f / su;
            row[lane] = e0 * inv; row[lane + 64] = e1 * inv;
            row[lane + 128] = e2 * inv; row[lane + 192] = e3 * inv;
        }
    }
    __syncthreads();

    // P4: PV — thread owns (d, row)
    {
        int row = kq;
        int hh = f >> 5;
        const float* vcol = vin + (long)b * 65536 + f;
        const float* p0 = sy.s[row][hh];
        float a0 = 0.f;
#pragma unroll 4
        for (int j4 = 0; j4 < 64; j4++) {
            float4 pv0 = *(const float4*)(p0 + j4 * 4);
            float v0 = vcol[(long)(j4 * 4 + 0) * 256];
            float v1 = vcol[(long)(j4 * 4 + 1) * 256];
            float v2 = vcol[(long)(j4 * 4 + 2) * 256];
            float v3 = vcol[(long)(j4 * 4 + 3) * 256];
            a0 = fmaf(pv0.x, v0, a0); a0 = fmaf(pv0.y, v1, a0);
            a0 = fmaf(pv0.z, v2, a0); a0 = fmaf(pv0.w, v3, a0);
        }
        ao[row][f] = a0;
    }
    __syncthreads();

    // P5: O-proj (4-way k-split) + residual -> qb
    {
        const float* wt = woT_l + f;
        const int kb2 = kq * 64;
        float a0 = 0.f, a1 = 0.f, a2 = 0.f, a3 = 0.f;
        for (int k4 = 0; k4 < 16; k4++) {
            int kk = kb2 + k4 * 4;
            float w0 = wt[(kk + 0) << 8], w1 = wt[(kk + 1) << 8];
            float w2 = wt[(kk + 2) << 8], w3 = wt[(kk + 3) << 8];
            float4 x0 = *(const float4*)&ao[0][kk];
            float4 x1 = *(const float4*)&ao[1][kk];
            float4 x2 = *(const float4*)&ao[2][kk];
            float4 x3 = *(const float4*)&ao[3][kk];
            a0 = fmaf(w0, x0.x, a0); a0 = fmaf(w1, x0.y, a0);
            a0 = fmaf(w2, x0.z, a0); a0 = fmaf(w3, x0.w, a0);
            a1 = fmaf(w0, x1.x, a1); a1 = fmaf(w1, x1.y, a1);
            a1 = fmaf(w2, x1.z, a1); a1 = fmaf(w3, x1.w, a1);
            a2 = fmaf(w0, x2.x, a2); a2 = fmaf(w1, x2.y, a2);
            a2 = fmaf(w2, x2.z, a2); a2 = fmaf(w3, x2.w, a2);
            a3 = fmaf(w0, x3.x, a3); a3 = fmaf(w1, x3.y, a3);
            a3 = fmaf(w2, x3.z, a3); a3 = fmaf(w3, x3.w, a3);
        }
        pp[kq][0][f] = a0; pp[kq][1][f] = a1; pp[kq][2][f] = a2; pp[kq][3][f] = a3;
    }
    __syncthreads();
    {
        int r = kq;
        qb[r][f] = pp[0][r][f] + pp[1][r][f] + pp[2][r][f] + pp[3][r][f]
                 + bo_l[f] + zs[r][f];
    }
    __syncthreads();
    ln_reduce4(qb, mr, t);
    __syncthreads();
    {
        int r = kq;
        zs[r][f] = (qb[r][f] - mr[r][0]) * mr[r][1] * ln1g_l[f] + ln1b_l[f];
    }
    __syncthreads();

    // P7: FFN1 + gelu — thread owns one FFN dim (t), all 4 rows
    {
        const float* wt = c1T_l + t;
        float a0 = 0.f, a1 = 0.f, a2 = 0.f, a3 = 0.f;
        for (int k4 = 0; k4 < 64; k4++) {
            float w0 = wt[(k4 * 4 + 0) << 10], w1 = wt[(k4 * 4 + 1) << 10];
            float w2 = wt[(k4 * 4 + 2) << 10], w3 = wt[(k4 * 4 + 3) << 10];
            float4 x0 = *(const float4*)&zs[0][k4 * 4];
            float4 x1 = *(const float4*)&zs[1][k4 * 4];
            float4 x2 = *(const float4*)&zs[2][k4 * 4];
            float4 x3 = *(const float4*)&zs[3][k4 * 4];
            a0 = fmaf(w0, x0.x, a0); a0 = fmaf(w1, x0.y, a0);
            a0 = fmaf(w2, x0.z, a0); a0 = fmaf(w3, x0.w, a0);
            a1 = fmaf(w0, x1.x, a1); a1 = fmaf(w1, x1.y, a1);
            a1 = fmaf(w2, x1.z, a1); a1 = fmaf(w3, x1.w, a1);
            a2 = fmaf(w0, x2.x, a2); a2 = fmaf(w1, x2.y, a2);
            a2 = fmaf(w2, x2.z, a2); a2 = fmaf(w3, x2.w, a2);
            a3 = fmaf(w0, x3.x, a3); a3 = fmaf(w1, x3.y, a3);
            a3 = fmaf(w2, x3.z, a3); a3 = fmaf(w3, x3.w, a3);
        }
        float cb = c1b_l[t];
        sy.y[0][t] = gelu_f(a0 + cb);
        sy.y[1][t] = gelu_f(a1 + cb);
        sy.y[2][t] = gelu_f(a2 + cb);
        sy.y[3][t] = gelu_f(a3 + cb);
    }
    __syncthreads();

    // P8: FFN2 (4-way k-split over K=1024) + residual -> qb
    {
        const float* wt = c2T_l + f;
        const int kb2 = kq * 256;
        float a0 = 0.f, a1 = 0.f, a2 = 0.f, a3 = 0.f;
        for (int k4 = 0; k4 < 64; k4++) {
            int kk = kb2 + k4 * 4;
            float w0 = wt[(kk + 0) << 8], w1 = wt[(kk + 1) << 8];
            float w2 = wt[(kk + 2) << 8], w3 = wt[(kk + 3) << 8];
            float4 y0 = *(const float4*)&sy.y[0][kk];
            float4 y1 = *(const float4*)&sy.y[1][kk];
            float4 y2 = *(const float4*)&sy.y[2][kk];
            float4 y3 = *(const float4*)&sy.y[3][kk];
            a0 = fmaf(w0, y0.x, a0); a0 = fmaf(w1, y0.y, a0);
            a0 = fmaf(w2, y0.z, a0); a0 = fmaf(w3, y0.w, a0);
            a1 = fmaf(w0, y1.x, a1); a1 = fmaf(w1, y1.y, a1);
            a1 = fmaf(w2, y1.z, a1); a1 = fmaf(w3, y1.w, a1);
            a2 = fmaf(w0, y2.x, a2); a2 = fmaf(w1, y2.y, a2);
            a2 = fmaf(w2, y2.z, a2); a2 = fmaf(w3, y2.w, a2);
            a3 = fmaf(w0, y3.x, a3); a3 = fmaf(w1, y3.y, a3);
            a3 = fmaf(w2, y3.z, a3); a3 = fmaf(w3, y3.w, a3);
        }
        pp[kq][0][f] = a0; pp[kq][1][f] = a1; pp[kq][2][f] = a2; pp[kq][3][f] = a3;
    }
    __syncthreads();
    {
        int r = kq;
        qb[r][f] = pp[0][r][f] + pp[1][r][f] + pp[2][r][f] + pp[3][r][f]
                 + c2b_l[f] + zs[r][f];
    }
    __syncthreads();
    ln_reduce4(qb, mr, t);
    __syncthreads();
    {
        int r = kq;
        float z2 = (qb[r][f] - mr[r][0]) * mr[r][1] * ln2g_l[f] + ln2b_l[f];
        zs[r][f] = z2;
        zout[(rowg0 + r) * 256 + f] = z2;
    }
    __syncthreads();

    if (!LAST) {
        // P9: QKV projections for next layer (4-way k-split, each W read once)
        const int kb2 = kq * 64;
        for (int mat = 0; mat < 3; mat++) {
            const float* wt = (mat == 0 ? wqT_n : mat == 1 ? wkT_n : wvT_n) + f;
            float a0 = 0.f, a1 = 0.f, a2 = 0.f, a3 = 0.f;
            for (int k4 = 0; k4 < 16; k4++) {
                int kk = kb2 + k4 * 4;
                float w0 = wt[(kk + 0) << 8], w1 = wt[(kk + 1) << 8];
                float w2 = wt[(kk + 2) << 8], w3 = wt[(kk + 3) << 8];
                float4 x0 = *(const float4*)&zs[0][kk];
                float4 x1 = *(const float4*)&zs[1][kk];
                float4 x2 = *(const float4*)&zs[2][kk];
                float4 x3 = *(const float4*)&zs[3][kk];
                a0 = fmaf(w0, x0.x, a0); a0 = fmaf(w1, x0.y, a0);
                a0 = fmaf(w2, x0.z, a0); a0 = fmaf(w3, x0.w, a0);
                a1 = fmaf(w0, x1.x, a1); a1 = fmaf(w1, x1.y, a1);
                a1 = fmaf(w2, x1.z, a1); a1 = fmaf(w3, x1.w, a1);
                a2 = fmaf(w0, x2.x, a2); a2 = fmaf(w1, x2.y, a2);
                a2 = fmaf(w2, x2.z, a2); a2 = fmaf(w3, x2.w, a2);
                a3 = fmaf(w0, x3.x, a3); a3 = fmaf(w1, x3.y, a3);
                a3 = fmaf(w2, x3.z, a3); a3 = fmaf(w3, x3.w, a3);
            }
            pp[kq][0][f] = a0; pp[kq][1][f] = a1; pp[kq][2][f] = a2; pp[kq][3][f] = a3;
            __syncthreads();
            {
                float bvv = (mat == 0 ? bq_n : mat == 1 ? bk_n : bv_n)[f];
                float* op = (mat == 0 ? qo : mat == 1 ? ko : vo);
                int r = kq;
                op[(rowg0 + r) * 256 + f] = pp[0][r][f] + pp[1][r][f] + pp[2][r][f] + pp[3][r][f] + bvv;
            }
            __syncthreads();
        }
    } else {
        ln_reduce4(zs, mr, t);
        __syncthreads();
        {
            int r = kq;
            lnf_out[(rowg0 + r) * 256 + f] =
                (zs[r][f] - mr[r][0]) * mr[r][1] * lnfg[f] + lnfb[f];
        }
    }
}

// ---------------- final: pooled mean over seq -> proj ----------------
__global__ __launch_bounds__(256)
void final_kernel(const float* __restrict__ zf, const float* __restrict__ pw,
                  const float* __restrict__ pb, float* __restrict__ out) {
    __shared__ float sm[8];
    int b = blockIdx.x, d = threadIdx.x;
    float s = 0.f;
    for (int c = 0; c < 256; c++) s += zf[((long)(b * 256 + c)) * 256 + d];
    float pooled = s * (1.f / 256.f);
    float c0 = pooled * pw[d], c1 = pooled * pw[256 + d];
    for (int off = 32; off > 0; off >>= 1) { c0 += __shfl_down(c0, off); c1 += __shfl_down(c1, off); }
    int lane = d & 63, wv = d >> 6;
    if (lane == 0) { sm[wv] = c0; sm[4 + wv] = c1; }
    __syncthreads();
    if (d == 0) {
        out[b * 2 + 0] = sm[0] + sm[1] + sm[2] + sm[3] + pb[0];
        out[b * 2 + 1] = sm[4] + sm[5] + sm[6] + sm[7] + pb[1];
    }
}

extern "C" void kernel_launch(void* const* d_in, const int* in_sizes, int n_in,
                              void* d_out, int out_size, void* d_ws, size_t ws_size,
                              hipStream_t stream) {
    const float* x       = (const float*)d_in[0];
    const float* filters = (const float*)d_in[1];
    const float* bn1_g   = (const float*)d_in[2];
    const float* bn1_b   = (const float*)d_in[3];
    const float* emb_w   = (const float*)d_in[4];
    const float* emb_b   = (const float*)d_in[5];
    const float* embbn_g = (const float*)d_in[6];
    const float* embbn_b = (const float*)d_in[7];
    const float* wq      = (const float*)d_in[8];
    const float* bq      = (const float*)d_in[9];
    const float* wk      = (const float*)d_in[10];
    const float* bk      = (const float*)d_in[11];
    const float* wv      = (const float*)d_in[12];
    const float* bv      = (const float*)d_in[13];
    const float* wo      = (const float*)d_in[14];
    const float* bo      = (const float*)d_in[15];
    const float* c1w     = (const float*)d_in[16];
    const float* c1b     = (const float*)d_in[17];
    const float* c2w     = (const float*)d_in[18];
    const float* c2b     = (const float*)d_in[19];
    const float* ln1g    = (const float*)d_in[20];
    const float* ln1b    = (const float*)d_in[21];
    const float* ln2g    = (const float*)d_in[22];
    const float* ln2b    = (const float*)d_in[23];
    const float* lnfg    = (const float*)d_in[24];
    const float* lnfb    = (const float*)d_in[25];
    const float* projw   = (const float*)d_in[26];
    const float* projb   = (const float*)d_in[27];

    const long wpackF = 2752512L;                   // 8*NKC*512 shorts, in floats
    const long wTF = 3145728L;                      // transposed layer weights
    const long fixedF = 22005760L + 5120 + wpackF + 9L * 262144 + wTF;
    long wsFloats = (long)(ws_size / 4);
    long Z = 32;
    while (Z > 8 && fixedF + Z * 262144L > wsFloats) Z >>= 1;
    const int kPerZ = KEMBP / (int)Z;

    float* ws = (float*)d_ws;
    float* h_raw  = ws;                             // 22,005,760
    float* bn1_sc = h_raw + 22005760;
    float* bn1_sh = bn1_sc + 256;
    float* e_sc   = bn1_sh + 256;
    float* e_sh   = e_sc + 256;
    float* bnp1   = e_sh + 256;                     // 2048
    float* bnp2   = bnp1 + 2048;                    // 2048
    float* part   = bnp2 + 2048;                    // Z * 262144
    float* wsp    = part + Z * 262144L;
    short* wpH    = (short*)wsp;                    // 8*NKC*512 shorts
    float* e      = wsp + wpackF;
    float* z      = e + 262144;
    float* qA     = z + 262144;
    float* kA     = qA + 262144;
    float* vA     = kA + 262144;
    float* qB     = vA + 262144;
    float* kB     = qB + 262144;
    float* vB     = kB + 262144;
    float* t1     = vB + 262144;
    float* wqT    = t1 + 262144;                    // 4*65536
    float* wkT    = wqT + 262144;
    float* wvT    = wkT + 262144;
    float* woT    = wvT + 262144;
    float* c1T    = woT + 262144;                   // 4*262144
    float* c2T    = c1T + 1048576;

    // conv packed filters alias onto `part` (only used before embed writes part)
    short* fpH = (short*)part;                      // 520*512 shorts

    filt_pack_kernel<<<520, 512, 0, stream>>>(filters, fpH);
    wpack_kernel<<<8 * NKC, 512, 0, stream>>>(emb_w, wpH);
    wtrans_kernel<<<3072, dim3(32, 8), 0, stream>>>(wq, wk, wv, wo, c1w, c2w,
                                                    wqT, wkT, wvT, woT, c1T, c2T);
    conv_mfma_kernel<<<dim3(672, 4), 512, 0, stream>>>(x, fpH, h_raw);
    bn_part_kernel<<<dim3(256, 8), 256, 0, stream>>>(h_raw, bnp1, bnp2);
    bn_fin_kernel<<<1, 256, 0, stream>>>(bnp1, bnp2, bn1_g, bn1_b, bn1_sc, bn1_sh);
    embed_mfma_kernel<<<dim3(8, 2, (int)Z), 256, 0, stream>>>(h_raw, wpH,
                                                              bn1_sc, bn1_sh, part, kPerZ);
    embed_combine_kernel<<<1024, 256, 0, stream>>>(part, emb_b, e, (int)Z);
    bn_stats_kernel<<<256, 256, 0, stream>>>(e, embbn_g, embbn_b, e_sc, e_sh,
                                             256, 256L * 256);
    qkv_init_kernel<<<256, 512, 0, stream>>>(e, e_sc, e_sh, wqT, bq, wkT, bk, wvT, bv,
                                             z, qA, kA, vA);

    float* qs[2][3] = {{qA, kA, vA}, {qB, kB, vB}};
    for (int l = 0; l < 4; l++) {
        float** in = qs[l & 1];
        float** ou = qs[(l + 1) & 1];
        const float* woT_l = woT + (long)l * 65536; const float* bo_l = bo + l * 256;
        const float* c1T_l = c1T + (long)l * 262144; const float* c1b_l = c1b + l * 1024;
        const float* c2T_l = c2T + (long)l * 262144; const float* c2b_l = c2b + l * 256;
        const float* l1g = ln1g + l * 256; const float* l1b = ln1b + l * 256;
        const float* l2g = ln2g + l * 256; const float* l2b = ln2b + l * 256;
        if (l < 3) {
            const float* wqT_n = wqT + (long)(l + 1) * 65536; const float* bq_n = bq + (l + 1) * 256;
            const float* wkT_n = wkT + (long)(l + 1) * 65536; const float* bk_n = bk + (l + 1) * 256;
            const float* wvT_n = wvT + (long)(l + 1) * 65536; const float* bv_n = bv + (l + 1) * 256;
            layer_kernel<0><<<256, 1024, 0, stream>>>(z, in[0], in[1], in[2],
                woT_l, bo_l, c1T_l, c1b_l, c2T_l, c2b_l, l1g, l1b, l2g, l2b,
                wqT_n, bq_n, wkT_n, bk_n, wvT_n, bv_n, lnfg, lnfb,
                z, ou[0], ou[1], ou[2], t1);
        } else {
            layer_kernel<1><<<256, 1024, 0, stream>>>(z, in[0], in[1], in[2],
                woT_l, bo_l, c1T_l, c1b_l, c2T_l, c2b_l, l1g, l1b, l2g, l2b,
                wqT, bq, wkT, bk, wvT, bv, lnfg, lnfb,
                z, ou[0], ou[1], ou[2], t1);
        }
    }

    final_kernel<<<4, 256, 0, stream>>>(t1, projw, projb, (float*)d_out);
}

// Round 9
// 690.170 us; speedup vs baseline: 5.4516x; 1.0413x over previous
//
#include <hip/hip_runtime.h>
#include <math.h>

#define L_IN 65494
#define T_POOL 21490
#define TPP 21496          // fp16 h row stride (16B-aligned rows)
#define KF 1025
#define RS 1144            // conv replica row stride (elements)
#define CWIN 1136          // conv x window per block: 96 + 1040
#define KEMB 21490
#define KEMBP 21504        // padded
#define NKC 1344           // KEMBP/16
#define FTILE 33280        // 65*512 shorts per conv filter tile

typedef short s16x4 __attribute__((ext_vector_type(4)));
typedef _Float16 f16x8 __attribute__((ext_vector_type(8)));
typedef float f32x16 __attribute__((ext_vector_type(16)));

__device__ inline float selu_f(float x) {
    float e = expf(fminf(x, 0.f));
    float neg = 1.6732632423543772f * (e - 1.f);
    return 1.0507009873554805f * (x > 0.f ? x : neg);
}

__device__ inline float gelu_f(float x) {
    return 0.5f * x * (1.f + erff(x * 0.7071067811865476f));
}

__device__ inline float dot4(float4 a, float4 b) {
    return fmaf(a.x, b.x, fmaf(a.y, b.y, fmaf(a.z, b.z, a.w * b.w)));
}

__device__ inline float sel4(float a0, float a1, float a2, float a3, int i) {
    float r = a0;
    r = (i == 1) ? a1 : r;
    r = (i == 2) ? a2 : r;
    r = (i == 3) ? a3 : r;
    return r;
}

__device__ inline short f2h_bits(float v) {
    _Float16 h = (_Float16)v;
    return *(short*)&h;
}

// x = hi + lo in fp16 (hi RTNE, lo = residual): exact to ~2^-22
__device__ inline void f16split(float v, short& hs, short& ls) {
    _Float16 h = (_Float16)v;
    float hf = (float)h;
    _Float16 l = (_Float16)(v - hf);
    hs = *(short*)&h;
    ls = *(short*)&l;
}

// ---------------- filter pack: fp16 single, fragment-major [ft][kc][lane][8] ----------------
__global__ __launch_bounds__(512)
void filt_pack_kernel(const float* __restrict__ filt, short* __restrict__ fpH) {
    int blk = blockIdx.x;            // ft*65 + kc  (grid 520)
    int ft = blk / 65, kc = blk % 65;
    int t = threadIdx.x, lane = t >> 3, e = t & 7;
    int f = ft * 32 + (lane & 31);
    int tap = kc * 16 + (lane >> 5) * 8 + e;
    float v = (tap < KF) ? filt[f * KF + tap] : 0.f;
    fpH[blk * 512 + t] = f2h_bits(v);
}

// ---------------- emb_w pack: fp16 single, fragment-major [ft][kc][lane][8] ----------------
__global__ __launch_bounds__(512)
void wpack_kernel(const float* __restrict__ wsrc, short* __restrict__ wpH) {
    int blk = blockIdx.x;            // ft*NKC + kc  (grid 8*NKC)
    int ft = blk / NKC, kc = blk % NKC;
    int t = threadIdx.x, lane = t >> 3, e = t & 7;
    int row = ft * 32 + (lane & 31);
    int tap = kc * 16 + (lane >> 5) * 8 + e;
    float v = (tap < KEMB) ? wsrc[(long)row * KEMB + tap] : 0.f;
    wpH[(long)blk * 512 + t] = f2h_bits(v);
}

// ---------------- weight transpose pack: Wt[k][f] = W[f][k] ----------------
__device__ inline void transpose_tile(const float* __restrict__ src, float* __restrict__ dst,
                                      int F, int K, int tf, int tk) {
    __shared__ float tile[32][33];
    int tx = threadIdx.x, ty = threadIdx.y;  // 32 x 8
#pragma unroll
    for (int r = 0; r < 4; r++) {
        int fi = tf * 32 + ty * 4 + r;
        tile[ty * 4 + r][tx] = src[(long)fi * K + tk * 32 + tx];
    }
    __syncthreads();
#pragma unroll
    for (int r = 0; r < 4; r++) {
        int ki = tk * 32 + ty * 4 + r;
        dst[(long)ki * F + tf * 32 + tx] = tile[tx][ty * 4 + r];
    }
}

__global__ __launch_bounds__(256)
void wtrans_kernel(const float* __restrict__ wq, const float* __restrict__ wk,
                   const float* __restrict__ wv, const float* __restrict__ wo,
                   const float* __restrict__ c1w, const float* __restrict__ c2w,
                   float* __restrict__ wqT, float* __restrict__ wkT,
                   float* __restrict__ wvT, float* __restrict__ woT,
                   float* __restrict__ c1T, float* __restrict__ c2T) {
    int bx = blockIdx.x;
    if (bx < 1024) {
        int m = bx >> 6, tile = bx & 63;
        int which = m >> 2, l = m & 3;
        int tk = tile >> 3, tf = tile & 7;
        const float* s; float* dd;
        if (which == 0) { s = wq; dd = wqT; }
        else if (which == 1) { s = wk; dd = wkT; }
        else if (which == 2) { s = wv; dd = wvT; }
        else { s = wo; dd = woT; }
        transpose_tile(s + l * 65536, dd + l * 65536, 256, 256, tf, tk);
    } else if (bx < 2048) {
        int b2 = bx - 1024, l = b2 >> 8, tile = b2 & 255;
        int tf = tile & 31, tk = tile >> 5;
        transpose_tile(c1w + (long)l * 262144, c1T + (long)l * 262144, 1024, 256, tf, tk);
    } else {
        int b2 = bx - 2048, l = b2 >> 8, tile = b2 & 255;
        int tf = tile & 7, tk = tile >> 3;
        transpose_tile(c2w + (long)l * 262144, c2T + (long)l * 262144, 256, 1024, tf, tk);
    }
}

// ---------------- SincConv via MFMA (fp16 2-pass) + |.| + maxpool3 ----------------
// 256 threads = 4 waves; wave owns 64 filters (2 B-tiles). 8-way shifted x replicas.
union ConvLDS {
    struct { short xh[8][RS]; short xl[8][RS]; } st;
    float ebuf[96][129];
};

#define MFMA2(ACC, AH, AL, BH) \
    ACC = __builtin_amdgcn_mfma_f32_32x32x16_f16(AL, BH, ACC, 0, 0, 0); \
    ACC = __builtin_amdgcn_mfma_f32_32x32x16_f16(AH, BH, ACC, 0, 0, 0);

__global__ __launch_bounds__(256, 3)
void conv_mfma_kernel(const float* __restrict__ x, const short* __restrict__ fpH,
                      _Float16* __restrict__ h) {
    __shared__ ConvLDS u;
    const int tid = threadIdx.x;
    const int pb = blockIdx.x;
    const int b = blockIdx.y;
    const int t0 = pb * 96;

    for (int i = tid; i < CWIN; i += 256) {
        int gi = t0 + i;
        float v = (gi < L_IN) ? x[b * L_IN + gi] : 0.f;
        short hs, ls;
        f16split(v, hs, ls);
#pragma unroll
        for (int s = 0; s < 8; s++) {
            int e = i - s;
            if (e >= 0) { u.st.xh[s][e] = hs; u.st.xl[s][e] = ls; }
        }
    }
    __syncthreads();

    const int lane = tid & 63;
    const int wid = tid >> 6;      // 0..3, wave owns filters [wid*64, wid*64+64)
    const int l31 = lane & 31;
    const int hi = lane >> 5;
    const int f0w = wid * 64;

    const short* aH = &u.st.xh[l31 & 7][8 * (l31 >> 3) + 8 * hi];
    const short* aL = &u.st.xl[l31 & 7][8 * (l31 >> 3) + 8 * hi];
    const short* bp0 = fpH + (long)(wid * 2) * FTILE + lane * 8;
    const short* bp1 = bp0 + FTILE;

    f32x16 a00 = {0}, a01 = {0}, a10 = {0}, a11 = {0}, a20 = {0}, a21 = {0};

#pragma unroll 1
    for (int kc = 0; kc < 65; kc++) {
        const int ko = kc * 16;
        const int kf = kc * 512;
        f16x8 ah0 = *(const f16x8*)(aH + ko);
        f16x8 ah1 = *(const f16x8*)(aH + ko + 32);
        f16x8 ah2 = *(const f16x8*)(aH + ko + 64);
        f16x8 al0 = *(const f16x8*)(aL + ko);
        f16x8 al1 = *(const f16x8*)(aL + ko + 32);
        f16x8 al2 = *(const f16x8*)(aL + ko + 64);
        f16x8 bh0 = *(const f16x8*)(bp0 + kf);
        f16x8 bh1 = *(const f16x8*)(bp1 + kf);
        MFMA2(a00, ah0, al0, bh0)
        MFMA2(a01, ah0, al0, bh1)
        MFMA2(a10, ah1, al1, bh0)
        MFMA2(a11, ah1, al1, bh1)
        MFMA2(a20, ah2, al2, bh0)
        MFMA2(a21, ah2, al2, bh1)
    }

    __syncthreads();
    const int t3l = tid & 31;
    const int t3 = pb * 32 + t3l;

#pragma unroll
    for (int half = 0; half < 2; half++) {
        if ((wid >> 1) == half) {
            int fcb = f0w - half * 128;
#define WRF(ACC, MT, NT)                                                   \
            {                                                              \
                int fc = fcb + NT * 32 + l31;                              \
                _Pragma("unroll")                                          \
                for (int r = 0; r < 16; r++) {                             \
                    int pos = MT * 32 + (r & 3) + 8 * (r >> 2) + 4 * hi;   \
                    u.ebuf[pos][fc] = fabsf(ACC[r]);                       \
                }                                                          \
            }
            WRF(a00, 0, 0) WRF(a01, 0, 1)
            WRF(a10, 1, 0) WRF(a11, 1, 1)
            WRF(a20, 2, 0) WRF(a21, 2, 1)
#undef WRF
        }
        __syncthreads();
        if (t3 < T_POOL) {
            for (int ff = tid >> 5; ff < 128; ff += 8) {
                float v = fmaxf(fmaxf(u.ebuf[3 * t3l][ff], u.ebuf[3 * t3l + 1][ff]),
                                u.ebuf[3 * t3l + 2][ff]);
                h[((long)(b * 256 + half * 128 + ff)) * TPP + t3] = (_Float16)v;
            }
        }
        __syncthreads();
    }
}

// ---------------- BatchNorm stats for h (fp16): two-stage ----------------
__global__ __launch_bounds__(256)
void bn_part_kernel(const _Float16* __restrict__ xin, float* __restrict__ p1,
                    float* __restrict__ p2) {
    __shared__ float sm[8];
    int c = blockIdx.x, s = blockIdx.y, tid = threadIdx.x;
    int t0 = s * 2687, t1 = min(T_POOL, t0 + 2687);
    float s1 = 0.f, s2 = 0.f;
    for (int b = 0; b < 4; b++) {
        const _Float16* p = xin + (long)b * 256 * TPP + (long)c * TPP;
        for (int t = t0 + tid; t < t1; t += 256) {
            float v = (float)p[t];
            s1 += v;
            s2 = fmaf(v, v, s2);
        }
    }
    for (int off = 32; off > 0; off >>= 1) { s1 += __shfl_down(s1, off); s2 += __shfl_down(s2, off); }
    int lane = tid & 63, wv = tid >> 6;
    if (lane == 0) { sm[wv] = s1; sm[4 + wv] = s2; }
    __syncthreads();
    if (tid == 0) {
        p1[c * 8 + s] = sm[0] + sm[1] + sm[2] + sm[3];
        p2[c * 8 + s] = sm[4] + sm[5] + sm[6] + sm[7];
    }
}

__global__ __launch_bounds__(256)
void bn_fin_kernel(const float* __restrict__ p1, const float* __restrict__ p2,
                   const float* __restrict__ g, const float* __restrict__ bb,
                   float* __restrict__ sc, float* __restrict__ sh) {
    int c = threadIdx.x;
    float S1 = 0.f, S2 = 0.f;
#pragma unroll
    for (int s = 0; s < 8; s++) { S1 += p1[c * 8 + s]; S2 += p2[c * 8 + s]; }
    float n = 4.f * (float)T_POOL;
    float mean = S1 / n;
    float var = S2 / n - mean * mean;
    float rstd = rsqrtf(var + 1e-5f);
    float gc = g[c], bc = bb[c];
    sc[c] = rstd * gc;
    sh[c] = bc - mean * rstd * gc;
}

// ---------------- BatchNorm stats (small, for e) ----------------
__global__ __launch_bounds__(256)
void bn_stats_kernel(const float* __restrict__ xin, const float* __restrict__ g,
                     const float* __restrict__ bb, float* __restrict__ sc,
                     float* __restrict__ sh, int ilen, long bstride) {
    __shared__ float sm[8];
    int c = blockIdx.x, tid = threadIdx.x;
    float s1 = 0.f, s2 = 0.f;
    for (int b = 0; b < 4; b++) {
        const float* p = xin + b * bstride + (long)c * ilen;
        for (int t = tid; t < ilen; t += 256) {
            float v = p[t];
            s1 += v;
            s2 = fmaf(v, v, s2);
        }
    }
    for (int off = 32; off > 0; off >>= 1) { s1 += __shfl_down(s1, off); s2 += __shfl_down(s2, off); }
    int lane = tid & 63, wv = tid >> 6;
    if (lane == 0) { sm[wv] = s1; sm[4 + wv] = s2; }
    __syncthreads();
    if (tid == 0) {
        float S1 = sm[0] + sm[1] + sm[2] + sm[3];
        float S2 = sm[4] + sm[5] + sm[6] + sm[7];
        float n = 4.f * (float)ilen;
        float mean = S1 / n;
        float var = S2 / n - mean * mean;
        float rstd = rsqrtf(var + 1e-5f);
        float gc = g[c], bc = bb[c];
        sc[c] = rstd * gc;
        sh[c] = bc - mean * rstd * gc;
    }
}

// ---------------- Embedding GEMM via MFMA (fp16 2-pass), split-K, packed B ----------------
__global__ __launch_bounds__(256, 2)
void embed_mfma_kernel(const _Float16* __restrict__ H, const short* __restrict__ Wh,
                       const float* __restrict__ sc, const float* __restrict__ sh,
                       float* __restrict__ P, int kPerZ) {
    __shared__ short Ah[128][36];
    __shared__ short Al[128][36];
    const int tid = threadIdx.x;
    const int rowBase = blockIdx.x * 128;
    const int colBase = blockIdx.y * 128;
    const int z = blockIdx.z;
    const int kz = z * kPerZ;
    const int iters = kPerZ >> 5;

    const int trow = tid >> 1, th = (tid & 1) * 16;
    const int arow = rowBase + trow;
    const float asc = sc[arow & 255], ash = sh[arow & 255];
    const _Float16* Ap = H + (long)arow * TPP;

    const int lane = tid & 63, wid = tid >> 6;
    const int l31 = lane & 31, hi = lane >> 5;
    const int wm = wid >> 1, wn = wid & 1;

    const short* bhp[2];
#pragma unroll
    for (int nt = 0; nt < 2; nt++) {
        int ft = (colBase >> 5) + wn * 2 + nt;
        bhp[nt] = Wh + (long)ft * NKC * 512 + lane * 8;
    }

    f32x16 acc[2][2] = {{{0}, {0}}, {{0}, {0}}};

    for (int it = 0; it < iters; it++) {
        const int k0 = kz + it * 32;
        __syncthreads();
        float av[16];
        if (k0 + 32 <= KEMB) {
            const f16x8* p8 = (const f16x8*)(Ap + k0 + th);
            f16x8 v0 = p8[0], v1 = p8[1];
#pragma unroll
            for (int e = 0; e < 8; e++) { av[e] = (float)v0[e]; av[8 + e] = (float)v1[e]; }
        } else {
#pragma unroll
            for (int e = 0; e < 16; e++) {
                int k = k0 + th + e;
                av[e] = (k < KEMB) ? (float)Ap[k] : 0.f;
            }
        }
#pragma unroll
        for (int q = 0; q < 4; q++) {
            s16x4 h4, l4;
#pragma unroll
            for (int e = 0; e < 4; e++) {
                float v = selu_f(fmaf(av[q * 4 + e], asc, ash));
                short hs, ls;
                f16split(v, hs, ls);
                h4[e] = hs; l4[e] = ls;
            }
            *(s16x4*)&Ah[trow][th + q * 4] = h4;
            *(s16x4*)&Al[trow][th + q * 4] = l4;
        }
        __syncthreads();

#pragma unroll
        for (int ks = 0; ks < 2; ks++) {
            const int kloc = ks * 16 + hi * 8;
            const long kcg = (long)((k0 >> 4) + ks) * 512;
            f16x8 ah[2], al[2], bh[2];
#pragma unroll
            for (int mt = 0; mt < 2; mt++) {
                const int r = wm * 64 + mt * 32 + l31;
                const short* ph = &Ah[r][kloc];
                const short* pl = &Al[r][kloc];
                union { f16x8 v; unsigned long long q[2]; } uh, ul;
                uh.q[0] = *(const unsigned long long*)(ph);
                uh.q[1] = *(const unsigned long long*)(ph + 4);
                ul.q[0] = *(const unsigned long long*)(pl);
                ul.q[1] = *(const unsigned long long*)(pl + 4);
                ah[mt] = uh.v; al[mt] = ul.v;
            }
#pragma unroll
            for (int nt = 0; nt < 2; nt++)
                bh[nt] = *(const f16x8*)(bhp[nt] + kcg);
#pragma unroll
            for (int mt = 0; mt < 2; mt++)
#pragma unroll
                for (int nt = 0; nt < 2; nt++) {
                    MFMA2(acc[mt][nt], ah[mt], al[mt], bh[nt])
                }
        }
    }

    float* Pz = P + (long)z * 262144;
#pragma unroll
    for (int mt = 0; mt < 2; mt++)
#pragma unroll
        for (int nt = 0; nt < 2; nt++) {
            int col = colBase + wn * 64 + nt * 32 + l31;
#pragma unroll
            for (int r = 0; r < 16; r++) {
                int row = rowBase + wm * 64 + mt * 32 + (r & 3) + 8 * (r >> 2) + 4 * hi;
                Pz[(long)row * 256 + col] = acc[mt][nt][r];
            }
        }
}

__global__ __launch_bounds__(256)
void embed_combine_kernel(const float* __restrict__ P, const float* __restrict__ eb,
                          float* __restrict__ e, int nsplit) {
    int idx = blockIdx.x * 256 + threadIdx.x;
    float s = 0.f;
    for (int z = 0; z < nsplit; z++) s += P[(long)z * 262144 + idx];
    e[idx] = s + eb[idx & 255];
}

// ---------------- fused zinit + layer-0 QKV (k-split, W read once/block) ----------------
__global__ __launch_bounds__(512)
void qkv_init_kernel(const float* __restrict__ e, const float* __restrict__ sc,
                     const float* __restrict__ sh,
                     const float* __restrict__ wqT0, const float* __restrict__ bq0,
                     const float* __restrict__ wkT0, const float* __restrict__ bk0,
                     const float* __restrict__ wvT0, const float* __restrict__ bv0,
                     float* __restrict__ z, float* __restrict__ qo,
                     float* __restrict__ ko, float* __restrict__ vo) {
    __shared__ float zs[4][256];
    __shared__ float pp[2][4][256];
    const int t = threadIdx.x;
    const long rowg0 = (long)blockIdx.x * 4;

    for (int idx = t; idx < 1024; idx += 512) {
        int i = idx >> 8, dd = idx & 255;
        int c = (int)((rowg0 + i) & 255);
        float v = fmaf(e[(rowg0 + i) * 256 + dd], sc[c], sh[c]);
        v = fmaxf(v, 0.f);
        int i2 = dd >> 1;
        float ang = (float)c * expf(-0.03597789207803195f * (float)(2 * i2));
        float pe = (dd & 1) ? cosf(ang) : sinf(ang);
        float zz = v + pe;
        zs[i][dd] = zz;
        z[(rowg0 + i) * 256 + dd] = zz;
    }
    __syncthreads();

    const int f = t & 255, kh = t >> 8, kb = kh * 128;
    for (int mat = 0; mat < 3; mat++) {
        const float* wt = (mat == 0 ? wqT0 : mat == 1 ? wkT0 : wvT0) + f;
        float a0 = 0.f, a1 = 0.f, a2 = 0.f, a3 = 0.f;
        for (int k4 = 0; k4 < 32; k4++) {
            int kk = kb + k4 * 4;
            float w0 = wt[(kk + 0) << 8], w1 = wt[(kk + 1) << 8];
            float w2 = wt[(kk + 2) << 8], w3 = wt[(kk + 3) << 8];
            float4 x0 = *(const float4*)&zs[0][kk];
            float4 x1 = *(const float4*)&zs[1][kk];
            float4 x2 = *(const float4*)&zs[2][kk];
            float4 x3 = *(const float4*)&zs[3][kk];
            a0 = fmaf(w0, x0.x, a0); a0 = fmaf(w1, x0.y, a0);
            a0 = fmaf(w2, x0.z, a0); a0 = fmaf(w3, x0.w, a0);
            a1 = fmaf(w0, x1.x, a1); a1 = fmaf(w1, x1.y, a1);
            a1 = fmaf(w2, x1.z, a1); a1 = fmaf(w3, x1.w, a1);
            a2 = fmaf(w0, x2.x, a2); a2 = fmaf(w1, x2.y, a2);
            a2 = fmaf(w2, x2.z, a2); a2 = fmaf(w3, x2.w, a2);
            a3 = fmaf(w0, x3.x, a3); a3 = fmaf(w1, x3.y, a3);
            a3 = fmaf(w2, x3.z, a3); a3 = fmaf(w3, x3.w, a3);
        }
        pp[kh][0][f] = a0; pp[kh][1][f] = a1; pp[kh][2][f] = a2; pp[kh][3][f] = a3;
        __syncthreads();
        {
            float bvv = (mat == 0 ? bq0 : mat == 1 ? bk0 : bv0)[f];
            float* op = (mat == 0 ? qo : mat == 1 ? ko : vo);
            int r0 = (t >> 8) * 2;
            op[(rowg0 + r0) * 256 + f] = pp[0][r0][f] + pp[1][r0][f] + bvv;
            op[(rowg0 + r0 + 1) * 256 + f] = pp[0][r0 + 1][f] + pp[1][r0 + 1][f] + bvv;
        }
        __syncthreads();
    }
}

// ---------------- fused transformer layer: 1024 threads, 4-way k-split ----------------
__device__ inline void ln_reduce4(const float (*buf)[256], float (*mr)[2], int t) {
    int wid = t >> 6, lane = t & 63;
    if (wid < 4) {
        float4 v = *(const float4*)&buf[wid][lane * 4];
        float s = v.x + v.y + v.z + v.w;
        float q = v.x * v.x + v.y * v.y + v.z * v.z + v.w * v.w;
#pragma unroll
        for (int off = 32; off > 0; off >>= 1) {
            s += __shfl_xor(s, off);
            q += __shfl_xor(q, off);
        }
        if (lane == 0) {
            float mean = s * (1.f / 256.f);
            float var = q * (1.f / 256.f) - mean * mean;
            mr[wid][0] = mean;
            mr[wid][1] = rsqrtf(var + 1e-5f);
        }
    }
}

template <int LAST>
__global__ __launch_bounds__(1024)
void layer_kernel(const float* __restrict__ zin, const float* __restrict__ qin,
                  const float* __restrict__ kin, const float* __restrict__ vin,
                  const float* __restrict__ woT_l, const float* __restrict__ bo_l,
                  const float* __restrict__ c1T_l, const float* __restrict__ c1b_l,
                  const float* __restrict__ c2T_l, const float* __restrict__ c2b_l,
                  const float* __restrict__ ln1g_l, const float* __restrict__ ln1b_l,
                  const float* __restrict__ ln2g_l, const float* __restrict__ ln2b_l,
                  const float* __restrict__ wqT_n, const float* __restrict__ bq_n,
                  const float* __restrict__ wkT_n, const float* __restrict__ bk_n,
                  const float* __restrict__ wvT_n, const float* __restrict__ bv_n,
                  const float* __restrict__ lnfg, const float* __restrict__ lnfb,
                  float* __restrict__ zout, float* __restrict__ qo,
                  float* __restrict__ ko, float* __restrict__ vo,
                  float* __restrict__ lnf_out) {
    __shared__ float zs[4][256];
    __shared__ float qb[4][256];
    __shared__ float ao[4][256];
    __shared__ float pp[4][4][256];
    __shared__ union { float s[4][8][256]; float y[4][1024]; } sy;
    __shared__ float mr[4][2];

    const int t = threadIdx.x;
    const int w = t >> 6, lane = t & 63;
    const long rowg0 = (long)blockIdx.x * 4;
    const int b = blockIdx.x >> 6;

    const int f = t & 255;       // output dim for 256-wide phases
    const int kq = t >> 8;       // k-quarter 0..3

    // P1: stage z (residual) and q rows — one element per thread
    {
        int r = t >> 8, dd = t & 255;
        zs[r][dd] = zin[(rowg0 + r) * 256 + dd];
        qb[r][dd] = qin[(rowg0 + r) * 256 + dd];
    }
    __syncthreads();

    // P2: scores — wave pair per head: head = w>>1, j-half = w&1
    {
        const float scale = 0.17677669529663687f;
        const int jq = lane >> 3, li = lane & 7, d4 = li * 4;
        const int hh = w >> 1, jh = w & 1;
        const float* kb = kin + (long)b * 65536 + hh * 32 + d4;
        float4 q0 = *(const float4*)&qb[0][hh * 32 + d4];
        float4 q1 = *(const float4*)&qb[1][hh * 32 + d4];
        float4 q2 = *(const float4*)&qb[2][hh * 32 + d4];
        float4 q3 = *(const float4*)&qb[3][hh * 32 + d4];
        for (int jb = 0; jb < 16; jb++) {
            int j = jh * 128 + jb * 8 + jq;
            float4 kv = *(const float4*)(kb + (long)j * 256);
            float a0 = dot4(kv, q0), a1 = dot4(kv, q1);
            float a2 = dot4(kv, q2), a3 = dot4(kv, q3);
#pragma unroll
            for (int off = 1; off < 8; off <<= 1) {
                a0 += __shfl_xor(a0, off); a1 += __shfl_xor(a1, off);
                a2 += __shfl_xor(a2, off); a3 += __shfl_xor(a3, off);
            }
            if (li < 4) sy.s[li][hh][j] = sel4(a0, a1, a2, a3, li) * scale;
        }
    }
    __syncthreads();

    // P3: softmax — 32 (row,head) pairs over 16 waves
    {
#pragma unroll
        for (int p = 0; p < 2; p++) {
            int pair = w * 2 + p;
            int i = pair >> 3, hh = pair & 7;
            float* row = sy.s[i][hh];
            float v0 = row[lane], v1 = row[lane + 64];
            float v2 = row[lane + 128], v3 = row[lane + 192];
            float m = fmaxf(fmaxf(v0, v1), fmaxf(v2, v3));
#pragma unroll
            for (int off = 32; off > 0; off >>= 1) m = fmaxf(m, __shfl_xor(m, off));
            float e0 = expf(v0 - m), e1 = expf(v1 - m);
            float e2 = expf(v2 - m), e3 = expf(v3 - m);
            float su = e0 + e1 + e2 + e3;
#pragma unroll
            for (int off = 32; off > 0; off >>= 1) su += __shfl_xor(su, off);
            float inv = 1.f / su;
            row[lane] = e0 * inv; row[lane + 64] = e1 * inv;
            row[lane + 128] = e2 * inv; row[lane + 192] = e3 * inv;
        }
    }
    __syncthreads();

    // P4: PV — thread owns (d, row)
    {
        int row = kq;
        int hh = f >> 5;
        const float* vcol = vin + (long)b * 65536 + f;
        const float* p0 = sy.s[row][hh];
        float a0 = 0.f;
#pragma unroll 4
        for (int j4 = 0; j4 < 64; j4++) {
            float4 pv0 = *(const float4*)(p0 + j4 * 4);
            float v0 = vcol[(long)(j4 * 4 + 0) * 256];
            float v1 = vcol[(long)(j4 * 4 + 1) * 256];
            float v2 = vcol[(long)(j4 * 4 + 2) * 256];
            float v3 = vcol[(long)(j4 * 4 + 3) * 256];
            a0 = fmaf(pv0.x, v0, a0); a0 = fmaf(pv0.y, v1, a0);
            a0 = fmaf(pv0.z, v2, a0); a0 = fmaf(pv0.w, v3, a0);
        }
        ao[row][f] = a0;
    }
    __syncthreads();

    // P5: O-proj (4-way k-split) + residual -> qb
    {
        const float* wt = woT_l + f;
        const int kb2 = kq * 64;
        float a0 = 0.f, a1 = 0.f, a2 = 0.f, a3 = 0.f;
        for (int k4 = 0; k4 < 16; k4++) {
            int kk = kb2 + k4 * 4;
            float w0 = wt[(kk + 0) << 8], w1 = wt[(kk + 1) << 8];
            float w2 = wt[(kk + 2) << 8], w3 = wt[(kk + 3) << 8];
            float4 x0 = *(const float4*)&ao[0][kk];
            float4 x1 = *(const float4*)&ao[1][kk];
            float4 x2 = *(const float4*)&ao[2][kk];
            float4 x3 = *(const float4*)&ao[3][kk];
            a0 = fmaf(w0, x0.x, a0); a0 = fmaf(w1, x0.y, a0);
            a0 = fmaf(w2, x0.z, a0); a0 = fmaf(w3, x0.w, a0);
            a1 = fmaf(w0, x1.x, a1); a1 = fmaf(w1, x1.y, a1);
            a1 = fmaf(w2, x1.z, a1); a1 = fmaf(w3, x1.w, a1);
            a2 = fmaf(w0, x2.x, a2); a2 = fmaf(w1, x2.y, a2);
            a2 = fmaf(w2, x2.z, a2); a2 = fmaf(w3, x2.w, a2);
            a3 = fmaf(w0, x3.x, a3); a3 = fmaf(w1, x3.y, a3);
            a3 = fmaf(w2, x3.z, a3); a3 = fmaf(w3, x3.w, a3);
        }
        pp[kq][0][f] = a0; pp[kq][1][f] = a1; pp[kq][2][f] = a2; pp[kq][3][f] = a3;
    }
    __syncthreads();
    {
        int r = kq;
        qb[r][f] = pp[0][r][f] + pp[1][r][f] + pp[2][r][f] + pp[3][r][f]
                 + bo_l[f] + zs[r][f];
    }
    __syncthreads();
    ln_reduce4(qb, mr, t);
    __syncthreads();
    {
        int r = kq;
        zs[r][f] = (qb[r][f] - mr[r][0]) * mr[r][1] * ln1g_l[f] + ln1b_l[f];
    }
    __syncthreads();

    // P7: FFN1 + gelu — thread owns one FFN dim (t), all 4 rows
    {
        const float* wt = c1T_l + t;
        float a0 = 0.f, a1 = 0.f, a2 = 0.f, a3 = 0.f;
        for (int k4 = 0; k4 < 64; k4++) {
            float w0 = wt[(k4 * 4 + 0) << 10], w1 = wt[(k4 * 4 + 1) << 10];
            float w2 = wt[(k4 * 4 + 2) << 10], w3 = wt[(k4 * 4 + 3) << 10];
            float4 x0 = *(const float4*)&zs[0][k4 * 4];
            float4 x1 = *(const float4*)&zs[1][k4 * 4];
            float4 x2 = *(const float4*)&zs[2][k4 * 4];
            float4 x3 = *(const float4*)&zs[3][k4 * 4];
            a0 = fmaf(w0, x0.x, a0); a0 = fmaf(w1, x0.y, a0);
            a0 = fmaf(w2, x0.z, a0); a0 = fmaf(w3, x0.w, a0);
            a1 = fmaf(w0, x1.x, a1); a1 = fmaf(w1, x1.y, a1);
            a1 = fmaf(w2, x1.z, a1); a1 = fmaf(w3, x1.w, a1);
            a2 = fmaf(w0, x2.x, a2); a2 = fmaf(w1, x2.y, a2);
            a2 = fmaf(w2, x2.z, a2); a2 = fmaf(w3, x2.w, a2);
            a3 = fmaf(w0, x3.x, a3); a3 = fmaf(w1, x3.y, a3);
            a3 = fmaf(w2, x3.z, a3); a3 = fmaf(w3, x3.w, a3);
        }
        float cb = c1b_l[t];
        sy.y[0][t] = gelu_f(a0 + cb);
        sy.y[1][t] = gelu_f(a1 + cb);
        sy.y[2][t] = gelu_f(a2 + cb);
        sy.y[3][t] = gelu_f(a3 + cb);
    }
    __syncthreads();

    // P8: FFN2 (4-way k-split over K=1024) + residual -> qb
    {
        const float* wt = c2T_l + f;
        const int kb2 = kq * 256;
        float a0 = 0.f, a1 = 0.f, a2 = 0.f, a3 = 0.f;
        for (int k4 = 0; k4 < 64; k4++) {
            int kk = kb2 + k4 * 4;
            float w0 = wt[(kk + 0) << 8], w1 = wt[(kk + 1) << 8];
            float w2 = wt[(kk + 2) << 8], w3 = wt[(kk + 3) << 8];
            float4 y0 = *(const float4*)&sy.y[0][kk];
            float4 y1 = *(const float4*)&sy.y[1][kk];
            float4 y2 = *(const float4*)&sy.y[2][kk];
            float4 y3 = *(const float4*)&sy.y[3][kk];
            a0 = fmaf(w0, y0.x, a0); a0 = fmaf(w1, y0.y, a0);
            a0 = fmaf(w2, y0.z, a0); a0 = fmaf(w3, y0.w, a0);
            a1 = fmaf(w0, y1.x, a1); a1 = fmaf(w1, y1.y, a1);
            a1 = fmaf(w2, y1.z, a1); a1 = fmaf(w3, y1.w, a1);
            a2 = fmaf(w0, y2.x, a2); a2 = fmaf(w1, y2.y, a2);
            a2 = fmaf(w2, y2.z, a2); a2 = fmaf(w3, y2.w, a2);
            a3 = fmaf(w0, y3.x, a3); a3 = fmaf(w1, y3.y, a3);
            a3 = fmaf(w2, y3.z, a3); a3 = fmaf(w3, y3.w, a3);
        }
        pp[kq][0][f] = a0; pp[kq][1][f] = a1; pp[kq][2][f] = a2; pp[kq][3][f] = a3;
    }
    __syncthreads();
    {
        int r = kq;
        qb[r][f] = pp[0][r][f] + pp[1][r][f] + pp[2][r][f] + pp[3][r][f]
                 + c2b_l[f] + zs[r][f];
    }
    __syncthreads();
    ln_reduce4(qb, mr, t);
    __syncthreads();
    {
        int r = kq;
        float z2 = (qb[r][f] - mr[r][0]) * mr[r][1] * ln2g_l[f] + ln2b_l[f];
        zs[r][f] = z2;
        zout[(rowg0 + r) * 256 + f] = z2;
    }
    __syncthreads();

    if (!LAST) {
        // P9: QKV projections for next layer (4-way k-split, each W read once)
        const int kb2 = kq * 64;
        for (int mat = 0; mat < 3; mat++) {
            const float* wt = (mat == 0 ? wqT_n : mat == 1 ? wkT_n : wvT_n) + f;
            float a0 = 0.f, a1 = 0.f, a2 = 0.f, a3 = 0.f;
            for (int k4 = 0; k4 < 16; k4++) {
                int kk = kb2 + k4 * 4;
                float w0 = wt[(kk + 0) << 8], w1 = wt[(kk + 1) << 8];
                float w2 = wt[(kk + 2) << 8], w3 = wt[(kk + 3) << 8];
                float4 x0 = *(const float4*)&zs[0][kk];
                float4 x1 = *(const float4*)&zs[1][kk];
                float4 x2 = *(const float4*)&zs[2][kk];
                float4 x3 = *(const float4*)&zs[3][kk];
                a0 = fmaf(w0, x0.x, a0); a0 = fmaf(w1, x0.y, a0);
                a0 = fmaf(w2, x0.z, a0); a0 = fmaf(w3, x0.w, a0);
                a1 = fmaf(w0, x1.x, a1); a1 = fmaf(w1, x1.y, a1);
                a1 = fmaf(w2, x1.z, a1); a1 = fmaf(w3, x1.w, a1);
                a2 = fmaf(w0, x2.x, a2); a2 = fmaf(w1, x2.y, a2);
                a2 = fmaf(w2, x2.z, a2); a2 = fmaf(w3, x2.w, a2);
                a3 = fmaf(w0, x3.x, a3); a3 = fmaf(w1, x3.y, a3);
                a3 = fmaf(w2, x3.z, a3); a3 = fmaf(w3, x3.w, a3);
            }
            pp[kq][0][f] = a0; pp[kq][1][f] = a1; pp[kq][2][f] = a2; pp[kq][3][f] = a3;
            __syncthreads();
            {
                float bvv = (mat == 0 ? bq_n : mat == 1 ? bk_n : bv_n)[f];
                float* op = (mat == 0 ? qo : mat == 1 ? ko : vo);
                int r = kq;
                op[(rowg0 + r) * 256 + f] = pp[0][r][f] + pp[1][r][f] + pp[2][r][f] + pp[3][r][f] + bvv;
            }
            __syncthreads();
        }
    } else {
        ln_reduce4(zs, mr, t);
        __syncthreads();
        {
            int r = kq;
            lnf_out[(rowg0 + r) * 256 + f] =
                (zs[r][f] - mr[r][0]) * mr[r][1] * lnfg[f] + lnfb[f];
        }
    }
}

// ---------------- final: pooled mean over seq -> proj ----------------
__global__ __launch_bounds__(256)
void final_kernel(const float* __restrict__ zf, const float* __restrict__ pw,
                  const float* __restrict__ pb, float* __restrict__ out) {
    __shared__ float sm[8];
    int b = blockIdx.x, d = threadIdx.x;
    float s = 0.f;
    for (int c = 0; c < 256; c++) s += zf[((long)(b * 256 + c)) * 256 + d];
    float pooled = s * (1.f / 256.f);
    float c0 = pooled * pw[d], c1 = pooled * pw[256 + d];
    for (int off = 32; off > 0; off >>= 1) { c0 += __shfl_down(c0, off); c1 += __shfl_down(c1, off); }
    int lane = d & 63, wv = d >> 6;
    if (lane == 0) { sm[wv] = c0; sm[4 + wv] = c1; }
    __syncthreads();
    if (d == 0) {
        out[b * 2 + 0] = sm[0] + sm[1] + sm[2] + sm[3] + pb[0];
        out[b * 2 + 1] = sm[4] + sm[5] + sm[6] + sm[7] + pb[1];
    }
}

extern "C" void kernel_launch(void* const* d_in, const int* in_sizes, int n_in,
                              void* d_out, int out_size, void* d_ws, size_t ws_size,
                              hipStream_t stream) {
    const float* x       = (const float*)d_in[0];
    const float* filters = (const float*)d_in[1];
    const float* bn1_g   = (const float*)d_in[2];
    const float* bn1_b   = (const float*)d_in[3];
    const float* emb_w   = (const float*)d_in[4];
    const float* emb_b   = (const float*)d_in[5];
    const float* embbn_g = (const float*)d_in[6];
    const float* embbn_b = (const float*)d_in[7];
    const float* wq      = (const float*)d_in[8];
    const float* bq      = (const float*)d_in[9];
    const float* wk      = (const float*)d_in[10];
    const float* bk      = (const float*)d_in[11];
    const float* wv      = (const float*)d_in[12];
    const float* bv      = (const float*)d_in[13];
    const float* wo      = (const float*)d_in[14];
    const float* bo      = (const float*)d_in[15];
    const float* c1w     = (const float*)d_in[16];
    const float* c1b     = (const float*)d_in[17];
    const float* c2w     = (const float*)d_in[18];
    const float* c2b     = (const float*)d_in[19];
    const float* ln1g    = (const float*)d_in[20];
    const float* ln1b    = (const float*)d_in[21];
    const float* ln2g    = (const float*)d_in[22];
    const float* ln2b    = (const float*)d_in[23];
    const float* lnfg    = (const float*)d_in[24];
    const float* lnfb    = (const float*)d_in[25];
    const float* projw   = (const float*)d_in[26];
    const float* projb   = (const float*)d_in[27];

    const long hF = 11005952L;                      // 1024*TPP halfs, in float units
    const long wpackF = 2752512L;                   // 8*NKC*512 shorts, in floats
    const long wTF = 3145728L;                      // transposed layer weights
    const long fixedF = hF + 5120 + wpackF + 9L * 262144 + wTF;
    long wsFloats = (long)(ws_size / 4);
    long Z = 32;
    while (Z > 8 && fixedF + Z * 262144L > wsFloats) Z >>= 1;
    const int kPerZ = KEMBP / (int)Z;

    float* ws = (float*)d_ws;
    _Float16* h16 = (_Float16*)ws;                  // 1024*TPP halfs
    float* bn1_sc = ws + hF;
    float* bn1_sh = bn1_sc + 256;
    float* e_sc   = bn1_sh + 256;
    float* e_sh   = e_sc + 256;
    float* bnp1   = e_sh + 256;                     // 2048
    float* bnp2   = bnp1 + 2048;                    // 2048
    float* part   = bnp2 + 2048;                    // Z * 262144
    float* wsp    = part + Z * 262144L;
    short* wpH    = (short*)wsp;                    // 8*NKC*512 shorts
    float* e      = wsp + wpackF;
    float* z      = e + 262144;
    float* qA     = z + 262144;
    float* kA     = qA + 262144;
    float* vA     = kA + 262144;
    float* qB     = vA + 262144;
    float* kB     = qB + 262144;
    float* vB     = kB + 262144;
    float* t1     = vB + 262144;
    float* wqT    = t1 + 262144;                    // 4*65536
    float* wkT    = wqT + 262144;
    float* wvT    = wkT + 262144;
    float* woT    = wvT + 262144;
    float* c1T    = woT + 262144;                   // 4*262144
    float* c2T    = c1T + 1048576;

    // conv packed filters alias onto `part` (only used before embed writes part)
    short* fpH = (short*)part;                      // 520*512 shorts

    filt_pack_kernel<<<520, 512, 0, stream>>>(filters, fpH);
    wpack_kernel<<<8 * NKC, 512, 0, stream>>>(emb_w, wpH);
    wtrans_kernel<<<3072, dim3(32, 8), 0, stream>>>(wq, wk, wv, wo, c1w, c2w,
                                                    wqT, wkT, wvT, woT, c1T, c2T);
    conv_mfma_kernel<<<dim3(672, 4), 256, 0, stream>>>(x, fpH, h16);
    bn_part_kernel<<<dim3(256, 8), 256, 0, stream>>>(h16, bnp1, bnp2);
    bn_fin_kernel<<<1, 256, 0, stream>>>(bnp1, bnp2, bn1_g, bn1_b, bn1_sc, bn1_sh);
    embed_mfma_kernel<<<dim3(8, 2, (int)Z), 256, 0, stream>>>(h16, wpH,
                                                              bn1_sc, bn1_sh, part, kPerZ);
    embed_combine_kernel<<<1024, 256, 0, stream>>>(part, emb_b, e, (int)Z);
    bn_stats_kernel<<<256, 256, 0, stream>>>(e, embbn_g, embbn_b, e_sc, e_sh,
                                             256, 256L * 256);
    qkv_init_kernel<<<256, 512, 0, stream>>>(e, e_sc, e_sh, wqT, bq, wkT, bk, wvT, bv,
                                             z, qA, kA, vA);

    float* qs[2][3] = {{qA, kA, vA}, {qB, kB, vB}};
    for (int l = 0; l < 4; l++) {
        float** in = qs[l & 1];
        float** ou = qs[(l + 1) & 1];
        const float* woT_l = woT + (long)l * 65536; const float* bo_l = bo + l * 256;
        const float* c1T_l = c1T + (long)l * 262144; const float* c1b_l = c1b + l * 1024;
        const float* c2T_l = c2T + (long)l * 262144; const float* c2b_l = c2b + l * 256;
        const float* l1g = ln1g + l * 256; const float* l1b = ln1b + l * 256;
        const float* l2g = ln2g + l * 256; const float* l2b = ln2b + l * 256;
        if (l < 3) {
            const float* wqT_n = wqT + (long)(l + 1) * 65536; const float* bq_n = bq + (l + 1) * 256;
            const float* wkT_n = wkT + (long)(l + 1) * 65536; const float* bk_n = bk + (l + 1) * 256;
            const float* wvT_n = wvT + (long)(l + 1) * 65536; const float* bv_n = bv + (l + 1) * 256;
            layer_kernel<0><<<256, 1024, 0, stream>>>(z, in[0], in[1], in[2],
                woT_l, bo_l, c1T_l, c1b_l, c2T_l, c2b_l, l1g, l1b, l2g, l2b,
                wqT_n, bq_n, wkT_n, bk_n, wvT_n, bv_n, lnfg, lnfb,
                z, ou[0], ou[1], ou[2], t1);
        } else {
            layer_kernel<1><<<256, 1024, 0, stream>>>(z, in[0], in[1], in[2],
                woT_l, bo_l, c1T_l, c1b_l, c2T_l, c2b_l, l1g, l1b, l2g, l2b,
                wqT, bq, wkT, bk, wvT, bv, lnfg, lnfb,
                z, ou[0], ou[1], ou[2], t1);
        }
    }

    final_kernel<<<4, 256, 0, stream>>>(t1, projw, projb, (float*)d_out);
}

// Round 10
// 571.655 us; speedup vs baseline: 6.5818x; 1.2073x over previous
//
#include <hip/hip_runtime.h>
#include <math.h>

#define L_IN 65494
#define T_POOL 21490
#define TPP 21496          // fp16 h row stride (16B-aligned rows)
#define KF 1025
#define RS 1144            // conv replica row stride (elements)
#define CWIN 1136          // conv x window per block: 96 + 1040
#define KEMB 21490
#define KEMBP 21504        // padded
#define NKC 1344           // KEMBP/16
#define FTILE 33280        // 65*512 shorts per conv filter tile
#define LWSZ 786432        // packed layer-weight shorts per layer

typedef short s16x4 __attribute__((ext_vector_type(4)));
typedef _Float16 f16x8 __attribute__((ext_vector_type(8)));
typedef float f32x4 __attribute__((ext_vector_type(4)));
typedef float f32x16 __attribute__((ext_vector_type(16)));

__device__ inline float selu_f(float x) {
    float e = expf(fminf(x, 0.f));
    float neg = 1.6732632423543772f * (e - 1.f);
    return 1.0507009873554805f * (x > 0.f ? x : neg);
}

__device__ inline float gelu_f(float x) {
    return 0.5f * x * (1.f + erff(x * 0.7071067811865476f));
}

__device__ inline float dot4(float4 a, float4 b) {
    return fmaf(a.x, b.x, fmaf(a.y, b.y, fmaf(a.z, b.z, a.w * b.w)));
}

__device__ inline float sel4(float a0, float a1, float a2, float a3, int i) {
    float r = a0;
    r = (i == 1) ? a1 : r;
    r = (i == 2) ? a2 : r;
    r = (i == 3) ? a3 : r;
    return r;
}

__device__ inline short f2h_bits(float v) {
    _Float16 h = (_Float16)v;
    return *(short*)&h;
}

// x = hi + lo in fp16 (hi RTNE, lo = residual): exact to ~2^-22
__device__ inline void f16split(float v, short& hs, short& ls) {
    _Float16 h = (_Float16)v;
    float hf = (float)h;
    _Float16 l = (_Float16)(v - hf);
    hs = *(short*)&h;
    ls = *(short*)&l;
}

__device__ inline void f16split2(float v, _Float16& h, _Float16& l) {
    h = (_Float16)v;
    l = (_Float16)(v - (float)h);
}

// ---------------- filter pack: fp16 single, fragment-major [ft][kc][lane][8] ----------------
__global__ __launch_bounds__(512)
void filt_pack_kernel(const float* __restrict__ filt, short* __restrict__ fpH) {
    int blk = blockIdx.x;            // ft*65 + kc  (grid 520)
    int ft = blk / 65, kc = blk % 65;
    int t = threadIdx.x, lane = t >> 3, e = t & 7;
    int f = ft * 32 + (lane & 31);
    int tap = kc * 16 + (lane >> 5) * 8 + e;
    float v = (tap < KF) ? filt[f * KF + tap] : 0.f;
    fpH[blk * 512 + t] = f2h_bits(v);
}

// ---------------- emb_w pack: fp16 single, fragment-major [ft][kc][lane][8] ----------------
__global__ __launch_bounds__(512)
void wpack_kernel(const float* __restrict__ wsrc, short* __restrict__ wpH) {
    int blk = blockIdx.x;            // ft*NKC + kc  (grid 8*NKC)
    int ft = blk / NKC, kc = blk % NKC;
    int t = threadIdx.x, lane = t >> 3, e = t & 7;
    int row = ft * 32 + (lane & 31);
    int tap = kc * 16 + (lane >> 5) * 8 + e;
    float v = (tap < KEMB) ? wsrc[(long)row * KEMB + tap] : 0.f;
    wpH[(long)blk * 512 + t] = f2h_bits(v);
}

// ---------------- layer weight pack: fp16 fragment-major for 16x16x32 B-operand ----------------
// per layer: wo(+0) wq(+65536) wk(+131072) wv(+196608) c1(+262144) c2(+524288)
__global__ __launch_bounds__(512)
void lwpack_kernel(const float* __restrict__ wo, const float* __restrict__ wq,
                   const float* __restrict__ wk, const float* __restrict__ wv,
                   const float* __restrict__ c1w, const float* __restrict__ c2w,
                   short* __restrict__ lw) {
    int b = blockIdx.x;              // grid 4*1536
    int layer = b / 1536, r = b % 1536;
    int t = threadIdx.x, lane = t >> 3, e = t & 7;
    const float* src;
    int K, t2;
    long dst;
    if (r < 512) {
        int mat = r >> 7; t2 = r & 127;
        const float* m0 = (mat == 0 ? wo : mat == 1 ? wq : mat == 2 ? wk : wv);
        src = m0 + (long)layer * 65536; K = 256;
        dst = (long)layer * LWSZ + (long)mat * 65536 + (long)t2 * 512;
    } else if (r < 1024) {
        t2 = r - 512;
        src = c1w + (long)layer * 262144; K = 256;
        dst = (long)layer * LWSZ + 262144 + (long)t2 * 512;
    } else {
        t2 = r - 1024;
        src = c2w + (long)layer * 262144; K = 1024;
        dst = (long)layer * LWSZ + 524288 + (long)t2 * 512;
    }
    int KB = K >> 5;
    int nt = t2 / KB, kb = t2 % KB;
    int n = nt * 16 + (lane & 15);
    int k = kb * 32 + ((lane >> 4) & 3) * 8 + e;
    lw[dst + t] = f2h_bits(src[(long)n * K + k]);
}

// ---------------- MFMA projection helper: one 16-col tile, M=16-padded (4 real rows) ----------
__device__ inline f32x4 mfma_nt(const _Float16* __restrict__ Xh, const _Float16* __restrict__ Xl,
                                int xstride, const short* __restrict__ wp_nt, int KB, int lane) {
    f32x4 acc = {0.f, 0.f, 0.f, 0.f};
    const int row = (lane & 15) & 3;
    const int ko0 = ((lane >> 4) & 3) * 8;
    const short* bp = wp_nt + lane * 8;
    const _Float16* xh = Xh + row * xstride + ko0;
    const _Float16* xl = Xl + row * xstride + ko0;
#pragma unroll 4
    for (int kb = 0; kb < KB; kb++) {
        f16x8 bf = *(const f16x8*)(bp + kb * 512);
        f16x8 ah = *(const f16x8*)(xh + kb * 32);
        f16x8 al = *(const f16x8*)(xl + kb * 32);
        acc = __builtin_amdgcn_mfma_f32_16x16x32_f16(al, bf, acc, 0, 0, 0);
        acc = __builtin_amdgcn_mfma_f32_16x16x32_f16(ah, bf, acc, 0, 0, 0);
    }
    return acc;
}

// ---------------- SincConv via MFMA (fp16 2-pass) + |.| + maxpool3 ----------------
union ConvLDS {
    struct { short xh[8][RS]; short xl[8][RS]; } st;
    float ebuf[96][129];
};

#define MFMA2(ACC, AH, AL, BH) \
    ACC = __builtin_amdgcn_mfma_f32_32x32x16_f16(AL, BH, ACC, 0, 0, 0); \
    ACC = __builtin_amdgcn_mfma_f32_32x32x16_f16(AH, BH, ACC, 0, 0, 0);

__global__ __launch_bounds__(256, 3)
void conv_mfma_kernel(const float* __restrict__ x, const short* __restrict__ fpH,
                      _Float16* __restrict__ h) {
    __shared__ ConvLDS u;
    const int tid = threadIdx.x;
    const int pb = blockIdx.x;
    const int b = blockIdx.y;
    const int t0 = pb * 96;

    for (int i = tid; i < CWIN; i += 256) {
        int gi = t0 + i;
        float v = (gi < L_IN) ? x[b * L_IN + gi] : 0.f;
        short hs, ls;
        f16split(v, hs, ls);
#pragma unroll
        for (int s = 0; s < 8; s++) {
            int e = i - s;
            if (e >= 0) { u.st.xh[s][e] = hs; u.st.xl[s][e] = ls; }
        }
    }
    __syncthreads();

    const int lane = tid & 63;
    const int wid = tid >> 6;
    const int l31 = lane & 31;
    const int hi = lane >> 5;
    const int f0w = wid * 64;

    const short* aH = &u.st.xh[l31 & 7][8 * (l31 >> 3) + 8 * hi];
    const short* aL = &u.st.xl[l31 & 7][8 * (l31 >> 3) + 8 * hi];
    const short* bp0 = fpH + (long)(wid * 2) * FTILE + lane * 8;
    const short* bp1 = bp0 + FTILE;

    f32x16 a00 = {0}, a01 = {0}, a10 = {0}, a11 = {0}, a20 = {0}, a21 = {0};

#pragma unroll 1
    for (int kc = 0; kc < 65; kc++) {
        const int ko = kc * 16;
        const int kf = kc * 512;
        f16x8 ah0 = *(const f16x8*)(aH + ko);
        f16x8 ah1 = *(const f16x8*)(aH + ko + 32);
        f16x8 ah2 = *(const f16x8*)(aH + ko + 64);
        f16x8 al0 = *(const f16x8*)(aL + ko);
        f16x8 al1 = *(const f16x8*)(aL + ko + 32);
        f16x8 al2 = *(const f16x8*)(aL + ko + 64);
        f16x8 bh0 = *(const f16x8*)(bp0 + kf);
        f16x8 bh1 = *(const f16x8*)(bp1 + kf);
        MFMA2(a00, ah0, al0, bh0)
        MFMA2(a01, ah0, al0, bh1)
        MFMA2(a10, ah1, al1, bh0)
        MFMA2(a11, ah1, al1, bh1)
        MFMA2(a20, ah2, al2, bh0)
        MFMA2(a21, ah2, al2, bh1)
    }

    __syncthreads();
    const int t3l = tid & 31;
    const int t3 = pb * 32 + t3l;

#pragma unroll
    for (int half = 0; half < 2; half++) {
        if ((wid >> 1) == half) {
            int fcb = f0w - half * 128;
#define WRF(ACC, MT, NT)                                                   \
            {                                                              \
                int fc = fcb + NT * 32 + l31;                              \
                _Pragma("unroll")                                          \
                for (int r = 0; r < 16; r++) {                             \
                    int pos = MT * 32 + (r & 3) + 8 * (r >> 2) + 4 * hi;   \
                    u.ebuf[pos][fc] = fabsf(ACC[r]);                       \
                }                                                          \
            }
            WRF(a00, 0, 0) WRF(a01, 0, 1)
            WRF(a10, 1, 0) WRF(a11, 1, 1)
            WRF(a20, 2, 0) WRF(a21, 2, 1)
#undef WRF
        }
        __syncthreads();
        if (t3 < T_POOL) {
            for (int ff = tid >> 5; ff < 128; ff += 8) {
                float v = fmaxf(fmaxf(u.ebuf[3 * t3l][ff], u.ebuf[3 * t3l + 1][ff]),
                                u.ebuf[3 * t3l + 2][ff]);
                h[((long)(b * 256 + half * 128 + ff)) * TPP + t3] = (_Float16)v;
            }
        }
        __syncthreads();
    }
}

// ---------------- BatchNorm stats for h (fp16): two-stage ----------------
__global__ __launch_bounds__(256)
void bn_part_kernel(const _Float16* __restrict__ xin, float* __restrict__ p1,
                    float* __restrict__ p2) {
    __shared__ float sm[8];
    int c = blockIdx.x, s = blockIdx.y, tid = threadIdx.x;
    int t0 = s * 2687, t1 = min(T_POOL, t0 + 2687);
    float s1 = 0.f, s2 = 0.f;
    for (int b = 0; b < 4; b++) {
        const _Float16* p = xin + (long)b * 256 * TPP + (long)c * TPP;
        for (int t = t0 + tid; t < t1; t += 256) {
            float v = (float)p[t];
            s1 += v;
            s2 = fmaf(v, v, s2);
        }
    }
    for (int off = 32; off > 0; off >>= 1) { s1 += __shfl_down(s1, off); s2 += __shfl_down(s2, off); }
    int lane = tid & 63, wv = tid >> 6;
    if (lane == 0) { sm[wv] = s1; sm[4 + wv] = s2; }
    __syncthreads();
    if (tid == 0) {
        p1[c * 8 + s] = sm[0] + sm[1] + sm[2] + sm[3];
        p2[c * 8 + s] = sm[4] + sm[5] + sm[6] + sm[7];
    }
}

__global__ __launch_bounds__(256)
void bn_fin_kernel(const float* __restrict__ p1, const float* __restrict__ p2,
                   const float* __restrict__ g, const float* __restrict__ bb,
                   float* __restrict__ sc, float* __restrict__ sh) {
    int c = threadIdx.x;
    float S1 = 0.f, S2 = 0.f;
#pragma unroll
    for (int s = 0; s < 8; s++) { S1 += p1[c * 8 + s]; S2 += p2[c * 8 + s]; }
    float n = 4.f * (float)T_POOL;
    float mean = S1 / n;
    float var = S2 / n - mean * mean;
    float rstd = rsqrtf(var + 1e-5f);
    float gc = g[c], bc = bb[c];
    sc[c] = rstd * gc;
    sh[c] = bc - mean * rstd * gc;
}

// ---------------- BatchNorm stats (small, for e) ----------------
__global__ __launch_bounds__(256)
void bn_stats_kernel(const float* __restrict__ xin, const float* __restrict__ g,
                     const float* __restrict__ bb, float* __restrict__ sc,
                     float* __restrict__ sh, int ilen, long bstride) {
    __shared__ float sm[8];
    int c = blockIdx.x, tid = threadIdx.x;
    float s1 = 0.f, s2 = 0.f;
    for (int b = 0; b < 4; b++) {
        const float* p = xin + b * bstride + (long)c * ilen;
        for (int t = tid; t < ilen; t += 256) {
            float v = p[t];
            s1 += v;
            s2 = fmaf(v, v, s2);
        }
    }
    for (int off = 32; off > 0; off >>= 1) { s1 += __shfl_down(s1, off); s2 += __shfl_down(s2, off); }
    int lane = tid & 63, wv = tid >> 6;
    if (lane == 0) { sm[wv] = s1; sm[4 + wv] = s2; }
    __syncthreads();
    if (tid == 0) {
        float S1 = sm[0] + sm[1] + sm[2] + sm[3];
        float S2 = sm[4] + sm[5] + sm[6] + sm[7];
        float n = 4.f * (float)ilen;
        float mean = S1 / n;
        float var = S2 / n - mean * mean;
        float rstd = rsqrtf(var + 1e-5f);
        float gc = g[c], bc = bb[c];
        sc[c] = rstd * gc;
        sh[c] = bc - mean * rstd * gc;
    }
}

// ---------------- Embedding GEMM via MFMA (fp16 2-pass), split-K, packed B ----------------
__global__ __launch_bounds__(256, 2)
void embed_mfma_kernel(const _Float16* __restrict__ H, const short* __restrict__ Wh,
                       const float* __restrict__ sc, const float* __restrict__ sh,
                       float* __restrict__ P, int kPerZ) {
    __shared__ short Ah[128][36];
    __shared__ short Al[128][36];
    const int tid = threadIdx.x;
    const int rowBase = blockIdx.x * 128;
    const int colBase = blockIdx.y * 128;
    const int z = blockIdx.z;
    const int kz = z * kPerZ;
    const int iters = kPerZ >> 5;

    const int trow = tid >> 1, th = (tid & 1) * 16;
    const int arow = rowBase + trow;
    const float asc = sc[arow & 255], ash_ = sh[arow & 255];
    const _Float16* Ap = H + (long)arow * TPP;

    const int lane = tid & 63, wid = tid >> 6;
    const int l31 = lane & 31, hi = lane >> 5;
    const int wm = wid >> 1, wn = wid & 1;

    const short* bhp[2];
#pragma unroll
    for (int nt = 0; nt < 2; nt++) {
        int ft = (colBase >> 5) + wn * 2 + nt;
        bhp[nt] = Wh + (long)ft * NKC * 512 + lane * 8;
    }

    f32x16 acc[2][2] = {{{0}, {0}}, {{0}, {0}}};

    for (int it = 0; it < iters; it++) {
        const int k0 = kz + it * 32;
        __syncthreads();
        float av[16];
        if (k0 + 32 <= KEMB) {
            const f16x8* p8 = (const f16x8*)(Ap + k0 + th);
            f16x8 v0 = p8[0], v1 = p8[1];
#pragma unroll
            for (int e = 0; e < 8; e++) { av[e] = (float)v0[e]; av[8 + e] = (float)v1[e]; }
        } else {
#pragma unroll
            for (int e = 0; e < 16; e++) {
                int k = k0 + th + e;
                av[e] = (k < KEMB) ? (float)Ap[k] : 0.f;
            }
        }
#pragma unroll
        for (int q = 0; q < 4; q++) {
            s16x4 h4, l4;
#pragma unroll
            for (int e = 0; e < 4; e++) {
                float v = selu_f(fmaf(av[q * 4 + e], asc, ash_));
                short hs, ls;
                f16split(v, hs, ls);
                h4[e] = hs; l4[e] = ls;
            }
            *(s16x4*)&Ah[trow][th + q * 4] = h4;
            *(s16x4*)&Al[trow][th + q * 4] = l4;
        }
        __syncthreads();

#pragma unroll
        for (int ks = 0; ks < 2; ks++) {
            const int kloc = ks * 16 + hi * 8;
            const long kcg = (long)((k0 >> 4) + ks) * 512;
            f16x8 ah[2], al[2], bh[2];
#pragma unroll
            for (int mt = 0; mt < 2; mt++) {
                const int r = wm * 64 + mt * 32 + l31;
                const short* ph = &Ah[r][kloc];
                const short* pl = &Al[r][kloc];
                union { f16x8 v; unsigned long long q[2]; } uh, ul;
                uh.q[0] = *(const unsigned long long*)(ph);
                uh.q[1] = *(const unsigned long long*)(ph + 4);
                ul.q[0] = *(const unsigned long long*)(pl);
                ul.q[1] = *(const unsigned long long*)(pl + 4);
                ah[mt] = uh.v; al[mt] = ul.v;
            }
#pragma unroll
            for (int nt = 0; nt < 2; nt++)
                bh[nt] = *(const f16x8*)(bhp[nt] + kcg);
#pragma unroll
            for (int mt = 0; mt < 2; mt++)
#pragma unroll
                for (int nt = 0; nt < 2; nt++) {
                    MFMA2(acc[mt][nt], ah[mt], al[mt], bh[nt])
                }
        }
    }

    float* Pz = P + (long)z * 262144;
#pragma unroll
    for (int mt = 0; mt < 2; mt++)
#pragma unroll
        for (int nt = 0; nt < 2; nt++) {
            int col = colBase + wn * 64 + nt * 32 + l31;
#pragma unroll
            for (int r = 0; r < 16; r++) {
                int row = rowBase + wm * 64 + mt * 32 + (r & 3) + 8 * (r >> 2) + 4 * hi;
                Pz[(long)row * 256 + col] = acc[mt][nt][r];
            }
        }
}

__global__ __launch_bounds__(256)
void embed_combine_kernel(const float* __restrict__ P, const float* __restrict__ eb,
                          float* __restrict__ e, int nsplit) {
    int idx = blockIdx.x * 256 + threadIdx.x;
    float s = 0.f;
    for (int z = 0; z < nsplit; z++) s += P[(long)z * 262144 + idx];
    e[idx] = s + eb[idx & 255];
}

// ---------------- fused zinit + layer-0 QKV (MFMA, packed fp16 weights) ----------------
__global__ __launch_bounds__(512)
void qkv_init_kernel(const float* __restrict__ e, const float* __restrict__ sc,
                     const float* __restrict__ sh, const short* __restrict__ lw0,
                     const float* __restrict__ bq0, const float* __restrict__ bk0,
                     const float* __restrict__ bv0,
                     float* __restrict__ z, float* __restrict__ qo,
                     float* __restrict__ ko, float* __restrict__ vo) {
    __shared__ _Float16 zsh[4][256], zsl[4][256];
    const int t = threadIdx.x;
    const int w = t >> 6, lane = t & 63;
    const long rowg0 = (long)blockIdx.x * 4;

    for (int idx = t; idx < 1024; idx += 512) {
        int i = idx >> 8, dd = idx & 255;
        int c = (int)((rowg0 + i) & 255);
        float v = fmaf(e[(rowg0 + i) * 256 + dd], sc[c], sh[c]);
        v = fmaxf(v, 0.f);
        int i2 = dd >> 1;
        float ang = (float)c * expf(-0.03597789207803195f * (float)(2 * i2));
        float pe = (dd & 1) ? cosf(ang) : sinf(ang);
        float zz = v + pe;
        z[(rowg0 + i) * 256 + dd] = zz;
        _Float16 hh, ll;
        f16split2(zz, hh, ll);
        zsh[i][dd] = hh; zsl[i][dd] = ll;
    }
    __syncthreads();

#pragma unroll
    for (int mat = 0; mat < 3; mat++) {
        const short* wp = lw0 + 65536 * (1 + mat);
        const float* bb = (mat == 0 ? bq0 : mat == 1 ? bk0 : bv0);
        float* op = (mat == 0 ? qo : mat == 1 ? ko : vo);
        for (int nt = w; nt < 16; nt += 8) {
            f32x4 acc = mfma_nt(&zsh[0][0], &zsl[0][0], 256, wp + nt * 8 * 512, 8, lane);
            if (lane < 16) {
                int col = nt * 16 + lane;
                float bv2 = bb[col];
#pragma unroll
                for (int r = 0; r < 4; r++)
                    op[(rowg0 + r) * 256 + col] = acc[r] + bv2;
            }
        }
    }
}

// ---------------- fused transformer layer: attention GEMV + MFMA projections ----------------
__device__ inline void ln_reduce4(const float (*buf)[256], float (*mr)[2], int t) {
    int wid = t >> 6, lane = t & 63;
    if (wid < 4) {
        float4 v = *(const float4*)&buf[wid][lane * 4];
        float s = v.x + v.y + v.z + v.w;
        float q = v.x * v.x + v.y * v.y + v.z * v.z + v.w * v.w;
#pragma unroll
        for (int off = 32; off > 0; off >>= 1) {
            s += __shfl_xor(s, off);
            q += __shfl_xor(q, off);
        }
        if (lane == 0) {
            float mean = s * (1.f / 256.f);
            float var = q * (1.f / 256.f) - mean * mean;
            mr[wid][0] = mean;
            mr[wid][1] = rsqrtf(var + 1e-5f);
        }
    }
}

template <int LAST>
__global__ __launch_bounds__(1024)
void layer_kernel(const float* __restrict__ zin, const float* __restrict__ qin,
                  const float* __restrict__ kin, const float* __restrict__ vin,
                  const short* __restrict__ lw_l, const short* __restrict__ lw_n,
                  const float* __restrict__ bo_l,
                  const float* __restrict__ c1b_l, const float* __restrict__ c2b_l,
                  const float* __restrict__ ln1g_l, const float* __restrict__ ln1b_l,
                  const float* __restrict__ ln2g_l, const float* __restrict__ ln2b_l,
                  const float* __restrict__ bq_n, const float* __restrict__ bk_n,
                  const float* __restrict__ bv_n,
                  const float* __restrict__ lnfg, const float* __restrict__ lnfb,
                  float* __restrict__ zout, float* __restrict__ qo,
                  float* __restrict__ ko, float* __restrict__ vo,
                  float* __restrict__ lnf_out) {
    __shared__ float zs[4][256];
    __shared__ float qb[4][256];
    __shared__ float sscore[4][8][256];
    __shared__ _Float16 zsh[4][256], zsl[4][256];
    __shared__ _Float16 yh[4][1024], yl[4][1024];
    __shared__ float mr[4][2];

    const int t = threadIdx.x;
    const int w = t >> 6, lane = t & 63;
    const long rowg0 = (long)blockIdx.x * 4;
    const int b = blockIdx.x >> 6;

    const int f = t & 255;       // output dim for 256-wide phases
    const int kq = t >> 8;       // row 0..3

    // P1: stage z (residual) and q rows
    {
        int r = t >> 8, dd = t & 255;
        zs[r][dd] = zin[(rowg0 + r) * 256 + dd];
        qb[r][dd] = qin[(rowg0 + r) * 256 + dd];
    }
    __syncthreads();

    // P2: scores — wave pair per head
    {
        const float scale = 0.17677669529663687f;
        const int jq = lane >> 3, li = lane & 7, d4 = li * 4;
        const int hh = w >> 1, jh = w & 1;
        const float* kb = kin + (long)b * 65536 + hh * 32 + d4;
        float4 q0 = *(const float4*)&qb[0][hh * 32 + d4];
        float4 q1 = *(const float4*)&qb[1][hh * 32 + d4];
        float4 q2 = *(const float4*)&qb[2][hh * 32 + d4];
        float4 q3 = *(const float4*)&qb[3][hh * 32 + d4];
        for (int jb = 0; jb < 16; jb++) {
            int j = jh * 128 + jb * 8 + jq;
            float4 kv = *(const float4*)(kb + (long)j * 256);
            float a0 = dot4(kv, q0), a1 = dot4(kv, q1);
            float a2 = dot4(kv, q2), a3 = dot4(kv, q3);
#pragma unroll
            for (int off = 1; off < 8; off <<= 1) {
                a0 += __shfl_xor(a0, off); a1 += __shfl_xor(a1, off);
                a2 += __shfl_xor(a2, off); a3 += __shfl_xor(a3, off);
            }
            if (li < 4) sscore[li][hh][j] = sel4(a0, a1, a2, a3, li) * scale;
        }
    }
    __syncthreads();

    // P3: softmax
    {
#pragma unroll
        for (int p = 0; p < 2; p++) {
            int pair = w * 2 + p;
            int i = pair >> 3, hh = pair & 7;
            float* row = sscore[i][hh];
            float v0 = row[lane], v1 = row[lane + 64];
            float v2 = row[lane + 128], v3 = row[lane + 192];
            float m = fmaxf(fmaxf(v0, v1), fmaxf(v2, v3));
#pragma unroll
            for (int off = 32; off > 0; off >>= 1) m = fmaxf(m, __shfl_xor(m, off));
            float e0 = expf(v0 - m), e1 = expf(v1 - m);
            float e2 = expf(v2 - m), e3 = expf(v3 - m);
            float su = e0 + e1 + e2 + e3;
#pragma unroll
            for (int off = 32; off > 0; off >>= 1) su += __shfl_xor(su, off);
            float inv = 1.f / su;
            row[lane] = e0 * inv; row[lane + 64] = e1 * inv;
            row[lane + 128] = e2 * inv; row[lane + 192] = e3 * inv;
        }
    }
    __syncthreads();

    // P4: PV — thread owns (f, row); write split attention output
    {
        int row = kq;
        int hh = f >> 5;
        const float* vcol = vin + (long)b * 65536 + f;
        const float* p0 = sscore[row][hh];
        float a0 = 0.f;
#pragma unroll 4
        for (int j4 = 0; j4 < 64; j4++) {
            float4 pv0 = *(const float4*)(p0 + j4 * 4);
            float v0 = vcol[(long)(j4 * 4 + 0) * 256];
            float v1 = vcol[(long)(j4 * 4 + 1) * 256];
            float v2 = vcol[(long)(j4 * 4 + 2) * 256];
            float v3 = vcol[(long)(j4 * 4 + 3) * 256];
            a0 = fmaf(pv0.x, v0, a0); a0 = fmaf(pv0.y, v1, a0);
            a0 = fmaf(pv0.z, v2, a0); a0 = fmaf(pv0.w, v3, a0);
        }
        _Float16 hh2, ll;
        f16split2(a0, hh2, ll);
        zsh[row][f] = hh2; zsl[row][f] = ll;
    }
    __syncthreads();

    // P5: O-proj MFMA + bias + residual -> qb
    {
        int nt = w;
        f32x4 acc = mfma_nt(&zsh[0][0], &zsl[0][0], 256, lw_l + nt * 8 * 512, 8, lane);
        if (lane < 16) {
            int col = nt * 16 + lane;
            float bb = bo_l[col];
#pragma unroll
            for (int r = 0; r < 4; r++)
                qb[r][col] = acc[r] + bb + zs[r][col];
        }
    }
    __syncthreads();
    ln_reduce4(qb, mr, t);
    __syncthreads();
    {
        int r = kq;
        float z1 = (qb[r][f] - mr[r][0]) * mr[r][1] * ln1g_l[f] + ln1b_l[f];
        zs[r][f] = z1;
        _Float16 hh2, ll;
        f16split2(z1, hh2, ll);
        zsh[r][f] = hh2; zsl[r][f] = ll;
    }
    __syncthreads();

    // P7: FFN1 MFMA + gelu -> yh/yl
    {
        const short* wp = lw_l + 262144;
        for (int nt = w; nt < 64; nt += 16) {
            f32x4 acc = mfma_nt(&zsh[0][0], &zsl[0][0], 256, wp + nt * 8 * 512, 8, lane);
            if (lane < 16) {
                int col = nt * 16 + lane;
                float cb = c1b_l[col];
#pragma unroll
                for (int r = 0; r < 4; r++) {
                    float g = gelu_f(acc[r] + cb);
                    _Float16 hh2, ll;
                    f16split2(g, hh2, ll);
                    yh[r][col] = hh2; yl[r][col] = ll;
                }
            }
        }
    }
    __syncthreads();

    // P8: FFN2 MFMA (K=1024) + bias + residual -> qb
    {
        const short* wp = lw_l + 524288;
        int nt = w;
        f32x4 acc = mfma_nt(&yh[0][0], &yl[0][0], 1024, wp + nt * 32 * 512, 32, lane);
        if (lane < 16) {
            int col = nt * 16 + lane;
            float cb = c2b_l[col];
#pragma unroll
            for (int r = 0; r < 4; r++)
                qb[r][col] = acc[r] + cb + zs[r][col];
        }
    }
    __syncthreads();
    ln_reduce4(qb, mr, t);
    __syncthreads();
    {
        int r = kq;
        float z2 = (qb[r][f] - mr[r][0]) * mr[r][1] * ln2g_l[f] + ln2b_l[f];
        zs[r][f] = z2;
        zout[(rowg0 + r) * 256 + f] = z2;
        _Float16 hh2, ll;
        f16split2(z2, hh2, ll);
        zsh[r][f] = hh2; zsl[r][f] = ll;
    }
    __syncthreads();

    if (!LAST) {
        // P9: QKV MFMA for next layer
#pragma unroll
        for (int mat = 0; mat < 3; mat++) {
            const short* wp = lw_n + 65536 * (1 + mat);
            const float* bb = (mat == 0 ? bq_n : mat == 1 ? bk_n : bv_n);
            float* op = (mat == 0 ? qo : mat == 1 ? ko : vo);
            int nt = w;
            f32x4 acc = mfma_nt(&zsh[0][0], &zsl[0][0], 256, wp + nt * 8 * 512, 8, lane);
            if (lane < 16) {
                int col = nt * 16 + lane;
                float bv2 = bb[col];
#pragma unroll
                for (int r = 0; r < 4; r++)
                    op[(rowg0 + r) * 256 + col] = acc[r] + bv2;
            }
        }
    } else {
        ln_reduce4(zs, mr, t);
        __syncthreads();
        {
            int r = kq;
            lnf_out[(rowg0 + r) * 256 + f] =
                (zs[r][f] - mr[r][0]) * mr[r][1] * lnfg[f] + lnfb[f];
        }
    }
}

// ---------------- final: pooled mean over seq -> proj ----------------
__global__ __launch_bounds__(256)
void final_kernel(const float* __restrict__ zf, const float* __restrict__ pw,
                  const float* __restrict__ pb, float* __restrict__ out) {
    __shared__ float sm[8];
    int b = blockIdx.x, d = threadIdx.x;
    float s = 0.f;
    for (int c = 0; c < 256; c++) s += zf[((long)(b * 256 + c)) * 256 + d];
    float pooled = s * (1.f / 256.f);
    float c0 = pooled * pw[d], c1 = pooled * pw[256 + d];
    for (int off = 32; off > 0; off >>= 1) { c0 += __shfl_down(c0, off); c1 += __shfl_down(c1, off); }
    int lane = d & 63, wv = d >> 6;
    if (lane == 0) { sm[wv] = c0; sm[4 + wv] = c1; }
    __syncthreads();
    if (d == 0) {
        out[b * 2 + 0] = sm[0] + sm[1] + sm[2] + sm[3] + pb[0];
        out[b * 2 + 1] = sm[4] + sm[5] + sm[6] + sm[7] + pb[1];
    }
}

extern "C" void kernel_launch(void* const* d_in, const int* in_sizes, int n_in,
                              void* d_out, int out_size, void* d_ws, size_t ws_size,
                              hipStream_t stream) {
    const float* x       = (const float*)d_in[0];
    const float* filters = (const float*)d_in[1];
    const float* bn1_g   = (const float*)d_in[2];
    const float* bn1_b   = (const float*)d_in[3];
    const float* emb_w   = (const float*)d_in[4];
    const float* emb_b   = (const float*)d_in[5];
    const float* embbn_g = (const float*)d_in[6];
    const float* embbn_b = (const float*)d_in[7];
    const float* wq      = (const float*)d_in[8];
    const float* bq      = (const float*)d_in[9];
    const float* wk      = (const float*)d_in[10];
    const float* bk      = (const float*)d_in[11];
    const float* wv      = (const float*)d_in[12];
    const float* bv      = (const float*)d_in[13];
    const float* wo      = (const float*)d_in[14];
    const float* bo      = (const float*)d_in[15];
    const float* c1w     = (const float*)d_in[16];
    const float* c1b     = (const float*)d_in[17];
    const float* c2w     = (const float*)d_in[18];
    const float* c2b     = (const float*)d_in[19];
    const float* ln1g    = (const float*)d_in[20];
    const float* ln1b    = (const float*)d_in[21];
    const float* ln2g    = (const float*)d_in[22];
    const float* ln2b    = (const float*)d_in[23];
    const float* lnfg    = (const float*)d_in[24];
    const float* lnfb    = (const float*)d_in[25];
    const float* projw   = (const float*)d_in[26];
    const float* projb   = (const float*)d_in[27];

    const long hF = 11005952L;                      // 1024*TPP halfs, in float units
    const long wpackF = 2752512L;                   // 8*NKC*512 shorts, in floats
    const long lwF = 1572864L;                      // 4*LWSZ shorts, in floats
    const long fixedF = hF + 5120 + wpackF + lwF + 9L * 262144;
    long wsFloats = (long)(ws_size / 4);
    long Z = 32;
    while (Z > 8 && fixedF + Z * 262144L > wsFloats) Z >>= 1;
    const int kPerZ = KEMBP / (int)Z;

    float* ws = (float*)d_ws;
    _Float16* h16 = (_Float16*)ws;                  // 1024*TPP halfs
    float* bn1_sc = ws + hF;
    float* bn1_sh = bn1_sc + 256;
    float* e_sc   = bn1_sh + 256;
    float* e_sh   = e_sc + 256;
    float* bnp1   = e_sh + 256;                     // 2048
    float* bnp2   = bnp1 + 2048;                    // 2048
    float* part   = bnp2 + 2048;                    // Z * 262144
    float* wsp    = part + Z * 262144L;
    short* wpH    = (short*)wsp;                    // 8*NKC*512 shorts
    float* e      = wsp + wpackF;
    float* z      = e + 262144;
    float* qA     = z + 262144;
    float* kA     = qA + 262144;
    float* vA     = kA + 262144;
    float* qB     = vA + 262144;
    float* kB     = qB + 262144;
    float* vB     = kB + 262144;
    float* t1     = vB + 262144;
    short* lw     = (short*)(t1 + 262144);          // 4*LWSZ shorts

    // conv packed filters alias onto `part` (only used before embed writes part)
    short* fpH = (short*)part;                      // 520*512 shorts

    filt_pack_kernel<<<520, 512, 0, stream>>>(filters, fpH);
    wpack_kernel<<<8 * NKC, 512, 0, stream>>>(emb_w, wpH);
    lwpack_kernel<<<6144, 512, 0, stream>>>(wo, wq, wk, wv, c1w, c2w, lw);
    conv_mfma_kernel<<<dim3(672, 4), 256, 0, stream>>>(x, fpH, h16);
    bn_part_kernel<<<dim3(256, 8), 256, 0, stream>>>(h16, bnp1, bnp2);
    bn_fin_kernel<<<1, 256, 0, stream>>>(bnp1, bnp2, bn1_g, bn1_b, bn1_sc, bn1_sh);
    embed_mfma_kernel<<<dim3(8, 2, (int)Z), 256, 0, stream>>>(h16, wpH,
                                                              bn1_sc, bn1_sh, part, kPerZ);
    embed_combine_kernel<<<1024, 256, 0, stream>>>(part, emb_b, e, (int)Z);
    bn_stats_kernel<<<256, 256, 0, stream>>>(e, embbn_g, embbn_b, e_sc, e_sh,
                                             256, 256L * 256);
    qkv_init_kernel<<<256, 512, 0, stream>>>(e, e_sc, e_sh, lw, bq, bk, bv,
                                             z, qA, kA, vA);

    float* qs[2][3] = {{qA, kA, vA}, {qB, kB, vB}};
    for (int l = 0; l < 4; l++) {
        float** in = qs[l & 1];
        float** ou = qs[(l + 1) & 1];
        const short* lw_l = lw + (long)l * LWSZ;
        const short* lw_n = lw + (long)((l + 1) & 3) * LWSZ;
        const float* bo_l = bo + l * 256;
        const float* c1b_l = c1b + l * 1024;
        const float* c2b_l = c2b + l * 256;
        const float* l1g = ln1g + l * 256; const float* l1b = ln1b + l * 256;
        const float* l2g = ln2g + l * 256; const float* l2b = ln2b + l * 256;
        if (l < 3) {
            const float* bq_n = bq + (l + 1) * 256;
            const float* bk_n = bk + (l + 1) * 256;
            const float* bv_n = bv + (l + 1) * 256;
            layer_kernel<0><<<256, 1024, 0, stream>>>(z, in[0], in[1], in[2],
                lw_l, lw_n, bo_l, c1b_l, c2b_l, l1g, l1b, l2g, l2b,
                bq_n, bk_n, bv_n, lnfg, lnfb,
                z, ou[0], ou[1], ou[2], t1);
        } else {
            layer_kernel<1><<<256, 1024, 0, stream>>>(z, in[0], in[1], in[2],
                lw_l, lw_n, bo_l, c1b_l, c2b_l, l1g, l1b, l2g, l2b,
                bq, bk, bv, lnfg, lnfb,
                z, ou[0], ou[1], ou[2], t1);
        }
    }

    final_kernel<<<4, 256, 0, stream>>>(t1, projw, projb, (float*)d_out);
}

// Round 11
// 559.890 us; speedup vs baseline: 6.7201x; 1.0210x over previous
//
#include <hip/hip_runtime.h>
#include <math.h>

#define L_IN 65494
#define T_POOL 21490
#define TPP 21496          // fp16 h row stride (16B-aligned rows)
#define KF 1025
#define RS 1144            // conv replica row stride (elements)
#define NCH 141            // 8-col chunks per replica row (cols 0..1127)
#define KEMB 21490
#define KEMBP 21504        // padded
#define NKC 1344           // KEMBP/16
#define FTILE 33280        // 65*512 shorts per conv filter tile
#define LWSZ 786432        // packed layer-weight shorts per layer

typedef short s16x4 __attribute__((ext_vector_type(4)));
typedef _Float16 f16x8 __attribute__((ext_vector_type(8)));
typedef float f32x4 __attribute__((ext_vector_type(4)));
typedef float f32x16 __attribute__((ext_vector_type(16)));

__device__ inline float selu_f(float x) {
    float e = expf(fminf(x, 0.f));
    float neg = 1.6732632423543772f * (e - 1.f);
    return 1.0507009873554805f * (x > 0.f ? x : neg);
}

__device__ inline float gelu_f(float x) {
    return 0.5f * x * (1.f + erff(x * 0.7071067811865476f));
}

__device__ inline float dot4(float4 a, float4 b) {
    return fmaf(a.x, b.x, fmaf(a.y, b.y, fmaf(a.z, b.z, a.w * b.w)));
}

__device__ inline float sel4(float a0, float a1, float a2, float a3, int i) {
    float r = a0;
    r = (i == 1) ? a1 : r;
    r = (i == 2) ? a2 : r;
    r = (i == 3) ? a3 : r;
    return r;
}

__device__ inline short f2h_bits(float v) {
    _Float16 h = (_Float16)v;
    return *(short*)&h;
}

// x = hi + lo in fp16 (hi RTNE, lo = residual): exact to ~2^-22
__device__ inline void f16split(float v, short& hs, short& ls) {
    _Float16 h = (_Float16)v;
    float hf = (float)h;
    _Float16 l = (_Float16)(v - hf);
    hs = *(short*)&h;
    ls = *(short*)&l;
}

__device__ inline void f16split2(float v, _Float16& h, _Float16& l) {
    h = (_Float16)v;
    l = (_Float16)(v - (float)h);
}

// ---------------- filter pack: fp16 single, fragment-major [ft][kc][lane][8] ----------------
__global__ __launch_bounds__(512)
void filt_pack_kernel(const float* __restrict__ filt, short* __restrict__ fpH) {
    int blk = blockIdx.x;            // ft*65 + kc  (grid 520)
    int ft = blk / 65, kc = blk % 65;
    int t = threadIdx.x, lane = t >> 3, e = t & 7;
    int f = ft * 32 + (lane & 31);
    int tap = kc * 16 + (lane >> 5) * 8 + e;
    float v = (tap < KF) ? filt[f * KF + tap] : 0.f;
    fpH[blk * 512 + t] = f2h_bits(v);
}

// ---------------- emb_w pack: fp16 single, fragment-major [ft][kc][lane][8] ----------------
__global__ __launch_bounds__(512)
void wpack_kernel(const float* __restrict__ wsrc, short* __restrict__ wpH) {
    int blk = blockIdx.x;            // ft*NKC + kc  (grid 8*NKC)
    int ft = blk / NKC, kc = blk % NKC;
    int t = threadIdx.x, lane = t >> 3, e = t & 7;
    int row = ft * 32 + (lane & 31);
    int tap = kc * 16 + (lane >> 5) * 8 + e;
    float v = (tap < KEMB) ? wsrc[(long)row * KEMB + tap] : 0.f;
    wpH[(long)blk * 512 + t] = f2h_bits(v);
}

// ---------------- layer weight pack: fp16 fragment-major for 16x16x32 B-operand ----------------
// per layer: wo(+0) wq(+65536) wk(+131072) wv(+196608) c1(+262144) c2(+524288)
__global__ __launch_bounds__(512)
void lwpack_kernel(const float* __restrict__ wo, const float* __restrict__ wq,
                   const float* __restrict__ wk, const float* __restrict__ wv,
                   const float* __restrict__ c1w, const float* __restrict__ c2w,
                   short* __restrict__ lw) {
    int b = blockIdx.x;              // grid 4*1536
    int layer = b / 1536, r = b % 1536;
    int t = threadIdx.x, lane = t >> 3, e = t & 7;
    const float* src;
    int K, t2;
    long dst;
    if (r < 512) {
        int mat = r >> 7; t2 = r & 127;
        const float* m0 = (mat == 0 ? wo : mat == 1 ? wq : mat == 2 ? wk : wv);
        src = m0 + (long)layer * 65536; K = 256;
        dst = (long)layer * LWSZ + (long)mat * 65536 + (long)t2 * 512;
    } else if (r < 1024) {
        t2 = r - 512;
        src = c1w + (long)layer * 262144; K = 256;
        dst = (long)layer * LWSZ + 262144 + (long)t2 * 512;
    } else {
        t2 = r - 1024;
        src = c2w + (long)layer * 262144; K = 1024;
        dst = (long)layer * LWSZ + 524288 + (long)t2 * 512;
    }
    int KB = K >> 5;
    int nt = t2 / KB, kb = t2 % KB;
    int n = nt * 16 + (lane & 15);
    int k = kb * 32 + ((lane >> 4) & 3) * 8 + e;
    lw[dst + t] = f2h_bits(src[(long)n * K + k]);
}

// ---------------- MFMA projection helper: one 16-col tile, M=16-padded (4 real rows) ----------
__device__ inline f32x4 mfma_nt(const _Float16* __restrict__ Xh, const _Float16* __restrict__ Xl,
                                int xstride, const short* __restrict__ wp_nt, int KB, int lane) {
    f32x4 acc = {0.f, 0.f, 0.f, 0.f};
    const int row = (lane & 15) & 3;
    const int ko0 = ((lane >> 4) & 3) * 8;
    const short* bp = wp_nt + lane * 8;
    const _Float16* xh = Xh + row * xstride + ko0;
    const _Float16* xl = Xl + row * xstride + ko0;
#pragma unroll 4
    for (int kb = 0; kb < KB; kb++) {
        f16x8 bf = *(const f16x8*)(bp + kb * 512);
        f16x8 ah = *(const f16x8*)(xh + kb * 32);
        f16x8 al = *(const f16x8*)(xl + kb * 32);
        acc = __builtin_amdgcn_mfma_f32_16x16x32_f16(al, bf, acc, 0, 0, 0);
        acc = __builtin_amdgcn_mfma_f32_16x16x32_f16(ah, bf, acc, 0, 0, 0);
    }
    return acc;
}

// ---------------- SincConv via MFMA (fp16 2-pass) + |.| + maxpool3 ----------------
union ConvLDS {
    struct { short xh[8][RS]; short xl[8][RS]; } st;
    float ebuf[96][129];
};

#define MFMA2(ACC, AH, AL, BH) \
    ACC = __builtin_amdgcn_mfma_f32_32x32x16_f16(AL, BH, ACC, 0, 0, 0); \
    ACC = __builtin_amdgcn_mfma_f32_32x32x16_f16(AH, BH, ACC, 0, 0, 0);

__global__ __launch_bounds__(256, 3)
void conv_mfma_kernel(const float* __restrict__ x, const short* __restrict__ fpH,
                      _Float16* __restrict__ h) {
    __shared__ ConvLDS u;
    const int tid = threadIdx.x;
    const int pb = blockIdx.x;
    const int b = blockIdx.y;
    const int t0 = pb * 96;
    const float* xb = x + (long)b * L_IN;

    // staging: thread owns (replica s, 8-col chunk j); vectorized b128 writes.
    if (pb < 671) {
        for (int idx = tid; idx < 8 * NCH; idx += 256) {
            int s = idx / NCH, j = idx - s * NCH;
            int gi = t0 + s + j * 8;
            f16x8 hv, lv;
#pragma unroll
            for (int e = 0; e < 8; e++) {
                float v = xb[gi + e];
                _Float16 hh, ll;
                f16split2(v, hh, ll);
                hv[e] = hh; lv[e] = ll;
            }
            *(f16x8*)&u.st.xh[s][j * 8] = hv;
            *(f16x8*)&u.st.xl[s][j * 8] = lv;
        }
    } else {
        for (int idx = tid; idx < 8 * NCH; idx += 256) {
            int s = idx / NCH, j = idx - s * NCH;
            int gi = t0 + s + j * 8;
            f16x8 hv, lv;
#pragma unroll
            for (int e = 0; e < 8; e++) {
                float v = (gi + e < L_IN) ? xb[gi + e] : 0.f;
                _Float16 hh, ll;
                f16split2(v, hh, ll);
                hv[e] = hh; lv[e] = ll;
            }
            *(f16x8*)&u.st.xh[s][j * 8] = hv;
            *(f16x8*)&u.st.xl[s][j * 8] = lv;
        }
    }
    __syncthreads();

    const int lane = tid & 63;
    const int wid = tid >> 6;
    const int l31 = lane & 31;
    const int hi = lane >> 5;
    const int f0w = wid * 64;

    const short* aH = &u.st.xh[l31 & 7][8 * (l31 >> 3) + 8 * hi];
    const short* aL = &u.st.xl[l31 & 7][8 * (l31 >> 3) + 8 * hi];
    const short* bp0 = fpH + (long)(wid * 2) * FTILE + lane * 8;
    const short* bp1 = bp0 + FTILE;

    f32x16 a00 = {0}, a01 = {0}, a10 = {0}, a11 = {0}, a20 = {0}, a21 = {0};

#pragma unroll 1
    for (int kc = 0; kc < 65; kc++) {
        const int ko = kc * 16;
        const int kf = kc * 512;
        f16x8 ah0 = *(const f16x8*)(aH + ko);
        f16x8 ah1 = *(const f16x8*)(aH + ko + 32);
        f16x8 ah2 = *(const f16x8*)(aH + ko + 64);
        f16x8 al0 = *(const f16x8*)(aL + ko);
        f16x8 al1 = *(const f16x8*)(aL + ko + 32);
        f16x8 al2 = *(const f16x8*)(aL + ko + 64);
        f16x8 bh0 = *(const f16x8*)(bp0 + kf);
        f16x8 bh1 = *(const f16x8*)(bp1 + kf);
        MFMA2(a00, ah0, al0, bh0)
        MFMA2(a01, ah0, al0, bh1)
        MFMA2(a10, ah1, al1, bh0)
        MFMA2(a11, ah1, al1, bh1)
        MFMA2(a20, ah2, al2, bh0)
        MFMA2(a21, ah2, al2, bh1)
    }

    __syncthreads();
    const int t3l = tid & 31;
    const int t3 = pb * 32 + t3l;

#pragma unroll
    for (int half = 0; half < 2; half++) {
        if ((wid >> 1) == half) {
            int fcb = f0w - half * 128;
#define WRF(ACC, MT, NT)                                                   \
            {                                                              \
                int fc = fcb + NT * 32 + l31;                              \
                _Pragma("unroll")                                          \
                for (int r = 0; r < 16; r++) {                             \
                    int pos = MT * 32 + (r & 3) + 8 * (r >> 2) + 4 * hi;   \
                    u.ebuf[pos][fc] = fabsf(ACC[r]);                       \
                }                                                          \
            }
            WRF(a00, 0, 0) WRF(a01, 0, 1)
            WRF(a10, 1, 0) WRF(a11, 1, 1)
            WRF(a20, 2, 0) WRF(a21, 2, 1)
#undef WRF
        }
        __syncthreads();
        if (t3 < T_POOL) {
            for (int ff = tid >> 5; ff < 128; ff += 8) {
                float v = fmaxf(fmaxf(u.ebuf[3 * t3l][ff], u.ebuf[3 * t3l + 1][ff]),
                                u.ebuf[3 * t3l + 2][ff]);
                h[((long)(b * 256 + half * 128 + ff)) * TPP + t3] = (_Float16)v;
            }
        }
        __syncthreads();
    }
}

// ---------------- BatchNorm stats for h (fp16): two-stage ----------------
__global__ __launch_bounds__(256)
void bn_part_kernel(const _Float16* __restrict__ xin, float* __restrict__ p1,
                    float* __restrict__ p2) {
    __shared__ float sm[8];
    int c = blockIdx.x, s = blockIdx.y, tid = threadIdx.x;
    int t0 = s * 2687, t1 = min(T_POOL, t0 + 2687);
    float s1 = 0.f, s2 = 0.f;
    for (int b = 0; b < 4; b++) {
        const _Float16* p = xin + (long)b * 256 * TPP + (long)c * TPP;
        for (int t = t0 + tid; t < t1; t += 256) {
            float v = (float)p[t];
            s1 += v;
            s2 = fmaf(v, v, s2);
        }
    }
    for (int off = 32; off > 0; off >>= 1) { s1 += __shfl_down(s1, off); s2 += __shfl_down(s2, off); }
    int lane = tid & 63, wv = tid >> 6;
    if (lane == 0) { sm[wv] = s1; sm[4 + wv] = s2; }
    __syncthreads();
    if (tid == 0) {
        p1[c * 8 + s] = sm[0] + sm[1] + sm[2] + sm[3];
        p2[c * 8 + s] = sm[4] + sm[5] + sm[6] + sm[7];
    }
}

__global__ __launch_bounds__(256)
void bn_fin_kernel(const float* __restrict__ p1, const float* __restrict__ p2,
                   const float* __restrict__ g, const float* __restrict__ bb,
                   float* __restrict__ sc, float* __restrict__ sh) {
    int c = threadIdx.x;
    float S1 = 0.f, S2 = 0.f;
#pragma unroll
    for (int s = 0; s < 8; s++) { S1 += p1[c * 8 + s]; S2 += p2[c * 8 + s]; }
    float n = 4.f * (float)T_POOL;
    float mean = S1 / n;
    float var = S2 / n - mean * mean;
    float rstd = rsqrtf(var + 1e-5f);
    float gc = g[c], bc = bb[c];
    sc[c] = rstd * gc;
    sh[c] = bc - mean * rstd * gc;
}

// ---------------- BatchNorm stats (small, for e) ----------------
__global__ __launch_bounds__(256)
void bn_stats_kernel(const float* __restrict__ xin, const float* __restrict__ g,
                     const float* __restrict__ bb, float* __restrict__ sc,
                     float* __restrict__ sh, int ilen, long bstride) {
    __shared__ float sm[8];
    int c = blockIdx.x, tid = threadIdx.x;
    float s1 = 0.f, s2 = 0.f;
    for (int b = 0; b < 4; b++) {
        const float* p = xin + b * bstride + (long)c * ilen;
        for (int t = tid; t < ilen; t += 256) {
            float v = p[t];
            s1 += v;
            s2 = fmaf(v, v, s2);
        }
    }
    for (int off = 32; off > 0; off >>= 1) { s1 += __shfl_down(s1, off); s2 += __shfl_down(s2, off); }
    int lane = tid & 63, wv = tid >> 6;
    if (lane == 0) { sm[wv] = s1; sm[4 + wv] = s2; }
    __syncthreads();
    if (tid == 0) {
        float S1 = sm[0] + sm[1] + sm[2] + sm[3];
        float S2 = sm[4] + sm[5] + sm[6] + sm[7];
        float n = 4.f * (float)ilen;
        float mean = S1 / n;
        float var = S2 / n - mean * mean;
        float rstd = rsqrtf(var + 1e-5f);
        float gc = g[c], bc = bb[c];
        sc[c] = rstd * gc;
        sh[c] = bc - mean * rstd * gc;
    }
}

// ---------------- Embedding GEMM via MFMA (fp16 2-pass), split-K, packed B ----------------
__global__ __launch_bounds__(256, 2)
void embed_mfma_kernel(const _Float16* __restrict__ H, const short* __restrict__ Wh,
                       const float* __restrict__ sc, const float* __restrict__ sh,
                       float* __restrict__ P, int kPerZ) {
    __shared__ short Ah[128][36];
    __shared__ short Al[128][36];
    const int tid = threadIdx.x;
    const int rowBase = blockIdx.x * 128;
    const int colBase = blockIdx.y * 128;
    const int z = blockIdx.z;
    const int kz = z * kPerZ;
    const int iters = kPerZ >> 5;

    const int trow = tid >> 1, th = (tid & 1) * 16;
    const int arow = rowBase + trow;
    const float asc = sc[arow & 255], ash_ = sh[arow & 255];
    const _Float16* Ap = H + (long)arow * TPP;

    const int lane = tid & 63, wid = tid >> 6;
    const int l31 = lane & 31, hi = lane >> 5;
    const int wm = wid >> 1, wn = wid & 1;

    const short* bhp[2];
#pragma unroll
    for (int nt = 0; nt < 2; nt++) {
        int ft = (colBase >> 5) + wn * 2 + nt;
        bhp[nt] = Wh + (long)ft * NKC * 512 + lane * 8;
    }

    f32x16 acc[2][2] = {{{0}, {0}}, {{0}, {0}}};

    for (int it = 0; it < iters; it++) {
        const int k0 = kz + it * 32;
        __syncthreads();
        float av[16];
        if (k0 + 32 <= KEMB) {
            const f16x8* p8 = (const f16x8*)(Ap + k0 + th);
            f16x8 v0 = p8[0], v1 = p8[1];
#pragma unroll
            for (int e = 0; e < 8; e++) { av[e] = (float)v0[e]; av[8 + e] = (float)v1[e]; }
        } else {
#pragma unroll
            for (int e = 0; e < 16; e++) {
                int k = k0 + th + e;
                av[e] = (k < KEMB) ? (float)Ap[k] : 0.f;
            }
        }
#pragma unroll
        for (int q = 0; q < 4; q++) {
            s16x4 h4, l4;
#pragma unroll
            for (int e = 0; e < 4; e++) {
                float v = selu_f(fmaf(av[q * 4 + e], asc, ash_));
                short hs, ls;
                f16split(v, hs, ls);
                h4[e] = hs; l4[e] = ls;
            }
            *(s16x4*)&Ah[trow][th + q * 4] = h4;
            *(s16x4*)&Al[trow][th + q * 4] = l4;
        }
        __syncthreads();

#pragma unroll
        for (int ks = 0; ks < 2; ks++) {
            const int kloc = ks * 16 + hi * 8;
            const long kcg = (long)((k0 >> 4) + ks) * 512;
            f16x8 ah[2], al[2], bh[2];
#pragma unroll
            for (int mt = 0; mt < 2; mt++) {
                const int r = wm * 64 + mt * 32 + l31;
                const short* ph = &Ah[r][kloc];
                const short* pl = &Al[r][kloc];
                union { f16x8 v; unsigned long long q[2]; } uh, ul;
                uh.q[0] = *(const unsigned long long*)(ph);
                uh.q[1] = *(const unsigned long long*)(ph + 4);
                ul.q[0] = *(const unsigned long long*)(pl);
                ul.q[1] = *(const unsigned long long*)(pl + 4);
                ah[mt] = uh.v; al[mt] = ul.v;
            }
#pragma unroll
            for (int nt = 0; nt < 2; nt++)
                bh[nt] = *(const f16x8*)(bhp[nt] + kcg);
#pragma unroll
            for (int mt = 0; mt < 2; mt++)
#pragma unroll
                for (int nt = 0; nt < 2; nt++) {
                    MFMA2(acc[mt][nt], ah[mt], al[mt], bh[nt])
                }
        }
    }

    float* Pz = P + (long)z * 262144;
#pragma unroll
    for (int mt = 0; mt < 2; mt++)
#pragma unroll
        for (int nt = 0; nt < 2; nt++) {
            int col = colBase + wn * 64 + nt * 32 + l31;
#pragma unroll
            for (int r = 0; r < 16; r++) {
                int row = rowBase + wm * 64 + mt * 32 + (r & 3) + 8 * (r >> 2) + 4 * hi;
                Pz[(long)row * 256 + col] = acc[mt][nt][r];
            }
        }
}

__global__ __launch_bounds__(256)
void embed_combine_kernel(const float* __restrict__ P, const float* __restrict__ eb,
                          float* __restrict__ e, int nsplit) {
    int idx = blockIdx.x * 256 + threadIdx.x;
    float s = 0.f;
    for (int z = 0; z < nsplit; z++) s += P[(long)z * 262144 + idx];
    e[idx] = s + eb[idx & 255];
}

// ---------------- fused zinit + layer-0 QKV (MFMA, packed fp16 weights) ----------------
__global__ __launch_bounds__(512)
void qkv_init_kernel(const float* __restrict__ e, const float* __restrict__ sc,
                     const float* __restrict__ sh, const short* __restrict__ lw0,
                     const float* __restrict__ bq0, const float* __restrict__ bk0,
                     const float* __restrict__ bv0,
                     float* __restrict__ z, float* __restrict__ qo,
                     float* __restrict__ ko, float* __restrict__ vo) {
    __shared__ _Float16 zsh[4][256], zsl[4][256];
    const int t = threadIdx.x;
    const int w = t >> 6, lane = t & 63;
    const long rowg0 = (long)blockIdx.x * 4;

    for (int idx = t; idx < 1024; idx += 512) {
        int i = idx >> 8, dd = idx & 255;
        int c = (int)((rowg0 + i) & 255);
        float v = fmaf(e[(rowg0 + i) * 256 + dd], sc[c], sh[c]);
        v = fmaxf(v, 0.f);
        int i2 = dd >> 1;
        float ang = (float)c * expf(-0.03597789207803195f * (float)(2 * i2));
        float pe = (dd & 1) ? cosf(ang) : sinf(ang);
        float zz = v + pe;
        z[(rowg0 + i) * 256 + dd] = zz;
        _Float16 hh, ll;
        f16split2(zz, hh, ll);
        zsh[i][dd] = hh; zsl[i][dd] = ll;
    }
    __syncthreads();

#pragma unroll
    for (int mat = 0; mat < 3; mat++) {
        const short* wp = lw0 + 65536 * (1 + mat);
        const float* bb = (mat == 0 ? bq0 : mat == 1 ? bk0 : bv0);
        float* op = (mat == 0 ? qo : mat == 1 ? ko : vo);
        for (int nt = w; nt < 16; nt += 8) {
            f32x4 acc = mfma_nt(&zsh[0][0], &zsl[0][0], 256, wp + nt * 8 * 512, 8, lane);
            if (lane < 16) {
                int col = nt * 16 + lane;
                float bv2 = bb[col];
#pragma unroll
                for (int r = 0; r < 4; r++)
                    op[(rowg0 + r) * 256 + col] = acc[r] + bv2;
            }
        }
    }
}

// ---------------- fused transformer layer: attention GEMV + MFMA projections ----------------
__device__ inline void ln_reduce4(const float (*buf)[256], float (*mr)[2], int t) {
    int wid = t >> 6, lane = t & 63;
    if (wid < 4) {
        float4 v = *(const float4*)&buf[wid][lane * 4];
        float s = v.x + v.y + v.z + v.w;
        float q = v.x * v.x + v.y * v.y + v.z * v.z + v.w * v.w;
#pragma unroll
        for (int off = 32; off > 0; off >>= 1) {
            s += __shfl_xor(s, off);
            q += __shfl_xor(q, off);
        }
        if (lane == 0) {
            float mean = s * (1.f / 256.f);
            float var = q * (1.f / 256.f) - mean * mean;
            mr[wid][0] = mean;
            mr[wid][1] = rsqrtf(var + 1e-5f);
        }
    }
}

template <int LAST>
__global__ __launch_bounds__(1024)
void layer_kernel(const float* __restrict__ zin, const float* __restrict__ qin,
                  const float* __restrict__ kin, const float* __restrict__ vin,
                  const short* __restrict__ lw_l, const short* __restrict__ lw_n,
                  const float* __restrict__ bo_l,
                  const float* __restrict__ c1b_l, const float* __restrict__ c2b_l,
                  const float* __restrict__ ln1g_l, const float* __restrict__ ln1b_l,
                  const float* __restrict__ ln2g_l, const float* __restrict__ ln2b_l,
                  const float* __restrict__ bq_n, const float* __restrict__ bk_n,
                  const float* __restrict__ bv_n,
                  const float* __restrict__ lnfg, const float* __restrict__ lnfb,
                  float* __restrict__ zout, float* __restrict__ qo,
                  float* __restrict__ ko, float* __restrict__ vo,
                  float* __restrict__ lnf_out) {
    __shared__ float zs[4][256];
    __shared__ float qb[4][256];
    __shared__ float sscore[4][8][256];
    __shared__ _Float16 zsh[4][256], zsl[4][256];
    __shared__ _Float16 yh[4][1024], yl[4][1024];
    __shared__ float mr[4][2];

    const int t = threadIdx.x;
    const int w = t >> 6, lane = t & 63;
    const long rowg0 = (long)blockIdx.x * 4;
    const int b = blockIdx.x >> 6;

    const int f = t & 255;       // output dim for 256-wide phases
    const int kq = t >> 8;       // row 0..3

    // P1: stage z (residual) and q rows
    {
        int r = t >> 8, dd = t & 255;
        zs[r][dd] = zin[(rowg0 + r) * 256 + dd];
        qb[r][dd] = qin[(rowg0 + r) * 256 + dd];
    }
    __syncthreads();

    // P2: scores — wave pair per head
    {
        const float scale = 0.17677669529663687f;
        const int jq = lane >> 3, li = lane & 7, d4 = li * 4;
        const int hh = w >> 1, jh = w & 1;
        const float* kb = kin + (long)b * 65536 + hh * 32 + d4;
        float4 q0 = *(const float4*)&qb[0][hh * 32 + d4];
        float4 q1 = *(const float4*)&qb[1][hh * 32 + d4];
        float4 q2 = *(const float4*)&qb[2][hh * 32 + d4];
        float4 q3 = *(const float4*)&qb[3][hh * 32 + d4];
        for (int jb = 0; jb < 16; jb++) {
            int j = jh * 128 + jb * 8 + jq;
            float4 kv = *(const float4*)(kb + (long)j * 256);
            float a0 = dot4(kv, q0), a1 = dot4(kv, q1);
            float a2 = dot4(kv, q2), a3 = dot4(kv, q3);
#pragma unroll
            for (int off = 1; off < 8; off <<= 1) {
                a0 += __shfl_xor(a0, off); a1 += __shfl_xor(a1, off);
                a2 += __shfl_xor(a2, off); a3 += __shfl_xor(a3, off);
            }
            if (li < 4) sscore[li][hh][j] = sel4(a0, a1, a2, a3, li) * scale;
        }
    }
    __syncthreads();

    // P3: softmax
    {
#pragma unroll
        for (int p = 0; p < 2; p++) {
            int pair = w * 2 + p;
            int i = pair >> 3, hh = pair & 7;
            float* row = sscore[i][hh];
            float v0 = row[lane], v1 = row[lane + 64];
            float v2 = row[lane + 128], v3 = row[lane + 192];
            float m = fmaxf(fmaxf(v0, v1), fmaxf(v2, v3));
#pragma unroll
            for (int off = 32; off > 0; off >>= 1) m = fmaxf(m, __shfl_xor(m, off));
            float e0 = expf(v0 - m), e1 = expf(v1 - m);
            float e2 = expf(v2 - m), e3 = expf(v3 - m);
            float su = e0 + e1 + e2 + e3;
#pragma unroll
            for (int off = 32; off > 0; off >>= 1) su += __shfl_xor(su, off);
            float inv = 1.f / su;
            row[lane] = e0 * inv; row[lane + 64] = e1 * inv;
            row[lane + 128] = e2 * inv; row[lane + 192] = e3 * inv;
        }
    }
    __syncthreads();

    // P4: PV — thread owns (f, row); write split attention output
    {
        int row = kq;
        int hh = f >> 5;
        const float* vcol = vin + (long)b * 65536 + f;
        const float* p0 = sscore[row][hh];
        float a0 = 0.f;
#pragma unroll 4
        for (int j4 = 0; j4 < 64; j4++) {
            float4 pv0 = *(const float4*)(p0 + j4 * 4);
            float v0 = vcol[(long)(j4 * 4 + 0) * 256];
            float v1 = vcol[(long)(j4 * 4 + 1) * 256];
            float v2 = vcol[(long)(j4 * 4 + 2) * 256];
            float v3 = vcol[(long)(j4 * 4 + 3) * 256];
            a0 = fmaf(pv0.x, v0, a0); a0 = fmaf(pv0.y, v1, a0);
            a0 = fmaf(pv0.z, v2, a0); a0 = fmaf(pv0.w, v3, a0);
        }
        _Float16 hh2, ll;
        f16split2(a0, hh2, ll);
        zsh[row][f] = hh2; zsl[row][f] = ll;
    }
    __syncthreads();

    // P5: O-proj MFMA + bias + residual -> qb
    {
        int nt = w;
        f32x4 acc = mfma_nt(&zsh[0][0], &zsl[0][0], 256, lw_l + nt * 8 * 512, 8, lane);
        if (lane < 16) {
            int col = nt * 16 + lane;
            float bb = bo_l[col];
#pragma unroll
            for (int r = 0; r < 4; r++)
                qb[r][col] = acc[r] + bb + zs[r][col];
        }
    }
    __syncthreads();
    ln_reduce4(qb, mr, t);
    __syncthreads();
    {
        int r = kq;
        float z1 = (qb[r][f] - mr[r][0]) * mr[r][1] * ln1g_l[f] + ln1b_l[f];
        zs[r][f] = z1;
        _Float16 hh2, ll;
        f16split2(z1, hh2, ll);
        zsh[r][f] = hh2; zsl[r][f] = ll;
    }
    __syncthreads();

    // P7: FFN1 MFMA + gelu -> yh/yl
    {
        const short* wp = lw_l + 262144;
        for (int nt = w; nt < 64; nt += 16) {
            f32x4 acc = mfma_nt(&zsh[0][0], &zsl[0][0], 256, wp + nt * 8 * 512, 8, lane);
            if (lane < 16) {
                int col = nt * 16 + lane;
                float cb = c1b_l[col];
#pragma unroll
                for (int r = 0; r < 4; r++) {
                    float g = gelu_f(acc[r] + cb);
                    _Float16 hh2, ll;
                    f16split2(g, hh2, ll);
                    yh[r][col] = hh2; yl[r][col] = ll;
                }
            }
        }
    }
    __syncthreads();

    // P8: FFN2 MFMA (K=1024) + bias + residual -> qb
    {
        const short* wp = lw_l + 524288;
        int nt = w;
        f32x4 acc = mfma_nt(&yh[0][0], &yl[0][0], 1024, wp + nt * 32 * 512, 32, lane);
        if (lane < 16) {
            int col = nt * 16 + lane;
            float cb = c2b_l[col];
#pragma unroll
            for (int r = 0; r < 4; r++)
                qb[r][col] = acc[r] + cb + zs[r][col];
        }
    }
    __syncthreads();
    ln_reduce4(qb, mr, t);
    __syncthreads();
    {
        int r = kq;
        float z2 = (qb[r][f] - mr[r][0]) * mr[r][1] * ln2g_l[f] + ln2b_l[f];
        zs[r][f] = z2;
        zout[(rowg0 + r) * 256 + f] = z2;
        _Float16 hh2, ll;
        f16split2(z2, hh2, ll);
        zsh[r][f] = hh2; zsl[r][f] = ll;
    }
    __syncthreads();

    if (!LAST) {
        // P9: QKV MFMA for next layer
#pragma unroll
        for (int mat = 0; mat < 3; mat++) {
            const short* wp = lw_n + 65536 * (1 + mat);
            const float* bb = (mat == 0 ? bq_n : mat == 1 ? bk_n : bv_n);
            float* op = (mat == 0 ? qo : mat == 1 ? ko : vo);
            int nt = w;
            f32x4 acc = mfma_nt(&zsh[0][0], &zsl[0][0], 256, wp + nt * 8 * 512, 8, lane);
            if (lane < 16) {
                int col = nt * 16 + lane;
                float bv2 = bb[col];
#pragma unroll
                for (int r = 0; r < 4; r++)
                    op[(rowg0 + r) * 256 + col] = acc[r] + bv2;
            }
        }
    } else {
        ln_reduce4(zs, mr, t);
        __syncthreads();
        {
            int r = kq;
            lnf_out[(rowg0 + r) * 256 + f] =
                (zs[r][f] - mr[r][0]) * mr[r][1] * lnfg[f] + lnfb[f];
        }
    }
}

// ---------------- final: pooled mean over seq -> proj ----------------
__global__ __launch_bounds__(256)
void final_kernel(const float* __restrict__ zf, const float* __restrict__ pw,
                  const float* __restrict__ pb, float* __restrict__ out) {
    __shared__ float sm[8];
    int b = blockIdx.x, d = threadIdx.x;
    float s = 0.f;
    for (int c = 0; c < 256; c++) s += zf[((long)(b * 256 + c)) * 256 + d];
    float pooled = s * (1.f / 256.f);
    float c0 = pooled * pw[d], c1 = pooled * pw[256 + d];
    for (int off = 32; off > 0; off >>= 1) { c0 += __shfl_down(c0, off); c1 += __shfl_down(c1, off); }
    int lane = d & 63, wv = d >> 6;
    if (lane == 0) { sm[wv] = c0; sm[4 + wv] = c1; }
    __syncthreads();
    if (d == 0) {
        out[b * 2 + 0] = sm[0] + sm[1] + sm[2] + sm[3] + pb[0];
        out[b * 2 + 1] = sm[4] + sm[5] + sm[6] + sm[7] + pb[1];
    }
}

extern "C" void kernel_launch(void* const* d_in, const int* in_sizes, int n_in,
                              void* d_out, int out_size, void* d_ws, size_t ws_size,
                              hipStream_t stream) {
    const float* x       = (const float*)d_in[0];
    const float* filters = (const float*)d_in[1];
    const float* bn1_g   = (const float*)d_in[2];
    const float* bn1_b   = (const float*)d_in[3];
    const float* emb_w   = (const float*)d_in[4];
    const float* emb_b   = (const float*)d_in[5];
    const float* embbn_g = (const float*)d_in[6];
    const float* embbn_b = (const float*)d_in[7];
    const float* wq      = (const float*)d_in[8];
    const float* bq      = (const float*)d_in[9];
    const float* wk      = (const float*)d_in[10];
    const float* bk      = (const float*)d_in[11];
    const float* wv      = (const float*)d_in[12];
    const float* bv      = (const float*)d_in[13];
    const float* wo      = (const float*)d_in[14];
    const float* bo      = (const float*)d_in[15];
    const float* c1w     = (const float*)d_in[16];
    const float* c1b     = (const float*)d_in[17];
    const float* c2w     = (const float*)d_in[18];
    const float* c2b     = (const float*)d_in[19];
    const float* ln1g    = (const float*)d_in[20];
    const float* ln1b    = (const float*)d_in[21];
    const float* ln2g    = (const float*)d_in[22];
    const float* ln2b    = (const float*)d_in[23];
    const float* lnfg    = (const float*)d_in[24];
    const float* lnfb    = (const float*)d_in[25];
    const float* projw   = (const float*)d_in[26];
    const float* projb   = (const float*)d_in[27];

    const long hF = 11005952L;                      // 1024*TPP halfs, in float units
    const long wpackF = 2752512L;                   // 8*NKC*512 shorts, in floats
    const long lwF = 1572864L;                      // 4*LWSZ shorts, in floats
    const long fixedF = hF + 5120 + wpackF + lwF + 9L * 262144;
    long wsFloats = (long)(ws_size / 4);
    long Z = 32;
    while (Z > 8 && fixedF + Z * 262144L > wsFloats) Z >>= 1;
    const int kPerZ = KEMBP / (int)Z;

    float* ws = (float*)d_ws;
    _Float16* h16 = (_Float16*)ws;                  // 1024*TPP halfs
    float* bn1_sc = ws + hF;
    float* bn1_sh = bn1_sc + 256;
    float* e_sc   = bn1_sh + 256;
    float* e_sh   = e_sc + 256;
    float* bnp1   = e_sh + 256;                     // 2048
    float* bnp2   = bnp1 + 2048;                    // 2048
    float* part   = bnp2 + 2048;                    // Z * 262144
    float* wsp    = part + Z * 262144L;
    short* wpH    = (short*)wsp;                    // 8*NKC*512 shorts
    float* e      = wsp + wpackF;
    float* z      = e + 262144;
    float* qA     = z + 262144;
    float* kA     = qA + 262144;
    float* vA     = kA + 262144;
    float* qB     = vA + 262144;
    float* kB     = qB + 262144;
    float* vB     = kB + 262144;
    float* t1     = vB + 262144;
    short* lw     = (short*)(t1 + 262144);          // 4*LWSZ shorts

    // conv packed filters alias onto `part` (only used before embed writes part)
    short* fpH = (short*)part;                      // 520*512 shorts

    filt_pack_kernel<<<520, 512, 0, stream>>>(filters, fpH);
    wpack_kernel<<<8 * NKC, 512, 0, stream>>>(emb_w, wpH);
    lwpack_kernel<<<6144, 512, 0, stream>>>(wo, wq, wk, wv, c1w, c2w, lw);
    conv_mfma_kernel<<<dim3(672, 4), 256, 0, stream>>>(x, fpH, h16);
    bn_part_kernel<<<dim3(256, 8), 256, 0, stream>>>(h16, bnp1, bnp2);
    bn_fin_kernel<<<1, 256, 0, stream>>>(bnp1, bnp2, bn1_g, bn1_b, bn1_sc, bn1_sh);
    embed_mfma_kernel<<<dim3(8, 2, (int)Z), 256, 0, stream>>>(h16, wpH,
                                                              bn1_sc, bn1_sh, part, kPerZ);
    embed_combine_kernel<<<1024, 256, 0, stream>>>(part, emb_b, e, (int)Z);
    bn_stats_kernel<<<256, 256, 0, stream>>>(e, embbn_g, embbn_b, e_sc, e_sh,
                                             256, 256L * 256);
    qkv_init_kernel<<<256, 512, 0, stream>>>(e, e_sc, e_sh, lw, bq, bk, bv,
                                             z, qA, kA, vA);

    float* qs[2][3] = {{qA, kA, vA}, {qB, kB, vB}};
    for (int l = 0; l < 4; l++) {
        float** in = qs[l & 1];
        float** ou = qs[(l + 1) & 1];
        const short* lw_l = lw + (long)l * LWSZ;
        const short* lw_n = lw + (long)((l + 1) & 3) * LWSZ;
        const float* bo_l = bo + l * 256;
        const float* c1b_l = c1b + l * 1024;
        const float* c2b_l = c2b + l * 256;
        const float* l1g = ln1g + l * 256; const float* l1b = ln1b + l * 256;
        const float* l2g = ln2g + l * 256; const float* l2b = ln2b + l * 256;
        if (l < 3) {
            const float* bq_n = bq + (l + 1) * 256;
            const float* bk_n = bk + (l + 1) * 256;
            const float* bv_n = bv + (l + 1) * 256;
            layer_kernel<0><<<256, 1024, 0, stream>>>(z, in[0], in[1], in[2],
                lw_l, lw_n, bo_l, c1b_l, c2b_l, l1g, l1b, l2g, l2b,
                bq_n, bk_n, bv_n, lnfg, lnfb,
                z, ou[0], ou[1], ou[2], t1);
        } else {
            layer_kernel<1><<<256, 1024, 0, stream>>>(z, in[0], in[1], in[2],
                lw_l, lw_n, bo_l, c1b_l, c2b_l, l1g, l1b, l2g, l2b,
                bq, bk, bv, lnfg, lnfb,
                z, ou[0], ou[1], ou[2], t1);
        }
    }

    final_kernel<<<4, 256, 0, stream>>>(t1, projw, projb, (float*)d_out);
}

// Round 12
// 461.469 us; speedup vs baseline: 8.1534x; 1.2133x over previous
//
#include <hip/hip_runtime.h>
#include <math.h>

#define L_IN 65494
#define T_POOL 21490
#define TPP 21496          // fp16 h row stride (16B-aligned rows)
#define KF 1025
#define RS 1144            // conv replica row stride (elements)
#define NCH 141            // 8-col chunks per replica row
#define KEMB 21490
#define KEMBP 21504        // padded
#define NKC 1344           // KEMBP/16
#define FTILE 33280        // 65*512 shorts per conv filter tile
#define LWSZ 786432        // packed layer-weight shorts per layer

typedef short s16x4 __attribute__((ext_vector_type(4)));
typedef _Float16 f16x8 __attribute__((ext_vector_type(8)));
typedef float f32x4 __attribute__((ext_vector_type(4)));
typedef float f32x16 __attribute__((ext_vector_type(16)));

__device__ inline float selu_f(float x) {
    float e = expf(fminf(x, 0.f));
    float neg = 1.6732632423543772f * (e - 1.f);
    return 1.0507009873554805f * (x > 0.f ? x : neg);
}

__device__ inline float gelu_f(float x) {
    return 0.5f * x * (1.f + erff(x * 0.7071067811865476f));
}

__device__ inline float dot4(float4 a, float4 b) {
    return fmaf(a.x, b.x, fmaf(a.y, b.y, fmaf(a.z, b.z, a.w * b.w)));
}

__device__ inline float sel4(float a0, float a1, float a2, float a3, int i) {
    float r = a0;
    r = (i == 1) ? a1 : r;
    r = (i == 2) ? a2 : r;
    r = (i == 3) ? a3 : r;
    return r;
}

__device__ inline short f2h_bits(float v) {
    _Float16 h = (_Float16)v;
    return *(short*)&h;
}

// x = hi + lo in fp16 (hi RTNE, lo = residual): exact to ~2^-22
__device__ inline void f16split(float v, short& hs, short& ls) {
    _Float16 h = (_Float16)v;
    float hf = (float)h;
    _Float16 l = (_Float16)(v - hf);
    hs = *(short*)&h;
    ls = *(short*)&l;
}

__device__ inline void f16split2(float v, _Float16& h, _Float16& l) {
    h = (_Float16)v;
    l = (_Float16)(v - (float)h);
}

// ---------------- filter pack: fp16 single, fragment-major [ft][kc][lane][8] ----------------
__global__ __launch_bounds__(512)
void filt_pack_kernel(const float* __restrict__ filt, short* __restrict__ fpH) {
    int blk = blockIdx.x;            // ft*65 + kc  (grid 520)
    int ft = blk / 65, kc = blk % 65;
    int t = threadIdx.x, lane = t >> 3, e = t & 7;
    int f = ft * 32 + (lane & 31);
    int tap = kc * 16 + (lane >> 5) * 8 + e;
    float v = (tap < KF) ? filt[f * KF + tap] : 0.f;
    fpH[blk * 512 + t] = f2h_bits(v);
}

// ---------------- emb_w pack: fp16 single, fragment-major [ft][kc][lane][8] ----------------
__global__ __launch_bounds__(512)
void wpack_kernel(const float* __restrict__ wsrc, short* __restrict__ wpH) {
    int blk = blockIdx.x;            // ft*NKC + kc  (grid 8*NKC)
    int ft = blk / NKC, kc = blk % NKC;
    int t = threadIdx.x, lane = t >> 3, e = t & 7;
    int row = ft * 32 + (lane & 31);
    int tap = kc * 16 + (lane >> 5) * 8 + e;
    float v = (tap < KEMB) ? wsrc[(long)row * KEMB + tap] : 0.f;
    wpH[(long)blk * 512 + t] = f2h_bits(v);
}

// ---------------- layer weight pack: fp16 fragment-major for 16x16x32 B-operand ----------------
__global__ __launch_bounds__(512)
void lwpack_kernel(const float* __restrict__ wo, const float* __restrict__ wq,
                   const float* __restrict__ wk, const float* __restrict__ wv,
                   const float* __restrict__ c1w, const float* __restrict__ c2w,
                   short* __restrict__ lw) {
    int b = blockIdx.x;              // grid 4*1536
    int layer = b / 1536, r = b % 1536;
    int t = threadIdx.x, lane = t >> 3, e = t & 7;
    const float* src;
    int K, t2;
    long dst;
    if (r < 512) {
        int mat = r >> 7; t2 = r & 127;
        const float* m0 = (mat == 0 ? wo : mat == 1 ? wq : mat == 2 ? wk : wv);
        src = m0 + (long)layer * 65536; K = 256;
        dst = (long)layer * LWSZ + (long)mat * 65536 + (long)t2 * 512;
    } else if (r < 1024) {
        t2 = r - 512;
        src = c1w + (long)layer * 262144; K = 256;
        dst = (long)layer * LWSZ + 262144 + (long)t2 * 512;
    } else {
        t2 = r - 1024;
        src = c2w + (long)layer * 262144; K = 1024;
        dst = (long)layer * LWSZ + 524288 + (long)t2 * 512;
    }
    int KB = K >> 5;
    int nt = t2 / KB, kb = t2 % KB;
    int n = nt * 16 + (lane & 15);
    int k = kb * 32 + ((lane >> 4) & 3) * 8 + e;
    lw[dst + t] = f2h_bits(src[(long)n * K + k]);
}

// ---------------- MFMA projection helper: one 16-col tile, M=16-padded (4 real rows) ----------
__device__ inline f32x4 mfma_nt(const _Float16* __restrict__ Xh, const _Float16* __restrict__ Xl,
                                int xstride, const short* __restrict__ wp_nt, int KB, int lane) {
    f32x4 acc = {0.f, 0.f, 0.f, 0.f};
    const int row = (lane & 15) & 3;
    const int ko0 = ((lane >> 4) & 3) * 8;
    const short* bp = wp_nt + lane * 8;
    const _Float16* xh = Xh + row * xstride + ko0;
    const _Float16* xl = Xl + row * xstride + ko0;
#pragma unroll 4
    for (int kb = 0; kb < KB; kb++) {
        f16x8 bf = *(const f16x8*)(bp + kb * 512);
        f16x8 ah = *(const f16x8*)(xh + kb * 32);
        f16x8 al = *(const f16x8*)(xl + kb * 32);
        acc = __builtin_amdgcn_mfma_f32_16x16x32_f16(al, bf, acc, 0, 0, 0);
        acc = __builtin_amdgcn_mfma_f32_16x16x32_f16(ah, bf, acc, 0, 0, 0);
    }
    return acc;
}

// ---------------- SincConv via MFMA (fp16 single-pass) + |.| + maxpool3 ----------------
union ConvLDS {
    short xh[8][RS];
    float ebuf[96][129];
};

#define MFMA2(ACC, AH, AL, BH) \
    ACC = __builtin_amdgcn_mfma_f32_32x32x16_f16(AL, BH, ACC, 0, 0, 0); \
    ACC = __builtin_amdgcn_mfma_f32_32x32x16_f16(AH, BH, ACC, 0, 0, 0);

__global__ __launch_bounds__(256, 3)
void conv_mfma_kernel(const float* __restrict__ x, const short* __restrict__ fpH,
                      _Float16* __restrict__ h) {
    __shared__ ConvLDS u;
    const int tid = threadIdx.x;
    const int pb = blockIdx.x;
    const int b = blockIdx.y;
    const int t0 = pb * 96;
    const float* xb = x + (long)b * L_IN;

    // staging: thread owns (replica s, 8-col chunk j); single fp16, b128 writes.
    if (pb < 671) {
        for (int idx = tid; idx < 8 * NCH; idx += 256) {
            int s = idx / NCH, j = idx - s * NCH;
            int gi = t0 + s + j * 8;
            f16x8 hv;
#pragma unroll
            for (int e = 0; e < 8; e++) hv[e] = (_Float16)xb[gi + e];
            *(f16x8*)&u.xh[s][j * 8] = hv;
        }
    } else {
        for (int idx = tid; idx < 8 * NCH; idx += 256) {
            int s = idx / NCH, j = idx - s * NCH;
            int gi = t0 + s + j * 8;
            f16x8 hv;
#pragma unroll
            for (int e = 0; e < 8; e++) {
                float v = (gi + e < L_IN) ? xb[gi + e] : 0.f;
                hv[e] = (_Float16)v;
            }
            *(f16x8*)&u.xh[s][j * 8] = hv;
        }
    }
    __syncthreads();

    const int lane = tid & 63;
    const int wid = tid >> 6;
    const int l31 = lane & 31;
    const int hi = lane >> 5;
    const int f0w = wid * 64;

    const short* aH = &u.xh[l31 & 7][8 * (l31 >> 3) + 8 * hi];
    const short* bp0 = fpH + (long)(wid * 2) * FTILE + lane * 8;
    const short* bp1 = bp0 + FTILE;

    f32x16 a00 = {0}, a01 = {0}, a10 = {0}, a11 = {0}, a20 = {0}, a21 = {0};

#pragma unroll 1
    for (int kc = 0; kc < 65; kc++) {
        const int ko = kc * 16;
        const int kf = kc * 512;
        f16x8 ah0 = *(const f16x8*)(aH + ko);
        f16x8 ah1 = *(const f16x8*)(aH + ko + 32);
        f16x8 ah2 = *(const f16x8*)(aH + ko + 64);
        f16x8 bh0 = *(const f16x8*)(bp0 + kf);
        f16x8 bh1 = *(const f16x8*)(bp1 + kf);
        a00 = __builtin_amdgcn_mfma_f32_32x32x16_f16(ah0, bh0, a00, 0, 0, 0);
        a01 = __builtin_amdgcn_mfma_f32_32x32x16_f16(ah0, bh1, a01, 0, 0, 0);
        a10 = __builtin_amdgcn_mfma_f32_32x32x16_f16(ah1, bh0, a10, 0, 0, 0);
        a11 = __builtin_amdgcn_mfma_f32_32x32x16_f16(ah1, bh1, a11, 0, 0, 0);
        a20 = __builtin_amdgcn_mfma_f32_32x32x16_f16(ah2, bh0, a20, 0, 0, 0);
        a21 = __builtin_amdgcn_mfma_f32_32x32x16_f16(ah2, bh1, a21, 0, 0, 0);
    }

    __syncthreads();
    const int t3l = tid & 31;
    const int t3 = pb * 32 + t3l;

#pragma unroll
    for (int half = 0; half < 2; half++) {
        if ((wid >> 1) == half) {
            int fcb = f0w - half * 128;
#define WRF(ACC, MT, NT)                                                   \
            {                                                              \
                int fc = fcb + NT * 32 + l31;                              \
                _Pragma("unroll")                                          \
                for (int r = 0; r < 16; r++) {                             \
                    int pos = MT * 32 + (r & 3) + 8 * (r >> 2) + 4 * hi;   \
                    u.ebuf[pos][fc] = fabsf(ACC[r]);                       \
                }                                                          \
            }
            WRF(a00, 0, 0) WRF(a01, 0, 1)
            WRF(a10, 1, 0) WRF(a11, 1, 1)
            WRF(a20, 2, 0) WRF(a21, 2, 1)
#undef WRF
        }
        __syncthreads();
        if (t3 < T_POOL) {
            for (int ff = tid >> 5; ff < 128; ff += 8) {
                float v = fmaxf(fmaxf(u.ebuf[3 * t3l][ff], u.ebuf[3 * t3l + 1][ff]),
                                u.ebuf[3 * t3l + 2][ff]);
                h[((long)(b * 256 + half * 128 + ff)) * TPP + t3] = (_Float16)v;
            }
        }
        __syncthreads();
    }
}

// ---------------- BatchNorm stats for h (fp16): two-stage ----------------
__global__ __launch_bounds__(256)
void bn_part_kernel(const _Float16* __restrict__ xin, float* __restrict__ p1,
                    float* __restrict__ p2) {
    __shared__ float sm[8];
    int c = blockIdx.x, s = blockIdx.y, tid = threadIdx.x;
    int t0 = s * 2687, t1 = min(T_POOL, t0 + 2687);
    float s1 = 0.f, s2 = 0.f;
    for (int b = 0; b < 4; b++) {
        const _Float16* p = xin + (long)b * 256 * TPP + (long)c * TPP;
        for (int t = t0 + tid; t < t1; t += 256) {
            float v = (float)p[t];
            s1 += v;
            s2 = fmaf(v, v, s2);
        }
    }
    for (int off = 32; off > 0; off >>= 1) { s1 += __shfl_down(s1, off); s2 += __shfl_down(s2, off); }
    int lane = tid & 63, wv = tid >> 6;
    if (lane == 0) { sm[wv] = s1; sm[4 + wv] = s2; }
    __syncthreads();
    if (tid == 0) {
        p1[c * 8 + s] = sm[0] + sm[1] + sm[2] + sm[3];
        p2[c * 8 + s] = sm[4] + sm[5] + sm[6] + sm[7];
    }
}

__global__ __launch_bounds__(256)
void bn_fin_kernel(const float* __restrict__ p1, const float* __restrict__ p2,
                   const float* __restrict__ g, const float* __restrict__ bb,
                   float* __restrict__ sc, float* __restrict__ sh) {
    int c = threadIdx.x;
    float S1 = 0.f, S2 = 0.f;
#pragma unroll
    for (int s = 0; s < 8; s++) { S1 += p1[c * 8 + s]; S2 += p2[c * 8 + s]; }
    float n = 4.f * (float)T_POOL;
    float mean = S1 / n;
    float var = S2 / n - mean * mean;
    float rstd = rsqrtf(var + 1e-5f);
    float gc = g[c], bc = bb[c];
    sc[c] = rstd * gc;
    sh[c] = bc - mean * rstd * gc;
}

// ---------------- BatchNorm stats (small, for e) ----------------
__global__ __launch_bounds__(256)
void bn_stats_kernel(const float* __restrict__ xin, const float* __restrict__ g,
                     const float* __restrict__ bb, float* __restrict__ sc,
                     float* __restrict__ sh, int ilen, long bstride) {
    __shared__ float sm[8];
    int c = blockIdx.x, tid = threadIdx.x;
    float s1 = 0.f, s2 = 0.f;
    for (int b = 0; b < 4; b++) {
        const float* p = xin + b * bstride + (long)c * ilen;
        for (int t = tid; t < ilen; t += 256) {
            float v = p[t];
            s1 += v;
            s2 = fmaf(v, v, s2);
        }
    }
    for (int off = 32; off > 0; off >>= 1) { s1 += __shfl_down(s1, off); s2 += __shfl_down(s2, off); }
    int lane = tid & 63, wv = tid >> 6;
    if (lane == 0) { sm[wv] = s1; sm[4 + wv] = s2; }
    __syncthreads();
    if (tid == 0) {
        float S1 = sm[0] + sm[1] + sm[2] + sm[3];
        float S2 = sm[4] + sm[5] + sm[6] + sm[7];
        float n = 4.f * (float)ilen;
        float mean = S1 / n;
        float var = S2 / n - mean * mean;
        float rstd = rsqrtf(var + 1e-5f);
        float gc = g[c], bc = bb[c];
        sc[c] = rstd * gc;
        sh[c] = bc - mean * rstd * gc;
    }
}

// ---------------- Embedding GEMM via MFMA (fp16 2-pass), split-K, packed B ----------------
__global__ __launch_bounds__(256, 2)
void embed_mfma_kernel(const _Float16* __restrict__ H, const short* __restrict__ Wh,
                       const float* __restrict__ sc, const float* __restrict__ sh,
                       float* __restrict__ P, int kPerZ) {
    __shared__ short Ah[128][36];
    __shared__ short Al[128][36];
    const int tid = threadIdx.x;
    const int rowBase = blockIdx.x * 128;
    const int colBase = blockIdx.y * 128;
    const int z = blockIdx.z;
    const int kz = z * kPerZ;
    const int iters = kPerZ >> 5;

    const int trow = tid >> 1, th = (tid & 1) * 16;
    const int arow = rowBase + trow;
    const float asc = sc[arow & 255], ash_ = sh[arow & 255];
    const _Float16* Ap = H + (long)arow * TPP;

    const int lane = tid & 63, wid = tid >> 6;
    const int l31 = lane & 31, hi = lane >> 5;
    const int wm = wid >> 1, wn = wid & 1;

    const short* bhp[2];
#pragma unroll
    for (int nt = 0; nt < 2; nt++) {
        int ft = (colBase >> 5) + wn * 2 + nt;
        bhp[nt] = Wh + (long)ft * NKC * 512 + lane * 8;
    }

    f32x16 acc[2][2] = {{{0}, {0}}, {{0}, {0}}};

    for (int it = 0; it < iters; it++) {
        const int k0 = kz + it * 32;
        __syncthreads();
        float av[16];
        if (k0 + 32 <= KEMB) {
            const f16x8* p8 = (const f16x8*)(Ap + k0 + th);
            f16x8 v0 = p8[0], v1 = p8[1];
#pragma unroll
            for (int e = 0; e < 8; e++) { av[e] = (float)v0[e]; av[8 + e] = (float)v1[e]; }
        } else {
#pragma unroll
            for (int e = 0; e < 16; e++) {
                int k = k0 + th + e;
                av[e] = (k < KEMB) ? (float)Ap[k] : 0.f;
            }
        }
#pragma unroll
        for (int q = 0; q < 4; q++) {
            s16x4 h4, l4;
#pragma unroll
            for (int e = 0; e < 4; e++) {
                float v = selu_f(fmaf(av[q * 4 + e], asc, ash_));
                short hs, ls;
                f16split(v, hs, ls);
                h4[e] = hs; l4[e] = ls;
            }
            *(s16x4*)&Ah[trow][th + q * 4] = h4;
            *(s16x4*)&Al[trow][th + q * 4] = l4;
        }
        __syncthreads();

#pragma unroll
        for (int ks = 0; ks < 2; ks++) {
            const int kloc = ks * 16 + hi * 8;
            const long kcg = (long)((k0 >> 4) + ks) * 512;
            f16x8 ah[2], al[2], bh[2];
#pragma unroll
            for (int mt = 0; mt < 2; mt++) {
                const int r = wm * 64 + mt * 32 + l31;
                const short* ph = &Ah[r][kloc];
                const short* pl = &Al[r][kloc];
                union { f16x8 v; unsigned long long q[2]; } uh, ul;
                uh.q[0] = *(const unsigned long long*)(ph);
                uh.q[1] = *(const unsigned long long*)(ph + 4);
                ul.q[0] = *(const unsigned long long*)(pl);
                ul.q[1] = *(const unsigned long long*)(pl + 4);
                ah[mt] = uh.v; al[mt] = ul.v;
            }
#pragma unroll
            for (int nt = 0; nt < 2; nt++)
                bh[nt] = *(const f16x8*)(bhp[nt] + kcg);
#pragma unroll
            for (int mt = 0; mt < 2; mt++)
#pragma unroll
                for (int nt = 0; nt < 2; nt++) {
                    MFMA2(acc[mt][nt], ah[mt], al[mt], bh[nt])
                }
        }
    }

    float* Pz = P + (long)z * 262144;
#pragma unroll
    for (int mt = 0; mt < 2; mt++)
#pragma unroll
        for (int nt = 0; nt < 2; nt++) {
            int col = colBase + wn * 64 + nt * 32 + l31;
#pragma unroll
            for (int r = 0; r < 16; r++) {
                int row = rowBase + wm * 64 + mt * 32 + (r & 3) + 8 * (r >> 2) + 4 * hi;
                Pz[(long)row * 256 + col] = acc[mt][nt][r];
            }
        }
}

__global__ __launch_bounds__(256)
void embed_combine_kernel(const float* __restrict__ P, const float* __restrict__ eb,
                          float* __restrict__ e, int nsplit) {
    int idx = blockIdx.x * 256 + threadIdx.x;
    float s = 0.f;
    for (int z = 0; z < nsplit; z++) s += P[(long)z * 262144 + idx];
    e[idx] = s + eb[idx & 255];
}

// ---------------- fused zinit + layer-0 QKV (MFMA, packed fp16 weights) ----------------
__global__ __launch_bounds__(512)
void qkv_init_kernel(const float* __restrict__ e, const float* __restrict__ sc,
                     const float* __restrict__ sh, const short* __restrict__ lw0,
                     const float* __restrict__ bq0, const float* __restrict__ bk0,
                     const float* __restrict__ bv0,
                     float* __restrict__ z, float* __restrict__ qo,
                     float* __restrict__ ko, float* __restrict__ vo) {
    __shared__ _Float16 zsh[4][256], zsl[4][256];
    const int t = threadIdx.x;
    const int w = t >> 6, lane = t & 63;
    const long rowg0 = (long)blockIdx.x * 4;

    for (int idx = t; idx < 1024; idx += 512) {
        int i = idx >> 8, dd = idx & 255;
        int c = (int)((rowg0 + i) & 255);
        float v = fmaf(e[(rowg0 + i) * 256 + dd], sc[c], sh[c]);
        v = fmaxf(v, 0.f);
        int i2 = dd >> 1;
        float ang = (float)c * expf(-0.03597789207803195f * (float)(2 * i2));
        float pe = (dd & 1) ? cosf(ang) : sinf(ang);
        float zz = v + pe;
        z[(rowg0 + i) * 256 + dd] = zz;
        _Float16 hh, ll;
        f16split2(zz, hh, ll);
        zsh[i][dd] = hh; zsl[i][dd] = ll;
    }
    __syncthreads();

#pragma unroll
    for (int mat = 0; mat < 3; mat++) {
        const short* wp = lw0 + 65536 * (1 + mat);
        const float* bb = (mat == 0 ? bq0 : mat == 1 ? bk0 : bv0);
        float* op = (mat == 0 ? qo : mat == 1 ? ko : vo);
        for (int nt = w; nt < 16; nt += 8) {
            f32x4 acc = mfma_nt(&zsh[0][0], &zsl[0][0], 256, wp + nt * 8 * 512, 8, lane);
            if (lane < 16) {
                int col = nt * 16 + lane;
                float bv2 = bb[col];
#pragma unroll
                for (int r = 0; r < 4; r++)
                    op[(rowg0 + r) * 256 + col] = acc[r] + bv2;
            }
        }
    }
}

// ---------------- fused transformer layer: attention GEMV + MFMA projections ----------------
__device__ inline void ln_reduce4(const float (*buf)[256], float (*mr)[2], int t) {
    int wid = t >> 6, lane = t & 63;
    if (wid < 4) {
        float4 v = *(const float4*)&buf[wid][lane * 4];
        float s = v.x + v.y + v.z + v.w;
        float q = v.x * v.x + v.y * v.y + v.z * v.z + v.w * v.w;
#pragma unroll
        for (int off = 32; off > 0; off >>= 1) {
            s += __shfl_xor(s, off);
            q += __shfl_xor(q, off);
        }
        if (lane == 0) {
            float mean = s * (1.f / 256.f);
            float var = q * (1.f / 256.f) - mean * mean;
            mr[wid][0] = mean;
            mr[wid][1] = rsqrtf(var + 1e-5f);
        }
    }
}

template <int LAST>
__global__ __launch_bounds__(1024)
void layer_kernel(const float* __restrict__ zin, const float* __restrict__ qin,
                  const float* __restrict__ kin, const float* __restrict__ vin,
                  const short* __restrict__ lw_l, const short* __restrict__ lw_n,
                  const float* __restrict__ bo_l,
                  const float* __restrict__ c1b_l, const float* __restrict__ c2b_l,
                  const float* __restrict__ ln1g_l, const float* __restrict__ ln1b_l,
                  const float* __restrict__ ln2g_l, const float* __restrict__ ln2b_l,
                  const float* __restrict__ bq_n, const float* __restrict__ bk_n,
                  const float* __restrict__ bv_n,
                  const float* __restrict__ lnfg, const float* __restrict__ lnfb,
                  float* __restrict__ zout, float* __restrict__ qo,
                  float* __restrict__ ko, float* __restrict__ vo,
                  float* __restrict__ lnf_out) {
    __shared__ float zs[4][256];
    __shared__ float qb[4][256];
    __shared__ float sscore[4][8][256];
    __shared__ _Float16 zsh[4][256], zsl[4][256];
    __shared__ _Float16 yh[4][1024], yl[4][1024];
    __shared__ float mr[4][2];

    const int t = threadIdx.x;
    const int w = t >> 6, lane = t & 63;
    const long rowg0 = (long)blockIdx.x * 4;
    const int b = blockIdx.x >> 6;

    const int f = t & 255;       // output dim for 256-wide phases
    const int kq = t >> 8;       // row 0..3

    // P1: stage z (residual) and q rows
    {
        int r = t >> 8, dd = t & 255;
        zs[r][dd] = zin[(rowg0 + r) * 256 + dd];
        qb[r][dd] = qin[(rowg0 + r) * 256 + dd];
    }
    __syncthreads();

    // P2: scores — wave pair per head
    {
        const float scale = 0.17677669529663687f;
        const int jq = lane >> 3, li = lane & 7, d4 = li * 4;
        const int hh = w >> 1, jh = w & 1;
        const float* kb = kin + (long)b * 65536 + hh * 32 + d4;
        float4 q0 = *(const float4*)&qb[0][hh * 32 + d4];
        float4 q1 = *(const float4*)&qb[1][hh * 32 + d4];
        float4 q2 = *(const float4*)&qb[2][hh * 32 + d4];
        float4 q3 = *(const float4*)&qb[3][hh * 32 + d4];
        for (int jb = 0; jb < 16; jb++) {
            int j = jh * 128 + jb * 8 + jq;
            float4 kv = *(const float4*)(kb + (long)j * 256);
            float a0 = dot4(kv, q0), a1 = dot4(kv, q1);
            float a2 = dot4(kv, q2), a3 = dot4(kv, q3);
#pragma unroll
            for (int off = 1; off < 8; off <<= 1) {
                a0 += __shfl_xor(a0, off); a1 += __shfl_xor(a1, off);
                a2 += __shfl_xor(a2, off); a3 += __shfl_xor(a3, off);
            }
            if (li < 4) sscore[li][hh][j] = sel4(a0, a1, a2, a3, li) * scale;
        }
    }
    __syncthreads();

    // P3: softmax
    {
#pragma unroll
        for (int p = 0; p < 2; p++) {
            int pair = w * 2 + p;
            int i = pair >> 3, hh = pair & 7;
            float* row = sscore[i][hh];
            float v0 = row[lane], v1 = row[lane + 64];
            float v2 = row[lane + 128], v3 = row[lane + 192];
            float m = fmaxf(fmaxf(v0, v1), fmaxf(v2, v3));
#pragma unroll
            for (int off = 32; off > 0; off >>= 1) m = fmaxf(m, __shfl_xor(m, off));
            float e0 = expf(v0 - m), e1 = expf(v1 - m);
            float e2 = expf(v2 - m), e3 = expf(v3 - m);
            float su = e0 + e1 + e2 + e3;
#pragma unroll
            for (int off = 32; off > 0; off >>= 1) su += __shfl_xor(su, off);
            float inv = 1.f / su;
            row[lane] = e0 * inv; row[lane + 64] = e1 * inv;
            row[lane + 128] = e2 * inv; row[lane + 192] = e3 * inv;
        }
    }
    __syncthreads();

    // P4: PV — thread owns (f, row); write split attention output
    {
        int row = kq;
        int hh = f >> 5;
        const float* vcol = vin + (long)b * 65536 + f;
        const float* p0 = sscore[row][hh];
        float a0 = 0.f;
#pragma unroll 4
        for (int j4 = 0; j4 < 64; j4++) {
            float4 pv0 = *(const float4*)(p0 + j4 * 4);
            float v0 = vcol[(long)(j4 * 4 + 0) * 256];
            float v1 = vcol[(long)(j4 * 4 + 1) * 256];
            float v2 = vcol[(long)(j4 * 4 + 2) * 256];
            float v3 = vcol[(long)(j4 * 4 + 3) * 256];
            a0 = fmaf(pv0.x, v0, a0); a0 = fmaf(pv0.y, v1, a0);
            a0 = fmaf(pv0.z, v2, a0); a0 = fmaf(pv0.w, v3, a0);
        }
        _Float16 hh2, ll;
        f16split2(a0, hh2, ll);
        zsh[row][f] = hh2; zsl[row][f] = ll;
    }
    __syncthreads();

    // P5: O-proj MFMA + bias + residual -> qb
    {
        int nt = w;
        f32x4 acc = mfma_nt(&zsh[0][0], &zsl[0][0], 256, lw_l + nt * 8 * 512, 8, lane);
        if (lane < 16) {
            int col = nt * 16 + lane;
            float bb = bo_l[col];
#pragma unroll
            for (int r = 0; r < 4; r++)
                qb[r][col] = acc[r] + bb + zs[r][col];
        }
    }
    __syncthreads();
    ln_reduce4(qb, mr, t);
    __syncthreads();
    {
        int r = kq;
        float z1 = (qb[r][f] - mr[r][0]) * mr[r][1] * ln1g_l[f] + ln1b_l[f];
        zs[r][f] = z1;
        _Float16 hh2, ll;
        f16split2(z1, hh2, ll);
        zsh[r][f] = hh2; zsl[r][f] = ll;
    }
    __syncthreads();

    // P7: FFN1 MFMA + gelu -> yh/yl
    {
        const short* wp = lw_l + 262144;
        for (int nt = w; nt < 64; nt += 16) {
            f32x4 acc = mfma_nt(&zsh[0][0], &zsl[0][0], 256, wp + nt * 8 * 512, 8, lane);
            if (lane < 16) {
                int col = nt * 16 + lane;
                float cb = c1b_l[col];
#pragma unroll
                for (int r = 0; r < 4; r++) {
                    float g = gelu_f(acc[r] + cb);
                    _Float16 hh2, ll;
                    f16split2(g, hh2, ll);
                    yh[r][col] = hh2; yl[r][col] = ll;
                }
            }
        }
    }
    __syncthreads();

    // P8: FFN2 MFMA (K=1024) + bias + residual -> qb
    {
        const short* wp = lw_l + 524288;
        int nt = w;
        f32x4 acc = mfma_nt(&yh[0][0], &yl[0][0], 1024, wp + nt * 32 * 512, 32, lane);
        if (lane < 16) {
            int col = nt * 16 + lane;
            float cb = c2b_l[col];
#pragma unroll
            for (int r = 0; r < 4; r++)
                qb[r][col] = acc[r] + cb + zs[r][col];
        }
    }
    __syncthreads();
    ln_reduce4(qb, mr, t);
    __syncthreads();
    {
        int r = kq;
        float z2 = (qb[r][f] - mr[r][0]) * mr[r][1] * ln2g_l[f] + ln2b_l[f];
        zs[r][f] = z2;
        zout[(rowg0 + r) * 256 + f] = z2;
        _Float16 hh2, ll;
        f16split2(z2, hh2, ll);
        zsh[r][f] = hh2; zsl[r][f] = ll;
    }
    __syncthreads();

    if (!LAST) {
        // P9: QKV MFMA for next layer
#pragma unroll
        for (int mat = 0; mat < 3; mat++) {
            const short* wp = lw_n + 65536 * (1 + mat);
            const float* bb = (mat == 0 ? bq_n : mat == 1 ? bk_n : bv_n);
            float* op = (mat == 0 ? qo : mat == 1 ? ko : vo);
            int nt = w;
            f32x4 acc = mfma_nt(&zsh[0][0], &zsl[0][0], 256, wp + nt * 8 * 512, 8, lane);
            if (lane < 16) {
                int col = nt * 16 + lane;
                float bv2 = bb[col];
#pragma unroll
                for (int r = 0; r < 4; r++)
                    op[(rowg0 + r) * 256 + col] = acc[r] + bv2;
            }
        }
    } else {
        ln_reduce4(zs, mr, t);
        __syncthreads();
        {
            int r = kq;
            lnf_out[(rowg0 + r) * 256 + f] =
                (zs[r][f] - mr[r][0]) * mr[r][1] * lnfg[f] + lnfb[f];
        }
    }
}

// ---------------- final: pooled mean over seq -> proj ----------------
__global__ __launch_bounds__(256)
void final_kernel(const float* __restrict__ zf, const float* __restrict__ pw,
                  const float* __restrict__ pb, float* __restrict__ out) {
    __shared__ float sm[8];
    int b = blockIdx.x, d = threadIdx.x;
    float s = 0.f;
    for (int c = 0; c < 256; c++) s += zf[((long)(b * 256 + c)) * 256 + d];
    float pooled = s * (1.f / 256.f);
    float c0 = pooled * pw[d], c1 = pooled * pw[256 + d];
    for (int off = 32; off > 0; off >>= 1) { c0 += __shfl_down(c0, off); c1 += __shfl_down(c1, off); }
    int lane = d & 63, wv = d >> 6;
    if (lane == 0) { sm[wv] = c0; sm[4 + wv] = c1; }
    __syncthreads();
    if (d == 0) {
        out[b * 2 + 0] = sm[0] + sm[1] + sm[2] + sm[3] + pb[0];
        out[b * 2 + 1] = sm[4] + sm[5] + sm[6] + sm[7] + pb[1];
    }
}

extern "C" void kernel_launch(void* const* d_in, const int* in_sizes, int n_in,
                              void* d_out, int out_size, void* d_ws, size_t ws_size,
                              hipStream_t stream) {
    const float* x       = (const float*)d_in[0];
    const float* filters = (const float*)d_in[1];
    const float* bn1_g   = (const float*)d_in[2];
    const float* bn1_b   = (const float*)d_in[3];
    const float* emb_w   = (const float*)d_in[4];
    const float* emb_b   = (const float*)d_in[5];
    const float* embbn_g = (const float*)d_in[6];
    const float* embbn_b = (const float*)d_in[7];
    const float* wq      = (const float*)d_in[8];
    const float* bq      = (const float*)d_in[9];
    const float* wk      = (const float*)d_in[10];
    const float* bk      = (const float*)d_in[11];
    const float* wv      = (const float*)d_in[12];
    const float* bv      = (const float*)d_in[13];
    const float* wo      = (const float*)d_in[14];
    const float* bo      = (const float*)d_in[15];
    const float* c1w     = (const float*)d_in[16];
    const float* c1b     = (const float*)d_in[17];
    const float* c2w     = (const float*)d_in[18];
    const float* c2b     = (const float*)d_in[19];
    const float* ln1g    = (const float*)d_in[20];
    const float* ln1b    = (const float*)d_in[21];
    const float* ln2g    = (const float*)d_in[22];
    const float* ln2b    = (const float*)d_in[23];
    const float* lnfg    = (const float*)d_in[24];
    const float* lnfb    = (const float*)d_in[25];
    const float* projw   = (const float*)d_in[26];
    const float* projb   = (const float*)d_in[27];

    const long hF = 11005952L;                      // 1024*TPP halfs, in float units
    const long wpackF = 2752512L;                   // 8*NKC*512 shorts, in floats
    const long lwF = 1572864L;                      // 4*LWSZ shorts, in floats
    const long fixedF = hF + 5120 + wpackF + lwF + 9L * 262144;
    long wsFloats = (long)(ws_size / 4);
    long Z = 32;
    while (Z > 8 && fixedF + Z * 262144L > wsFloats) Z >>= 1;
    const int kPerZ = KEMBP / (int)Z;

    float* ws = (float*)d_ws;
    _Float16* h16 = (_Float16*)ws;                  // 1024*TPP halfs
    float* bn1_sc = ws + hF;
    float* bn1_sh = bn1_sc + 256;
    float* e_sc   = bn1_sh + 256;
    float* e_sh   = e_sc + 256;
    float* bnp1   = e_sh + 256;                     // 2048
    float* bnp2   = bnp1 + 2048;                    // 2048
    float* part   = bnp2 + 2048;                    // Z * 262144
    float* wsp    = part + Z * 262144L;
    short* wpH    = (short*)wsp;                    // 8*NKC*512 shorts
    float* e      = wsp + wpackF;
    float* z      = e + 262144;
    float* qA     = z + 262144;
    float* kA     = qA + 262144;
    float* vA     = kA + 262144;
    float* qB     = vA + 262144;
    float* kB     = qB + 262144;
    float* vB     = kB + 262144;
    float* t1     = vB + 262144;
    short* lw     = (short*)(t1 + 262144);          // 4*LWSZ shorts

    // conv packed filters alias onto `part` (only used before embed writes part)
    short* fpH = (short*)part;                      // 520*512 shorts

    filt_pack_kernel<<<520, 512, 0, stream>>>(filters, fpH);
    wpack_kernel<<<8 * NKC, 512, 0, stream>>>(emb_w, wpH);
    lwpack_kernel<<<6144, 512, 0, stream>>>(wo, wq, wk, wv, c1w, c2w, lw);
    conv_mfma_kernel<<<dim3(672, 4), 256, 0, stream>>>(x, fpH, h16);
    bn_part_kernel<<<dim3(256, 8), 256, 0, stream>>>(h16, bnp1, bnp2);
    bn_fin_kernel<<<1, 256, 0, stream>>>(bnp1, bnp2, bn1_g, bn1_b, bn1_sc, bn1_sh);
    embed_mfma_kernel<<<dim3(8, 2, (int)Z), 256, 0, stream>>>(h16, wpH,
                                                              bn1_sc, bn1_sh, part, kPerZ);
    embed_combine_kernel<<<1024, 256, 0, stream>>>(part, emb_b, e, (int)Z);
    bn_stats_kernel<<<256, 256, 0, stream>>>(e, embbn_g, embbn_b, e_sc, e_sh,
                                             256, 256L * 256);
    qkv_init_kernel<<<256, 512, 0, stream>>>(e, e_sc, e_sh, lw, bq, bk, bv,
                                             z, qA, kA, vA);

    float* qs[2][3] = {{qA, kA, vA}, {qB, kB, vB}};
    for (int l = 0; l < 4; l++) {
        float** in = qs[l & 1];
        float** ou = qs[(l + 1) & 1];
        const short* lw_l = lw + (long)l * LWSZ;
        const short* lw_n = lw + (long)((l + 1) & 3) * LWSZ;
        const float* bo_l = bo + l * 256;
        const float* c1b_l = c1b + l * 1024;
        const float* c2b_l = c2b + l * 256;
        const float* l1g = ln1g + l * 256; const float* l1b = ln1b + l * 256;
        const float* l2g = ln2g + l * 256; const float* l2b = ln2b + l * 256;
        if (l < 3) {
            const float* bq_n = bq + (l + 1) * 256;
            const float* bk_n = bk + (l + 1) * 256;
            const float* bv_n = bv + (l + 1) * 256;
            layer_kernel<0><<<256, 1024, 0, stream>>>(z, in[0], in[1], in[2],
                lw_l, lw_n, bo_l, c1b_l, c2b_l, l1g, l1b, l2g, l2b,
                bq_n, bk_n, bv_n, lnfg, lnfb,
                z, ou[0], ou[1], ou[2], t1);
        } else {
            layer_kernel<1><<<256, 1024, 0, stream>>>(z, in[0], in[1], in[2],
                lw_l, lw_n, bo_l, c1b_l, c2b_l, l1g, l1b, l2g, l2b,
                bq, bk, bv, lnfg, lnfb,
                z, ou[0], ou[1], ou[2], t1);
        }
    }

    final_kernel<<<4, 256, 0, stream>>>(t1, projw, projb, (float*)d_out);
}